// Round 1
// baseline (3046.844 us; speedup 1.0000x reference)
//
#include <hip/hip_runtime.h>
#include <math.h>

#define NN 20000
#define EE 640000
#define HD 128
#define NC 160      // scan chunks
#define CS 125      // chunk size: NC*CS == NN

__device__ __forceinline__ float sigf(float x) { return 1.0f / (1.0f + __expf(-x)); }

// 32-row x 128-col GEMM tile: each of 256 threads owns 4 rows x 4 interleaved cols.
// Weights streamed through LDS in K-chunks of 16 (coalesced global loads, conflict-free LDS reads).
template<int KTOT, int LDX>
__device__ __forceinline__ void gemm32(const float* __restrict__ W, int ldw,
                                       float (*Ws)[129], float (*X)[LDX],
                                       int e0, int je, int tid, float acc[4][4])
{
    for (int k0 = 0; k0 < KTOT; k0 += 16) {
        __syncthreads();
        for (int idx = tid; idx < 16 * HD; idx += 256) {
            int j = idx >> 4, kk = idx & 15;
            Ws[kk][j] = W[j * ldw + k0 + kk];
        }
        __syncthreads();
        #pragma unroll
        for (int kk = 0; kk < 16; ++kk) {
            float xr[4], wr[4];
            #pragma unroll
            for (int i = 0; i < 4; ++i) xr[i] = X[e0 + i][k0 + kk];   // broadcast within half-wave
            #pragma unroll
            for (int m = 0; m < 4; ++m) wr[m] = Ws[kk][je + 32 * m];  // conflict-free
            #pragma unroll
            for (int i = 0; i < 4; ++i)
                #pragma unroll
                for (int m = 0; m < 4; ++m)
                    acc[i][m] = fmaf(xr[i], wr[m], acc[i][m]);
        }
    }
}

// ---------------- edge phase: MLPs + attention + coord weights + segment atomics ------------
__global__ __launch_bounds__(256) void edge_kernel(
    const float* __restrict__ h, const float* __restrict__ coord,
    const int* __restrict__ ei,
    const float* __restrict__ We1, const float* __restrict__ be1,
    const float* __restrict__ We2, const float* __restrict__ be2,
    const float* __restrict__ watt, const float* __restrict__ batt,
    const float* __restrict__ Wc1, const float* __restrict__ bc1,
    const float* __restrict__ Wc2,
    float* __restrict__ mi, float* __restrict__ ssum, float* __restrict__ cnt)
{
    __shared__ float xe[32][259];     // [h[e1] | h[e0] | radial]
    __shared__ float ybuf[32][133];
    __shared__ float Ws[16][129];
    __shared__ float wcol[HD];        // We1 column 256 (radial)
    __shared__ float cdp[32][3];
    __shared__ int ej0[32], ej1[32];

    const int tid = threadIdx.x;
    const int ebase = blockIdx.x * 32;

    if (tid < 32) { ej0[tid] = ei[ebase + tid]; ej1[tid] = ei[EE + ebase + tid]; }
    if (tid >= 128) wcol[tid - 128] = We1[(tid - 128) * 257 + 256];
    __syncthreads();

    for (int idx = tid; idx < 32 * 256; idx += 256) {
        int e = idx >> 8, k = idx & 255;
        xe[e][k] = (k < HD) ? h[ej1[e] * HD + k] : h[ej0[e] * HD + (k - HD)];
    }
    if (tid < 32) {
        float rr = 0.f;
        #pragma unroll
        for (int c = 0; c < 3; ++c) {
            float d = coord[ej0[tid] * 3 + c] - coord[ej1[tid] * 3 + c];
            cdp[tid][c] = d; rr += d * d;
        }
        xe[tid][256] = rr;
    }

    const int je = tid & 31;
    const int e0 = (tid >> 5) * 4;
    const float batt0 = batt[0];

    // layer 1 (K=256 via MFMA-style tiling, +radial column)
    float acc[4][4];
    #pragma unroll
    for (int i = 0; i < 4; ++i)
        #pragma unroll
        for (int m = 0; m < 4; ++m) acc[i][m] = 0.f;
    gemm32<256, 259>(We1, 257, Ws, xe, e0, je, tid, acc);
    #pragma unroll
    for (int i = 0; i < 4; ++i) {
        float rad = xe[e0 + i][256];
        #pragma unroll
        for (int m = 0; m < 4; ++m) acc[i][m] = fmaf(rad, wcol[je + 32 * m], acc[i][m]);
    }
    #pragma unroll
    for (int i = 0; i < 4; ++i)
        #pragma unroll
        for (int m = 0; m < 4; ++m)
            ybuf[e0 + i][je + 32 * m] = fmaxf(acc[i][m] + be1[je + 32 * m], 0.f);

    // layer 2 -> mij
    float acc2[4][4];
    #pragma unroll
    for (int i = 0; i < 4; ++i)
        #pragma unroll
        for (int m = 0; m < 4; ++m) acc2[i][m] = 0.f;
    gemm32<128, 133>(We2, 128, Ws, ybuf, e0, je, tid, acc2);
    float mij[4][4];
    #pragma unroll
    for (int i = 0; i < 4; ++i)
        #pragma unroll
        for (int m = 0; m < 4; ++m)
            mij[i][m] = fmaxf(acc2[i][m] + be2[je + 32 * m], 0.f);

    // attention gate (per-edge dot over 128 = 4 regs x 32 lanes)
    float p[4];
    #pragma unroll
    for (int i = 0; i < 4; ++i) {
        float s = 0.f;
        #pragma unroll
        for (int m = 0; m < 4; ++m) s += mij[i][m] * watt[je + 32 * m];
        p[i] = s;
    }
    #pragma unroll
    for (int off = 1; off < 32; off <<= 1) {
        #pragma unroll
        for (int i = 0; i < 4; ++i) p[i] += __shfl_xor(p[i], off);
    }
    float ef[4][4];
    #pragma unroll
    for (int i = 0; i < 4; ++i) {
        float att = sigf(p[i] + batt0);
        #pragma unroll
        for (int m = 0; m < 4; ++m) ef[i][m] = mij[i][m] * att;
    }
    // segment-sum mi
    #pragma unroll
    for (int i = 0; i < 4; ++i)
        #pragma unroll
        for (int m = 0; m < 4; ++m)
            atomicAdd(&mi[(size_t)ej0[e0 + i] * HD + je + 32 * m], ef[i][m]);

    __syncthreads();
    #pragma unroll
    for (int i = 0; i < 4; ++i)
        #pragma unroll
        for (int m = 0; m < 4; ++m)
            ybuf[e0 + i][je + 32 * m] = ef[i][m];

    // coord MLP: relu(ef@Wc1^T+bc1) dotted with Wc2
    float acc3[4][4];
    #pragma unroll
    for (int i = 0; i < 4; ++i)
        #pragma unroll
        for (int m = 0; m < 4; ++m) acc3[i][m] = 0.f;
    gemm32<128, 133>(Wc1, 128, Ws, ybuf, e0, je, tid, acc3);
    float q[4];
    #pragma unroll
    for (int i = 0; i < 4; ++i) {
        float s = 0.f;
        #pragma unroll
        for (int m = 0; m < 4; ++m) {
            float tf = fmaxf(acc3[i][m] + bc1[je + 32 * m], 0.f);
            s += tf * Wc2[je + 32 * m];
        }
        q[i] = s;
    }
    #pragma unroll
    for (int off = 1; off < 32; off <<= 1) {
        #pragma unroll
        for (int i = 0; i < 4; ++i) q[i] += __shfl_xor(q[i], off);
    }
    if (je == 0) {
        #pragma unroll
        for (int i = 0; i < 4; ++i) {
            int e = e0 + i;
            int nd = ej0[e];
            float tv = q[i];
            #pragma unroll
            for (int c = 0; c < 3; ++c) {
                float tr = cdp[e][c] * tv;
                tr = fminf(fmaxf(tr, -100.f), 100.f);
                atomicAdd(&ssum[nd * 3 + c], tr);
            }
            atomicAdd(&cnt[nd], 1.f);
        }
    }
}

// ---------------- node MLP + layernorm + clip ----------------
__global__ __launch_bounds__(256) void node_kernel(
    const float* __restrict__ mi, const float* __restrict__ h,
    const float* __restrict__ Wn1, const float* __restrict__ bn1,
    const float* __restrict__ Wn2, const float* __restrict__ bn2,
    const float* __restrict__ lng, const float* __restrict__ lnb,
    float* __restrict__ xout)
{
    __shared__ float xs[32][259];
    __shared__ float ybuf[32][133];
    __shared__ float Ws[16][129];
    __shared__ float mu_s[32], rs_s[32];
    const int tid = threadIdx.x;
    const int nbase = blockIdx.x * 32;

    for (int idx = tid; idx < 32 * 256; idx += 256) {
        int n = idx >> 8, k = idx & 255;
        xs[n][k] = (k < HD) ? mi[(size_t)(nbase + n) * HD + k] : h[(size_t)(nbase + n) * HD + (k - HD)];
    }
    const int je = tid & 31;
    const int e0 = (tid >> 5) * 4;

    float acc[4][4];
    #pragma unroll
    for (int i = 0; i < 4; ++i)
        #pragma unroll
        for (int m = 0; m < 4; ++m) acc[i][m] = 0.f;
    gemm32<256, 259>(Wn1, 256, Ws, xs, e0, je, tid, acc);
    #pragma unroll
    for (int i = 0; i < 4; ++i)
        #pragma unroll
        for (int m = 0; m < 4; ++m)
            ybuf[e0 + i][je + 32 * m] = fmaxf(acc[i][m] + bn1[je + 32 * m], 0.f);

    float acc2[4][4];
    #pragma unroll
    for (int i = 0; i < 4; ++i)
        #pragma unroll
        for (int m = 0; m < 4; ++m) acc2[i][m] = 0.f;
    gemm32<128, 133>(Wn2, 128, Ws, ybuf, e0, je, tid, acc2);
    #pragma unroll
    for (int i = 0; i < 4; ++i)
        #pragma unroll
        for (int m = 0; m < 4; ++m)
            ybuf[e0 + i][je + 32 * m] = acc2[i][m] + bn2[je + 32 * m];
    __syncthreads();

    // layernorm: 8 threads per node
    const int nl = tid >> 3, r = tid & 7;
    float s1 = 0.f, s2 = 0.f;
    #pragma unroll
    for (int k = r * 16; k < r * 16 + 16; ++k) { float v = ybuf[nl][k]; s1 += v; s2 += v * v; }
    #pragma unroll
    for (int off = 1; off < 8; off <<= 1) { s1 += __shfl_xor(s1, off); s2 += __shfl_xor(s2, off); }
    if (r == 0) {
        float mu = s1 * (1.f / HD);
        float var = s2 * (1.f / HD) - mu * mu;
        mu_s[nl] = mu;
        rs_s[nl] = rsqrtf(fmaxf(var, 0.f) + 1e-5f);
    }
    __syncthreads();
    for (int idx = tid; idx < 32 * HD; idx += 256) {
        int n = idx >> 7, j = idx & 127;
        float v = (ybuf[n][j] - mu_s[n]) * rs_s[n] * lng[j] + lnb[j];
        v = fminf(fmaxf(v, -10.f), 10.f);
        xout[(size_t)(nbase + n) * HD + j] = v;
    }
}

// ---------------- coord update ----------------
__global__ __launch_bounds__(256) void coord_kernel(
    const float* __restrict__ coord, const float* __restrict__ ssum,
    const float* __restrict__ cnt, float* __restrict__ outp)
{
    int idx = blockIdx.x * 256 + threadIdx.x;
    if (idx < NN * 3) {
        int n = idx / 3;
        outp[idx] = coord[idx] + ssum[idx] / fmaxf(cnt[n], 1.f);
    }
}

// ---------------- mamba in_proj: u and silu(z) ----------------
__global__ __launch_bounds__(256) void xz_kernel(
    const float* __restrict__ x, const float* __restrict__ Wip,
    float* __restrict__ u, float* __restrict__ zs)
{
    __shared__ float xs[32][130];
    __shared__ float Ws[16][257];
    const int tid = threadIdx.x;
    const int nbase = blockIdx.x * 32;
    for (int idx = tid; idx < 32 * HD; idx += 256) {
        int n = idx >> 7, k = idx & 127;
        xs[n][k] = x[(size_t)(nbase + n) * HD + k];
    }
    const int jj = tid & 63;
    const int n0 = (tid >> 6) * 8;
    float acc[8][4];
    #pragma unroll
    for (int i = 0; i < 8; ++i)
        #pragma unroll
        for (int m = 0; m < 4; ++m) acc[i][m] = 0.f;
    for (int k0 = 0; k0 < HD; k0 += 16) {
        __syncthreads();
        for (int idx = tid; idx < 16 * 256; idx += 256) {
            int j = idx >> 4, kk = idx & 15;
            Ws[kk][j] = Wip[j * HD + k0 + kk];
        }
        __syncthreads();
        #pragma unroll
        for (int kk = 0; kk < 16; ++kk) {
            float xr[8], wr[4];
            #pragma unroll
            for (int i = 0; i < 8; ++i) xr[i] = xs[n0 + i][k0 + kk];
            #pragma unroll
            for (int m = 0; m < 4; ++m) wr[m] = Ws[kk][jj + 64 * m];
            #pragma unroll
            for (int i = 0; i < 8; ++i)
                #pragma unroll
                for (int m = 0; m < 4; ++m)
                    acc[i][m] = fmaf(xr[i], wr[m], acc[i][m]);
        }
    }
    #pragma unroll
    for (int i = 0; i < 8; ++i)
        #pragma unroll
        for (int m = 0; m < 4; ++m) {
            int j = jj + 64 * m;
            size_t n = (size_t)(nbase + n0 + i);
            float v = acc[i][m];
            if (j < HD) u[n * HD + j] = v;
            else        zs[n * HD + (j - HD)] = v * sigf(v);
        }
}

// ---------------- causal depthwise conv + silu ----------------
__global__ __launch_bounds__(256) void conv_kernel(
    const float* __restrict__ u, const float* __restrict__ cw, const float* __restrict__ cb,
    float* __restrict__ uc)
{
    int idx = blockIdx.x * 256 + threadIdx.x;
    int n = idx >> 7, hh = idx & 127;
    float a = cb[hh];
    #pragma unroll
    for (int k = 0; k < 4; ++k) {
        int t = n - 3 + k;
        if (t >= 0) a = fmaf(u[t * HD + hh], cw[hh * 4 + k], a);
    }
    uc[idx] = a * sigf(a);
}

// ---------------- x_proj + dt_proj(softplus), emit dt/B/C ----------------
__global__ __launch_bounds__(256) void xdbl_kernel(
    const float* __restrict__ uc, const float* __restrict__ Wxp,
    const float* __restrict__ Wdt, const float* __restrict__ bdt,
    float* __restrict__ dt, float* __restrict__ Bm, float* __restrict__ Cm)
{
    __shared__ float xs[16][130];
    __shared__ float xd8[16][9];
    const int tid = threadIdx.x;
    const int nbase = blockIdx.x * 16;
    for (int idx = tid; idx < 16 * HD; idx += 256) {
        int n = idx >> 7, k = idx & 127;
        xs[n][k] = uc[(size_t)(nbase + n) * HD + k];
    }
    __syncthreads();
    const int nl = tid >> 4, jj = tid & 15;
    #pragma unroll
    for (int rep = 0; rep < 9; ++rep) {
        int j = jj + rep * 16;
        if (j < 136) {
            float a = 0.f;
            for (int k = 0; k < HD; ++k) a = fmaf(xs[nl][k], Wxp[j * HD + k], a);
            int n = nbase + nl;
            if (j < 8)       xd8[nl][j] = a;
            else if (j < 72) Bm[(size_t)n * 64 + (j - 8)] = a;
            else             Cm[(size_t)n * 64 + (j - 72)] = a;
        }
    }
    __syncthreads();
    #pragma unroll
    for (int q = 0; q < 8; ++q) {
        int hh = jj * 8 + q;
        float a = bdt[hh];
        #pragma unroll
        for (int r2 = 0; r2 < 8; ++r2) a = fmaf(xd8[nl][r2], Wdt[hh * 8 + r2], a);
        float sp = (a > 20.f) ? a : log1pf(__expf(a));
        dt[(size_t)(nbase + nl) * HD + hh] = sp;
    }
}

// ---------------- chunked SSM scan ----------------
__global__ __launch_bounds__(256) void scan1_kernel(
    const float* __restrict__ dt, const float* __restrict__ uc,
    const float* __restrict__ Bm, const float* __restrict__ Alog,
    float* __restrict__ cP, float* __restrict__ cS)
{
    int g = blockIdx.x * 256 + threadIdx.x;
    int c = g >> 13;
    int r = g & 8191;
    int hh = r >> 6;
    int d = r & 63;
    float A = -__expf(Alog[hh * 64 + d]);
    float P = 1.f, S = 0.f;
    int t0 = c * CS;
    for (int t = t0; t < t0 + CS; ++t) {
        float dtv = dt[t * HD + hh];
        float a = __expf(dtv * A);
        float bv = Bm[t * 64 + d];
        float uv = uc[t * HD + hh];
        P *= a;
        S = fmaf(a, S, dtv * uv * bv);
    }
    cP[g] = P; cS[g] = S;
}

__global__ __launch_bounds__(256) void scan2_kernel(
    const float* __restrict__ cP, const float* __restrict__ cS, float* __restrict__ cI)
{
    int g = blockIdx.x * 256 + threadIdx.x;   // 8192 threads
    float S = 0.f;
    for (int c = 0; c < NC; ++c) {
        cI[c * 8192 + g] = S;
        S = fmaf(cP[c * 8192 + g], S, cS[c * 8192 + g]);
    }
}

__global__ __launch_bounds__(256) void scan3_kernel(
    const float* __restrict__ dt, const float* __restrict__ uc,
    const float* __restrict__ Bm, const float* __restrict__ Cm,
    const float* __restrict__ Alog, const float* __restrict__ Dskip,
    const float* __restrict__ cI, float* __restrict__ y)
{
    int g = blockIdx.x * 256 + threadIdx.x;
    int c = g >> 13;
    int r = g & 8191;
    int hh = r >> 6;
    int d = r & 63;
    float A = -__expf(Alog[hh * 64 + d]);
    float s = cI[g];
    float Dh = Dskip[hh];
    int t0 = c * CS;
    for (int t = t0; t < t0 + CS; ++t) {
        float dtv = dt[t * HD + hh];
        float a = __expf(dtv * A);
        float uv = uc[t * HD + hh];
        s = fmaf(a, s, dtv * uv * Bm[t * 64 + d]);
        float yp = s * Cm[t * 64 + d];
        #pragma unroll
        for (int off = 1; off < 64; off <<= 1) yp += __shfl_xor(yp, off);
        if (d == 0) y[t * HD + hh] = yp + Dh * uv;
    }
}

// ---------------- out_proj: (y * silu(z)) @ Wop^T ----------------
__global__ __launch_bounds__(256) void out_kernel(
    const float* __restrict__ y, const float* __restrict__ zs,
    const float* __restrict__ Wop, float* __restrict__ outp)
{
    __shared__ float xs[32][130];
    __shared__ float Ws[16][129];
    const int tid = threadIdx.x;
    const int nbase = blockIdx.x * 32;
    for (int idx = tid; idx < 32 * HD; idx += 256) {
        int n = idx >> 7, k = idx & 127;
        size_t gn = (size_t)(nbase + n);
        xs[n][k] = y[gn * HD + k] * zs[gn * HD + k];
    }
    const int je = tid & 31;
    const int e0 = (tid >> 5) * 4;
    float acc[4][4];
    #pragma unroll
    for (int i = 0; i < 4; ++i)
        #pragma unroll
        for (int m = 0; m < 4; ++m) acc[i][m] = 0.f;
    gemm32<128, 130>(Wop, 128, Ws, xs, e0, je, tid, acc);
    #pragma unroll
    for (int i = 0; i < 4; ++i)
        #pragma unroll
        for (int m = 0; m < 4; ++m)
            outp[(size_t)(nbase + e0 + i) * HD + je + 32 * m] = acc[i][m];
}

extern "C" void kernel_launch(void* const* d_in, const int* in_sizes, int n_in,
                              void* d_out, int out_size, void* d_ws, size_t ws_size,
                              hipStream_t stream)
{
    const float* h     = (const float*)d_in[0];
    const float* coord = (const float*)d_in[1];
    const int*   ei    = (const int*)d_in[2];
    const float* We1   = (const float*)d_in[3];
    const float* be1   = (const float*)d_in[4];
    const float* We2   = (const float*)d_in[5];
    const float* be2   = (const float*)d_in[6];
    const float* watt  = (const float*)d_in[7];
    const float* batt  = (const float*)d_in[8];
    const float* Wn1   = (const float*)d_in[9];
    const float* bn1   = (const float*)d_in[10];
    const float* Wn2   = (const float*)d_in[11];
    const float* bn2   = (const float*)d_in[12];
    const float* Wc1   = (const float*)d_in[13];
    const float* bc1   = (const float*)d_in[14];
    const float* Wc2   = (const float*)d_in[15];
    const float* lng   = (const float*)d_in[16];
    const float* lnb   = (const float*)d_in[17];
    const float* Wip   = (const float*)d_in[18];
    const float* convw = (const float*)d_in[19];
    const float* convb = (const float*)d_in[20];
    const float* Wxp   = (const float*)d_in[21];
    const float* Wdt   = (const float*)d_in[22];
    const float* bdt   = (const float*)d_in[23];
    const float* Alog  = (const float*)d_in[24];
    const float* Dskip = (const float*)d_in[25];
    const float* Wop   = (const float*)d_in[26];

    float* ws   = (float*)d_ws;
    float* mi   = ws;                                  // NN*HD   (zeroed)
    float* ssum = mi   + (size_t)NN * HD;              // NN*3    (zeroed)
    float* cnt  = ssum + (size_t)NN * 3;               // NN      (zeroed)
    float* xbuf = cnt  + NN;                           // NN*HD   (hn; later dt)
    float* zsb  = xbuf + (size_t)NN * HD;              // NN*HD   silu(z)
    float* ubuf = zsb  + (size_t)NN * HD;              // NN*HD   u; later B|C
    float* ucb  = ubuf + (size_t)NN * HD;              // NN*HD   uc
    float* cP   = ucb  + (size_t)NN * HD;              // NC*8192
    float* cSb  = cP   + (size_t)NC * 8192;            // NC*8192
    float* cIb  = cSb  + (size_t)NC * 8192;            // NC*8192
    float* dtb  = xbuf;
    float* Bm   = ubuf;
    float* Cm   = ubuf + (size_t)NN * 64;

    float* outp     = (float*)d_out;
    float* yb       = outp;                            // reuse out region for y
    float* coordout = outp + (size_t)NN * HD;

    hipMemsetAsync(ws, 0, sizeof(float) * (size_t)NN * (HD + 4), stream);

    edge_kernel<<<EE / 32, 256, 0, stream>>>(h, coord, ei, We1, be1, We2, be2,
                                             watt, batt, Wc1, bc1, Wc2, mi, ssum, cnt);
    node_kernel<<<NN / 32, 256, 0, stream>>>(mi, h, Wn1, bn1, Wn2, bn2, lng, lnb, xbuf);
    coord_kernel<<<(NN * 3 + 255) / 256, 256, 0, stream>>>(coord, ssum, cnt, coordout);
    xz_kernel<<<NN / 32, 256, 0, stream>>>(xbuf, Wip, ubuf, zsb);
    conv_kernel<<<NN * HD / 256, 256, 0, stream>>>(ubuf, convw, convb, ucb);
    xdbl_kernel<<<NN / 16, 256, 0, stream>>>(ucb, Wxp, Wdt, bdt, dtb, Bm, Cm);
    scan1_kernel<<<NC * 8192 / 256, 256, 0, stream>>>(dtb, ucb, Bm, Alog, cP, cSb);
    scan2_kernel<<<8192 / 256, 256, 0, stream>>>(cP, cSb, cIb);
    scan3_kernel<<<NC * 8192 / 256, 256, 0, stream>>>(dtb, ucb, Bm, Cm, Alog, Dskip, cIb, yb);
    out_kernel<<<NN / 32, 256, 0, stream>>>(yb, zsb, Wop, outp);
}

// Round 2
// 1082.461 us; speedup vs baseline: 2.8147x; 2.8147x over previous
//
#include <hip/hip_runtime.h>
#include <math.h>

#define NN 20000
#define EE 640000
#define HD 128
#define NC 160      // scan chunks
#define CS 125      // chunk size: NC*CS == NN

typedef unsigned short ushort_t;
typedef __attribute__((ext_vector_type(8))) short short8v;
typedef __attribute__((ext_vector_type(4))) float f32x4;

#define MFMA16(a,b,c) __builtin_amdgcn_mfma_f32_16x16x32_bf16(a,b,c,0,0,0)

__device__ __forceinline__ float sigf(float x) { return 1.0f / (1.0f + __expf(-x)); }

__device__ __forceinline__ ushort_t f2b(float x) {
    unsigned u = __builtin_bit_cast(unsigned, x);
    unsigned r = (u + 0x7FFFu + ((u >> 16) & 1u)) >> 16;
    return (ushort_t)r;
}

// ---------------- prep: convert h and edge weights to bf16 ----------------
__global__ __launch_bounds__(256) void prep_kernel(
    const float* __restrict__ h, const float* __restrict__ We1,
    const float* __restrict__ We2, const float* __restrict__ Wc1,
    ushort_t* __restrict__ hb, ushort_t* __restrict__ We1b,
    ushort_t* __restrict__ We2b, ushort_t* __restrict__ Wc1b)
{
    int i = blockIdx.x * 256 + threadIdx.x;
    if (i < NN * HD) hb[i] = f2b(h[i]);
    if (i < 128 * 256) We1b[i] = f2b(We1[(i >> 8) * 257 + (i & 255)]);
    if (i < 128 * 128) { We2b[i] = f2b(We2[i]); Wc1b[i] = f2b(Wc1[i]); }
}

// ---------------- edge phase (MFMA bf16) ----------------
// block: 128 edges x 128 outputs; 4 waves in 2x2; wave tile 64x64 (4x4 MFMA tiles)
__global__ __launch_bounds__(256) void edge_mfma(
    const ushort_t* __restrict__ hb, const float* __restrict__ coord,
    const int* __restrict__ ei, const float* __restrict__ We1,
    const ushort_t* __restrict__ We1b, const float* __restrict__ be1,
    const ushort_t* __restrict__ We2b, const float* __restrict__ be2,
    const float* __restrict__ watt, const float* __restrict__ batt,
    const ushort_t* __restrict__ Wc1b, const float* __restrict__ bc1,
    const float* __restrict__ Wc2,
    float* __restrict__ mi, float* __restrict__ ssum, float* __restrict__ cnt)
{
    extern __shared__ __align__(16) char smem[];
    ushort_t* xeb  = (ushort_t*)smem;            // [128][40]
    ushort_t* Wb   = xeb + 5120;                 // [128][40]
    ushort_t* ybuf = Wb + 5120;                  // [128][128], xor-swizzled
    float*    rad  = (float*)(ybuf + 16384);
    float*    cdp  = rad + 128;                  // [128][3]
    float*    wcols= cdp + 384;
    float*    be1s = wcols + 128;
    float*    be2s = be1s + 128;
    float*    bc1s = be2s + 128;
    float*    watts= bc1s + 128;
    float*    wc2s = watts + 128;
    float*    pq   = wc2s + 128;                 // [2][128]
    int*      ej0s = (int*)(pq + 256);
    int*      ej1s = ej0s + 128;

    const int tid = threadIdx.x;
    const int ebase = blockIdx.x * 128;
    const int lane = tid & 63;
    const int wid = tid >> 6;
    const int wm = wid >> 1, wn = wid & 1;
    const int g = lane >> 4, r16 = lane & 15;
    const int es = tid >> 1, hf = tid & 1;
    const float batt0 = batt[0];

    if (tid < 128) {
        ej0s[tid] = ei[ebase + tid];
    } else {
        int t = tid - 128;
        ej1s[t] = ei[EE + ebase + t];
        wcols[t] = We1[t * 257 + 256];
        be1s[t] = be1[t]; be2s[t] = be2[t]; bc1s[t] = bc1[t];
        watts[t] = watt[t]; wc2s[t] = Wc2[t];
    }
    __syncthreads();
    if (tid < 128) {
        int a = ej0s[tid], b = ej1s[tid];
        float rr = 0.f;
        #pragma unroll
        for (int c = 0; c < 3; ++c) {
            float d = coord[a * 3 + c] - coord[b * 3 + c];
            cdp[tid * 3 + c] = d; rr += d * d;
        }
        rad[tid] = rr;
    }

    f32x4 acc[4][4];
    #pragma unroll
    for (int mt = 0; mt < 4; ++mt)
        #pragma unroll
        for (int nt = 0; nt < 4; ++nt)
            acc[mt][nt] = (f32x4){0.f, 0.f, 0.f, 0.f};

    // ---- layer 1: x_edge[128x256] @ We1^T ----
    for (int c = 0; c < 8; ++c) {
        __syncthreads();
        {
            int srow = (c < 4) ? ej1s[es] : ej0s[es];
            const uint4* sx = (const uint4*)(hb + (size_t)srow * HD + (c & 3) * 32 + hf * 16);
            uint4 x0 = sx[0], x1 = sx[1];
            const uint4* sw = (const uint4*)(We1b + es * 256 + c * 32 + hf * 16);
            uint4 w0 = sw[0], w1 = sw[1];
            uint4* dx = (uint4*)(xeb + es * 40 + hf * 16);
            dx[0] = x0; dx[1] = x1;
            uint4* dw = (uint4*)(Wb + es * 40 + hf * 16);
            dw[0] = w0; dw[1] = w1;
        }
        __syncthreads();
        short8v afr[4], bfr[4];
        #pragma unroll
        for (int mt = 0; mt < 4; ++mt)
            afr[mt] = *(const short8v*)(xeb + (wm * 64 + mt * 16 + r16) * 40 + g * 8);
        #pragma unroll
        for (int nt = 0; nt < 4; ++nt)
            bfr[nt] = *(const short8v*)(Wb + (wn * 64 + nt * 16 + r16) * 40 + g * 8);
        #pragma unroll
        for (int mt = 0; mt < 4; ++mt)
            #pragma unroll
            for (int nt = 0; nt < 4; ++nt)
                acc[mt][nt] = MFMA16(afr[mt], bfr[nt], acc[mt][nt]);
    }

    // epilogue 1: + radial*wcol + bias, relu -> ybuf (bf16 swizzled)
    #pragma unroll
    for (int mt = 0; mt < 4; ++mt)
        #pragma unroll
        for (int nt = 0; nt < 4; ++nt)
            #pragma unroll
            for (int r = 0; r < 4; ++r) {
                int row = wm * 64 + mt * 16 + g * 4 + r;
                int col = wn * 64 + nt * 16 + r16;
                float v = acc[mt][nt][r] + rad[row] * wcols[col] + be1s[col];
                v = fmaxf(v, 0.f);
                int off = (row << 8) + (((col << 1)) ^ ((row & 7) << 4));
                *(ushort_t*)((char*)ybuf + off) = f2b(v);
            }

    // ---- layer 2: y1 @ We2^T -> mij ----
    #pragma unroll
    for (int mt = 0; mt < 4; ++mt)
        #pragma unroll
        for (int nt = 0; nt < 4; ++nt)
            acc[mt][nt] = (f32x4){0.f, 0.f, 0.f, 0.f};
    for (int c = 0; c < 4; ++c) {
        __syncthreads();
        {
            const uint4* sw = (const uint4*)(We2b + es * 128 + c * 32 + hf * 16);
            uint4 w0 = sw[0], w1 = sw[1];
            uint4* dw = (uint4*)(Wb + es * 40 + hf * 16);
            dw[0] = w0; dw[1] = w1;
        }
        __syncthreads();
        short8v afr[4], bfr[4];
        #pragma unroll
        for (int mt = 0; mt < 4; ++mt) {
            int row = wm * 64 + mt * 16 + r16;
            int off = (row << 8) + ((c * 64 + g * 16) ^ ((row & 7) << 4));
            afr[mt] = *(const short8v*)((const char*)ybuf + off);
        }
        #pragma unroll
        for (int nt = 0; nt < 4; ++nt)
            bfr[nt] = *(const short8v*)(Wb + (wn * 64 + nt * 16 + r16) * 40 + g * 8);
        #pragma unroll
        for (int mt = 0; mt < 4; ++mt)
            #pragma unroll
            for (int nt = 0; nt < 4; ++nt)
                acc[mt][nt] = MFMA16(afr[mt], bfr[nt], acc[mt][nt]);
    }

    // epilogue 2: mij = relu(+be2); att = sigmoid(mij.watt + batt); ef = mij*att
    {
        float p[4][4];
        #pragma unroll
        for (int mt = 0; mt < 4; ++mt)
            #pragma unroll
            for (int r = 0; r < 4; ++r) p[mt][r] = 0.f;
        #pragma unroll
        for (int mt = 0; mt < 4; ++mt)
            #pragma unroll
            for (int nt = 0; nt < 4; ++nt)
                #pragma unroll
                for (int r = 0; r < 4; ++r) {
                    int col = wn * 64 + nt * 16 + r16;
                    float v = fmaxf(acc[mt][nt][r] + be2s[col], 0.f);
                    acc[mt][nt][r] = v;
                    p[mt][r] += v * watts[col];
                }
        #pragma unroll
        for (int off = 1; off < 16; off <<= 1)
            #pragma unroll
            for (int mt = 0; mt < 4; ++mt)
                #pragma unroll
                for (int r = 0; r < 4; ++r) p[mt][r] += __shfl_xor(p[mt][r], off);
        if (r16 == 0) {
            #pragma unroll
            for (int mt = 0; mt < 4; ++mt)
                #pragma unroll
                for (int r = 0; r < 4; ++r)
                    pq[wn * 128 + wm * 64 + mt * 16 + g * 4 + r] = p[mt][r];
        }
        __syncthreads();
        float att[4][4];
        #pragma unroll
        for (int mt = 0; mt < 4; ++mt)
            #pragma unroll
            for (int r = 0; r < 4; ++r) {
                int row = wm * 64 + mt * 16 + g * 4 + r;
                att[mt][r] = sigf(pq[row] + pq[128 + row] + batt0);
            }
        #pragma unroll
        for (int mt = 0; mt < 4; ++mt)
            #pragma unroll
            for (int nt = 0; nt < 4; ++nt)
                #pragma unroll
                for (int r = 0; r < 4; ++r) {
                    int row = wm * 64 + mt * 16 + g * 4 + r;
                    int col = wn * 64 + nt * 16 + r16;
                    float v = acc[mt][nt][r] * att[mt][r];
                    acc[mt][nt][r] = v;
                    atomicAdd(&mi[(size_t)ej0s[row] * HD + col], v);
                }
        __syncthreads();   // pq reads + ybuf layer-2 reads done -> safe to overwrite ybuf
        #pragma unroll
        for (int mt = 0; mt < 4; ++mt)
            #pragma unroll
            for (int nt = 0; nt < 4; ++nt)
                #pragma unroll
                for (int r = 0; r < 4; ++r) {
                    int row = wm * 64 + mt * 16 + g * 4 + r;
                    int col = wn * 64 + nt * 16 + r16;
                    int off = (row << 8) + (((col << 1)) ^ ((row & 7) << 4));
                    *(ushort_t*)((char*)ybuf + off) = f2b(acc[mt][nt][r]);
                }
    }

    // ---- layer 3: ef @ Wc1^T, dot Wc2 -> coord atomics ----
    #pragma unroll
    for (int mt = 0; mt < 4; ++mt)
        #pragma unroll
        for (int nt = 0; nt < 4; ++nt)
            acc[mt][nt] = (f32x4){0.f, 0.f, 0.f, 0.f};
    for (int c = 0; c < 4; ++c) {
        __syncthreads();
        {
            const uint4* sw = (const uint4*)(Wc1b + es * 128 + c * 32 + hf * 16);
            uint4 w0 = sw[0], w1 = sw[1];
            uint4* dw = (uint4*)(Wb + es * 40 + hf * 16);
            dw[0] = w0; dw[1] = w1;
        }
        __syncthreads();
        short8v afr[4], bfr[4];
        #pragma unroll
        for (int mt = 0; mt < 4; ++mt) {
            int row = wm * 64 + mt * 16 + r16;
            int off = (row << 8) + ((c * 64 + g * 16) ^ ((row & 7) << 4));
            afr[mt] = *(const short8v*)((const char*)ybuf + off);
        }
        #pragma unroll
        for (int nt = 0; nt < 4; ++nt)
            bfr[nt] = *(const short8v*)(Wb + (wn * 64 + nt * 16 + r16) * 40 + g * 8);
        #pragma unroll
        for (int mt = 0; mt < 4; ++mt)
            #pragma unroll
            for (int nt = 0; nt < 4; ++nt)
                acc[mt][nt] = MFMA16(afr[mt], bfr[nt], acc[mt][nt]);
    }
    {
        float q[4][4];
        #pragma unroll
        for (int mt = 0; mt < 4; ++mt)
            #pragma unroll
            for (int r = 0; r < 4; ++r) q[mt][r] = 0.f;
        #pragma unroll
        for (int mt = 0; mt < 4; ++mt)
            #pragma unroll
            for (int nt = 0; nt < 4; ++nt)
                #pragma unroll
                for (int r = 0; r < 4; ++r) {
                    int col = wn * 64 + nt * 16 + r16;
                    float v = fmaxf(acc[mt][nt][r] + bc1s[col], 0.f);
                    q[mt][r] += v * wc2s[col];
                }
        #pragma unroll
        for (int off = 1; off < 16; off <<= 1)
            #pragma unroll
            for (int mt = 0; mt < 4; ++mt)
                #pragma unroll
                for (int r = 0; r < 4; ++r) q[mt][r] += __shfl_xor(q[mt][r], off);
        if (r16 == 0) {
            #pragma unroll
            for (int mt = 0; mt < 4; ++mt)
                #pragma unroll
                for (int r = 0; r < 4; ++r)
                    pq[wn * 128 + wm * 64 + mt * 16 + g * 4 + r] = q[mt][r];
        }
        __syncthreads();
        if (wn == 0 && r16 == 0) {
            #pragma unroll
            for (int mt = 0; mt < 4; ++mt)
                #pragma unroll
                for (int r = 0; r < 4; ++r) {
                    int row = wm * 64 + mt * 16 + g * 4 + r;
                    float tv = pq[row] + pq[128 + row];
                    int node = ej0s[row];
                    #pragma unroll
                    for (int c = 0; c < 3; ++c) {
                        float tr = cdp[row * 3 + c] * tv;
                        tr = fminf(fmaxf(tr, -100.f), 100.f);
                        atomicAdd(&ssum[node * 3 + c], tr);
                    }
                    atomicAdd(&cnt[node], 1.f);
                }
        }
    }
}

// 32-row x 128-col fp32 GEMM tile helper (kept for node/xz/out kernels)
template<int KTOT, int LDX>
__device__ __forceinline__ void gemm32(const float* __restrict__ W, int ldw,
                                       float (*Ws)[129], float (*X)[LDX],
                                       int e0, int je, int tid, float acc[4][4])
{
    for (int k0 = 0; k0 < KTOT; k0 += 16) {
        __syncthreads();
        for (int idx = tid; idx < 16 * HD; idx += 256) {
            int j = idx >> 4, kk = idx & 15;
            Ws[kk][j] = W[j * ldw + k0 + kk];
        }
        __syncthreads();
        #pragma unroll
        for (int kk = 0; kk < 16; ++kk) {
            float xr[4], wr[4];
            #pragma unroll
            for (int i = 0; i < 4; ++i) xr[i] = X[e0 + i][k0 + kk];
            #pragma unroll
            for (int m = 0; m < 4; ++m) wr[m] = Ws[kk][je + 32 * m];
            #pragma unroll
            for (int i = 0; i < 4; ++i)
                #pragma unroll
                for (int m = 0; m < 4; ++m)
                    acc[i][m] = fmaf(xr[i], wr[m], acc[i][m]);
        }
    }
}

// ---------------- node MLP + layernorm + clip ----------------
__global__ __launch_bounds__(256) void node_kernel(
    const float* __restrict__ mi, const float* __restrict__ h,
    const float* __restrict__ Wn1, const float* __restrict__ bn1,
    const float* __restrict__ Wn2, const float* __restrict__ bn2,
    const float* __restrict__ lng, const float* __restrict__ lnb,
    float* __restrict__ xout)
{
    __shared__ float xs[32][259];
    __shared__ float ybuf[32][133];
    __shared__ float Ws[16][129];
    __shared__ float mu_s[32], rs_s[32];
    const int tid = threadIdx.x;
    const int nbase = blockIdx.x * 32;

    for (int idx = tid; idx < 32 * 256; idx += 256) {
        int n = idx >> 8, k = idx & 255;
        xs[n][k] = (k < HD) ? mi[(size_t)(nbase + n) * HD + k] : h[(size_t)(nbase + n) * HD + (k - HD)];
    }
    const int je = tid & 31;
    const int e0 = (tid >> 5) * 4;

    float acc[4][4];
    #pragma unroll
    for (int i = 0; i < 4; ++i)
        #pragma unroll
        for (int m = 0; m < 4; ++m) acc[i][m] = 0.f;
    gemm32<256, 259>(Wn1, 256, Ws, xs, e0, je, tid, acc);
    #pragma unroll
    for (int i = 0; i < 4; ++i)
        #pragma unroll
        for (int m = 0; m < 4; ++m)
            ybuf[e0 + i][je + 32 * m] = fmaxf(acc[i][m] + bn1[je + 32 * m], 0.f);

    float acc2[4][4];
    #pragma unroll
    for (int i = 0; i < 4; ++i)
        #pragma unroll
        for (int m = 0; m < 4; ++m) acc2[i][m] = 0.f;
    gemm32<128, 133>(Wn2, 128, Ws, ybuf, e0, je, tid, acc2);
    #pragma unroll
    for (int i = 0; i < 4; ++i)
        #pragma unroll
        for (int m = 0; m < 4; ++m)
            ybuf[e0 + i][je + 32 * m] = acc2[i][m] + bn2[je + 32 * m];
    __syncthreads();

    const int nl = tid >> 3, r = tid & 7;
    float s1 = 0.f, s2 = 0.f;
    #pragma unroll
    for (int k = r * 16; k < r * 16 + 16; ++k) { float v = ybuf[nl][k]; s1 += v; s2 += v * v; }
    #pragma unroll
    for (int off = 1; off < 8; off <<= 1) { s1 += __shfl_xor(s1, off); s2 += __shfl_xor(s2, off); }
    if (r == 0) {
        float mu = s1 * (1.f / HD);
        float var = s2 * (1.f / HD) - mu * mu;
        mu_s[nl] = mu;
        rs_s[nl] = rsqrtf(fmaxf(var, 0.f) + 1e-5f);
    }
    __syncthreads();
    for (int idx = tid; idx < 32 * HD; idx += 256) {
        int n = idx >> 7, j = idx & 127;
        float v = (ybuf[n][j] - mu_s[n]) * rs_s[n] * lng[j] + lnb[j];
        v = fminf(fmaxf(v, -10.f), 10.f);
        xout[(size_t)(nbase + n) * HD + j] = v;
    }
}

// ---------------- coord update ----------------
__global__ __launch_bounds__(256) void coord_kernel(
    const float* __restrict__ coord, const float* __restrict__ ssum,
    const float* __restrict__ cnt, float* __restrict__ outp)
{
    int idx = blockIdx.x * 256 + threadIdx.x;
    if (idx < NN * 3) {
        int n = idx / 3;
        outp[idx] = coord[idx] + ssum[idx] / fmaxf(cnt[n], 1.f);
    }
}

// ---------------- mamba in_proj ----------------
__global__ __launch_bounds__(256) void xz_kernel(
    const float* __restrict__ x, const float* __restrict__ Wip,
    float* __restrict__ u, float* __restrict__ zs)
{
    __shared__ float xs[32][130];
    __shared__ float Ws[16][257];
    const int tid = threadIdx.x;
    const int nbase = blockIdx.x * 32;
    for (int idx = tid; idx < 32 * HD; idx += 256) {
        int n = idx >> 7, k = idx & 127;
        xs[n][k] = x[(size_t)(nbase + n) * HD + k];
    }
    const int jj = tid & 63;
    const int n0 = (tid >> 6) * 8;
    float acc[8][4];
    #pragma unroll
    for (int i = 0; i < 8; ++i)
        #pragma unroll
        for (int m = 0; m < 4; ++m) acc[i][m] = 0.f;
    for (int k0 = 0; k0 < HD; k0 += 16) {
        __syncthreads();
        for (int idx = tid; idx < 16 * 256; idx += 256) {
            int j = idx >> 4, kk = idx & 15;
            Ws[kk][j] = Wip[j * HD + k0 + kk];
        }
        __syncthreads();
        #pragma unroll
        for (int kk = 0; kk < 16; ++kk) {
            float xr[8], wr[4];
            #pragma unroll
            for (int i = 0; i < 8; ++i) xr[i] = xs[n0 + i][k0 + kk];
            #pragma unroll
            for (int m = 0; m < 4; ++m) wr[m] = Ws[kk][jj + 64 * m];
            #pragma unroll
            for (int i = 0; i < 8; ++i)
                #pragma unroll
                for (int m = 0; m < 4; ++m)
                    acc[i][m] = fmaf(xr[i], wr[m], acc[i][m]);
        }
    }
    #pragma unroll
    for (int i = 0; i < 8; ++i)
        #pragma unroll
        for (int m = 0; m < 4; ++m) {
            int j = jj + 64 * m;
            size_t n = (size_t)(nbase + n0 + i);
            float v = acc[i][m];
            if (j < HD) u[n * HD + j] = v;
            else        zs[n * HD + (j - HD)] = v * sigf(v);
        }
}

// ---------------- causal depthwise conv + silu ----------------
__global__ __launch_bounds__(256) void conv_kernel(
    const float* __restrict__ u, const float* __restrict__ cw, const float* __restrict__ cb,
    float* __restrict__ uc)
{
    int idx = blockIdx.x * 256 + threadIdx.x;
    int n = idx >> 7, hh = idx & 127;
    float a = cb[hh];
    #pragma unroll
    for (int k = 0; k < 4; ++k) {
        int t = n - 3 + k;
        if (t >= 0) a = fmaf(u[t * HD + hh], cw[hh * 4 + k], a);
    }
    uc[idx] = a * sigf(a);
}

// ---------------- x_proj + dt_proj ----------------
__global__ __launch_bounds__(256) void xdbl_kernel(
    const float* __restrict__ uc, const float* __restrict__ Wxp,
    const float* __restrict__ Wdt, const float* __restrict__ bdt,
    float* __restrict__ dt, float* __restrict__ Bm, float* __restrict__ Cm)
{
    __shared__ float xs[16][130];
    __shared__ float xd8[16][9];
    const int tid = threadIdx.x;
    const int nbase = blockIdx.x * 16;
    for (int idx = tid; idx < 16 * HD; idx += 256) {
        int n = idx >> 7, k = idx & 127;
        xs[n][k] = uc[(size_t)(nbase + n) * HD + k];
    }
    __syncthreads();
    const int nl = tid >> 4, jj = tid & 15;
    #pragma unroll
    for (int rep = 0; rep < 9; ++rep) {
        int j = jj + rep * 16;
        if (j < 136) {
            float a = 0.f;
            for (int k = 0; k < HD; ++k) a = fmaf(xs[nl][k], Wxp[j * HD + k], a);
            int n = nbase + nl;
            if (j < 8)       xd8[nl][j] = a;
            else if (j < 72) Bm[(size_t)n * 64 + (j - 8)] = a;
            else             Cm[(size_t)n * 64 + (j - 72)] = a;
        }
    }
    __syncthreads();
    #pragma unroll
    for (int q = 0; q < 8; ++q) {
        int hh = jj * 8 + q;
        float a = bdt[hh];
        #pragma unroll
        for (int r2 = 0; r2 < 8; ++r2) a = fmaf(xd8[nl][r2], Wdt[hh * 8 + r2], a);
        float sp = (a > 20.f) ? a : log1pf(__expf(a));
        dt[(size_t)(nbase + nl) * HD + hh] = sp;
    }
}

// ---------------- chunked SSM scan ----------------
__global__ __launch_bounds__(256) void scan1_kernel(
    const float* __restrict__ dt, const float* __restrict__ uc,
    const float* __restrict__ Bm, const float* __restrict__ Alog,
    float* __restrict__ cP, float* __restrict__ cS)
{
    int g = blockIdx.x * 256 + threadIdx.x;
    int c = g >> 13;
    int r = g & 8191;
    int hh = r >> 6;
    int d = r & 63;
    float A = -__expf(Alog[hh * 64 + d]);
    float P = 1.f, S = 0.f;
    int t0 = c * CS;
    for (int t = t0; t < t0 + CS; ++t) {
        float dtv = dt[t * HD + hh];
        float a = __expf(dtv * A);
        float bv = Bm[t * 64 + d];
        float uv = uc[t * HD + hh];
        P *= a;
        S = fmaf(a, S, dtv * uv * bv);
    }
    cP[g] = P; cS[g] = S;
}

__global__ __launch_bounds__(256) void scan2_kernel(
    const float* __restrict__ cP, const float* __restrict__ cS, float* __restrict__ cI)
{
    int g = blockIdx.x * 256 + threadIdx.x;
    float S = 0.f;
    for (int c = 0; c < NC; ++c) {
        cI[c * 8192 + g] = S;
        S = fmaf(cP[c * 8192 + g], S, cS[c * 8192 + g]);
    }
}

__global__ __launch_bounds__(256) void scan3_kernel(
    const float* __restrict__ dt, const float* __restrict__ uc,
    const float* __restrict__ Bm, const float* __restrict__ Cm,
    const float* __restrict__ Alog, const float* __restrict__ Dskip,
    const float* __restrict__ cI, float* __restrict__ y)
{
    int g = blockIdx.x * 256 + threadIdx.x;
    int c = g >> 13;
    int r = g & 8191;
    int hh = r >> 6;
    int d = r & 63;
    float A = -__expf(Alog[hh * 64 + d]);
    float s = cI[g];
    float Dh = Dskip[hh];
    int t0 = c * CS;
    for (int t = t0; t < t0 + CS; ++t) {
        float dtv = dt[t * HD + hh];
        float a = __expf(dtv * A);
        float uv = uc[t * HD + hh];
        s = fmaf(a, s, dtv * uv * Bm[t * 64 + d]);
        float yp = s * Cm[t * 64 + d];
        #pragma unroll
        for (int off = 1; off < 64; off <<= 1) yp += __shfl_xor(yp, off);
        if (d == 0) y[t * HD + hh] = yp + Dh * uv;
    }
}

// ---------------- out_proj ----------------
__global__ __launch_bounds__(256) void out_kernel(
    const float* __restrict__ y, const float* __restrict__ zs,
    const float* __restrict__ Wop, float* __restrict__ outp)
{
    __shared__ float xs[32][130];
    __shared__ float Ws[16][129];
    const int tid = threadIdx.x;
    const int nbase = blockIdx.x * 32;
    for (int idx = tid; idx < 32 * HD; idx += 256) {
        int n = idx >> 7, k = idx & 127;
        size_t gn = (size_t)(nbase + n);
        xs[n][k] = y[gn * HD + k] * zs[gn * HD + k];
    }
    const int je = tid & 31;
    const int e0 = (tid >> 5) * 4;
    float acc[4][4];
    #pragma unroll
    for (int i = 0; i < 4; ++i)
        #pragma unroll
        for (int m = 0; m < 4; ++m) acc[i][m] = 0.f;
    gemm32<128, 130>(Wop, 128, Ws, xs, e0, je, tid, acc);
    #pragma unroll
    for (int i = 0; i < 4; ++i)
        #pragma unroll
        for (int m = 0; m < 4; ++m)
            outp[(size_t)(nbase + e0 + i) * HD + je + 32 * m] = acc[i][m];
}

extern "C" void kernel_launch(void* const* d_in, const int* in_sizes, int n_in,
                              void* d_out, int out_size, void* d_ws, size_t ws_size,
                              hipStream_t stream)
{
    const float* h     = (const float*)d_in[0];
    const float* coord = (const float*)d_in[1];
    const int*   ei    = (const int*)d_in[2];
    const float* We1   = (const float*)d_in[3];
    const float* be1   = (const float*)d_in[4];
    const float* We2   = (const float*)d_in[5];
    const float* be2   = (const float*)d_in[6];
    const float* watt  = (const float*)d_in[7];
    const float* batt  = (const float*)d_in[8];
    const float* Wn1   = (const float*)d_in[9];
    const float* bn1   = (const float*)d_in[10];
    const float* Wn2   = (const float*)d_in[11];
    const float* bn2   = (const float*)d_in[12];
    const float* Wc1   = (const float*)d_in[13];
    const float* bc1   = (const float*)d_in[14];
    const float* Wc2   = (const float*)d_in[15];
    const float* lng   = (const float*)d_in[16];
    const float* lnb   = (const float*)d_in[17];
    const float* Wip   = (const float*)d_in[18];
    const float* convw = (const float*)d_in[19];
    const float* convb = (const float*)d_in[20];
    const float* Wxp   = (const float*)d_in[21];
    const float* Wdt   = (const float*)d_in[22];
    const float* bdt   = (const float*)d_in[23];
    const float* Alog  = (const float*)d_in[24];
    const float* Dskip = (const float*)d_in[25];
    const float* Wop   = (const float*)d_in[26];

    float* ws   = (float*)d_ws;
    float* mi   = ws;                                  // NN*HD   (zeroed)
    float* ssum = mi   + (size_t)NN * HD;              // NN*3    (zeroed)
    float* cnt  = ssum + (size_t)NN * 3;               // NN      (zeroed)
    float* xbuf = cnt  + NN;                           // NN*HD   (hn; later dt)
    float* zsb  = xbuf + (size_t)NN * HD;              // NN*HD
    float* ubuf = zsb  + (size_t)NN * HD;              // NN*HD   u; later B|C
    float* ucb  = ubuf + (size_t)NN * HD;              // NN*HD
    float* cP   = ucb  + (size_t)NN * HD;              // NC*8192
    float* cSb  = cP   + (size_t)NC * 8192;
    float* cIb  = cSb  + (size_t)NC * 8192;
    float* bfb  = cIb  + (size_t)NC * 8192;            // bf16 region
    ushort_t* hbp   = (ushort_t*)bfb;                  // NN*HD bf16
    ushort_t* We1bp = hbp + (size_t)NN * HD;           // 128*256
    ushort_t* We2bp = We1bp + 128 * 256;               // 128*128
    ushort_t* Wc1bp = We2bp + 128 * 128;               // 128*128
    float* dtb  = xbuf;
    float* Bm   = ubuf;
    float* Cm   = ubuf + (size_t)NN * 64;

    float* outp     = (float*)d_out;
    float* yb       = outp;
    float* coordout = outp + (size_t)NN * HD;

    hipMemsetAsync(ws, 0, sizeof(float) * (size_t)NN * (HD + 4), stream);

    prep_kernel<<<(NN * HD) / 256, 256, 0, stream>>>(h, We1, We2, Wc1, hbp, We1bp, We2bp, Wc1bp);
    edge_mfma<<<EE / 128, 256, 60416, stream>>>(hbp, coord, ei, We1, We1bp, be1,
                                                We2bp, be2, watt, batt, Wc1bp, bc1, Wc2,
                                                mi, ssum, cnt);
    node_kernel<<<NN / 32, 256, 0, stream>>>(mi, h, Wn1, bn1, Wn2, bn2, lng, lnb, xbuf);
    coord_kernel<<<(NN * 3 + 255) / 256, 256, 0, stream>>>(coord, ssum, cnt, coordout);
    xz_kernel<<<NN / 32, 256, 0, stream>>>(xbuf, Wip, ubuf, zsb);
    conv_kernel<<<NN * HD / 256, 256, 0, stream>>>(ubuf, convw, convb, ucb);
    xdbl_kernel<<<NN / 16, 256, 0, stream>>>(ucb, Wxp, Wdt, bdt, dtb, Bm, Cm);
    scan1_kernel<<<NC * 8192 / 256, 256, 0, stream>>>(dtb, ucb, Bm, Alog, cP, cSb);
    scan2_kernel<<<8192 / 256, 256, 0, stream>>>(cP, cSb, cIb);
    scan3_kernel<<<NC * 8192 / 256, 256, 0, stream>>>(dtb, ucb, Bm, Cm, Alog, Dskip, cIb, yb);
    out_kernel<<<NN / 32, 256, 0, stream>>>(yb, zsb, Wop, outp);
}

// Round 4
// 1071.761 us; speedup vs baseline: 2.8428x; 1.0100x over previous
//
#include <hip/hip_runtime.h>
#include <math.h>

#define NN 20000
#define EE 640000
#define HD 128
#define NC 160      // scan chunks
#define CS 125      // chunk size: NC*CS == NN

typedef unsigned short ushort_t;
typedef __attribute__((ext_vector_type(8))) short short8v;
typedef __attribute__((ext_vector_type(4))) float f32x4;

#define MFMA16(a,b,c) __builtin_amdgcn_mfma_f32_16x16x32_bf16(a,b,c,0,0,0)

__device__ __forceinline__ float sigf(float x) { return 1.0f / (1.0f + __expf(-x)); }

__device__ __forceinline__ ushort_t f2b(float x) {
    unsigned u = __builtin_bit_cast(unsigned, x);
    unsigned r = (u + 0x7FFFu + ((u >> 16) & 1u)) >> 16;
    return (ushort_t)r;
}
__device__ __forceinline__ float b2f(ushort_t u) {
    unsigned v = ((unsigned)u) << 16;
    return __builtin_bit_cast(float, v);
}

// ---------------- prep: bf16 conversions ----------------
// W12b[j][k], j<128: We1[j][k] (multiplies h[e1]); j>=128: We1[j-128][128+k] (multiplies h[e0])
__global__ __launch_bounds__(256) void prep_kernel(
    const float* __restrict__ h, const float* __restrict__ We1,
    const float* __restrict__ We2, const float* __restrict__ Wc1,
    ushort_t* __restrict__ hb, ushort_t* __restrict__ W12b,
    ushort_t* __restrict__ We2b, ushort_t* __restrict__ Wc1b)
{
    int i = blockIdx.x * 256 + threadIdx.x;
    if (i < NN * HD) hb[i] = f2b(h[i]);
    if (i < 256 * 128) {
        int j = i >> 7, k = i & 127;
        W12b[i] = f2b(We1[(j & 127) * 257 + ((j >> 7) << 7) + k]);
    }
    if (i < 128 * 128) { We2b[i] = f2b(We2[i]); Wc1b[i] = f2b(Wc1[i]); }
}

// ---------------- node projections: P12 = h @ [W1a|W1b]^T  (bf16 MFMA, no LDS) ----------------
__global__ __launch_bounds__(256) void p12_kernel(
    const ushort_t* __restrict__ hb, const ushort_t* __restrict__ W12b,
    ushort_t* __restrict__ P12b)
{
    const int tid = threadIdx.x;
    const int lane = tid & 63;
    const int wid = tid >> 6;
    const int wm = wid >> 1, wn = wid & 1;
    const int g = lane >> 4, r16 = lane & 15;
    const int rbase = blockIdx.x * 128 + wm * 64;

    f32x4 acc[4][8];
    #pragma unroll
    for (int mt = 0; mt < 4; ++mt)
        #pragma unroll
        for (int nt = 0; nt < 8; ++nt) acc[mt][nt] = (f32x4){0.f, 0.f, 0.f, 0.f};

    for (int c = 0; c < 4; ++c) {
        short8v afr[4], bfr[8];
        #pragma unroll
        for (int mt = 0; mt < 4; ++mt) {
            int row = rbase + mt * 16 + r16;
            if (row > NN - 1) row = NN - 1;
            afr[mt] = *(const short8v*)(hb + (size_t)row * HD + c * 32 + g * 8);
        }
        #pragma unroll
        for (int nt = 0; nt < 8; ++nt)
            bfr[nt] = *(const short8v*)(W12b + (size_t)(wn * 128 + nt * 16 + r16) * 128 + c * 32 + g * 8);
        #pragma unroll
        for (int mt = 0; mt < 4; ++mt)
            #pragma unroll
            for (int nt = 0; nt < 8; ++nt)
                acc[mt][nt] = MFMA16(afr[mt], bfr[nt], acc[mt][nt]);
    }
    #pragma unroll
    for (int mt = 0; mt < 4; ++mt)
        #pragma unroll
        for (int nt = 0; nt < 8; ++nt)
            #pragma unroll
            for (int r = 0; r < 4; ++r) {
                int row = rbase + mt * 16 + g * 4 + r;
                if (row < NN)
                    P12b[(size_t)row * 256 + wn * 128 + nt * 16 + r16] = f2b(acc[mt][nt][r]);
            }
}

// ---------------- edge phase (MFMA bf16, register-resident weights) ----------------
// block: 128 edges; 4 waves 2x2; wave tile 64 rows x 64 cols (4x4 MFMA tiles)
__global__ __launch_bounds__(256) void edge_mfma(
    const ushort_t* __restrict__ P12b, const float* __restrict__ coord,
    const int* __restrict__ ei, const float* __restrict__ We1,
    const float* __restrict__ be1,
    const ushort_t* __restrict__ We2b, const float* __restrict__ be2,
    const float* __restrict__ watt, const float* __restrict__ batt,
    const ushort_t* __restrict__ Wc1b, const float* __restrict__ bc1,
    const float* __restrict__ Wc2,
    float* __restrict__ mi, float* __restrict__ ssum, float* __restrict__ cnt)
{
    __shared__ ushort_t ybuf[128 * 128];   // 32KB, XOR-swizzled: byte = (row<<8) + ((col*2) ^ ((row&15)<<4))
    __shared__ float rad[128];
    __shared__ float cdp[128][3];
    __shared__ float wcols[128], be1s[128], be2s[128], bc1s[128], watts[128], wc2s[128];
    __shared__ float pq[2][128];
    __shared__ int ej0s[128], ej1s[128];

    const int tid = threadIdx.x;
    const int ebase = blockIdx.x * 128;
    const int lane = tid & 63;
    const int wid = tid >> 6;
    const int wm = wid >> 1, wn = wid & 1;
    const int g = lane >> 4, r16 = lane & 15;
    const float batt0 = batt[0];

    if (tid < 128) {
        ej0s[tid] = ei[ebase + tid];
    } else {
        int t = tid - 128;
        ej1s[t] = ei[EE + ebase + t];
        wcols[t] = We1[t * 257 + 256];
        be1s[t] = be1[t]; be2s[t] = be2[t]; bc1s[t] = bc1[t];
        watts[t] = watt[t]; wc2s[t] = Wc2[t];
    }
    __syncthreads();

    // preload layer-2 weight fragments into registers (latency hides under phase A)
    short8v b2_[4][4];
    {
        const ushort_t* W2p = We2b + (size_t)(wn * 64 + r16) * 128 + g * 8;
        #pragma unroll
        for (int nt = 0; nt < 4; ++nt)
            #pragma unroll
            for (int c = 0; c < 4; ++c)
                b2_[nt][c] = *(const short8v*)(W2p + nt * 2048 + c * 32);
    }

    if (tid < 128) {
        int a = ej0s[tid], b = ej1s[tid];
        float rr = 0.f;
        #pragma unroll
        for (int c = 0; c < 3; ++c) {
            float d = coord[a * 3 + c] - coord[b * 3 + c];
            cdp[tid][c] = d; rr += d * d;
        }
        rad[tid] = rr;
    }
    __syncthreads();

    // ---- phase A: y1 = relu(P1[e1] + P2[e0] + rad*wcol + be1) -> ybuf ----
    {
        const int e = tid >> 1, hf = tid & 1;
        const int n1 = ej1s[e], n0 = ej0s[e];
        const ushort_t* p1 = P12b + (size_t)n1 * 256 + hf * 64;
        const ushort_t* p2 = P12b + (size_t)n0 * 256 + 128 + hf * 64;
        const float radv = rad[e];
        const int colbase = hf * 64;
        #pragma unroll
        for (int q = 0; q < 8; ++q) {
            short8v a = *(const short8v*)(p1 + q * 8);
            short8v b = *(const short8v*)(p2 + q * 8);
            short8v ov;
            #pragma unroll
            for (int jj = 0; jj < 8; ++jj) {
                int col = colbase + q * 8 + jj;
                float v = b2f((ushort_t)a[jj]) + b2f((ushort_t)b[jj]) + radv * wcols[col] + be1s[col];
                ov[jj] = (short)f2b(fmaxf(v, 0.f));
            }
            int off = (e << 8) + ((colbase * 2 + q * 16) ^ ((e & 15) << 4));
            *(short8v*)((char*)ybuf + off) = ov;
        }
    }
    __syncthreads();

    // ---- layer 2: y1 @ We2^T ----
    f32x4 acc[4][4];
    #pragma unroll
    for (int mt = 0; mt < 4; ++mt)
        #pragma unroll
        for (int nt = 0; nt < 4; ++nt) acc[mt][nt] = (f32x4){0.f, 0.f, 0.f, 0.f};
    #pragma unroll
    for (int c = 0; c < 4; ++c) {
        short8v afr[4];
        #pragma unroll
        for (int mt = 0; mt < 4; ++mt) {
            int row = wm * 64 + mt * 16 + r16;
            afr[mt] = *(const short8v*)((const char*)ybuf + (row << 8) + ((c * 64 + g * 16) ^ (r16 << 4)));
        }
        #pragma unroll
        for (int mt = 0; mt < 4; ++mt)
            #pragma unroll
            for (int nt = 0; nt < 4; ++nt)
                acc[mt][nt] = MFMA16(afr[mt], b2_[nt][c], acc[mt][nt]);
    }

    // preload layer-3 weights (latency hides under epilogue 2)
    short8v b3_[4][4];
    {
        const ushort_t* W3p = Wc1b + (size_t)(wn * 64 + r16) * 128 + g * 8;
        #pragma unroll
        for (int nt = 0; nt < 4; ++nt)
            #pragma unroll
            for (int c = 0; c < 4; ++c)
                b3_[nt][c] = *(const short8v*)(W3p + nt * 2048 + c * 32);
    }

    // epilogue 2: mij = relu(+be2); att = sigmoid(mij.watt + batt); ef = mij*att
    {
        float p[4][4];
        #pragma unroll
        for (int mt = 0; mt < 4; ++mt)
            #pragma unroll
            for (int r = 0; r < 4; ++r) p[mt][r] = 0.f;
        #pragma unroll
        for (int mt = 0; mt < 4; ++mt)
            #pragma unroll
            for (int nt = 0; nt < 4; ++nt)
                #pragma unroll
                for (int r = 0; r < 4; ++r) {
                    int col = wn * 64 + nt * 16 + r16;
                    float v = fmaxf(acc[mt][nt][r] + be2s[col], 0.f);
                    acc[mt][nt][r] = v;
                    p[mt][r] += v * watts[col];
                }
        #pragma unroll
        for (int off = 1; off < 16; off <<= 1)
            #pragma unroll
            for (int mt = 0; mt < 4; ++mt)
                #pragma unroll
                for (int r = 0; r < 4; ++r) p[mt][r] += __shfl_xor(p[mt][r], off);
        if (r16 == 0) {
            #pragma unroll
            for (int mt = 0; mt < 4; ++mt)
                #pragma unroll
                for (int r = 0; r < 4; ++r)
                    pq[wn][wm * 64 + mt * 16 + g * 4 + r] = p[mt][r];
        }
        __syncthreads();
        float att[4][4];
        #pragma unroll
        for (int mt = 0; mt < 4; ++mt)
            #pragma unroll
            for (int r = 0; r < 4; ++r) {
                int row = wm * 64 + mt * 16 + g * 4 + r;
                att[mt][r] = sigf(pq[0][row] + pq[1][row] + batt0);
            }
        #pragma unroll
        for (int mt = 0; mt < 4; ++mt)
            #pragma unroll
            for (int nt = 0; nt < 4; ++nt)
                #pragma unroll
                for (int r = 0; r < 4; ++r) {
                    int row = wm * 64 + mt * 16 + g * 4 + r;
                    int col = wn * 64 + nt * 16 + r16;
                    float v = acc[mt][nt][r] * att[mt][r];
                    acc[mt][nt][r] = v;
                    atomicAdd(&mi[(size_t)ej0s[row] * HD + col], v);
                }
        __syncthreads();   // all layer-2 ybuf reads done -> safe to overwrite
        #pragma unroll
        for (int mt = 0; mt < 4; ++mt)
            #pragma unroll
            for (int nt = 0; nt < 4; ++nt)
                #pragma unroll
                for (int r = 0; r < 4; ++r) {
                    int row = wm * 64 + mt * 16 + g * 4 + r;
                    int col = wn * 64 + nt * 16 + r16;
                    int off = (row << 8) + (((col << 1)) ^ ((row & 15) << 4));
                    *(ushort_t*)((char*)ybuf + off) = f2b(acc[mt][nt][r]);
                }
    }
    __syncthreads();   // ef writes visible before layer-3 reads

    // ---- layer 3: ef @ Wc1^T, dot Wc2 -> coord atomics ----
    #pragma unroll
    for (int mt = 0; mt < 4; ++mt)
        #pragma unroll
        for (int nt = 0; nt < 4; ++nt) acc[mt][nt] = (f32x4){0.f, 0.f, 0.f, 0.f};
    #pragma unroll
    for (int c = 0; c < 4; ++c) {
        short8v afr[4];
        #pragma unroll
        for (int mt = 0; mt < 4; ++mt) {
            int row = wm * 64 + mt * 16 + r16;
            afr[mt] = *(const short8v*)((const char*)ybuf + (row << 8) + ((c * 64 + g * 16) ^ (r16 << 4)));
        }
        #pragma unroll
        for (int mt = 0; mt < 4; ++mt)
            #pragma unroll
            for (int nt = 0; nt < 4; ++nt)
                acc[mt][nt] = MFMA16(afr[mt], b3_[nt][c], acc[mt][nt]);
    }
    {
        float q[4][4];
        #pragma unroll
        for (int mt = 0; mt < 4; ++mt)
            #pragma unroll
            for (int r = 0; r < 4; ++r) q[mt][r] = 0.f;
        #pragma unroll
        for (int mt = 0; mt < 4; ++mt)
            #pragma unroll
            for (int nt = 0; nt < 4; ++nt)
                #pragma unroll
                for (int r = 0; r < 4; ++r) {
                    int col = wn * 64 + nt * 16 + r16;
                    float v = fmaxf(acc[mt][nt][r] + bc1s[col], 0.f);
                    q[mt][r] += v * wc2s[col];
                }
        #pragma unroll
        for (int off = 1; off < 16; off <<= 1)
            #pragma unroll
            for (int mt = 0; mt < 4; ++mt)
                #pragma unroll
                for (int r = 0; r < 4; ++r) q[mt][r] += __shfl_xor(q[mt][r], off);
        if (r16 == 0) {
            #pragma unroll
            for (int mt = 0; mt < 4; ++mt)
                #pragma unroll
                for (int r = 0; r < 4; ++r)
                    pq[wn][wm * 64 + mt * 16 + g * 4 + r] = q[mt][r];
        }
        __syncthreads();
        if (wn == 0 && r16 == 0) {
            #pragma unroll
            for (int mt = 0; mt < 4; ++mt)
                #pragma unroll
                for (int r = 0; r < 4; ++r) {
                    int row = wm * 64 + mt * 16 + g * 4 + r;
                    float tv = pq[0][row] + pq[1][row];
                    int node = ej0s[row];
                    #pragma unroll
                    for (int c = 0; c < 3; ++c) {
                        float tr = cdp[row][c] * tv;
                        tr = fminf(fmaxf(tr, -100.f), 100.f);
                        atomicAdd(&ssum[node * 3 + c], tr);
                    }
                    atomicAdd(&cnt[node], 1.f);
                }
        }
    }
}

// 32-row x 128-col fp32 GEMM tile helper (node/xz/out kernels)
template<int KTOT, int LDX>
__device__ __forceinline__ void gemm32(const float* __restrict__ W, int ldw,
                                       float (*Ws)[129], float (*X)[LDX],
                                       int e0, int je, int tid, float acc[4][4])
{
    for (int k0 = 0; k0 < KTOT; k0 += 16) {
        __syncthreads();
        for (int idx = tid; idx < 16 * HD; idx += 256) {
            int j = idx >> 4, kk = idx & 15;
            Ws[kk][j] = W[j * ldw + k0 + kk];
        }
        __syncthreads();
        #pragma unroll
        for (int kk = 0; kk < 16; ++kk) {
            float xr[4], wr[4];
            #pragma unroll
            for (int i = 0; i < 4; ++i) xr[i] = X[e0 + i][k0 + kk];
            #pragma unroll
            for (int m = 0; m < 4; ++m) wr[m] = Ws[kk][je + 32 * m];
            #pragma unroll
            for (int i = 0; i < 4; ++i)
                #pragma unroll
                for (int m = 0; m < 4; ++m)
                    acc[i][m] = fmaf(xr[i], wr[m], acc[i][m]);
        }
    }
}

// ---------------- node MLP + layernorm + clip ----------------
__global__ __launch_bounds__(256) void node_kernel(
    const float* __restrict__ mi, const float* __restrict__ h,
    const float* __restrict__ Wn1, const float* __restrict__ bn1,
    const float* __restrict__ Wn2, const float* __restrict__ bn2,
    const float* __restrict__ lng, const float* __restrict__ lnb,
    float* __restrict__ xout)
{
    __shared__ float xs[32][259];
    __shared__ float ybuf[32][133];
    __shared__ float Ws[16][129];
    __shared__ float mu_s[32], rs_s[32];
    const int tid = threadIdx.x;
    const int nbase = blockIdx.x * 32;

    for (int idx = tid; idx < 32 * 256; idx += 256) {
        int n = idx >> 8, k = idx & 255;
        xs[n][k] = (k < HD) ? mi[(size_t)(nbase + n) * HD + k] : h[(size_t)(nbase + n) * HD + (k - HD)];
    }
    const int je = tid & 31;
    const int e0 = (tid >> 5) * 4;

    float acc[4][4];
    #pragma unroll
    for (int i = 0; i < 4; ++i)
        #pragma unroll
        for (int m = 0; m < 4; ++m) acc[i][m] = 0.f;
    gemm32<256, 259>(Wn1, 256, Ws, xs, e0, je, tid, acc);
    #pragma unroll
    for (int i = 0; i < 4; ++i)
        #pragma unroll
        for (int m = 0; m < 4; ++m)
            ybuf[e0 + i][je + 32 * m] = fmaxf(acc[i][m] + bn1[je + 32 * m], 0.f);

    float acc2[4][4];
    #pragma unroll
    for (int i = 0; i < 4; ++i)
        #pragma unroll
        for (int m = 0; m < 4; ++m) acc2[i][m] = 0.f;
    gemm32<128, 133>(Wn2, 128, Ws, ybuf, e0, je, tid, acc2);
    #pragma unroll
    for (int i = 0; i < 4; ++i)
        #pragma unroll
        for (int m = 0; m < 4; ++m)
            ybuf[e0 + i][je + 32 * m] = acc2[i][m] + bn2[je + 32 * m];
    __syncthreads();

    const int nl = tid >> 3, r = tid & 7;
    float s1 = 0.f, s2 = 0.f;
    #pragma unroll
    for (int k = r * 16; k < r * 16 + 16; ++k) { float v = ybuf[nl][k]; s1 += v; s2 += v * v; }
    #pragma unroll
    for (int off = 1; off < 8; off <<= 1) { s1 += __shfl_xor(s1, off); s2 += __shfl_xor(s2, off); }
    if (r == 0) {
        float mu = s1 * (1.f / HD);
        float var = s2 * (1.f / HD) - mu * mu;
        mu_s[nl] = mu;
        rs_s[nl] = rsqrtf(fmaxf(var, 0.f) + 1e-5f);
    }
    __syncthreads();
    for (int idx = tid; idx < 32 * HD; idx += 256) {
        int n = idx >> 7, j = idx & 127;
        float v = (ybuf[n][j] - mu_s[n]) * rs_s[n] * lng[j] + lnb[j];
        v = fminf(fmaxf(v, -10.f), 10.f);
        xout[(size_t)(nbase + n) * HD + j] = v;
    }
}

// ---------------- coord update ----------------
__global__ __launch_bounds__(256) void coord_kernel(
    const float* __restrict__ coord, const float* __restrict__ ssum,
    const float* __restrict__ cnt, float* __restrict__ outp)
{
    int idx = blockIdx.x * 256 + threadIdx.x;
    if (idx < NN * 3) {
        int n = idx / 3;
        outp[idx] = coord[idx] + ssum[idx] / fmaxf(cnt[n], 1.f);
    }
}

// ---------------- mamba in_proj ----------------
__global__ __launch_bounds__(256) void xz_kernel(
    const float* __restrict__ x, const float* __restrict__ Wip,
    float* __restrict__ u, float* __restrict__ zs)
{
    __shared__ float xs[32][130];
    __shared__ float Ws[16][257];
    const int tid = threadIdx.x;
    const int nbase = blockIdx.x * 32;
    for (int idx = tid; idx < 32 * HD; idx += 256) {
        int n = idx >> 7, k = idx & 127;
        xs[n][k] = x[(size_t)(nbase + n) * HD + k];
    }
    const int jj = tid & 63;
    const int n0 = (tid >> 6) * 8;
    float acc[8][4];
    #pragma unroll
    for (int i = 0; i < 8; ++i)
        #pragma unroll
        for (int m = 0; m < 4; ++m) acc[i][m] = 0.f;
    for (int k0 = 0; k0 < HD; k0 += 16) {
        __syncthreads();
        for (int idx = tid; idx < 16 * 256; idx += 256) {
            int j = idx >> 4, kk = idx & 15;
            Ws[kk][j] = Wip[j * HD + k0 + kk];
        }
        __syncthreads();
        #pragma unroll
        for (int kk = 0; kk < 16; ++kk) {
            float xr[8], wr[4];
            #pragma unroll
            for (int i = 0; i < 8; ++i) xr[i] = xs[n0 + i][k0 + kk];
            #pragma unroll
            for (int m = 0; m < 4; ++m) wr[m] = Ws[kk][jj + 64 * m];
            #pragma unroll
            for (int i = 0; i < 8; ++i)
                #pragma unroll
                for (int m = 0; m < 4; ++m)
                    acc[i][m] = fmaf(xr[i], wr[m], acc[i][m]);
        }
    }
    #pragma unroll
    for (int i = 0; i < 8; ++i)
        #pragma unroll
        for (int m = 0; m < 4; ++m) {
            int j = jj + 64 * m;
            size_t n = (size_t)(nbase + n0 + i);
            float v = acc[i][m];
            if (j < HD) u[n * HD + j] = v;
            else        zs[n * HD + (j - HD)] = v * sigf(v);
        }
}

// ---------------- causal depthwise conv + silu ----------------
__global__ __launch_bounds__(256) void conv_kernel(
    const float* __restrict__ u, const float* __restrict__ cw, const float* __restrict__ cb,
    float* __restrict__ uc)
{
    int idx = blockIdx.x * 256 + threadIdx.x;
    int n = idx >> 7, hh = idx & 127;
    float a = cb[hh];
    #pragma unroll
    for (int k = 0; k < 4; ++k) {
        int t = n - 3 + k;
        if (t >= 0) a = fmaf(u[t * HD + hh], cw[hh * 4 + k], a);
    }
    uc[idx] = a * sigf(a);
}

// ---------------- x_proj + dt_proj ----------------
__global__ __launch_bounds__(256) void xdbl_kernel(
    const float* __restrict__ uc, const float* __restrict__ Wxp,
    const float* __restrict__ Wdt, const float* __restrict__ bdt,
    float* __restrict__ dt, float* __restrict__ Bm, float* __restrict__ Cm)
{
    __shared__ float xs[16][130];
    __shared__ float xd8[16][9];
    const int tid = threadIdx.x;
    const int nbase = blockIdx.x * 16;
    for (int idx = tid; idx < 16 * HD; idx += 256) {
        int n = idx >> 7, k = idx & 127;
        xs[n][k] = uc[(size_t)(nbase + n) * HD + k];
    }
    __syncthreads();
    const int nl = tid >> 4, jj = tid & 15;
    #pragma unroll
    for (int rep = 0; rep < 9; ++rep) {
        int j = jj + rep * 16;
        if (j < 136) {
            float a = 0.f;
            for (int k = 0; k < HD; ++k) a = fmaf(xs[nl][k], Wxp[j * HD + k], a);
            int n = nbase + nl;
            if (j < 8)       xd8[nl][j] = a;
            else if (j < 72) Bm[(size_t)n * 64 + (j - 8)] = a;
            else             Cm[(size_t)n * 64 + (j - 72)] = a;
        }
    }
    __syncthreads();
    #pragma unroll
    for (int q = 0; q < 8; ++q) {
        int hh = jj * 8 + q;
        float a = bdt[hh];
        #pragma unroll
        for (int r2 = 0; r2 < 8; ++r2) a = fmaf(xd8[nl][r2], Wdt[hh * 8 + r2], a);
        float sp = (a > 20.f) ? a : log1pf(__expf(a));
        dt[(size_t)(nbase + nl) * HD + hh] = sp;
    }
}

// ---------------- chunked SSM scan ----------------
__global__ __launch_bounds__(256) void scan1_kernel(
    const float* __restrict__ dt, const float* __restrict__ uc,
    const float* __restrict__ Bm, const float* __restrict__ Alog,
    float* __restrict__ cP, float* __restrict__ cS)
{
    int g = blockIdx.x * 256 + threadIdx.x;
    int c = g >> 13;
    int r = g & 8191;
    int hh = r >> 6;
    int d = r & 63;
    float A = -__expf(Alog[hh * 64 + d]);
    float P = 1.f, S = 0.f;
    int t0 = c * CS;
    for (int t = t0; t < t0 + CS; ++t) {
        float dtv = dt[t * HD + hh];
        float a = __expf(dtv * A);
        float bv = Bm[t * 64 + d];
        float uv = uc[t * HD + hh];
        P *= a;
        S = fmaf(a, S, dtv * uv * bv);
    }
    cP[g] = P; cS[g] = S;
}

__global__ __launch_bounds__(256) void scan2_kernel(
    const float* __restrict__ cP, const float* __restrict__ cS, float* __restrict__ cI)
{
    int g = blockIdx.x * 256 + threadIdx.x;
    float S = 0.f;
    for (int c = 0; c < NC; ++c) {
        cI[c * 8192 + g] = S;
        S = fmaf(cP[c * 8192 + g], S, cS[c * 8192 + g]);
    }
}

__global__ __launch_bounds__(256) void scan3_kernel(
    const float* __restrict__ dt, const float* __restrict__ uc,
    const float* __restrict__ Bm, const float* __restrict__ Cm,
    const float* __restrict__ Alog, const float* __restrict__ Dskip,
    const float* __restrict__ cI, float* __restrict__ y)
{
    int g = blockIdx.x * 256 + threadIdx.x;
    int c = g >> 13;
    int r = g & 8191;
    int hh = r >> 6;
    int d = r & 63;
    float A = -__expf(Alog[hh * 64 + d]);
    float s = cI[g];
    float Dh = Dskip[hh];
    int t0 = c * CS;
    for (int t = t0; t < t0 + CS; ++t) {
        float dtv = dt[t * HD + hh];
        float a = __expf(dtv * A);
        float uv = uc[t * HD + hh];
        s = fmaf(a, s, dtv * uv * Bm[t * 64 + d]);
        float yp = s * Cm[t * 64 + d];
        #pragma unroll
        for (int off = 1; off < 64; off <<= 1) yp += __shfl_xor(yp, off);
        if (d == 0) y[t * HD + hh] = yp + Dh * uv;
    }
}

// ---------------- out_proj ----------------
__global__ __launch_bounds__(256) void out_kernel(
    const float* __restrict__ y, const float* __restrict__ zs,
    const float* __restrict__ Wop, float* __restrict__ outp)
{
    __shared__ float xs[32][130];
    __shared__ float Ws[16][129];
    const int tid = threadIdx.x;
    const int nbase = blockIdx.x * 32;
    for (int idx = tid; idx < 32 * HD; idx += 256) {
        int n = idx >> 7, k = idx & 127;
        size_t gn = (size_t)(nbase + n);
        xs[n][k] = y[gn * HD + k] * zs[gn * HD + k];
    }
    const int je = tid & 31;
    const int e0 = (tid >> 5) * 4;
    float acc[4][4];
    #pragma unroll
    for (int i = 0; i < 4; ++i)
        #pragma unroll
        for (int m = 0; m < 4; ++m) acc[i][m] = 0.f;
    gemm32<128, 130>(Wop, 128, Ws, xs, e0, je, tid, acc);
    #pragma unroll
    for (int i = 0; i < 4; ++i)
        #pragma unroll
        for (int m = 0; m < 4; ++m)
            outp[(size_t)(nbase + e0 + i) * HD + je + 32 * m] = acc[i][m];
}

extern "C" void kernel_launch(void* const* d_in, const int* in_sizes, int n_in,
                              void* d_out, int out_size, void* d_ws, size_t ws_size,
                              hipStream_t stream)
{
    const float* h     = (const float*)d_in[0];
    const float* coord = (const float*)d_in[1];
    const int*   ei    = (const int*)d_in[2];
    const float* We1   = (const float*)d_in[3];
    const float* be1   = (const float*)d_in[4];
    const float* We2   = (const float*)d_in[5];
    const float* be2   = (const float*)d_in[6];
    const float* watt  = (const float*)d_in[7];
    const float* batt  = (const float*)d_in[8];
    const float* Wn1   = (const float*)d_in[9];
    const float* bn1   = (const float*)d_in[10];
    const float* Wn2   = (const float*)d_in[11];
    const float* bn2   = (const float*)d_in[12];
    const float* Wc1   = (const float*)d_in[13];
    const float* bc1   = (const float*)d_in[14];
    const float* Wc2   = (const float*)d_in[15];
    const float* lng   = (const float*)d_in[16];
    const float* lnb   = (const float*)d_in[17];
    const float* Wip   = (const float*)d_in[18];
    const float* convw = (const float*)d_in[19];
    const float* convb = (const float*)d_in[20];
    const float* Wxp   = (const float*)d_in[21];
    const float* Wdt   = (const float*)d_in[22];
    const float* bdt   = (const float*)d_in[23];
    const float* Alog  = (const float*)d_in[24];
    const float* Dskip = (const float*)d_in[25];
    const float* Wop   = (const float*)d_in[26];

    float* ws   = (float*)d_ws;
    float* mi   = ws;                                  // NN*HD   (zeroed)
    float* ssum = mi   + (size_t)NN * HD;              // NN*3    (zeroed)
    float* cnt  = ssum + (size_t)NN * 3;               // NN      (zeroed)
    float* xbuf = cnt  + NN;                           // NN*HD   (hn; later dt)
    float* zsb  = xbuf + (size_t)NN * HD;              // NN*HD
    float* ubuf = zsb  + (size_t)NN * HD;              // NN*HD   u; later B|C
    float* ucb  = ubuf + (size_t)NN * HD;              // NN*HD
    float* cP   = ucb  + (size_t)NN * HD;              // NC*8192
    float* cSb  = cP   + (size_t)NC * 8192;
    float* cIb  = cSb  + (size_t)NC * 8192;
    float* bfb  = cIb  + (size_t)NC * 8192;            // bf16 region
    ushort_t* hbp   = (ushort_t*)bfb;                  // NN*HD bf16
    ushort_t* W12bp = hbp + (size_t)NN * HD;           // 256*128
    ushort_t* We2bp = W12bp + 256 * 128;               // 128*128
    ushort_t* Wc1bp = We2bp + 128 * 128;               // 128*128
    ushort_t* P12bp = (ushort_t*)cP;                   // NN*256 bf16 (10.24MB, aliases cP/cS: free until scan1)
    float* dtb  = xbuf;
    float* Bm   = ubuf;
    float* Cm   = ubuf + (size_t)NN * 64;

    float* outp     = (float*)d_out;
    float* yb       = outp;
    float* coordout = outp + (size_t)NN * HD;

    hipMemsetAsync(ws, 0, sizeof(float) * (size_t)NN * (HD + 4), stream);

    prep_kernel<<<(NN * HD) / 256, 256, 0, stream>>>(h, We1, We2, Wc1, hbp, W12bp, We2bp, Wc1bp);
    p12_kernel<<<(NN + 127) / 128, 256, 0, stream>>>(hbp, W12bp, P12bp);
    edge_mfma<<<EE / 128, 256, 0, stream>>>(P12bp, coord, ei, We1, be1,
                                            We2bp, be2, watt, batt, Wc1bp, bc1, Wc2,
                                            mi, ssum, cnt);
    node_kernel<<<NN / 32, 256, 0, stream>>>(mi, h, Wn1, bn1, Wn2, bn2, lng, lnb, xbuf);
    coord_kernel<<<(NN * 3 + 255) / 256, 256, 0, stream>>>(coord, ssum, cnt, coordout);
    xz_kernel<<<NN / 32, 256, 0, stream>>>(xbuf, Wip, ubuf, zsb);
    conv_kernel<<<NN * HD / 256, 256, 0, stream>>>(ubuf, convw, convb, ucb);
    xdbl_kernel<<<NN / 16, 256, 0, stream>>>(ucb, Wxp, Wdt, bdt, dtb, Bm, Cm);
    scan1_kernel<<<NC * 8192 / 256, 256, 0, stream>>>(dtb, ucb, Bm, Alog, cP, cSb);
    scan2_kernel<<<8192 / 256, 256, 0, stream>>>(cP, cSb, cIb);
    scan3_kernel<<<NC * 8192 / 256, 256, 0, stream>>>(dtb, ucb, Bm, Cm, Alog, Dskip, cIb, yb);
    out_kernel<<<NN / 32, 256, 0, stream>>>(yb, zsb, Wop, outp);
}

// Round 5
// 1009.277 us; speedup vs baseline: 3.0188x; 1.0619x over previous
//
#include <hip/hip_runtime.h>
#include <math.h>

#define NN 20000
#define EE 640000
#define HD 128
#define NC 160      // scan chunks
#define CS 125      // chunk size: NC*CS == NN

typedef unsigned short ushort_t;
typedef __attribute__((ext_vector_type(8))) short short8v;
typedef __attribute__((ext_vector_type(4))) float f32x4;

#define MFMA16(a,b,c) __builtin_amdgcn_mfma_f32_16x16x32_bf16(a,b,c,0,0,0)

__device__ __forceinline__ float sigf(float x) { return 1.0f / (1.0f + __expf(-x)); }

__device__ __forceinline__ ushort_t f2b(float x) {
    unsigned u = __builtin_bit_cast(unsigned, x);
    unsigned r = (u + 0x7FFFu + ((u >> 16) & 1u)) >> 16;
    return (ushort_t)r;
}
__device__ __forceinline__ float b2f(ushort_t u) {
    unsigned v = ((unsigned)u) << 16;
    return __builtin_bit_cast(float, v);
}

// ---------------- counting sort of edges by e0 ----------------
__global__ __launch_bounds__(256) void hist_kernel(const int* __restrict__ ei,
                                                   int* __restrict__ histI)
{
    int i = blockIdx.x * 256 + threadIdx.x;
    if (i < EE) atomicAdd(&histI[ei[i]], 1);
}

__global__ __launch_bounds__(256) void prefix_kernel(const int* __restrict__ hist,
                                                     int* __restrict__ baseI)
{
    __shared__ int wsum[4];
    __shared__ int carry;
    const int tid = threadIdx.x;
    const int lane = tid & 63, wid = tid >> 6;
    if (tid == 0) carry = 0;
    __syncthreads();
    for (int c0 = 0; c0 < NN; c0 += 256) {
        int i = c0 + tid;
        int v = (i < NN) ? hist[i] : 0;
        int orig = v;
        #pragma unroll
        for (int off = 1; off < 64; off <<= 1) {
            int t = __shfl_up(v, off);
            if (lane >= off) v += t;
        }
        if (lane == 63) wsum[wid] = v;
        __syncthreads();
        if (tid == 0) {
            int s = 0;
            #pragma unroll
            for (int w = 0; w < 4; ++w) { int t = wsum[w]; wsum[w] = s; s += t; }
        }
        __syncthreads();
        int incl = v + wsum[wid] + carry;
        if (i < NN) baseI[i] = incl - orig;   // exclusive prefix
        __syncthreads();
        if (tid == 255) carry = incl;
        __syncthreads();
    }
}

__global__ __launch_bounds__(256) void scatter_kernel(const int* __restrict__ ei,
                                                      const int* __restrict__ baseI,
                                                      int* __restrict__ cursor,
                                                      int* __restrict__ perm)
{
    int i = blockIdx.x * 256 + threadIdx.x;
    if (i < EE) {
        int n = ei[i];
        int p = baseI[n] + atomicAdd(&cursor[n], 1);
        perm[p] = i;
    }
}

// ---------------- prep: bf16 conversions ----------------
__global__ __launch_bounds__(256) void prep_kernel(
    const float* __restrict__ h, const float* __restrict__ We1,
    const float* __restrict__ We2, const float* __restrict__ Wc1,
    ushort_t* __restrict__ hb, ushort_t* __restrict__ W12b,
    ushort_t* __restrict__ We2b, ushort_t* __restrict__ Wc1b)
{
    int i = blockIdx.x * 256 + threadIdx.x;
    if (i < NN * HD) hb[i] = f2b(h[i]);
    if (i < 256 * 128) {
        int j = i >> 7, k = i & 127;
        W12b[i] = f2b(We1[(j & 127) * 257 + ((j >> 7) << 7) + k]);
    }
    if (i < 128 * 128) { We2b[i] = f2b(We2[i]); Wc1b[i] = f2b(Wc1[i]); }
}

// ---------------- node projections: P12 = h @ [W1a|W1b]^T ----------------
__global__ __launch_bounds__(256) void p12_kernel(
    const ushort_t* __restrict__ hb, const ushort_t* __restrict__ W12b,
    ushort_t* __restrict__ P12b)
{
    const int tid = threadIdx.x;
    const int lane = tid & 63;
    const int wid = tid >> 6;
    const int wm = wid >> 1, wn = wid & 1;
    const int g = lane >> 4, r16 = lane & 15;
    const int rbase = blockIdx.x * 128 + wm * 64;

    f32x4 acc[4][8];
    #pragma unroll
    for (int mt = 0; mt < 4; ++mt)
        #pragma unroll
        for (int nt = 0; nt < 8; ++nt) acc[mt][nt] = (f32x4){0.f, 0.f, 0.f, 0.f};

    for (int c = 0; c < 4; ++c) {
        short8v afr[4], bfr[8];
        #pragma unroll
        for (int mt = 0; mt < 4; ++mt) {
            int row = rbase + mt * 16 + r16;
            if (row > NN - 1) row = NN - 1;
            afr[mt] = *(const short8v*)(hb + (size_t)row * HD + c * 32 + g * 8);
        }
        #pragma unroll
        for (int nt = 0; nt < 8; ++nt)
            bfr[nt] = *(const short8v*)(W12b + (size_t)(wn * 128 + nt * 16 + r16) * 128 + c * 32 + g * 8);
        #pragma unroll
        for (int mt = 0; mt < 4; ++mt)
            #pragma unroll
            for (int nt = 0; nt < 8; ++nt)
                acc[mt][nt] = MFMA16(afr[mt], bfr[nt], acc[mt][nt]);
    }
    #pragma unroll
    for (int mt = 0; mt < 4; ++mt)
        #pragma unroll
        for (int nt = 0; nt < 8; ++nt)
            #pragma unroll
            for (int r = 0; r < 4; ++r) {
                int row = rbase + mt * 16 + g * 4 + r;
                if (row < NN)
                    P12b[(size_t)row * 256 + wn * 128 + nt * 16 + r16] = f2b(acc[mt][nt][r]);
            }
}

// ---------------- edge phase (MFMA bf16, sorted edges, segment-aggregated sums) -------------
__global__ __launch_bounds__(256) void edge_mfma(
    const ushort_t* __restrict__ P12b, const float* __restrict__ coord,
    const int* __restrict__ ei, const int* __restrict__ perm,
    const float* __restrict__ We1, const float* __restrict__ be1,
    const ushort_t* __restrict__ We2b, const float* __restrict__ be2,
    const float* __restrict__ watt, const float* __restrict__ batt,
    const ushort_t* __restrict__ Wc1b, const float* __restrict__ bc1,
    const float* __restrict__ Wc2,
    float* __restrict__ mi, float* __restrict__ ssum)
{
    __shared__ ushort_t ybuf[128 * 128];   // 32KB, swizzled: byte = (row<<8) + ((col*2) ^ ((row&15)<<4))
    __shared__ float rad[128];
    __shared__ float cdp[128][3];
    __shared__ float wcols[128], be1s[128], be2s[128], bc1s[128], watts[128], wc2s[128];
    __shared__ float pq[2][128];
    __shared__ int ej0s[128], ej1s[128];

    const int tid = threadIdx.x;
    const int ebase = blockIdx.x * 128;
    const int lane = tid & 63;
    const int wid = tid >> 6;
    const int wm = wid >> 1, wn = wid & 1;
    const int g = lane >> 4, r16 = lane & 15;
    const float batt0 = batt[0];

    if (tid < 128) {
        int eg = perm[ebase + tid];
        ej0s[tid] = ei[eg];
    } else {
        int t = tid - 128;
        int eg = perm[ebase + t];
        ej1s[t] = ei[EE + eg];
        wcols[t] = We1[t * 257 + 256];
        be1s[t] = be1[t]; be2s[t] = be2[t]; bc1s[t] = bc1[t];
        watts[t] = watt[t]; wc2s[t] = Wc2[t];
    }
    __syncthreads();

    // preload layer-2 weight fragments into registers
    short8v b2_[4][4];
    {
        const ushort_t* W2p = We2b + (size_t)(wn * 64 + r16) * 128 + g * 8;
        #pragma unroll
        for (int nt = 0; nt < 4; ++nt)
            #pragma unroll
            for (int c = 0; c < 4; ++c)
                b2_[nt][c] = *(const short8v*)(W2p + nt * 2048 + c * 32);
    }

    if (tid < 128) {
        int a = ej0s[tid], b = ej1s[tid];
        float rr = 0.f;
        #pragma unroll
        for (int c = 0; c < 3; ++c) {
            float d = coord[a * 3 + c] - coord[b * 3 + c];
            cdp[tid][c] = d; rr += d * d;
        }
        rad[tid] = rr;
    }
    __syncthreads();

    // ---- phase A: y1 = relu(P1[e1] + P2[e0] + rad*wcol + be1) -> ybuf ----
    {
        const int e = tid >> 1, hf = tid & 1;
        const int n1 = ej1s[e], n0 = ej0s[e];
        const ushort_t* p1 = P12b + (size_t)n1 * 256 + hf * 64;
        const ushort_t* p2 = P12b + (size_t)n0 * 256 + 128 + hf * 64;
        const float radv = rad[e];
        const int colbase = hf * 64;
        #pragma unroll
        for (int q = 0; q < 8; ++q) {
            short8v a = *(const short8v*)(p1 + q * 8);
            short8v b = *(const short8v*)(p2 + q * 8);
            short8v ov;
            #pragma unroll
            for (int jj = 0; jj < 8; ++jj) {
                int col = colbase + q * 8 + jj;
                float v = b2f((ushort_t)a[jj]) + b2f((ushort_t)b[jj]) + radv * wcols[col] + be1s[col];
                ov[jj] = (short)f2b(fmaxf(v, 0.f));
            }
            int off = (e << 8) + ((colbase * 2 + q * 16) ^ ((e & 15) << 4));
            *(short8v*)((char*)ybuf + off) = ov;
        }
    }
    __syncthreads();

    // ---- layer 2: y1 @ We2^T ----
    f32x4 acc[4][4];
    #pragma unroll
    for (int mt = 0; mt < 4; ++mt)
        #pragma unroll
        for (int nt = 0; nt < 4; ++nt) acc[mt][nt] = (f32x4){0.f, 0.f, 0.f, 0.f};
    #pragma unroll
    for (int c = 0; c < 4; ++c) {
        short8v afr[4];
        #pragma unroll
        for (int mt = 0; mt < 4; ++mt) {
            int row = wm * 64 + mt * 16 + r16;
            afr[mt] = *(const short8v*)((const char*)ybuf + (row << 8) + ((c * 64 + g * 16) ^ (r16 << 4)));
        }
        #pragma unroll
        for (int mt = 0; mt < 4; ++mt)
            #pragma unroll
            for (int nt = 0; nt < 4; ++nt)
                acc[mt][nt] = MFMA16(afr[mt], b2_[nt][c], acc[mt][nt]);
    }

    // preload layer-3 weights
    short8v b3_[4][4];
    {
        const ushort_t* W3p = Wc1b + (size_t)(wn * 64 + r16) * 128 + g * 8;
        #pragma unroll
        for (int nt = 0; nt < 4; ++nt)
            #pragma unroll
            for (int c = 0; c < 4; ++c)
                b3_[nt][c] = *(const short8v*)(W3p + nt * 2048 + c * 32);
    }

    // epilogue 2: mij = relu(+be2); att = sigmoid(mij.watt + batt); ef = mij*att -> ybuf
    {
        float p[4][4];
        #pragma unroll
        for (int mt = 0; mt < 4; ++mt)
            #pragma unroll
            for (int r = 0; r < 4; ++r) p[mt][r] = 0.f;
        #pragma unroll
        for (int mt = 0; mt < 4; ++mt)
            #pragma unroll
            for (int nt = 0; nt < 4; ++nt)
                #pragma unroll
                for (int r = 0; r < 4; ++r) {
                    int col = wn * 64 + nt * 16 + r16;
                    float v = fmaxf(acc[mt][nt][r] + be2s[col], 0.f);
                    acc[mt][nt][r] = v;
                    p[mt][r] += v * watts[col];
                }
        #pragma unroll
        for (int off = 1; off < 16; off <<= 1)
            #pragma unroll
            for (int mt = 0; mt < 4; ++mt)
                #pragma unroll
                for (int r = 0; r < 4; ++r) p[mt][r] += __shfl_xor(p[mt][r], off);
        if (r16 == 0) {
            #pragma unroll
            for (int mt = 0; mt < 4; ++mt)
                #pragma unroll
                for (int r = 0; r < 4; ++r)
                    pq[wn][wm * 64 + mt * 16 + g * 4 + r] = p[mt][r];
        }
        __syncthreads();
        float att[4][4];
        #pragma unroll
        for (int mt = 0; mt < 4; ++mt)
            #pragma unroll
            for (int r = 0; r < 4; ++r) {
                int row = wm * 64 + mt * 16 + g * 4 + r;
                att[mt][r] = sigf(pq[0][row] + pq[1][row] + batt0);
            }
        __syncthreads();   // layer-2 ybuf reads + pq reads done -> safe to overwrite ybuf
        #pragma unroll
        for (int mt = 0; mt < 4; ++mt)
            #pragma unroll
            for (int nt = 0; nt < 4; ++nt)
                #pragma unroll
                for (int r = 0; r < 4; ++r) {
                    int row = wm * 64 + mt * 16 + g * 4 + r;
                    int col = wn * 64 + nt * 16 + r16;
                    int off = (row << 8) + (((col << 1)) ^ ((row & 15) << 4));
                    *(ushort_t*)((char*)ybuf + off) = f2b(acc[mt][nt][r] * att[mt][r]);
                }
    }
    __syncthreads();   // ef visible to all

    // ---- segment-sum ef over sorted e0 runs -> mi (few atomics per block) ----
    {
        const int col = tid & 127, half = tid >> 7;
        const int r0 = half * 64, r1 = r0 + 64;
        float sacc = 0.f; int cur = ej0s[r0];
        for (int r = r0; r < r1; ++r) {
            int node = ej0s[r];
            if (node != cur) {
                atomicAdd(&mi[(size_t)cur * HD + col], sacc);
                sacc = 0.f; cur = node;
            }
            int off = (r << 8) + (((col << 1)) ^ ((r & 15) << 4));
            sacc += b2f(*(const ushort_t*)((const char*)ybuf + off));
        }
        atomicAdd(&mi[(size_t)cur * HD + col], sacc);
    }

    // ---- layer 3: ef @ Wc1^T, dot Wc2 ----
    #pragma unroll
    for (int mt = 0; mt < 4; ++mt)
        #pragma unroll
        for (int nt = 0; nt < 4; ++nt) acc[mt][nt] = (f32x4){0.f, 0.f, 0.f, 0.f};
    #pragma unroll
    for (int c = 0; c < 4; ++c) {
        short8v afr[4];
        #pragma unroll
        for (int mt = 0; mt < 4; ++mt) {
            int row = wm * 64 + mt * 16 + r16;
            afr[mt] = *(const short8v*)((const char*)ybuf + (row << 8) + ((c * 64 + g * 16) ^ (r16 << 4)));
        }
        #pragma unroll
        for (int mt = 0; mt < 4; ++mt)
            #pragma unroll
            for (int nt = 0; nt < 4; ++nt)
                acc[mt][nt] = MFMA16(afr[mt], b3_[nt][c], acc[mt][nt]);
    }
    {
        float q[4][4];
        #pragma unroll
        for (int mt = 0; mt < 4; ++mt)
            #pragma unroll
            for (int r = 0; r < 4; ++r) q[mt][r] = 0.f;
        #pragma unroll
        for (int mt = 0; mt < 4; ++mt)
            #pragma unroll
            for (int nt = 0; nt < 4; ++nt)
                #pragma unroll
                for (int r = 0; r < 4; ++r) {
                    int col = wn * 64 + nt * 16 + r16;
                    float v = fmaxf(acc[mt][nt][r] + bc1s[col], 0.f);
                    q[mt][r] += v * wc2s[col];
                }
        #pragma unroll
        for (int off = 1; off < 16; off <<= 1)
            #pragma unroll
            for (int mt = 0; mt < 4; ++mt)
                #pragma unroll
                for (int r = 0; r < 4; ++r) q[mt][r] += __shfl_xor(q[mt][r], off);
        if (r16 == 0) {
            #pragma unroll
            for (int mt = 0; mt < 4; ++mt)
                #pragma unroll
                for (int r = 0; r < 4; ++r)
                    pq[wn][wm * 64 + mt * 16 + g * 4 + r] = q[mt][r];
        }
        __syncthreads();
        // segment-sum of clipped trans over sorted e0 runs (6 lanes)
        if (tid < 6) {
            int c = tid % 3, half = tid / 3;
            int r0 = half * 64, r1 = r0 + 64;
            float sacc = 0.f; int cur = ej0s[r0];
            for (int r = r0; r < r1; ++r) {
                int node = ej0s[r];
                if (node != cur) {
                    atomicAdd(&ssum[cur * 3 + c], sacc);
                    sacc = 0.f; cur = node;
                }
                float tv = pq[0][r] + pq[1][r];
                float tr = cdp[r][c] * tv;
                tr = fminf(fmaxf(tr, -100.f), 100.f);
                sacc += tr;
            }
            atomicAdd(&ssum[cur * 3 + c], sacc);
        }
    }
}

// 32-row x 128-col fp32 GEMM tile helper (node/xz/out kernels)
template<int KTOT, int LDX>
__device__ __forceinline__ void gemm32(const float* __restrict__ W, int ldw,
                                       float (*Ws)[129], float (*X)[LDX],
                                       int e0, int je, int tid, float acc[4][4])
{
    for (int k0 = 0; k0 < KTOT; k0 += 16) {
        __syncthreads();
        for (int idx = tid; idx < 16 * HD; idx += 256) {
            int j = idx >> 4, kk = idx & 15;
            Ws[kk][j] = W[j * ldw + k0 + kk];
        }
        __syncthreads();
        #pragma unroll
        for (int kk = 0; kk < 16; ++kk) {
            float xr[4], wr[4];
            #pragma unroll
            for (int i = 0; i < 4; ++i) xr[i] = X[e0 + i][k0 + kk];
            #pragma unroll
            for (int m = 0; m < 4; ++m) wr[m] = Ws[kk][je + 32 * m];
            #pragma unroll
            for (int i = 0; i < 4; ++i)
                #pragma unroll
                for (int m = 0; m < 4; ++m)
                    acc[i][m] = fmaf(xr[i], wr[m], acc[i][m]);
        }
    }
}

// ---------------- node MLP + layernorm + clip ----------------
__global__ __launch_bounds__(256) void node_kernel(
    const float* __restrict__ mi, const float* __restrict__ h,
    const float* __restrict__ Wn1, const float* __restrict__ bn1,
    const float* __restrict__ Wn2, const float* __restrict__ bn2,
    const float* __restrict__ lng, const float* __restrict__ lnb,
    float* __restrict__ xout)
{
    __shared__ float xs[32][259];
    __shared__ float ybuf[32][133];
    __shared__ float Ws[16][129];
    __shared__ float mu_s[32], rs_s[32];
    const int tid = threadIdx.x;
    const int nbase = blockIdx.x * 32;

    for (int idx = tid; idx < 32 * 256; idx += 256) {
        int n = idx >> 8, k = idx & 255;
        xs[n][k] = (k < HD) ? mi[(size_t)(nbase + n) * HD + k] : h[(size_t)(nbase + n) * HD + (k - HD)];
    }
    const int je = tid & 31;
    const int e0 = (tid >> 5) * 4;

    float acc[4][4];
    #pragma unroll
    for (int i = 0; i < 4; ++i)
        #pragma unroll
        for (int m = 0; m < 4; ++m) acc[i][m] = 0.f;
    gemm32<256, 259>(Wn1, 256, Ws, xs, e0, je, tid, acc);
    #pragma unroll
    for (int i = 0; i < 4; ++i)
        #pragma unroll
        for (int m = 0; m < 4; ++m)
            ybuf[e0 + i][je + 32 * m] = fmaxf(acc[i][m] + bn1[je + 32 * m], 0.f);

    float acc2[4][4];
    #pragma unroll
    for (int i = 0; i < 4; ++i)
        #pragma unroll
        for (int m = 0; m < 4; ++m) acc2[i][m] = 0.f;
    gemm32<128, 133>(Wn2, 128, Ws, ybuf, e0, je, tid, acc2);
    #pragma unroll
    for (int i = 0; i < 4; ++i)
        #pragma unroll
        for (int m = 0; m < 4; ++m)
            ybuf[e0 + i][je + 32 * m] = acc2[i][m] + bn2[je + 32 * m];
    __syncthreads();

    const int nl = tid >> 3, r = tid & 7;
    float s1 = 0.f, s2 = 0.f;
    #pragma unroll
    for (int k = r * 16; k < r * 16 + 16; ++k) { float v = ybuf[nl][k]; s1 += v; s2 += v * v; }
    #pragma unroll
    for (int off = 1; off < 8; off <<= 1) { s1 += __shfl_xor(s1, off); s2 += __shfl_xor(s2, off); }
    if (r == 0) {
        float mu = s1 * (1.f / HD);
        float var = s2 * (1.f / HD) - mu * mu;
        mu_s[nl] = mu;
        rs_s[nl] = rsqrtf(fmaxf(var, 0.f) + 1e-5f);
    }
    __syncthreads();
    for (int idx = tid; idx < 32 * HD; idx += 256) {
        int n = idx >> 7, j = idx & 127;
        float v = (ybuf[n][j] - mu_s[n]) * rs_s[n] * lng[j] + lnb[j];
        v = fminf(fmaxf(v, -10.f), 10.f);
        xout[(size_t)(nbase + n) * HD + j] = v;
    }
}

// ---------------- coord update (cnt from histogram) ----------------
__global__ __launch_bounds__(256) void coord_kernel(
    const float* __restrict__ coord, const float* __restrict__ ssum,
    const int* __restrict__ histI, float* __restrict__ outp)
{
    int idx = blockIdx.x * 256 + threadIdx.x;
    if (idx < NN * 3) {
        int n = idx / 3;
        float c = (float)histI[n];
        outp[idx] = coord[idx] + ssum[idx] / fmaxf(c, 1.f);
    }
}

// ---------------- mamba in_proj ----------------
__global__ __launch_bounds__(256) void xz_kernel(
    const float* __restrict__ x, const float* __restrict__ Wip,
    float* __restrict__ u, float* __restrict__ zs)
{
    __shared__ float xs[32][130];
    __shared__ float Ws[16][257];
    const int tid = threadIdx.x;
    const int nbase = blockIdx.x * 32;
    for (int idx = tid; idx < 32 * HD; idx += 256) {
        int n = idx >> 7, k = idx & 127;
        xs[n][k] = x[(size_t)(nbase + n) * HD + k];
    }
    const int jj = tid & 63;
    const int n0 = (tid >> 6) * 8;
    float acc[8][4];
    #pragma unroll
    for (int i = 0; i < 8; ++i)
        #pragma unroll
        for (int m = 0; m < 4; ++m) acc[i][m] = 0.f;
    for (int k0 = 0; k0 < HD; k0 += 16) {
        __syncthreads();
        for (int idx = tid; idx < 16 * 256; idx += 256) {
            int j = idx >> 4, kk = idx & 15;
            Ws[kk][j] = Wip[j * HD + k0 + kk];
        }
        __syncthreads();
        #pragma unroll
        for (int kk = 0; kk < 16; ++kk) {
            float xr[8], wr[4];
            #pragma unroll
            for (int i = 0; i < 8; ++i) xr[i] = xs[n0 + i][k0 + kk];
            #pragma unroll
            for (int m = 0; m < 4; ++m) wr[m] = Ws[kk][jj + 64 * m];
            #pragma unroll
            for (int i = 0; i < 8; ++i)
                #pragma unroll
                for (int m = 0; m < 4; ++m)
                    acc[i][m] = fmaf(xr[i], wr[m], acc[i][m]);
        }
    }
    #pragma unroll
    for (int i = 0; i < 8; ++i)
        #pragma unroll
        for (int m = 0; m < 4; ++m) {
            int j = jj + 64 * m;
            size_t n = (size_t)(nbase + n0 + i);
            float v = acc[i][m];
            if (j < HD) u[n * HD + j] = v;
            else        zs[n * HD + (j - HD)] = v * sigf(v);
        }
}

// ---------------- causal depthwise conv + silu ----------------
__global__ __launch_bounds__(256) void conv_kernel(
    const float* __restrict__ u, const float* __restrict__ cw, const float* __restrict__ cb,
    float* __restrict__ uc)
{
    int idx = blockIdx.x * 256 + threadIdx.x;
    int n = idx >> 7, hh = idx & 127;
    float a = cb[hh];
    #pragma unroll
    for (int k = 0; k < 4; ++k) {
        int t = n - 3 + k;
        if (t >= 0) a = fmaf(u[t * HD + hh], cw[hh * 4 + k], a);
    }
    uc[idx] = a * sigf(a);
}

// ---------------- x_proj + dt_proj ----------------
__global__ __launch_bounds__(256) void xdbl_kernel(
    const float* __restrict__ uc, const float* __restrict__ Wxp,
    const float* __restrict__ Wdt, const float* __restrict__ bdt,
    float* __restrict__ dt, float* __restrict__ Bm, float* __restrict__ Cm)
{
    __shared__ float xs[16][130];
    __shared__ float xd8[16][9];
    const int tid = threadIdx.x;
    const int nbase = blockIdx.x * 16;
    for (int idx = tid; idx < 16 * HD; idx += 256) {
        int n = idx >> 7, k = idx & 127;
        xs[n][k] = uc[(size_t)(nbase + n) * HD + k];
    }
    __syncthreads();
    const int nl = tid >> 4, jj = tid & 15;
    #pragma unroll
    for (int rep = 0; rep < 9; ++rep) {
        int j = jj + rep * 16;
        if (j < 136) {
            float a = 0.f;
            for (int k = 0; k < HD; ++k) a = fmaf(xs[nl][k], Wxp[j * HD + k], a);
            int n = nbase + nl;
            if (j < 8)       xd8[nl][j] = a;
            else if (j < 72) Bm[(size_t)n * 64 + (j - 8)] = a;
            else             Cm[(size_t)n * 64 + (j - 72)] = a;
        }
    }
    __syncthreads();
    #pragma unroll
    for (int q = 0; q < 8; ++q) {
        int hh = jj * 8 + q;
        float a = bdt[hh];
        #pragma unroll
        for (int r2 = 0; r2 < 8; ++r2) a = fmaf(xd8[nl][r2], Wdt[hh * 8 + r2], a);
        float sp = (a > 20.f) ? a : log1pf(__expf(a));
        dt[(size_t)(nbase + nl) * HD + hh] = sp;
    }
}

// ---------------- chunked SSM scan ----------------
__global__ __launch_bounds__(256) void scan1_kernel(
    const float* __restrict__ dt, const float* __restrict__ uc,
    const float* __restrict__ Bm, const float* __restrict__ Alog,
    float* __restrict__ cP, float* __restrict__ cS)
{
    int g = blockIdx.x * 256 + threadIdx.x;
    int c = g >> 13;
    int r = g & 8191;
    int hh = r >> 6;
    int d = r & 63;
    float A = -__expf(Alog[hh * 64 + d]);
    float P = 1.f, S = 0.f;
    int t0 = c * CS;
    for (int t = t0; t < t0 + CS; ++t) {
        float dtv = dt[t * HD + hh];
        float a = __expf(dtv * A);
        float bv = Bm[t * 64 + d];
        float uv = uc[t * HD + hh];
        P *= a;
        S = fmaf(a, S, dtv * uv * bv);
    }
    cP[g] = P; cS[g] = S;
}

__global__ __launch_bounds__(256) void scan2_kernel(
    const float* __restrict__ cP, const float* __restrict__ cS, float* __restrict__ cI)
{
    int g = blockIdx.x * 256 + threadIdx.x;
    float S = 0.f;
    for (int c = 0; c < NC; ++c) {
        cI[c * 8192 + g] = S;
        S = fmaf(cP[c * 8192 + g], S, cS[c * 8192 + g]);
    }
}

__global__ __launch_bounds__(256) void scan3_kernel(
    const float* __restrict__ dt, const float* __restrict__ uc,
    const float* __restrict__ Bm, const float* __restrict__ Cm,
    const float* __restrict__ Alog, const float* __restrict__ Dskip,
    const float* __restrict__ cI, float* __restrict__ y)
{
    int g = blockIdx.x * 256 + threadIdx.x;
    int c = g >> 13;
    int r = g & 8191;
    int hh = r >> 6;
    int d = r & 63;
    float A = -__expf(Alog[hh * 64 + d]);
    float s = cI[g];
    float Dh = Dskip[hh];
    int t0 = c * CS;
    for (int t = t0; t < t0 + CS; ++t) {
        float dtv = dt[t * HD + hh];
        float a = __expf(dtv * A);
        float uv = uc[t * HD + hh];
        s = fmaf(a, s, dtv * uv * Bm[t * 64 + d]);
        float yp = s * Cm[t * 64 + d];
        #pragma unroll
        for (int off = 1; off < 64; off <<= 1) yp += __shfl_xor(yp, off);
        if (d == 0) y[t * HD + hh] = yp + Dh * uv;
    }
}

// ---------------- out_proj ----------------
__global__ __launch_bounds__(256) void out_kernel(
    const float* __restrict__ y, const float* __restrict__ zs,
    const float* __restrict__ Wop, float* __restrict__ outp)
{
    __shared__ float xs[32][130];
    __shared__ float Ws[16][129];
    const int tid = threadIdx.x;
    const int nbase = blockIdx.x * 32;
    for (int idx = tid; idx < 32 * HD; idx += 256) {
        int n = idx >> 7, k = idx & 127;
        size_t gn = (size_t)(nbase + n);
        xs[n][k] = y[gn * HD + k] * zs[gn * HD + k];
    }
    const int je = tid & 31;
    const int e0 = (tid >> 5) * 4;
    float acc[4][4];
    #pragma unroll
    for (int i = 0; i < 4; ++i)
        #pragma unroll
        for (int m = 0; m < 4; ++m) acc[i][m] = 0.f;
    gemm32<128, 130>(Wop, 128, Ws, xs, e0, je, tid, acc);
    #pragma unroll
    for (int i = 0; i < 4; ++i)
        #pragma unroll
        for (int m = 0; m < 4; ++m)
            outp[(size_t)(nbase + e0 + i) * HD + je + 32 * m] = acc[i][m];
}

extern "C" void kernel_launch(void* const* d_in, const int* in_sizes, int n_in,
                              void* d_out, int out_size, void* d_ws, size_t ws_size,
                              hipStream_t stream)
{
    const float* h     = (const float*)d_in[0];
    const float* coord = (const float*)d_in[1];
    const int*   ei    = (const int*)d_in[2];
    const float* We1   = (const float*)d_in[3];
    const float* be1   = (const float*)d_in[4];
    const float* We2   = (const float*)d_in[5];
    const float* be2   = (const float*)d_in[6];
    const float* watt  = (const float*)d_in[7];
    const float* batt  = (const float*)d_in[8];
    const float* Wn1   = (const float*)d_in[9];
    const float* bn1   = (const float*)d_in[10];
    const float* Wn2   = (const float*)d_in[11];
    const float* bn2   = (const float*)d_in[12];
    const float* Wc1   = (const float*)d_in[13];
    const float* bc1   = (const float*)d_in[14];
    const float* Wc2   = (const float*)d_in[15];
    const float* lng   = (const float*)d_in[16];
    const float* lnb   = (const float*)d_in[17];
    const float* Wip   = (const float*)d_in[18];
    const float* convw = (const float*)d_in[19];
    const float* convb = (const float*)d_in[20];
    const float* Wxp   = (const float*)d_in[21];
    const float* Wdt   = (const float*)d_in[22];
    const float* bdt   = (const float*)d_in[23];
    const float* Alog  = (const float*)d_in[24];
    const float* Dskip = (const float*)d_in[25];
    const float* Wop   = (const float*)d_in[26];

    float* ws   = (float*)d_ws;
    float* mi   = ws;                                  // NN*HD f32 (zeroed)
    float* ssum = mi   + (size_t)NN * HD;              // NN*3  f32 (zeroed)
    int*   histI  = (int*)(ssum + (size_t)NN * 3);     // NN int (zeroed)
    int*   cursor = histI + NN;                        // NN int (zeroed)
    int*   baseI  = cursor + NN;                       // NN int
    int*   perm   = baseI + NN;                        // EE int
    float* xbuf = (float*)(perm + EE);                 // NN*HD  (hn; later dt)
    float* zsb  = xbuf + (size_t)NN * HD;              // NN*HD
    float* ubuf = zsb  + (size_t)NN * HD;              // NN*HD   u; later B|C
    float* ucb  = ubuf + (size_t)NN * HD;              // NN*HD
    float* cP   = ucb  + (size_t)NN * HD;              // NC*8192
    float* cSb  = cP   + (size_t)NC * 8192;
    float* cIb  = cSb  + (size_t)NC * 8192;
    float* bfb  = cIb  + (size_t)NC * 8192;            // bf16 region
    ushort_t* hbp   = (ushort_t*)bfb;                  // NN*HD bf16
    ushort_t* W12bp = hbp + (size_t)NN * HD;           // 256*128
    ushort_t* We2bp = W12bp + 256 * 128;               // 128*128
    ushort_t* Wc1bp = We2bp + 128 * 128;               // 128*128
    ushort_t* P12bp = (ushort_t*)cP;                   // NN*256 bf16 (aliases cP/cS; free until scan1)
    float* dtb  = xbuf;
    float* Bm   = ubuf;
    float* Cm   = ubuf + (size_t)NN * 64;

    float* outp     = (float*)d_out;
    float* yb       = outp;
    float* coordout = outp + (size_t)NN * HD;

    // zero mi, ssum, histI, cursor  (NN*(128+3)*4 + NN*8 bytes)
    hipMemsetAsync(ws, 0, (size_t)NN * 133 * 4, stream);

    hist_kernel<<<(EE + 255) / 256, 256, 0, stream>>>(ei, histI);
    prefix_kernel<<<1, 256, 0, stream>>>(histI, baseI);
    scatter_kernel<<<(EE + 255) / 256, 256, 0, stream>>>(ei, baseI, cursor, perm);
    prep_kernel<<<(NN * HD) / 256, 256, 0, stream>>>(h, We1, We2, Wc1, hbp, W12bp, We2bp, Wc1bp);
    p12_kernel<<<(NN + 127) / 128, 256, 0, stream>>>(hbp, W12bp, P12bp);
    edge_mfma<<<EE / 128, 256, 0, stream>>>(P12bp, coord, ei, perm, We1, be1,
                                            We2bp, be2, watt, batt, Wc1bp, bc1, Wc2,
                                            mi, ssum);
    node_kernel<<<NN / 32, 256, 0, stream>>>(mi, h, Wn1, bn1, Wn2, bn2, lng, lnb, xbuf);
    coord_kernel<<<(NN * 3 + 255) / 256, 256, 0, stream>>>(coord, ssum, histI, coordout);
    xz_kernel<<<NN / 32, 256, 0, stream>>>(xbuf, Wip, ubuf, zsb);
    conv_kernel<<<NN * HD / 256, 256, 0, stream>>>(ubuf, convw, convb, ucb);
    xdbl_kernel<<<NN / 16, 256, 0, stream>>>(ucb, Wxp, Wdt, bdt, dtb, Bm, Cm);
    scan1_kernel<<<NC * 8192 / 256, 256, 0, stream>>>(dtb, ucb, Bm, Alog, cP, cSb);
    scan2_kernel<<<8192 / 256, 256, 0, stream>>>(cP, cSb, cIb);
    scan3_kernel<<<NC * 8192 / 256, 256, 0, stream>>>(dtb, ucb, Bm, Cm, Alog, Dskip, cIb, yb);
    out_kernel<<<NN / 32, 256, 0, stream>>>(yb, zsb, Wop, outp);
}

// Round 9
// 795.709 us; speedup vs baseline: 3.8291x; 1.2684x over previous
//
#include <hip/hip_runtime.h>
#include <math.h>

#define NN 20000
#define EE 640000
#define HD 128
#define NC 160      // scan chunks
#define CS 125      // chunk size: NC*CS == NN

typedef unsigned short ushort_t;
typedef __attribute__((ext_vector_type(8))) short short8v;
typedef __attribute__((ext_vector_type(4))) float f32x4;

#define MFMA16(a,b,c) __builtin_amdgcn_mfma_f32_16x16x32_bf16(a,b,c,0,0,0)

__device__ __forceinline__ float sigf(float x) { return 1.0f / (1.0f + __expf(-x)); }

__device__ __forceinline__ ushort_t f2b(float x) {
    unsigned u = __builtin_bit_cast(unsigned, x);
    unsigned r = (u + 0x7FFFu + ((u >> 16) & 1u)) >> 16;
    return (ushort_t)r;
}
__device__ __forceinline__ float b2f(ushort_t u) {
    unsigned v = ((unsigned)u) << 16;
    return __builtin_bit_cast(float, v);
}
// split fp32 -> hi/lo bf16 pair (x ~= hi + lo, error ~2^-17 rel)
__device__ __forceinline__ void splitf(float v, ushort_t& h, ushort_t& l) {
    h = f2b(v);
    l = f2b(v - b2f(h));
}
__device__ __forceinline__ void cvt8x2(const float* p, short8v& hi, short8v& lo) {
    #pragma unroll
    for (int j = 0; j < 8; ++j) {
        float v = p[j];
        ushort_t h, l; splitf(v, h, l);
        hi[j] = (short)h; lo[j] = (short)l;
    }
}

// ---------------- counting sort of edges by e0 ----------------
__global__ __launch_bounds__(256) void hist_kernel(const int* __restrict__ ei,
                                                   int* __restrict__ histI)
{
    int i = blockIdx.x * 256 + threadIdx.x;
    if (i < EE) atomicAdd(&histI[ei[i]], 1);
}

__global__ __launch_bounds__(256) void prefix_kernel(const int* __restrict__ hist,
                                                     int* __restrict__ baseI)
{
    __shared__ int wsum[4];
    const int tid = threadIdx.x, lane = tid & 63, wid = tid >> 6;
    const int PER = 79;                 // 79*256 >= NN
    int i0 = tid * PER;
    int s = 0;
    for (int k = 0; k < PER; ++k) { int i = i0 + k; if (i < NN) s += hist[i]; }
    int v = s;
    #pragma unroll
    for (int off = 1; off < 64; off <<= 1) {
        int t = __shfl_up(v, off);
        if (lane >= off) v += t;
    }
    if (lane == 63) wsum[wid] = v;
    __syncthreads();
    if (tid == 0) {
        int acc = 0;
        #pragma unroll
        for (int w = 0; w < 4; ++w) { int t = wsum[w]; wsum[w] = acc; acc += t; }
    }
    __syncthreads();
    int excl = v - s + wsum[wid];
    for (int k = 0; k < PER; ++k) {
        int i = i0 + k;
        if (i < NN) { baseI[i] = excl; excl += hist[i]; }
    }
}

__global__ __launch_bounds__(256) void scatter_kernel(const int* __restrict__ ei,
                                                      const int* __restrict__ baseI,
                                                      int* __restrict__ cursor,
                                                      int* __restrict__ perm)
{
    int i = blockIdx.x * 256 + threadIdx.x;
    if (i < EE) {
        int n = ei[i];
        int p = baseI[n] + atomicAdd(&cursor[n], 1);
        perm[p] = i;
    }
}

// ---------------- prep: weight conversions (single bf16 for edge path, hi/lo for mamba) ----
__global__ __launch_bounds__(256) void prep_kernel(
    const float* __restrict__ We1, const float* __restrict__ We2,
    const float* __restrict__ Wc1, const float* __restrict__ Wn1,
    const float* __restrict__ Wn2, const float* __restrict__ Wip,
    const float* __restrict__ Wxp, const float* __restrict__ Wdt,
    const float* __restrict__ Wop,
    ushort_t* __restrict__ W12b, ushort_t* __restrict__ We2b,
    ushort_t* __restrict__ Wc1b,
    ushort_t* __restrict__ Wn1hi, ushort_t* __restrict__ Wn1lo,
    ushort_t* __restrict__ Wn2hi, ushort_t* __restrict__ Wn2lo,
    ushort_t* __restrict__ Wiphi, ushort_t* __restrict__ Wiplo,
    ushort_t* __restrict__ Wxp8hi, ushort_t* __restrict__ Wxp8lo,
    ushort_t* __restrict__ Wdt2hi, ushort_t* __restrict__ Wdt2lo,
    ushort_t* __restrict__ Wophi, ushort_t* __restrict__ Woplo)
{
    int i = blockIdx.x * 256 + threadIdx.x;
    if (i < 256 * 128) {
        int j = i >> 7, k = i & 127;
        W12b[i] = f2b(We1[(j & 127) * 257 + ((j >> 7) << 7) + k]);
        ushort_t h, l;
        splitf(Wn1[i], h, l); Wn1hi[i] = h; Wn1lo[i] = l;
        splitf(Wip[i], h, l); Wiphi[i] = h; Wiplo[i] = l;
    }
    if (i < 128 * 128) {
        We2b[i] = f2b(We2[i]);
        Wc1b[i] = f2b(Wc1[i]);
        ushort_t h, l;
        splitf(Wn2[i], h, l); Wn2hi[i] = h; Wn2lo[i] = l;
        splitf(Wop[i], h, l); Wophi[i] = h; Woplo[i] = l;
        int j = i >> 7, k = i & 127;
        splitf(Wxp[(8 + j) * 128 + k], h, l); Wxp8hi[i] = h; Wxp8lo[i] = l;
        float s = 0.f;
        #pragma unroll
        for (int r = 0; r < 8; ++r) s = fmaf(Wdt[j * 8 + r], Wxp[r * 128 + k], s);
        splitf(s, h, l); Wdt2hi[i] = h; Wdt2lo[i] = l;
    }
}

// ---------------- node projections: P12 = h @ [W1a|W1b]^T ----------------
__global__ __launch_bounds__(256) void p12_kernel(
    const float* __restrict__ h, const ushort_t* __restrict__ W12b,
    ushort_t* __restrict__ P12b)
{
    const int tid = threadIdx.x;
    const int lane = tid & 63;
    const int wid = tid >> 6;
    const int wm = wid >> 1, wn = wid & 1;
    const int g = lane >> 4, r16 = lane & 15;
    const int rbase = blockIdx.x * 128 + wm * 64;

    f32x4 acc[4][8];
    #pragma unroll
    for (int mt = 0; mt < 4; ++mt)
        #pragma unroll
        for (int nt = 0; nt < 8; ++nt) acc[mt][nt] = (f32x4){0.f, 0.f, 0.f, 0.f};

    for (int c = 0; c < 4; ++c) {
        short8v afr[4], bfr[8];
        #pragma unroll
        for (int mt = 0; mt < 4; ++mt) {
            int row = rbase + mt * 16 + r16;
            if (row > NN - 1) row = NN - 1;
            const float* p = h + (size_t)row * HD + c * 32 + g * 8;
            #pragma unroll
            for (int j = 0; j < 8; ++j) afr[mt][j] = (short)f2b(p[j]);
        }
        #pragma unroll
        for (int nt = 0; nt < 8; ++nt)
            bfr[nt] = *(const short8v*)(W12b + (size_t)(wn * 128 + nt * 16 + r16) * 128 + c * 32 + g * 8);
        #pragma unroll
        for (int mt = 0; mt < 4; ++mt)
            #pragma unroll
            for (int nt = 0; nt < 8; ++nt)
                acc[mt][nt] = MFMA16(afr[mt], bfr[nt], acc[mt][nt]);
    }
    #pragma unroll
    for (int mt = 0; mt < 4; ++mt)
        #pragma unroll
        for (int nt = 0; nt < 8; ++nt)
            #pragma unroll
            for (int r = 0; r < 4; ++r) {
                int row = rbase + mt * 16 + g * 4 + r;
                if (row < NN)
                    P12b[(size_t)row * 256 + wn * 128 + nt * 16 + r16] = f2b(acc[mt][nt][r]);
            }
}

// ---------------- edge phase (MFMA bf16, sorted edges, segment-aggregated sums) -------------
__global__ __launch_bounds__(256) void edge_mfma(
    const ushort_t* __restrict__ P12b, const float* __restrict__ coord,
    const int* __restrict__ ei, const int* __restrict__ perm,
    const float* __restrict__ We1, const float* __restrict__ be1,
    const ushort_t* __restrict__ We2b, const float* __restrict__ be2,
    const float* __restrict__ watt, const float* __restrict__ batt,
    const ushort_t* __restrict__ Wc1b, const float* __restrict__ bc1,
    const float* __restrict__ Wc2,
    float* __restrict__ mi, float* __restrict__ ssum)
{
    __shared__ ushort_t ybuf[128 * 128];
    __shared__ float rad[128];
    __shared__ float cdp[128][3];
    __shared__ float wcols[128], be1s[128], be2s[128], bc1s[128], watts[128], wc2s[128];
    __shared__ float pq[2][128];
    __shared__ int ej0s[128], ej1s[128];

    const int tid = threadIdx.x;
    const int ebase = blockIdx.x * 128;
    const int lane = tid & 63;
    const int wid = tid >> 6;
    const int wm = wid >> 1, wn = wid & 1;
    const int g = lane >> 4, r16 = lane & 15;
    const float batt0 = batt[0];

    if (tid < 128) {
        int eg = perm[ebase + tid];
        ej0s[tid] = ei[eg];
    } else {
        int t = tid - 128;
        int eg = perm[ebase + t];
        ej1s[t] = ei[EE + eg];
        wcols[t] = We1[t * 257 + 256];
        be1s[t] = be1[t]; be2s[t] = be2[t]; bc1s[t] = bc1[t];
        watts[t] = watt[t]; wc2s[t] = Wc2[t];
    }
    __syncthreads();

    short8v b2_[4][4];
    {
        const ushort_t* W2p = We2b + (size_t)(wn * 64 + r16) * 128 + g * 8;
        #pragma unroll
        for (int nt = 0; nt < 4; ++nt)
            #pragma unroll
            for (int c = 0; c < 4; ++c)
                b2_[nt][c] = *(const short8v*)(W2p + nt * 2048 + c * 32);
    }

    if (tid < 128) {
        int a = ej0s[tid], b = ej1s[tid];
        float rr = 0.f;
        #pragma unroll
        for (int c = 0; c < 3; ++c) {
            float d = coord[a * 3 + c] - coord[b * 3 + c];
            cdp[tid][c] = d; rr += d * d;
        }
        rad[tid] = rr;
    }
    __syncthreads();

    {
        const int e = tid >> 1, hf = tid & 1;
        const int n1 = ej1s[e], n0 = ej0s[e];
        const ushort_t* p1 = P12b + (size_t)n1 * 256 + hf * 64;
        const ushort_t* p2 = P12b + (size_t)n0 * 256 + 128 + hf * 64;
        const float radv = rad[e];
        const int colbase = hf * 64;
        #pragma unroll
        for (int q = 0; q < 8; ++q) {
            short8v a = *(const short8v*)(p1 + q * 8);
            short8v b = *(const short8v*)(p2 + q * 8);
            short8v ov;
            #pragma unroll
            for (int jj = 0; jj < 8; ++jj) {
                int col = colbase + q * 8 + jj;
                float v = b2f((ushort_t)a[jj]) + b2f((ushort_t)b[jj]) + radv * wcols[col] + be1s[col];
                ov[jj] = (short)f2b(fmaxf(v, 0.f));
            }
            int off = (e << 8) + ((colbase * 2 + q * 16) ^ ((e & 15) << 4));
            *(short8v*)((char*)ybuf + off) = ov;
        }
    }
    __syncthreads();

    f32x4 acc[4][4];
    #pragma unroll
    for (int mt = 0; mt < 4; ++mt)
        #pragma unroll
        for (int nt = 0; nt < 4; ++nt) acc[mt][nt] = (f32x4){0.f, 0.f, 0.f, 0.f};
    #pragma unroll
    for (int c = 0; c < 4; ++c) {
        short8v afr[4];
        #pragma unroll
        for (int mt = 0; mt < 4; ++mt) {
            int row = wm * 64 + mt * 16 + r16;
            afr[mt] = *(const short8v*)((const char*)ybuf + (row << 8) + ((c * 64 + g * 16) ^ (r16 << 4)));
        }
        #pragma unroll
        for (int mt = 0; mt < 4; ++mt)
            #pragma unroll
            for (int nt = 0; nt < 4; ++nt)
                acc[mt][nt] = MFMA16(afr[mt], b2_[nt][c], acc[mt][nt]);
    }

    short8v b3_[4][4];
    {
        const ushort_t* W3p = Wc1b + (size_t)(wn * 64 + r16) * 128 + g * 8;
        #pragma unroll
        for (int nt = 0; nt < 4; ++nt)
            #pragma unroll
            for (int c = 0; c < 4; ++c)
                b3_[nt][c] = *(const short8v*)(W3p + nt * 2048 + c * 32);
    }

    {
        float p[4][4];
        #pragma unroll
        for (int mt = 0; mt < 4; ++mt)
            #pragma unroll
            for (int r = 0; r < 4; ++r) p[mt][r] = 0.f;
        #pragma unroll
        for (int mt = 0; mt < 4; ++mt)
            #pragma unroll
            for (int nt = 0; nt < 4; ++nt)
                #pragma unroll
                for (int r = 0; r < 4; ++r) {
                    int col = wn * 64 + nt * 16 + r16;
                    float v = fmaxf(acc[mt][nt][r] + be2s[col], 0.f);
                    acc[mt][nt][r] = v;
                    p[mt][r] += v * watts[col];
                }
        #pragma unroll
        for (int off = 1; off < 16; off <<= 1)
            #pragma unroll
            for (int mt = 0; mt < 4; ++mt)
                #pragma unroll
                for (int r = 0; r < 4; ++r) p[mt][r] += __shfl_xor(p[mt][r], off);
        if (r16 == 0) {
            #pragma unroll
            for (int mt = 0; mt < 4; ++mt)
                #pragma unroll
                for (int r = 0; r < 4; ++r)
                    pq[wn][wm * 64 + mt * 16 + g * 4 + r] = p[mt][r];
        }
        __syncthreads();
        float att[4][4];
        #pragma unroll
        for (int mt = 0; mt < 4; ++mt)
            #pragma unroll
            for (int r = 0; r < 4; ++r) {
                int row = wm * 64 + mt * 16 + g * 4 + r;
                att[mt][r] = sigf(pq[0][row] + pq[1][row] + batt0);
            }
        __syncthreads();
        #pragma unroll
        for (int mt = 0; mt < 4; ++mt)
            #pragma unroll
            for (int nt = 0; nt < 4; ++nt)
                #pragma unroll
                for (int r = 0; r < 4; ++r) {
                    int row = wm * 64 + mt * 16 + g * 4 + r;
                    int col = wn * 64 + nt * 16 + r16;
                    int off = (row << 8) + (((col << 1)) ^ ((row & 15) << 4));
                    *(ushort_t*)((char*)ybuf + off) = f2b(acc[mt][nt][r] * att[mt][r]);
                }
    }
    __syncthreads();

    {
        const int col = tid & 127, half = tid >> 7;
        const int r0 = half * 64, r1 = r0 + 64;
        float sacc = 0.f; int cur = ej0s[r0];
        for (int r = r0; r < r1; ++r) {
            int node = ej0s[r];
            if (node != cur) {
                atomicAdd(&mi[(size_t)cur * HD + col], sacc);
                sacc = 0.f; cur = node;
            }
            int off = (r << 8) + (((col << 1)) ^ ((r & 15) << 4));
            sacc += b2f(*(const ushort_t*)((const char*)ybuf + off));
        }
        atomicAdd(&mi[(size_t)cur * HD + col], sacc);
    }

    #pragma unroll
    for (int mt = 0; mt < 4; ++mt)
        #pragma unroll
        for (int nt = 0; nt < 4; ++nt) acc[mt][nt] = (f32x4){0.f, 0.f, 0.f, 0.f};
    #pragma unroll
    for (int c = 0; c < 4; ++c) {
        short8v afr[4];
        #pragma unroll
        for (int mt = 0; mt < 4; ++mt) {
            int row = wm * 64 + mt * 16 + r16;
            afr[mt] = *(const short8v*)((const char*)ybuf + (row << 8) + ((c * 64 + g * 16) ^ (r16 << 4)));
        }
        #pragma unroll
        for (int mt = 0; mt < 4; ++mt)
            #pragma unroll
            for (int nt = 0; nt < 4; ++nt)
                acc[mt][nt] = MFMA16(afr[mt], b3_[nt][c], acc[mt][nt]);
    }
    {
        float q[4][4];
        #pragma unroll
        for (int mt = 0; mt < 4; ++mt)
            #pragma unroll
            for (int r = 0; r < 4; ++r) q[mt][r] = 0.f;
        #pragma unroll
        for (int mt = 0; mt < 4; ++mt)
            #pragma unroll
            for (int nt = 0; nt < 4; ++nt)
                #pragma unroll
                for (int r = 0; r < 4; ++r) {
                    int col = wn * 64 + nt * 16 + r16;
                    float v = fmaxf(acc[mt][nt][r] + bc1s[col], 0.f);
                    q[mt][r] += v * wc2s[col];
                }
        #pragma unroll
        for (int off = 1; off < 16; off <<= 1)
            #pragma unroll
            for (int mt = 0; mt < 4; ++mt)
                #pragma unroll
                for (int r = 0; r < 4; ++r) q[mt][r] += __shfl_xor(q[mt][r], off);
        if (r16 == 0) {
            #pragma unroll
            for (int mt = 0; mt < 4; ++mt)
                #pragma unroll
                for (int r = 0; r < 4; ++r)
                    pq[wn][wm * 64 + mt * 16 + g * 4 + r] = q[mt][r];
        }
        __syncthreads();
        if (tid < 6) {
            int c = tid % 3, half = tid / 3;
            int r0 = half * 64, r1 = r0 + 64;
            float sacc = 0.f; int cur = ej0s[r0];
            for (int r = r0; r < r1; ++r) {
                int node = ej0s[r];
                if (node != cur) {
                    atomicAdd(&ssum[cur * 3 + c], sacc);
                    sacc = 0.f; cur = node;
                }
                float tv = pq[0][r] + pq[1][r];
                float tr = cdp[r][c] * tv;
                tr = fminf(fmaxf(tr, -100.f), 100.f);
                sacc += tr;
            }
            atomicAdd(&ssum[cur * 3 + c], sacc);
        }
    }
}

// ---------------- node MLP + layernorm + clip (split-bf16 MFMA, ~fp32) -> hn fp32 -----------
__global__ __launch_bounds__(256) void node_mfma(
    const float* __restrict__ mi, const float* __restrict__ h,
    const ushort_t* __restrict__ Wn1hi, const ushort_t* __restrict__ Wn1lo,
    const float* __restrict__ bn1,
    const ushort_t* __restrict__ Wn2hi, const ushort_t* __restrict__ Wn2lo,
    const float* __restrict__ bn2,
    const float* __restrict__ lng, const float* __restrict__ lnb,
    float* __restrict__ hnf)
{
    __shared__ ushort_t yhi[128 * 128];
    __shared__ ushort_t ylo[128 * 128];
    __shared__ float bn1s[128], bn2s[128], lngs[128], lnbs[128];

    const int tid = threadIdx.x;
    const int nbase = blockIdx.x * 128;
    const int lane = tid & 63;
    const int wid = tid >> 6;
    const int wm = wid >> 1, wn = wid & 1;
    const int g = lane >> 4, r16 = lane & 15;

    if (tid < 128) { bn1s[tid] = bn1[tid]; bn2s[tid] = bn2[tid]; lngs[tid] = lng[tid]; lnbs[tid] = lnb[tid]; }
    __syncthreads();

    // layer 1: [mi | h] @ Wn1^T, K=256, split A and B
    f32x4 acc[4][4];
    #pragma unroll
    for (int mt = 0; mt < 4; ++mt)
        #pragma unroll
        for (int nt = 0; nt < 4; ++nt) acc[mt][nt] = (f32x4){0.f, 0.f, 0.f, 0.f};
    for (int c = 0; c < 8; ++c) {
        short8v ahi[4], alo[4], bhi[4], blo[4];
        #pragma unroll
        for (int mt = 0; mt < 4; ++mt) {
            int row = nbase + wm * 64 + mt * 16 + r16;
            if (row > NN - 1) row = NN - 1;
            const float* src = (c < 4) ? (mi + (size_t)row * HD + c * 32 + g * 8)
                                       : (h + (size_t)row * HD + (c - 4) * 32 + g * 8);
            cvt8x2(src, ahi[mt], alo[mt]);
        }
        #pragma unroll
        for (int nt = 0; nt < 4; ++nt) {
            size_t wo = (size_t)(wn * 64 + nt * 16 + r16) * 256 + c * 32 + g * 8;
            bhi[nt] = *(const short8v*)(Wn1hi + wo);
            blo[nt] = *(const short8v*)(Wn1lo + wo);
        }
        #pragma unroll
        for (int mt = 0; mt < 4; ++mt)
            #pragma unroll
            for (int nt = 0; nt < 4; ++nt) {
                acc[mt][nt] = MFMA16(ahi[mt], bhi[nt], acc[mt][nt]);
                acc[mt][nt] = MFMA16(ahi[mt], blo[nt], acc[mt][nt]);
                acc[mt][nt] = MFMA16(alo[mt], bhi[nt], acc[mt][nt]);
            }
    }
    // relu(+bn1) -> hi/lo LDS pair
    #pragma unroll
    for (int mt = 0; mt < 4; ++mt)
        #pragma unroll
        for (int nt = 0; nt < 4; ++nt)
            #pragma unroll
            for (int r = 0; r < 4; ++r) {
                int row = wm * 64 + mt * 16 + g * 4 + r;
                int col = wn * 64 + nt * 16 + r16;
                int off = (row << 8) + (((col << 1)) ^ ((row & 15) << 4));
                float v = fmaxf(acc[mt][nt][r] + bn1s[col], 0.f);
                ushort_t hh, ll; splitf(v, hh, ll);
                *(ushort_t*)((char*)yhi + off) = hh;
                *(ushort_t*)((char*)ylo + off) = ll;
            }
    __syncthreads();

    // layer 2: y1 @ Wn2^T, split A and B
    #pragma unroll
    for (int mt = 0; mt < 4; ++mt)
        #pragma unroll
        for (int nt = 0; nt < 4; ++nt) acc[mt][nt] = (f32x4){0.f, 0.f, 0.f, 0.f};
    #pragma unroll
    for (int c = 0; c < 4; ++c) {
        short8v ahi[4], alo[4], bhi[4], blo[4];
        #pragma unroll
        for (int mt = 0; mt < 4; ++mt) {
            int row = wm * 64 + mt * 16 + r16;
            int off = (row << 8) + ((c * 64 + g * 16) ^ (r16 << 4));
            ahi[mt] = *(const short8v*)((const char*)yhi + off);
            alo[mt] = *(const short8v*)((const char*)ylo + off);
        }
        #pragma unroll
        for (int nt = 0; nt < 4; ++nt) {
            size_t wo = (size_t)(wn * 64 + nt * 16 + r16) * 128 + c * 32 + g * 8;
            bhi[nt] = *(const short8v*)(Wn2hi + wo);
            blo[nt] = *(const short8v*)(Wn2lo + wo);
        }
        #pragma unroll
        for (int mt = 0; mt < 4; ++mt)
            #pragma unroll
            for (int nt = 0; nt < 4; ++nt) {
                acc[mt][nt] = MFMA16(ahi[mt], bhi[nt], acc[mt][nt]);
                acc[mt][nt] = MFMA16(ahi[mt], blo[nt], acc[mt][nt]);
                acc[mt][nt] = MFMA16(alo[mt], bhi[nt], acc[mt][nt]);
            }
    }
    __syncthreads();   // all layer-2 reads done -> safe to overwrite
    #pragma unroll
    for (int mt = 0; mt < 4; ++mt)
        #pragma unroll
        for (int nt = 0; nt < 4; ++nt)
            #pragma unroll
            for (int r = 0; r < 4; ++r) {
                int row = wm * 64 + mt * 16 + g * 4 + r;
                int col = wn * 64 + nt * 16 + r16;
                int off = (row << 8) + (((col << 1)) ^ ((row & 15) << 4));
                float v = acc[mt][nt][r] + bn2s[col];
                ushort_t hh, ll; splitf(v, hh, ll);
                *(ushort_t*)((char*)yhi + off) = hh;
                *(ushort_t*)((char*)ylo + off) = ll;
            }
    __syncthreads();

    // layernorm + clip + store hn fp32 (2 threads per row, 8 chunks each = FULL 128 cols)
    {
        const int row = tid >> 1, hf = tid & 1;
        const int rowg = nbase + row;
        float s1 = 0.f, s2 = 0.f;
        float vals[64];
        #pragma unroll
        for (int q = 0; q < 8; ++q) {
            int c8 = hf * 8 + q;
            int off = (row << 8) + ((c8 * 16) ^ ((row & 15) << 4));
            short8v vh = *(const short8v*)((const char*)yhi + off);
            short8v vl = *(const short8v*)((const char*)ylo + off);
            #pragma unroll
            for (int j = 0; j < 8; ++j) {
                float v = b2f((ushort_t)vh[j]) + b2f((ushort_t)vl[j]);
                vals[q * 8 + j] = v;
                s1 += v; s2 += v * v;
            }
        }
        s1 += __shfl_xor(s1, 1);
        s2 += __shfl_xor(s2, 1);
        float mu = s1 * (1.f / HD);
        float var = s2 * (1.f / HD) - mu * mu;
        float rs = rsqrtf(fmaxf(var, 0.f) + 1e-5f);
        if (rowg < NN) {
            #pragma unroll
            for (int q = 0; q < 8; ++q) {
                int c8 = hf * 8 + q;
                f32x4 o0, o1;
                #pragma unroll
                for (int j = 0; j < 8; ++j) {
                    int col = c8 * 8 + j;
                    float v = (vals[q * 8 + j] - mu) * rs * lngs[col] + lnbs[col];
                    v = fminf(fmaxf(v, -10.f), 10.f);
                    if (j < 4) o0[j] = v; else o1[j - 4] = v;
                }
                *(f32x4*)(hnf + (size_t)rowg * HD + c8 * 8) = o0;
                *(f32x4*)(hnf + (size_t)rowg * HD + c8 * 8 + 4) = o1;
            }
        }
    }
}

// ---------------- coord update (cnt from histogram) ----------------
__global__ __launch_bounds__(256) void coord_kernel(
    const float* __restrict__ coord, const float* __restrict__ ssum,
    const int* __restrict__ histI, float* __restrict__ outp)
{
    int idx = blockIdx.x * 256 + threadIdx.x;
    if (idx < NN * 3) {
        int n = idx / 3;
        float c = (float)histI[n];
        outp[idx] = coord[idx] + ssum[idx] / fmaxf(c, 1.f);
    }
}

// ---------------- mamba in_proj (split MFMA, ~fp32): u bf16, silu(z) fp32 ----------------
__global__ __launch_bounds__(256) void xz_mfma(
    const float* __restrict__ hnf,
    const ushort_t* __restrict__ Wiphi, const ushort_t* __restrict__ Wiplo,
    ushort_t* __restrict__ ub, float* __restrict__ zs)
{
    const int tid = threadIdx.x;
    const int lane = tid & 63;
    const int wn = tid >> 6;               // 4 waves over 256 output cols
    const int g = lane >> 4, r16 = lane & 15;
    const int rbase = blockIdx.x * 64;

    f32x4 acc[4][4];
    #pragma unroll
    for (int mt = 0; mt < 4; ++mt)
        #pragma unroll
        for (int nt = 0; nt < 4; ++nt) acc[mt][nt] = (f32x4){0.f, 0.f, 0.f, 0.f};

    for (int c = 0; c < 4; ++c) {
        short8v ahi[4], alo[4], bhi[4], blo[4];
        #pragma unroll
        for (int mt = 0; mt < 4; ++mt) {
            int row = rbase + mt * 16 + r16;
            if (row > NN - 1) row = NN - 1;
            cvt8x2(hnf + (size_t)row * HD + c * 32 + g * 8, ahi[mt], alo[mt]);
        }
        #pragma unroll
        for (int nt = 0; nt < 4; ++nt) {
            size_t wo = (size_t)(wn * 64 + nt * 16 + r16) * 128 + c * 32 + g * 8;
            bhi[nt] = *(const short8v*)(Wiphi + wo);
            blo[nt] = *(const short8v*)(Wiplo + wo);
        }
        #pragma unroll
        for (int mt = 0; mt < 4; ++mt)
            #pragma unroll
            for (int nt = 0; nt < 4; ++nt) {
                acc[mt][nt] = MFMA16(ahi[mt], bhi[nt], acc[mt][nt]);
                acc[mt][nt] = MFMA16(ahi[mt], blo[nt], acc[mt][nt]);
                acc[mt][nt] = MFMA16(alo[mt], bhi[nt], acc[mt][nt]);
            }
    }
    #pragma unroll
    for (int mt = 0; mt < 4; ++mt)
        #pragma unroll
        for (int nt = 0; nt < 4; ++nt)
            #pragma unroll
            for (int r = 0; r < 4; ++r) {
                int row = rbase + mt * 16 + g * 4 + r;
                if (row >= NN) continue;
                int j = wn * 64 + nt * 16 + r16;
                float v = acc[mt][nt][r];
                if (j < HD) ub[(size_t)row * HD + j] = f2b(v);
                else        zs[(size_t)row * HD + (j - HD)] = v * sigf(v);
            }
}

// ---- fused conv+silu -> uc; B|C = uc@Wxp8^T; dt = softplus(uc@Wdt2^T+bdt)  (split MFMA) ----
__global__ __launch_bounds__(256) void convdt_mfma(
    const ushort_t* __restrict__ ub, const float* __restrict__ cw,
    const float* __restrict__ cb,
    const ushort_t* __restrict__ Wxp8hi, const ushort_t* __restrict__ Wxp8lo,
    const ushort_t* __restrict__ Wdt2hi, const ushort_t* __restrict__ Wdt2lo,
    const float* __restrict__ bdt,
    float* __restrict__ uc, float* __restrict__ Bm, float* __restrict__ Cm,
    float* __restrict__ dt)
{
    __shared__ ushort_t yhi[128 * 128];
    __shared__ ushort_t ylo[128 * 128];
    __shared__ float cws[128][4], cbs[128], bdts[128];

    const int tid = threadIdx.x;
    const int nbase = blockIdx.x * 128;
    const int lane = tid & 63;
    const int wid = tid >> 6;
    const int wm = wid >> 1, wn = wid & 1;
    const int g = lane >> 4, r16 = lane & 15;

    if (tid < 128) {
        cbs[tid] = cb[tid]; bdts[tid] = bdt[tid];
        #pragma unroll
        for (int k = 0; k < 4; ++k) cws[tid][k] = cw[tid * 4 + k];
    }
    __syncthreads();

    // phase 1: causal depthwise conv + silu -> uc (fp32 global) + hi/lo LDS pair
    for (int it = tid; it < 128 * 16; it += 256) {
        int r = it >> 4, cg = it & 15;
        int t = nbase + r;
        int colb = cg * 8;
        float a[8];
        #pragma unroll
        for (int j = 0; j < 8; ++j) a[j] = cbs[colb + j];
        #pragma unroll
        for (int k = 0; k < 4; ++k) {
            int tt = t - 3 + k;
            if (tt >= 0 && tt < NN) {
                short8v uv = *(const short8v*)(ub + (size_t)tt * HD + colb);
                #pragma unroll
                for (int j = 0; j < 8; ++j) a[j] = fmaf(b2f((ushort_t)uv[j]), cws[colb + j][k], a[j]);
            }
        }
        short8v oh, ol;
        f32x4 u0, u1;
        #pragma unroll
        for (int j = 0; j < 8; ++j) {
            float s = (t < NN) ? a[j] * sigf(a[j]) : 0.f;
            ushort_t hh, ll; splitf(s, hh, ll);
            oh[j] = (short)hh; ol[j] = (short)ll;
            if (j < 4) u0[j] = s; else u1[j - 4] = s;
        }
        int off = (r << 8) + ((cg * 16) ^ ((r & 15) << 4));
        *(short8v*)((char*)yhi + off) = oh;
        *(short8v*)((char*)ylo + off) = ol;
        if (t < NN) {
            *(f32x4*)(uc + (size_t)t * HD + colb) = u0;
            *(f32x4*)(uc + (size_t)t * HD + colb + 4) = u1;
        }
    }
    __syncthreads();

    // phase 2: B|C = uc @ Wxp[8:136]^T  (128 cols), split
    f32x4 acc[4][4];
    #pragma unroll
    for (int mt = 0; mt < 4; ++mt)
        #pragma unroll
        for (int nt = 0; nt < 4; ++nt) acc[mt][nt] = (f32x4){0.f, 0.f, 0.f, 0.f};
    #pragma unroll
    for (int c = 0; c < 4; ++c) {
        short8v ahi[4], alo[4], bhi[4], blo[4];
        #pragma unroll
        for (int mt = 0; mt < 4; ++mt) {
            int row = wm * 64 + mt * 16 + r16;
            int off = (row << 8) + ((c * 64 + g * 16) ^ (r16 << 4));
            ahi[mt] = *(const short8v*)((const char*)yhi + off);
            alo[mt] = *(const short8v*)((const char*)ylo + off);
        }
        #pragma unroll
        for (int nt = 0; nt < 4; ++nt) {
            size_t wo = (size_t)(wn * 64 + nt * 16 + r16) * 128 + c * 32 + g * 8;
            bhi[nt] = *(const short8v*)(Wxp8hi + wo);
            blo[nt] = *(const short8v*)(Wxp8lo + wo);
        }
        #pragma unroll
        for (int mt = 0; mt < 4; ++mt)
            #pragma unroll
            for (int nt = 0; nt < 4; ++nt) {
                acc[mt][nt] = MFMA16(ahi[mt], bhi[nt], acc[mt][nt]);
                acc[mt][nt] = MFMA16(ahi[mt], blo[nt], acc[mt][nt]);
                acc[mt][nt] = MFMA16(alo[mt], bhi[nt], acc[mt][nt]);
            }
    }
    #pragma unroll
    for (int mt = 0; mt < 4; ++mt)
        #pragma unroll
        for (int nt = 0; nt < 4; ++nt)
            #pragma unroll
            for (int r = 0; r < 4; ++r) {
                int row = nbase + wm * 64 + mt * 16 + g * 4 + r;
                if (row >= NN) continue;
                int j = wn * 64 + nt * 16 + r16;
                float v = acc[mt][nt][r];
                if (j < 64) Bm[(size_t)row * 64 + j] = v;
                else        Cm[(size_t)row * 64 + (j - 64)] = v;
            }

    // phase 3: dt = softplus(uc @ Wdt2^T + bdt), split
    #pragma unroll
    for (int mt = 0; mt < 4; ++mt)
        #pragma unroll
        for (int nt = 0; nt < 4; ++nt) acc[mt][nt] = (f32x4){0.f, 0.f, 0.f, 0.f};
    #pragma unroll
    for (int c = 0; c < 4; ++c) {
        short8v ahi[4], alo[4], bhi[4], blo[4];
        #pragma unroll
        for (int mt = 0; mt < 4; ++mt) {
            int row = wm * 64 + mt * 16 + r16;
            int off = (row << 8) + ((c * 64 + g * 16) ^ (r16 << 4));
            ahi[mt] = *(const short8v*)((const char*)yhi + off);
            alo[mt] = *(const short8v*)((const char*)ylo + off);
        }
        #pragma unroll
        for (int nt = 0; nt < 4; ++nt) {
            size_t wo = (size_t)(wn * 64 + nt * 16 + r16) * 128 + c * 32 + g * 8;
            bhi[nt] = *(const short8v*)(Wdt2hi + wo);
            blo[nt] = *(const short8v*)(Wdt2lo + wo);
        }
        #pragma unroll
        for (int mt = 0; mt < 4; ++mt)
            #pragma unroll
            for (int nt = 0; nt < 4; ++nt) {
                acc[mt][nt] = MFMA16(ahi[mt], bhi[nt], acc[mt][nt]);
                acc[mt][nt] = MFMA16(ahi[mt], blo[nt], acc[mt][nt]);
                acc[mt][nt] = MFMA16(alo[mt], bhi[nt], acc[mt][nt]);
            }
    }
    #pragma unroll
    for (int mt = 0; mt < 4; ++mt)
        #pragma unroll
        for (int nt = 0; nt < 4; ++nt)
            #pragma unroll
            for (int r = 0; r < 4; ++r) {
                int row = nbase + wm * 64 + mt * 16 + g * 4 + r;
                if (row >= NN) continue;
                int j = wn * 64 + nt * 16 + r16;
                float a = acc[mt][nt][r] + bdts[j];
                float sp = (a > 20.f) ? a : log1pf(__expf(a));
                dt[(size_t)row * HD + j] = sp;
            }
}

// ---------------- chunked SSM scan ----------------
__global__ __launch_bounds__(256) void scan1_kernel(
    const float* __restrict__ dt, const float* __restrict__ uc,
    const float* __restrict__ Bm, const float* __restrict__ Alog,
    float* __restrict__ cP, float* __restrict__ cS)
{
    int g = blockIdx.x * 256 + threadIdx.x;
    int c = g >> 13;
    int r = g & 8191;
    int hh = r >> 6;
    int d = r & 63;
    float A = -__expf(Alog[hh * 64 + d]);
    float P = 1.f, S = 0.f;
    int t0 = c * CS;
    for (int t = t0; t < t0 + CS; ++t) {
        float dtv = dt[t * HD + hh];
        float a = __expf(dtv * A);
        float bv = Bm[t * 64 + d];
        float uv = uc[t * HD + hh];
        P *= a;
        S = fmaf(a, S, dtv * uv * bv);
    }
    cP[g] = P; cS[g] = S;
}

__global__ __launch_bounds__(256) void scan2_kernel(
    const float* __restrict__ cP, const float* __restrict__ cS, float* __restrict__ cI)
{
    int g = blockIdx.x * 256 + threadIdx.x;
    float S = 0.f;
    for (int c = 0; c < NC; ++c) {
        cI[c * 8192 + g] = S;
        S = fmaf(cP[c * 8192 + g], S, cS[c * 8192 + g]);
    }
}

__global__ __launch_bounds__(256) void scan3_kernel(
    const float* __restrict__ dt, const float* __restrict__ uc,
    const float* __restrict__ Bm, const float* __restrict__ Cm,
    const float* __restrict__ Alog, const float* __restrict__ Dskip,
    const float* __restrict__ cI, float* __restrict__ y)
{
    int g = blockIdx.x * 256 + threadIdx.x;
    int c = g >> 13;
    int r = g & 8191;
    int hh = r >> 6;
    int d = r & 63;
    float A = -__expf(Alog[hh * 64 + d]);
    float s = cI[g];
    float Dh = Dskip[hh];
    int t0 = c * CS;
    for (int t = t0; t < t0 + CS; ++t) {
        float dtv = dt[t * HD + hh];
        float a = __expf(dtv * A);
        float uv = uc[t * HD + hh];
        s = fmaf(a, s, dtv * uv * Bm[t * 64 + d]);
        float yp = s * Cm[t * 64 + d];
        #pragma unroll
        for (int off = 1; off < 64; off <<= 1) yp += __shfl_xor(yp, off);
        if (d == 0) y[t * HD + hh] = yp + Dh * uv;
    }
}

// ---------------- out_proj (split MFMA, ~fp32): (y*silu(z)) @ Wop^T ----------------
__global__ __launch_bounds__(256) void out_mfma(
    const float* __restrict__ y, const float* __restrict__ zs,
    const ushort_t* __restrict__ Wophi, const ushort_t* __restrict__ Woplo,
    float* __restrict__ outp)
{
    const int tid = threadIdx.x;
    const int lane = tid & 63;
    const int wid = tid >> 6;
    const int wm = wid >> 1, wn = wid & 1;
    const int g = lane >> 4, r16 = lane & 15;
    const int nbase = blockIdx.x * 128;

    f32x4 acc[4][4];
    #pragma unroll
    for (int mt = 0; mt < 4; ++mt)
        #pragma unroll
        for (int nt = 0; nt < 4; ++nt) acc[mt][nt] = (f32x4){0.f, 0.f, 0.f, 0.f};

    for (int c = 0; c < 4; ++c) {
        short8v ahi[4], alo[4], bhi[4], blo[4];
        #pragma unroll
        for (int mt = 0; mt < 4; ++mt) {
            int row = nbase + wm * 64 + mt * 16 + r16;
            if (row > NN - 1) row = NN - 1;
            const float* yp = y + (size_t)row * HD + c * 32 + g * 8;
            const float* zp = zs + (size_t)row * HD + c * 32 + g * 8;
            #pragma unroll
            for (int j = 0; j < 8; ++j) {
                float v = yp[j] * zp[j];
                ushort_t hh, ll; splitf(v, hh, ll);
                ahi[mt][j] = (short)hh; alo[mt][j] = (short)ll;
            }
        }
        #pragma unroll
        for (int nt = 0; nt < 4; ++nt) {
            size_t wo = (size_t)(wn * 64 + nt * 16 + r16) * 128 + c * 32 + g * 8;
            bhi[nt] = *(const short8v*)(Wophi + wo);
            blo[nt] = *(const short8v*)(Woplo + wo);
        }
        #pragma unroll
        for (int mt = 0; mt < 4; ++mt)
            #pragma unroll
            for (int nt = 0; nt < 4; ++nt) {
                acc[mt][nt] = MFMA16(ahi[mt], bhi[nt], acc[mt][nt]);
                acc[mt][nt] = MFMA16(ahi[mt], blo[nt], acc[mt][nt]);
                acc[mt][nt] = MFMA16(alo[mt], bhi[nt], acc[mt][nt]);
            }
    }
    #pragma unroll
    for (int mt = 0; mt < 4; ++mt)
        #pragma unroll
        for (int nt = 0; nt < 4; ++nt)
            #pragma unroll
            for (int r = 0; r < 4; ++r) {
                int row = nbase + wm * 64 + mt * 16 + g * 4 + r;
                if (row < NN)
                    outp[(size_t)row * HD + wn * 64 + nt * 16 + r16] = acc[mt][nt][r];
            }
}

extern "C" void kernel_launch(void* const* d_in, const int* in_sizes, int n_in,
                              void* d_out, int out_size, void* d_ws, size_t ws_size,
                              hipStream_t stream)
{
    const float* h     = (const float*)d_in[0];
    const float* coord = (const float*)d_in[1];
    const int*   ei    = (const int*)d_in[2];
    const float* We1   = (const float*)d_in[3];
    const float* be1   = (const float*)d_in[4];
    const float* We2   = (const float*)d_in[5];
    const float* be2   = (const float*)d_in[6];
    const float* watt  = (const float*)d_in[7];
    const float* batt  = (const float*)d_in[8];
    const float* Wn1   = (const float*)d_in[9];
    const float* bn1   = (const float*)d_in[10];
    const float* Wn2   = (const float*)d_in[11];
    const float* bn2   = (const float*)d_in[12];
    const float* Wc1   = (const float*)d_in[13];
    const float* bc1   = (const float*)d_in[14];
    const float* Wc2   = (const float*)d_in[15];
    const float* lng   = (const float*)d_in[16];
    const float* lnb   = (const float*)d_in[17];
    const float* Wip   = (const float*)d_in[18];
    const float* convw = (const float*)d_in[19];
    const float* convb = (const float*)d_in[20];
    const float* Wxp   = (const float*)d_in[21];
    const float* Wdt   = (const float*)d_in[22];
    const float* bdt   = (const float*)d_in[23];
    const float* Alog  = (const float*)d_in[24];
    const float* Dskip = (const float*)d_in[25];
    const float* Wop   = (const float*)d_in[26];

    float* ws   = (float*)d_ws;
    float* mi   = ws;                                  // NN*HD f32 (zeroed; reused as y after node)
    float* ssum = mi   + (size_t)NN * HD;              // NN*3  f32 (zeroed)
    int*   histI  = (int*)(ssum + (size_t)NN * 3);     // NN (zeroed)
    int*   cursor = histI + NN;                        // NN (zeroed)
    int*   baseI  = cursor + NN;                       // NN
    int*   perm   = baseI + NN;                        // EE
    float* zsb  = (float*)(perm + EE);                 // NN*HD
    float* ucb  = zsb  + (size_t)NN * HD;              // NN*HD
    float* dtb  = ucb  + (size_t)NN * HD;              // NN*HD
    float* Bm   = dtb  + (size_t)NN * HD;              // NN*64
    float* Cm   = Bm   + (size_t)NN * 64;              // NN*64
    float* cP   = Cm   + (size_t)NN * 64;              // NC*8192
    float* cSb  = cP   + (size_t)NC * 8192;
    float* cIb  = cSb  + (size_t)NC * 8192;
    ushort_t* ub    = (ushort_t*)(cIb + (size_t)NC * 8192);  // NN*HD bf16
    ushort_t* W12bp = ub + (size_t)NN * HD;            // 256*128
    ushort_t* We2bp = W12bp + 256 * 128;
    ushort_t* Wc1bp = We2bp + 128 * 128;
    ushort_t* Wn1hi = Wc1bp + 128 * 128;               // 128*256 pair
    ushort_t* Wn1lo = Wn1hi + 128 * 256;
    ushort_t* Wn2hi = Wn1lo + 128 * 256;               // 128*128 pair
    ushort_t* Wn2lo = Wn2hi + 128 * 128;
    ushort_t* Wiphi = Wn2lo + 128 * 128;               // 256*128 pair
    ushort_t* Wiplo = Wiphi + 256 * 128;
    ushort_t* Wxp8hi = Wiplo + 256 * 128;              // 128*128 pairs
    ushort_t* Wxp8lo = Wxp8hi + 128 * 128;
    ushort_t* Wdt2hi = Wxp8lo + 128 * 128;
    ushort_t* Wdt2lo = Wdt2hi + 128 * 128;
    ushort_t* Wophi  = Wdt2lo + 128 * 128;
    ushort_t* Woplo  = Wophi + 128 * 128;
    // P12b (NN*256 bf16 = 10.24MB) aliases cP+cS: written by p12, dead after edge.
    ushort_t* P12bp = (ushort_t*)cP;
    // hnf (NN*HD f32 = 10.24MB) also aliases cP+cS: written by node (after edge),
    // dead after xz (before scan1 writes cP/cS).
    float* hnf = cP;
    // y aliases mi: mi consumed by node_mfma, re-zeroed each launch by the memset.
    float* yb = mi;

    float* outp     = (float*)d_out;
    float* coordout = outp + (size_t)NN * HD;

    // zero mi, ssum, histI, cursor
    hipMemsetAsync(ws, 0, (size_t)NN * 133 * 4, stream);

    hist_kernel<<<(EE + 255) / 256, 256, 0, stream>>>(ei, histI);
    prefix_kernel<<<1, 256, 0, stream>>>(histI, baseI);
    scatter_kernel<<<(EE + 255) / 256, 256, 0, stream>>>(ei, baseI, cursor, perm);
    prep_kernel<<<128, 256, 0, stream>>>(We1, We2, Wc1, Wn1, Wn2, Wip, Wxp, Wdt, Wop,
                                         W12bp, We2bp, Wc1bp,
                                         Wn1hi, Wn1lo, Wn2hi, Wn2lo, Wiphi, Wiplo,
                                         Wxp8hi, Wxp8lo, Wdt2hi, Wdt2lo, Wophi, Woplo);
    p12_kernel<<<(NN + 127) / 128, 256, 0, stream>>>(h, W12bp, P12bp);
    edge_mfma<<<EE / 128, 256, 0, stream>>>(P12bp, coord, ei, perm, We1, be1,
                                            We2bp, be2, watt, batt, Wc1bp, bc1, Wc2,
                                            mi, ssum);
    node_mfma<<<(NN + 127) / 128, 256, 0, stream>>>(mi, h, Wn1hi, Wn1lo, bn1,
                                                    Wn2hi, Wn2lo, bn2, lng, lnb, hnf);
    coord_kernel<<<(NN * 3 + 255) / 256, 256, 0, stream>>>(coord, ssum, histI, coordout);
    xz_mfma<<<(NN + 63) / 64, 256, 0, stream>>>(hnf, Wiphi, Wiplo, ub, zsb);
    convdt_mfma<<<(NN + 127) / 128, 256, 0, stream>>>(ub, convw, convb,
                                                      Wxp8hi, Wxp8lo, Wdt2hi, Wdt2lo,
                                                      bdt, ucb, Bm, Cm, dtb);
    scan1_kernel<<<NC * 8192 / 256, 256, 0, stream>>>(dtb, ucb, Bm, Alog, cP, cSb);
    scan2_kernel<<<8192 / 256, 256, 0, stream>>>(cP, cSb, cIb);
    scan3_kernel<<<NC * 8192 / 256, 256, 0, stream>>>(dtb, ucb, Bm, Cm, Alog, Dskip, cIb, yb);
    out_mfma<<<(NN + 127) / 128, 256, 0, stream>>>(yb, zsb, Wophi, Woplo, outp);
}

// Round 10
// 773.929 us; speedup vs baseline: 3.9369x; 1.0281x over previous
//
#include <hip/hip_runtime.h>
#include <math.h>

#define NN 20000
#define EE 640000
#define HD 128
#define NC 160      // scan chunks
#define CS 125      // chunk size: NC*CS == NN

typedef unsigned short ushort_t;
typedef __attribute__((ext_vector_type(8))) short short8v;
typedef __attribute__((ext_vector_type(4))) float f32x4;

#define MFMA16(a,b,c) __builtin_amdgcn_mfma_f32_16x16x32_bf16(a,b,c,0,0,0)

__device__ __forceinline__ float sigf(float x) { return 1.0f / (1.0f + __expf(-x)); }

__device__ __forceinline__ ushort_t f2b(float x) {
    unsigned u = __builtin_bit_cast(unsigned, x);
    unsigned r = (u + 0x7FFFu + ((u >> 16) & 1u)) >> 16;
    return (ushort_t)r;
}
__device__ __forceinline__ float b2f(ushort_t u) {
    unsigned v = ((unsigned)u) << 16;
    return __builtin_bit_cast(float, v);
}
// split fp32 -> hi/lo bf16 pair (x ~= hi + lo, error ~2^-17 rel)
__device__ __forceinline__ void splitf(float v, ushort_t& h, ushort_t& l) {
    h = f2b(v);
    l = f2b(v - b2f(h));
}
__device__ __forceinline__ void cvt8x2(const float* p, short8v& hi, short8v& lo) {
    #pragma unroll
    for (int j = 0; j < 8; ++j) {
        float v = p[j];
        ushort_t h, l; splitf(v, h, l);
        hi[j] = (short)h; lo[j] = (short)l;
    }
}

// ---------------- counting sort of edges by e0 ----------------
__global__ __launch_bounds__(256) void hist_kernel(const int* __restrict__ ei,
                                                   int* __restrict__ histI)
{
    int i = blockIdx.x * 256 + threadIdx.x;
    if (i < EE) atomicAdd(&histI[ei[i]], 1);
}

__global__ __launch_bounds__(1024) void prefix_kernel(const int* __restrict__ hist,
                                                      int* __restrict__ baseI)
{
    __shared__ int wsum[16];
    const int tid = threadIdx.x, lane = tid & 63, wid = tid >> 6;
    const int PER = 20;                 // 20*1024 >= NN
    int i0 = tid * PER;
    int s = 0;
    for (int k = 0; k < PER; ++k) { int i = i0 + k; if (i < NN) s += hist[i]; }
    int v = s;
    #pragma unroll
    for (int off = 1; off < 64; off <<= 1) {
        int t = __shfl_up(v, off);
        if (lane >= off) v += t;
    }
    if (lane == 63) wsum[wid] = v;
    __syncthreads();
    if (tid == 0) {
        int acc = 0;
        #pragma unroll
        for (int w = 0; w < 16; ++w) { int t = wsum[w]; wsum[w] = acc; acc += t; }
    }
    __syncthreads();
    int excl = v - s + wsum[wid];
    for (int k = 0; k < PER; ++k) {
        int i = i0 + k;
        if (i < NN) { baseI[i] = excl; excl += hist[i]; }
    }
}

__global__ __launch_bounds__(256) void scatter_kernel(const int* __restrict__ ei,
                                                      const int* __restrict__ baseI,
                                                      int* __restrict__ cursor,
                                                      int* __restrict__ perm)
{
    int i = blockIdx.x * 256 + threadIdx.x;
    if (i < EE) {
        int n = ei[i];
        int p = baseI[n] + atomicAdd(&cursor[n], 1);
        perm[p] = i;
    }
}

// ---------------- prep: weight conversions (single bf16 for edge path, hi/lo for mamba) ----
__global__ __launch_bounds__(256) void prep_kernel(
    const float* __restrict__ We1, const float* __restrict__ We2,
    const float* __restrict__ Wc1, const float* __restrict__ Wn1,
    const float* __restrict__ Wn2, const float* __restrict__ Wip,
    const float* __restrict__ Wxp, const float* __restrict__ Wdt,
    const float* __restrict__ Wop,
    ushort_t* __restrict__ W12b, ushort_t* __restrict__ We2b,
    ushort_t* __restrict__ Wc1b,
    ushort_t* __restrict__ Wn1hi, ushort_t* __restrict__ Wn1lo,
    ushort_t* __restrict__ Wn2hi, ushort_t* __restrict__ Wn2lo,
    ushort_t* __restrict__ Wiphi, ushort_t* __restrict__ Wiplo,
    ushort_t* __restrict__ Wxp8hi, ushort_t* __restrict__ Wxp8lo,
    ushort_t* __restrict__ Wdt2hi, ushort_t* __restrict__ Wdt2lo,
    ushort_t* __restrict__ Wophi, ushort_t* __restrict__ Woplo)
{
    int i = blockIdx.x * 256 + threadIdx.x;
    if (i < 256 * 128) {
        int j = i >> 7, k = i & 127;
        W12b[i] = f2b(We1[(j & 127) * 257 + ((j >> 7) << 7) + k]);
        ushort_t h, l;
        splitf(Wn1[i], h, l); Wn1hi[i] = h; Wn1lo[i] = l;
        splitf(Wip[i], h, l); Wiphi[i] = h; Wiplo[i] = l;
    }
    if (i < 128 * 128) {
        We2b[i] = f2b(We2[i]);
        Wc1b[i] = f2b(Wc1[i]);
        ushort_t h, l;
        splitf(Wn2[i], h, l); Wn2hi[i] = h; Wn2lo[i] = l;
        splitf(Wop[i], h, l); Wophi[i] = h; Woplo[i] = l;
        int j = i >> 7, k = i & 127;
        splitf(Wxp[(8 + j) * 128 + k], h, l); Wxp8hi[i] = h; Wxp8lo[i] = l;
        float s = 0.f;
        #pragma unroll
        for (int r = 0; r < 8; ++r) s = fmaf(Wdt[j * 8 + r], Wxp[r * 128 + k], s);
        splitf(s, h, l); Wdt2hi[i] = h; Wdt2lo[i] = l;
    }
}

// ---------------- node projections: P12 = h @ [W1a|W1b]^T ----------------
__global__ __launch_bounds__(256) void p12_kernel(
    const float* __restrict__ h, const ushort_t* __restrict__ W12b,
    ushort_t* __restrict__ P12b)
{
    const int tid = threadIdx.x;
    const int lane = tid & 63;
    const int wid = tid >> 6;
    const int wm = wid >> 1, wn = wid & 1;
    const int g = lane >> 4, r16 = lane & 15;
    const int rbase = blockIdx.x * 128 + wm * 64;

    f32x4 acc[4][8];
    #pragma unroll
    for (int mt = 0; mt < 4; ++mt)
        #pragma unroll
        for (int nt = 0; nt < 8; ++nt) acc[mt][nt] = (f32x4){0.f, 0.f, 0.f, 0.f};

    for (int c = 0; c < 4; ++c) {
        short8v afr[4], bfr[8];
        #pragma unroll
        for (int mt = 0; mt < 4; ++mt) {
            int row = rbase + mt * 16 + r16;
            if (row > NN - 1) row = NN - 1;
            const float* p = h + (size_t)row * HD + c * 32 + g * 8;
            #pragma unroll
            for (int j = 0; j < 8; ++j) afr[mt][j] = (short)f2b(p[j]);
        }
        #pragma unroll
        for (int nt = 0; nt < 8; ++nt)
            bfr[nt] = *(const short8v*)(W12b + (size_t)(wn * 128 + nt * 16 + r16) * 128 + c * 32 + g * 8);
        #pragma unroll
        for (int mt = 0; mt < 4; ++mt)
            #pragma unroll
            for (int nt = 0; nt < 8; ++nt)
                acc[mt][nt] = MFMA16(afr[mt], bfr[nt], acc[mt][nt]);
    }
    #pragma unroll
    for (int mt = 0; mt < 4; ++mt)
        #pragma unroll
        for (int nt = 0; nt < 8; ++nt)
            #pragma unroll
            for (int r = 0; r < 4; ++r) {
                int row = rbase + mt * 16 + g * 4 + r;
                if (row < NN)
                    P12b[(size_t)row * 256 + wn * 128 + nt * 16 + r16] = f2b(acc[mt][nt][r]);
            }
}

// ---------------- edge phase (MFMA bf16, sorted edges, segment-aggregated sums) -------------
__global__ __launch_bounds__(256) void edge_mfma(
    const ushort_t* __restrict__ P12b, const float* __restrict__ coord,
    const int* __restrict__ ei, const int* __restrict__ perm,
    const float* __restrict__ We1, const float* __restrict__ be1,
    const ushort_t* __restrict__ We2b, const float* __restrict__ be2,
    const float* __restrict__ watt, const float* __restrict__ batt,
    const ushort_t* __restrict__ Wc1b, const float* __restrict__ bc1,
    const float* __restrict__ Wc2,
    float* __restrict__ mi, float* __restrict__ ssum)
{
    __shared__ ushort_t ybuf[128 * 128];
    __shared__ float cdp[128][3];
    __shared__ float wcols[128], be1s[128], be2s[128], bc1s[128], watts[128], wc2s[128];
    __shared__ float pq[2][128];
    __shared__ int ej0s[128];

    const int tid = threadIdx.x;
    const int ebase = blockIdx.x * 128;
    const int lane = tid & 63;
    const int wid = tid >> 6;
    const int wm = wid >> 1, wn = wid & 1;
    const int g = lane >> 4, r16 = lane & 15;
    const float batt0 = batt[0];

    // ---- early: per-pair index load + gather issue (before any barrier) ----
    const int e = tid >> 1, hf = tid & 1;
    const int eg = perm[ebase + e];
    const int n0 = ei[eg];
    const int n1 = ei[EE + eg];
    short8v ga[8], gb[8];
    {
        const ushort_t* p1 = P12b + (size_t)n1 * 256 + hf * 64;
        const ushort_t* p2 = P12b + (size_t)n0 * 256 + 128 + hf * 64;
        #pragma unroll
        for (int q = 0; q < 8; ++q) {
            ga[q] = *(const short8v*)(p1 + q * 8);
            gb[q] = *(const short8v*)(p2 + q * 8);
        }
    }
    if (hf == 0) ej0s[e] = n0;
    // stage per-col consts (latency overlaps gathers)
    {
        int t = tid & 127;
        if (tid < 128) {
            wcols[t] = We1[t * 257 + 256];
            be1s[t] = be1[t];
            be2s[t] = be2[t];
        } else {
            bc1s[t] = bc1[t];
            watts[t] = watt[t];
            wc2s[t] = Wc2[t];
        }
    }
    // radial + coord-diff (both pair threads compute rr; even thread writes cdp)
    float rr;
    {
        float d0 = coord[n0 * 3 + 0] - coord[n1 * 3 + 0];
        float d1 = coord[n0 * 3 + 1] - coord[n1 * 3 + 1];
        float d2 = coord[n0 * 3 + 2] - coord[n1 * 3 + 2];
        rr = d0 * d0 + d1 * d1 + d2 * d2;
        if (hf == 0) { cdp[e][0] = d0; cdp[e][1] = d1; cdp[e][2] = d2; }
    }
    __syncthreads();

    // ---- phase A: y1 = relu(P1[e1] + P2[e0] + rad*wcol + be1) -> ybuf ----
    {
        const int colbase = hf * 64;
        #pragma unroll
        for (int q = 0; q < 8; ++q) {
            short8v ov;
            #pragma unroll
            for (int jj = 0; jj < 8; ++jj) {
                int col = colbase + q * 8 + jj;
                float v = b2f((ushort_t)ga[q][jj]) + b2f((ushort_t)gb[q][jj]) + rr * wcols[col] + be1s[col];
                ov[jj] = (short)f2b(fmaxf(v, 0.f));
            }
            int off = (e << 8) + ((colbase * 2 + q * 16) ^ ((e & 15) << 4));
            *(short8v*)((char*)ybuf + off) = ov;
        }
    }
    // preload layer-2 weights (latency hides under the barrier)
    short8v b2_[4][4];
    {
        const ushort_t* W2p = We2b + (size_t)(wn * 64 + r16) * 128 + g * 8;
        #pragma unroll
        for (int nt = 0; nt < 4; ++nt)
            #pragma unroll
            for (int c = 0; c < 4; ++c)
                b2_[nt][c] = *(const short8v*)(W2p + nt * 2048 + c * 32);
    }
    __syncthreads();

    // ---- layer 2: y1 @ We2^T ----
    f32x4 acc[4][4];
    #pragma unroll
    for (int mt = 0; mt < 4; ++mt)
        #pragma unroll
        for (int nt = 0; nt < 4; ++nt) acc[mt][nt] = (f32x4){0.f, 0.f, 0.f, 0.f};
    #pragma unroll
    for (int c = 0; c < 4; ++c) {
        short8v afr[4];
        #pragma unroll
        for (int mt = 0; mt < 4; ++mt) {
            int row = wm * 64 + mt * 16 + r16;
            afr[mt] = *(const short8v*)((const char*)ybuf + (row << 8) + ((c * 64 + g * 16) ^ (r16 << 4)));
        }
        #pragma unroll
        for (int mt = 0; mt < 4; ++mt)
            #pragma unroll
            for (int nt = 0; nt < 4; ++nt)
                acc[mt][nt] = MFMA16(afr[mt], b2_[nt][c], acc[mt][nt]);
    }

    // epilogue 2: mij = relu(+be2); att = sigmoid(mij.watt + batt); ef = mij*att -> ybuf
    {
        float p[4][4];
        #pragma unroll
        for (int mt = 0; mt < 4; ++mt)
            #pragma unroll
            for (int r = 0; r < 4; ++r) p[mt][r] = 0.f;
        #pragma unroll
        for (int mt = 0; mt < 4; ++mt)
            #pragma unroll
            for (int nt = 0; nt < 4; ++nt)
                #pragma unroll
                for (int r = 0; r < 4; ++r) {
                    int col = wn * 64 + nt * 16 + r16;
                    float v = fmaxf(acc[mt][nt][r] + be2s[col], 0.f);
                    acc[mt][nt][r] = v;
                    p[mt][r] += v * watts[col];
                }
        #pragma unroll
        for (int off = 1; off < 16; off <<= 1)
            #pragma unroll
            for (int mt = 0; mt < 4; ++mt)
                #pragma unroll
                for (int r = 0; r < 4; ++r) p[mt][r] += __shfl_xor(p[mt][r], off);
        if (r16 == 0) {
            #pragma unroll
            for (int mt = 0; mt < 4; ++mt)
                #pragma unroll
                for (int r = 0; r < 4; ++r)
                    pq[wn][wm * 64 + mt * 16 + g * 4 + r] = p[mt][r];
        }
        __syncthreads();
        float att[4][4];
        #pragma unroll
        for (int mt = 0; mt < 4; ++mt)
            #pragma unroll
            for (int r = 0; r < 4; ++r) {
                int row = wm * 64 + mt * 16 + g * 4 + r;
                att[mt][r] = sigf(pq[0][row] + pq[1][row] + batt0);
            }
        __syncthreads();   // layer-2 ybuf reads + pq reads done -> safe to overwrite ybuf
        #pragma unroll
        for (int mt = 0; mt < 4; ++mt)
            #pragma unroll
            for (int nt = 0; nt < 4; ++nt)
                #pragma unroll
                for (int r = 0; r < 4; ++r) {
                    int row = wm * 64 + mt * 16 + g * 4 + r;
                    int col = wn * 64 + nt * 16 + r16;
                    int off = (row << 8) + (((col << 1)) ^ ((row & 15) << 4));
                    *(ushort_t*)((char*)ybuf + off) = f2b(acc[mt][nt][r] * att[mt][r]);
                }
    }
    __syncthreads();   // ef visible to all

    // preload layer-3 weights (latency hides under the segment-sum below)
    short8v b3_[4][4];
    {
        const ushort_t* W3p = Wc1b + (size_t)(wn * 64 + r16) * 128 + g * 8;
        #pragma unroll
        for (int nt = 0; nt < 4; ++nt)
            #pragma unroll
            for (int c = 0; c < 4; ++c)
                b3_[nt][c] = *(const short8v*)(W3p + nt * 2048 + c * 32);
    }

    // ---- segment-sum ef over sorted e0 runs -> mi (128 threads: 8 cols x 16 rows each) ----
    if (tid < 128) {
        const int cg = tid & 15;          // cols cg*8 .. cg*8+7
        const int rg = tid >> 4;          // rows rg*16 .. rg*16+15
        const int r0 = rg * 16;
        float sa[8];
        #pragma unroll
        for (int j = 0; j < 8; ++j) sa[j] = 0.f;
        int cur = ej0s[r0];
        for (int r = r0; r < r0 + 16; ++r) {
            int node = ej0s[r];
            if (node != cur) {
                #pragma unroll
                for (int j = 0; j < 8; ++j) atomicAdd(&mi[(size_t)cur * HD + cg * 8 + j], sa[j]);
                #pragma unroll
                for (int j = 0; j < 8; ++j) sa[j] = 0.f;
                cur = node;
            }
            int off = (r << 8) + ((cg * 16) ^ ((r & 15) << 4));
            short8v v = *(const short8v*)((const char*)ybuf + off);
            #pragma unroll
            for (int j = 0; j < 8; ++j) sa[j] += b2f((ushort_t)v[j]);
        }
        #pragma unroll
        for (int j = 0; j < 8; ++j) atomicAdd(&mi[(size_t)cur * HD + cg * 8 + j], sa[j]);
    }

    // ---- layer 3: ef @ Wc1^T, dot Wc2 ----
    #pragma unroll
    for (int mt = 0; mt < 4; ++mt)
        #pragma unroll
        for (int nt = 0; nt < 4; ++nt) acc[mt][nt] = (f32x4){0.f, 0.f, 0.f, 0.f};
    #pragma unroll
    for (int c = 0; c < 4; ++c) {
        short8v afr[4];
        #pragma unroll
        for (int mt = 0; mt < 4; ++mt) {
            int row = wm * 64 + mt * 16 + r16;
            afr[mt] = *(const short8v*)((const char*)ybuf + (row << 8) + ((c * 64 + g * 16) ^ (r16 << 4)));
        }
        #pragma unroll
        for (int mt = 0; mt < 4; ++mt)
            #pragma unroll
            for (int nt = 0; nt < 4; ++nt)
                acc[mt][nt] = MFMA16(afr[mt], b3_[nt][c], acc[mt][nt]);
    }
    {
        float q[4][4];
        #pragma unroll
        for (int mt = 0; mt < 4; ++mt)
            #pragma unroll
            for (int r = 0; r < 4; ++r) q[mt][r] = 0.f;
        #pragma unroll
        for (int mt = 0; mt < 4; ++mt)
            #pragma unroll
            for (int nt = 0; nt < 4; ++nt)
                #pragma unroll
                for (int r = 0; r < 4; ++r) {
                    int col = wn * 64 + nt * 16 + r16;
                    float v = fmaxf(acc[mt][nt][r] + bc1s[col], 0.f);
                    q[mt][r] += v * wc2s[col];
                }
        #pragma unroll
        for (int off = 1; off < 16; off <<= 1)
            #pragma unroll
            for (int mt = 0; mt < 4; ++mt)
                #pragma unroll
                for (int r = 0; r < 4; ++r) q[mt][r] += __shfl_xor(q[mt][r], off);
        if (r16 == 0) {
            #pragma unroll
            for (int mt = 0; mt < 4; ++mt)
                #pragma unroll
                for (int r = 0; r < 4; ++r)
                    pq[wn][wm * 64 + mt * 16 + g * 4 + r] = q[mt][r];
        }
        __syncthreads();
        // coord segment sums: 48 lanes, 8 rows each
        if (tid < 48) {
            int c = tid % 3, seg = tid / 3;
            int r0 = seg * 8, r1 = r0 + 8;
            float sacc = 0.f; int cur = ej0s[r0];
            for (int r = r0; r < r1; ++r) {
                int node = ej0s[r];
                if (node != cur) {
                    atomicAdd(&ssum[cur * 3 + c], sacc);
                    sacc = 0.f; cur = node;
                }
                float tv = pq[0][r] + pq[1][r];
                float tr = cdp[r][c] * tv;
                tr = fminf(fmaxf(tr, -100.f), 100.f);
                sacc += tr;
            }
            atomicAdd(&ssum[cur * 3 + c], sacc);
        }
    }
}

// ---------------- node MLP + layernorm + clip (split-bf16 MFMA, ~fp32) -> hn fp32 -----------
__global__ __launch_bounds__(256) void node_mfma(
    const float* __restrict__ mi, const float* __restrict__ h,
    const ushort_t* __restrict__ Wn1hi, const ushort_t* __restrict__ Wn1lo,
    const float* __restrict__ bn1,
    const ushort_t* __restrict__ Wn2hi, const ushort_t* __restrict__ Wn2lo,
    const float* __restrict__ bn2,
    const float* __restrict__ lng, const float* __restrict__ lnb,
    float* __restrict__ hnf)
{
    __shared__ ushort_t yhi[128 * 128];
    __shared__ ushort_t ylo[128 * 128];
    __shared__ float bn1s[128], bn2s[128], lngs[128], lnbs[128];

    const int tid = threadIdx.x;
    const int nbase = blockIdx.x * 128;
    const int lane = tid & 63;
    const int wid = tid >> 6;
    const int wm = wid >> 1, wn = wid & 1;
    const int g = lane >> 4, r16 = lane & 15;

    if (tid < 128) { bn1s[tid] = bn1[tid]; bn2s[tid] = bn2[tid]; lngs[tid] = lng[tid]; lnbs[tid] = lnb[tid]; }
    __syncthreads();

    // layer 1: [mi | h] @ Wn1^T, K=256, split A and B
    f32x4 acc[4][4];
    #pragma unroll
    for (int mt = 0; mt < 4; ++mt)
        #pragma unroll
        for (int nt = 0; nt < 4; ++nt) acc[mt][nt] = (f32x4){0.f, 0.f, 0.f, 0.f};
    for (int c = 0; c < 8; ++c) {
        short8v ahi[4], alo[4], bhi[4], blo[4];
        #pragma unroll
        for (int mt = 0; mt < 4; ++mt) {
            int row = nbase + wm * 64 + mt * 16 + r16;
            if (row > NN - 1) row = NN - 1;
            const float* src = (c < 4) ? (mi + (size_t)row * HD + c * 32 + g * 8)
                                       : (h + (size_t)row * HD + (c - 4) * 32 + g * 8);
            cvt8x2(src, ahi[mt], alo[mt]);
        }
        #pragma unroll
        for (int nt = 0; nt < 4; ++nt) {
            size_t wo = (size_t)(wn * 64 + nt * 16 + r16) * 256 + c * 32 + g * 8;
            bhi[nt] = *(const short8v*)(Wn1hi + wo);
            blo[nt] = *(const short8v*)(Wn1lo + wo);
        }
        #pragma unroll
        for (int mt = 0; mt < 4; ++mt)
            #pragma unroll
            for (int nt = 0; nt < 4; ++nt) {
                acc[mt][nt] = MFMA16(ahi[mt], bhi[nt], acc[mt][nt]);
                acc[mt][nt] = MFMA16(ahi[mt], blo[nt], acc[mt][nt]);
                acc[mt][nt] = MFMA16(alo[mt], bhi[nt], acc[mt][nt]);
            }
    }
    // relu(+bn1) -> hi/lo LDS pair
    #pragma unroll
    for (int mt = 0; mt < 4; ++mt)
        #pragma unroll
        for (int nt = 0; nt < 4; ++nt)
            #pragma unroll
            for (int r = 0; r < 4; ++r) {
                int row = wm * 64 + mt * 16 + g * 4 + r;
                int col = wn * 64 + nt * 16 + r16;
                int off = (row << 8) + (((col << 1)) ^ ((row & 15) << 4));
                float v = fmaxf(acc[mt][nt][r] + bn1s[col], 0.f);
                ushort_t hh, ll; splitf(v, hh, ll);
                *(ushort_t*)((char*)yhi + off) = hh;
                *(ushort_t*)((char*)ylo + off) = ll;
            }
    __syncthreads();

    // layer 2: y1 @ Wn2^T, split A and B
    #pragma unroll
    for (int mt = 0; mt < 4; ++mt)
        #pragma unroll
        for (int nt = 0; nt < 4; ++nt) acc[mt][nt] = (f32x4){0.f, 0.f, 0.f, 0.f};
    #pragma unroll
    for (int c = 0; c < 4; ++c) {
        short8v ahi[4], alo[4], bhi[4], blo[4];
        #pragma unroll
        for (int mt = 0; mt < 4; ++mt) {
            int row = wm * 64 + mt * 16 + r16;
            int off = (row << 8) + ((c * 64 + g * 16) ^ (r16 << 4));
            ahi[mt] = *(const short8v*)((const char*)yhi + off);
            alo[mt] = *(const short8v*)((const char*)ylo + off);
        }
        #pragma unroll
        for (int nt = 0; nt < 4; ++nt) {
            size_t wo = (size_t)(wn * 64 + nt * 16 + r16) * 128 + c * 32 + g * 8;
            bhi[nt] = *(const short8v*)(Wn2hi + wo);
            blo[nt] = *(const short8v*)(Wn2lo + wo);
        }
        #pragma unroll
        for (int mt = 0; mt < 4; ++mt)
            #pragma unroll
            for (int nt = 0; nt < 4; ++nt) {
                acc[mt][nt] = MFMA16(ahi[mt], bhi[nt], acc[mt][nt]);
                acc[mt][nt] = MFMA16(ahi[mt], blo[nt], acc[mt][nt]);
                acc[mt][nt] = MFMA16(alo[mt], bhi[nt], acc[mt][nt]);
            }
    }
    __syncthreads();   // all layer-2 reads done -> safe to overwrite
    #pragma unroll
    for (int mt = 0; mt < 4; ++mt)
        #pragma unroll
        for (int nt = 0; nt < 4; ++nt)
            #pragma unroll
            for (int r = 0; r < 4; ++r) {
                int row = wm * 64 + mt * 16 + g * 4 + r;
                int col = wn * 64 + nt * 16 + r16;
                int off = (row << 8) + (((col << 1)) ^ ((row & 15) << 4));
                float v = acc[mt][nt][r] + bn2s[col];
                ushort_t hh, ll; splitf(v, hh, ll);
                *(ushort_t*)((char*)yhi + off) = hh;
                *(ushort_t*)((char*)ylo + off) = ll;
            }
    __syncthreads();

    // layernorm + clip + store hn fp32 (2 threads per row, 8 chunks each = FULL 128 cols)
    {
        const int row = tid >> 1, hf = tid & 1;
        const int rowg = nbase + row;
        float s1 = 0.f, s2 = 0.f;
        float vals[64];
        #pragma unroll
        for (int q = 0; q < 8; ++q) {
            int c8 = hf * 8 + q;
            int off = (row << 8) + ((c8 * 16) ^ ((row & 15) << 4));
            short8v vh = *(const short8v*)((const char*)yhi + off);
            short8v vl = *(const short8v*)((const char*)ylo + off);
            #pragma unroll
            for (int j = 0; j < 8; ++j) {
                float v = b2f((ushort_t)vh[j]) + b2f((ushort_t)vl[j]);
                vals[q * 8 + j] = v;
                s1 += v; s2 += v * v;
            }
        }
        s1 += __shfl_xor(s1, 1);
        s2 += __shfl_xor(s2, 1);
        float mu = s1 * (1.f / HD);
        float var = s2 * (1.f / HD) - mu * mu;
        float rs = rsqrtf(fmaxf(var, 0.f) + 1e-5f);
        if (rowg < NN) {
            #pragma unroll
            for (int q = 0; q < 8; ++q) {
                int c8 = hf * 8 + q;
                f32x4 o0, o1;
                #pragma unroll
                for (int j = 0; j < 8; ++j) {
                    int col = c8 * 8 + j;
                    float v = (vals[q * 8 + j] - mu) * rs * lngs[col] + lnbs[col];
                    v = fminf(fmaxf(v, -10.f), 10.f);
                    if (j < 4) o0[j] = v; else o1[j - 4] = v;
                }
                *(f32x4*)(hnf + (size_t)rowg * HD + c8 * 8) = o0;
                *(f32x4*)(hnf + (size_t)rowg * HD + c8 * 8 + 4) = o1;
            }
        }
    }
}

// ---------------- coord update (cnt from histogram) ----------------
__global__ __launch_bounds__(256) void coord_kernel(
    const float* __restrict__ coord, const float* __restrict__ ssum,
    const int* __restrict__ histI, float* __restrict__ outp)
{
    int idx = blockIdx.x * 256 + threadIdx.x;
    if (idx < NN * 3) {
        int n = idx / 3;
        float c = (float)histI[n];
        outp[idx] = coord[idx] + ssum[idx] / fmaxf(c, 1.f);
    }
}

// ---------------- mamba in_proj (split MFMA, ~fp32): u bf16, silu(z) fp32 ----------------
__global__ __launch_bounds__(256) void xz_mfma(
    const float* __restrict__ hnf,
    const ushort_t* __restrict__ Wiphi, const ushort_t* __restrict__ Wiplo,
    ushort_t* __restrict__ ub, float* __restrict__ zs)
{
    const int tid = threadIdx.x;
    const int lane = tid & 63;
    const int wn = tid >> 6;               // 4 waves over 256 output cols
    const int g = lane >> 4, r16 = lane & 15;
    const int rbase = blockIdx.x * 64;

    f32x4 acc[4][4];
    #pragma unroll
    for (int mt = 0; mt < 4; ++mt)
        #pragma unroll
        for (int nt = 0; nt < 4; ++nt) acc[mt][nt] = (f32x4){0.f, 0.f, 0.f, 0.f};

    for (int c = 0; c < 4; ++c) {
        short8v ahi[4], alo[4], bhi[4], blo[4];
        #pragma unroll
        for (int mt = 0; mt < 4; ++mt) {
            int row = rbase + mt * 16 + r16;
            if (row > NN - 1) row = NN - 1;
            cvt8x2(hnf + (size_t)row * HD + c * 32 + g * 8, ahi[mt], alo[mt]);
        }
        #pragma unroll
        for (int nt = 0; nt < 4; ++nt) {
            size_t wo = (size_t)(wn * 64 + nt * 16 + r16) * 128 + c * 32 + g * 8;
            bhi[nt] = *(const short8v*)(Wiphi + wo);
            blo[nt] = *(const short8v*)(Wiplo + wo);
        }
        #pragma unroll
        for (int mt = 0; mt < 4; ++mt)
            #pragma unroll
            for (int nt = 0; nt < 4; ++nt) {
                acc[mt][nt] = MFMA16(ahi[mt], bhi[nt], acc[mt][nt]);
                acc[mt][nt] = MFMA16(ahi[mt], blo[nt], acc[mt][nt]);
                acc[mt][nt] = MFMA16(alo[mt], bhi[nt], acc[mt][nt]);
            }
    }
    #pragma unroll
    for (int mt = 0; mt < 4; ++mt)
        #pragma unroll
        for (int nt = 0; nt < 4; ++nt)
            #pragma unroll
            for (int r = 0; r < 4; ++r) {
                int row = rbase + mt * 16 + g * 4 + r;
                if (row >= NN) continue;
                int j = wn * 64 + nt * 16 + r16;
                float v = acc[mt][nt][r];
                if (j < HD) ub[(size_t)row * HD + j] = f2b(v);
                else        zs[(size_t)row * HD + (j - HD)] = v * sigf(v);
            }
}

// ---- fused conv+silu -> uc; B|C = uc@Wxp8^T; dt = softplus(uc@Wdt2^T+bdt)  (split MFMA) ----
__global__ __launch_bounds__(256) void convdt_mfma(
    const ushort_t* __restrict__ ub, const float* __restrict__ cw,
    const float* __restrict__ cb,
    const ushort_t* __restrict__ Wxp8hi, const ushort_t* __restrict__ Wxp8lo,
    const ushort_t* __restrict__ Wdt2hi, const ushort_t* __restrict__ Wdt2lo,
    const float* __restrict__ bdt,
    float* __restrict__ uc, float* __restrict__ Bm, float* __restrict__ Cm,
    float* __restrict__ dt)
{
    __shared__ ushort_t yhi[128 * 128];
    __shared__ ushort_t ylo[128 * 128];
    __shared__ float cws[128][4], cbs[128], bdts[128];

    const int tid = threadIdx.x;
    const int nbase = blockIdx.x * 128;
    const int lane = tid & 63;
    const int wid = tid >> 6;
    const int wm = wid >> 1, wn = wid & 1;
    const int g = lane >> 4, r16 = lane & 15;

    if (tid < 128) {
        cbs[tid] = cb[tid]; bdts[tid] = bdt[tid];
        #pragma unroll
        for (int k = 0; k < 4; ++k) cws[tid][k] = cw[tid * 4 + k];
    }
    __syncthreads();

    // phase 1: causal depthwise conv + silu -> uc (fp32 global) + hi/lo LDS pair
    for (int it = tid; it < 128 * 16; it += 256) {
        int r = it >> 4, cg = it & 15;
        int t = nbase + r;
        int colb = cg * 8;
        float a[8];
        #pragma unroll
        for (int j = 0; j < 8; ++j) a[j] = cbs[colb + j];
        #pragma unroll
        for (int k = 0; k < 4; ++k) {
            int tt = t - 3 + k;
            if (tt >= 0 && tt < NN) {
                short8v uv = *(const short8v*)(ub + (size_t)tt * HD + colb);
                #pragma unroll
                for (int j = 0; j < 8; ++j) a[j] = fmaf(b2f((ushort_t)uv[j]), cws[colb + j][k], a[j]);
            }
        }
        short8v oh, ol;
        f32x4 u0, u1;
        #pragma unroll
        for (int j = 0; j < 8; ++j) {
            float s = (t < NN) ? a[j] * sigf(a[j]) : 0.f;
            ushort_t hh, ll; splitf(s, hh, ll);
            oh[j] = (short)hh; ol[j] = (short)ll;
            if (j < 4) u0[j] = s; else u1[j - 4] = s;
        }
        int off = (r << 8) + ((cg * 16) ^ ((r & 15) << 4));
        *(short8v*)((char*)yhi + off) = oh;
        *(short8v*)((char*)ylo + off) = ol;
        if (t < NN) {
            *(f32x4*)(uc + (size_t)t * HD + colb) = u0;
            *(f32x4*)(uc + (size_t)t * HD + colb + 4) = u1;
        }
    }
    __syncthreads();

    // phase 2: B|C = uc @ Wxp[8:136]^T  (128 cols), split
    f32x4 acc[4][4];
    #pragma unroll
    for (int mt = 0; mt < 4; ++mt)
        #pragma unroll
        for (int nt = 0; nt < 4; ++nt) acc[mt][nt] = (f32x4){0.f, 0.f, 0.f, 0.f};
    #pragma unroll
    for (int c = 0; c < 4; ++c) {
        short8v ahi[4], alo[4], bhi[4], blo[4];
        #pragma unroll
        for (int mt = 0; mt < 4; ++mt) {
            int row = wm * 64 + mt * 16 + r16;
            int off = (row << 8) + ((c * 64 + g * 16) ^ (r16 << 4));
            ahi[mt] = *(const short8v*)((const char*)yhi + off);
            alo[mt] = *(const short8v*)((const char*)ylo + off);
        }
        #pragma unroll
        for (int nt = 0; nt < 4; ++nt) {
            size_t wo = (size_t)(wn * 64 + nt * 16 + r16) * 128 + c * 32 + g * 8;
            bhi[nt] = *(const short8v*)(Wxp8hi + wo);
            blo[nt] = *(const short8v*)(Wxp8lo + wo);
        }
        #pragma unroll
        for (int mt = 0; mt < 4; ++mt)
            #pragma unroll
            for (int nt = 0; nt < 4; ++nt) {
                acc[mt][nt] = MFMA16(ahi[mt], bhi[nt], acc[mt][nt]);
                acc[mt][nt] = MFMA16(ahi[mt], blo[nt], acc[mt][nt]);
                acc[mt][nt] = MFMA16(alo[mt], bhi[nt], acc[mt][nt]);
            }
    }
    #pragma unroll
    for (int mt = 0; mt < 4; ++mt)
        #pragma unroll
        for (int nt = 0; nt < 4; ++nt)
            #pragma unroll
            for (int r = 0; r < 4; ++r) {
                int row = nbase + wm * 64 + mt * 16 + g * 4 + r;
                if (row >= NN) continue;
                int j = wn * 64 + nt * 16 + r16;
                float v = acc[mt][nt][r];
                if (j < 64) Bm[(size_t)row * 64 + j] = v;
                else        Cm[(size_t)row * 64 + (j - 64)] = v;
            }

    // phase 3: dt = softplus(uc @ Wdt2^T + bdt), split
    #pragma unroll
    for (int mt = 0; mt < 4; ++mt)
        #pragma unroll
        for (int nt = 0; nt < 4; ++nt) acc[mt][nt] = (f32x4){0.f, 0.f, 0.f, 0.f};
    #pragma unroll
    for (int c = 0; c < 4; ++c) {
        short8v ahi[4], alo[4], bhi[4], blo[4];
        #pragma unroll
        for (int mt = 0; mt < 4; ++mt) {
            int row = wm * 64 + mt * 16 + r16;
            int off = (row << 8) + ((c * 64 + g * 16) ^ (r16 << 4));
            ahi[mt] = *(const short8v*)((const char*)yhi + off);
            alo[mt] = *(const short8v*)((const char*)ylo + off);
        }
        #pragma unroll
        for (int nt = 0; nt < 4; ++nt) {
            size_t wo = (size_t)(wn * 64 + nt * 16 + r16) * 128 + c * 32 + g * 8;
            bhi[nt] = *(const short8v*)(Wdt2hi + wo);
            blo[nt] = *(const short8v*)(Wdt2lo + wo);
        }
        #pragma unroll
        for (int mt = 0; mt < 4; ++mt)
            #pragma unroll
            for (int nt = 0; nt < 4; ++nt) {
                acc[mt][nt] = MFMA16(ahi[mt], bhi[nt], acc[mt][nt]);
                acc[mt][nt] = MFMA16(ahi[mt], blo[nt], acc[mt][nt]);
                acc[mt][nt] = MFMA16(alo[mt], bhi[nt], acc[mt][nt]);
            }
    }
    #pragma unroll
    for (int mt = 0; mt < 4; ++mt)
        #pragma unroll
        for (int nt = 0; nt < 4; ++nt)
            #pragma unroll
            for (int r = 0; r < 4; ++r) {
                int row = nbase + wm * 64 + mt * 16 + g * 4 + r;
                if (row >= NN) continue;
                int j = wn * 64 + nt * 16 + r16;
                float a = acc[mt][nt][r] + bdts[j];
                float sp = (a > 20.f) ? a : log1pf(__expf(a));
                dt[(size_t)row * HD + j] = sp;
            }
}

// ---------------- chunked SSM scan ----------------
__global__ __launch_bounds__(256) void scan1_kernel(
    const float* __restrict__ dt, const float* __restrict__ uc,
    const float* __restrict__ Bm, const float* __restrict__ Alog,
    float* __restrict__ cP, float* __restrict__ cS)
{
    int g = blockIdx.x * 256 + threadIdx.x;
    int c = g >> 13;
    int r = g & 8191;
    int hh = r >> 6;
    int d = r & 63;
    float A = -__expf(Alog[hh * 64 + d]);
    float P = 1.f, S = 0.f;
    int t0 = c * CS;
    for (int t = t0; t < t0 + CS; ++t) {
        float dtv = dt[t * HD + hh];
        float a = __expf(dtv * A);
        float bv = Bm[t * 64 + d];
        float uv = uc[t * HD + hh];
        P *= a;
        S = fmaf(a, S, dtv * uv * bv);
    }
    cP[g] = P; cS[g] = S;
}

__global__ __launch_bounds__(256) void scan2_kernel(
    const float* __restrict__ cP, const float* __restrict__ cS, float* __restrict__ cI)
{
    int g = blockIdx.x * 256 + threadIdx.x;
    float S = 0.f;
    for (int c = 0; c < NC; ++c) {
        cI[c * 8192 + g] = S;
        S = fmaf(cP[c * 8192 + g], S, cS[c * 8192 + g]);
    }
}

// 2 d-states per thread: 32 lanes per (c,hh); 5-level shfl reduce
__global__ __launch_bounds__(256) void scan3_kernel(
    const float* __restrict__ dt, const float* __restrict__ uc,
    const float* __restrict__ Bm, const float* __restrict__ Cm,
    const float* __restrict__ Alog, const float* __restrict__ Dskip,
    const float* __restrict__ cI, float* __restrict__ y)
{
    int g = blockIdx.x * 256 + threadIdx.x;   // NC*4096 threads
    int c = g >> 12;
    int r = g & 4095;
    int hh = r >> 5;
    int dp = (r & 31) * 2;
    float A0 = -__expf(Alog[hh * 64 + dp]);
    float A1 = -__expf(Alog[hh * 64 + dp + 1]);
    float s0 = cI[c * 8192 + hh * 64 + dp];
    float s1 = cI[c * 8192 + hh * 64 + dp + 1];
    float Dh = Dskip[hh];
    int t0 = c * CS;
    const int lane31 = threadIdx.x & 31;
    for (int t = t0; t < t0 + CS; ++t) {
        float dtv = dt[t * HD + hh];
        float uv = uc[t * HD + hh];
        float du = dtv * uv;
        float2 bv = *(const float2*)(Bm + (size_t)t * 64 + dp);
        float2 cv = *(const float2*)(Cm + (size_t)t * 64 + dp);
        s0 = fmaf(__expf(dtv * A0), s0, du * bv.x);
        s1 = fmaf(__expf(dtv * A1), s1, du * bv.y);
        float yp = fmaf(s0, cv.x, s1 * cv.y);
        #pragma unroll
        for (int off = 1; off < 32; off <<= 1) yp += __shfl_xor(yp, off);
        if (lane31 == 0) y[t * HD + hh] = yp + Dh * uv;
    }
}

// ---------------- out_proj (split MFMA, ~fp32): (y*silu(z)) @ Wop^T ----------------
__global__ __launch_bounds__(256) void out_mfma(
    const float* __restrict__ y, const float* __restrict__ zs,
    const ushort_t* __restrict__ Wophi, const ushort_t* __restrict__ Woplo,
    float* __restrict__ outp)
{
    const int tid = threadIdx.x;
    const int lane = tid & 63;
    const int wid = tid >> 6;
    const int wm = wid >> 1, wn = wid & 1;
    const int g = lane >> 4, r16 = lane & 15;
    const int nbase = blockIdx.x * 128;

    f32x4 acc[4][4];
    #pragma unroll
    for (int mt = 0; mt < 4; ++mt)
        #pragma unroll
        for (int nt = 0; nt < 4; ++nt) acc[mt][nt] = (f32x4){0.f, 0.f, 0.f, 0.f};

    for (int c = 0; c < 4; ++c) {
        short8v ahi[4], alo[4], bhi[4], blo[4];
        #pragma unroll
        for (int mt = 0; mt < 4; ++mt) {
            int row = nbase + wm * 64 + mt * 16 + r16;
            if (row > NN - 1) row = NN - 1;
            const float* yp = y + (size_t)row * HD + c * 32 + g * 8;
            const float* zp = zs + (size_t)row * HD + c * 32 + g * 8;
            #pragma unroll
            for (int j = 0; j < 8; ++j) {
                float v = yp[j] * zp[j];
                ushort_t hh, ll; splitf(v, hh, ll);
                ahi[mt][j] = (short)hh; alo[mt][j] = (short)ll;
            }
        }
        #pragma unroll
        for (int nt = 0; nt < 4; ++nt) {
            size_t wo = (size_t)(wn * 64 + nt * 16 + r16) * 128 + c * 32 + g * 8;
            bhi[nt] = *(const short8v*)(Wophi + wo);
            blo[nt] = *(const short8v*)(Woplo + wo);
        }
        #pragma unroll
        for (int mt = 0; mt < 4; ++mt)
            #pragma unroll
            for (int nt = 0; nt < 4; ++nt) {
                acc[mt][nt] = MFMA16(ahi[mt], bhi[nt], acc[mt][nt]);
                acc[mt][nt] = MFMA16(ahi[mt], blo[nt], acc[mt][nt]);
                acc[mt][nt] = MFMA16(alo[mt], bhi[nt], acc[mt][nt]);
            }
    }
    #pragma unroll
    for (int mt = 0; mt < 4; ++mt)
        #pragma unroll
        for (int nt = 0; nt < 4; ++nt)
            #pragma unroll
            for (int r = 0; r < 4; ++r) {
                int row = nbase + wm * 64 + mt * 16 + g * 4 + r;
                if (row < NN)
                    outp[(size_t)row * HD + wn * 64 + nt * 16 + r16] = acc[mt][nt][r];
            }
}

extern "C" void kernel_launch(void* const* d_in, const int* in_sizes, int n_in,
                              void* d_out, int out_size, void* d_ws, size_t ws_size,
                              hipStream_t stream)
{
    const float* h     = (const float*)d_in[0];
    const float* coord = (const float*)d_in[1];
    const int*   ei    = (const int*)d_in[2];
    const float* We1   = (const float*)d_in[3];
    const float* be1   = (const float*)d_in[4];
    const float* We2   = (const float*)d_in[5];
    const float* be2   = (const float*)d_in[6];
    const float* watt  = (const float*)d_in[7];
    const float* batt  = (const float*)d_in[8];
    const float* Wn1   = (const float*)d_in[9];
    const float* bn1   = (const float*)d_in[10];
    const float* Wn2   = (const float*)d_in[11];
    const float* bn2   = (const float*)d_in[12];
    const float* Wc1   = (const float*)d_in[13];
    const float* bc1   = (const float*)d_in[14];
    const float* Wc2   = (const float*)d_in[15];
    const float* lng   = (const float*)d_in[16];
    const float* lnb   = (const float*)d_in[17];
    const float* Wip   = (const float*)d_in[18];
    const float* convw = (const float*)d_in[19];
    const float* convb = (const float*)d_in[20];
    const float* Wxp   = (const float*)d_in[21];
    const float* Wdt   = (const float*)d_in[22];
    const float* bdt   = (const float*)d_in[23];
    const float* Alog  = (const float*)d_in[24];
    const float* Dskip = (const float*)d_in[25];
    const float* Wop   = (const float*)d_in[26];

    float* ws   = (float*)d_ws;
    float* mi   = ws;                                  // NN*HD f32 (zeroed; reused as y after node)
    float* ssum = mi   + (size_t)NN * HD;              // NN*3  f32 (zeroed)
    int*   histI  = (int*)(ssum + (size_t)NN * 3);     // NN (zeroed)
    int*   cursor = histI + NN;                        // NN (zeroed)
    int*   baseI  = cursor + NN;                       // NN
    int*   perm   = baseI + NN;                        // EE
    float* zsb  = (float*)(perm + EE);                 // NN*HD
    float* ucb  = zsb  + (size_t)NN * HD;              // NN*HD
    float* dtb  = ucb  + (size_t)NN * HD;              // NN*HD
    float* Bm   = dtb  + (size_t)NN * HD;              // NN*64
    float* Cm   = Bm   + (size_t)NN * 64;              // NN*64
    float* cP   = Cm   + (size_t)NN * 64;              // NC*8192
    float* cSb  = cP   + (size_t)NC * 8192;
    float* cIb  = cSb  + (size_t)NC * 8192;
    ushort_t* ub    = (ushort_t*)(cIb + (size_t)NC * 8192);  // NN*HD bf16
    ushort_t* W12bp = ub + (size_t)NN * HD;            // 256*128
    ushort_t* We2bp = W12bp + 256 * 128;
    ushort_t* Wc1bp = We2bp + 128 * 128;
    ushort_t* Wn1hi = Wc1bp + 128 * 128;               // 128*256 pair
    ushort_t* Wn1lo = Wn1hi + 128 * 256;
    ushort_t* Wn2hi = Wn1lo + 128 * 256;               // 128*128 pair
    ushort_t* Wn2lo = Wn2hi + 128 * 128;
    ushort_t* Wiphi = Wn2lo + 128 * 128;               // 256*128 pair
    ushort_t* Wiplo = Wiphi + 256 * 128;
    ushort_t* Wxp8hi = Wiplo + 256 * 128;              // 128*128 pairs
    ushort_t* Wxp8lo = Wxp8hi + 128 * 128;
    ushort_t* Wdt2hi = Wxp8lo + 128 * 128;
    ushort_t* Wdt2lo = Wdt2hi + 128 * 128;
    ushort_t* Wophi  = Wdt2lo + 128 * 128;
    ushort_t* Woplo  = Wophi + 128 * 128;
    // P12b (NN*256 bf16 = 10.24MB) aliases cP+cS: written by p12, dead after edge.
    ushort_t* P12bp = (ushort_t*)cP;
    // hnf (NN*HD f32 = 10.24MB) also aliases cP+cS: written by node (after edge),
    // dead after xz (before scan1 writes cP/cS).
    float* hnf = cP;
    // y aliases mi: mi consumed by node_mfma, re-zeroed each launch by the memset.
    float* yb = mi;

    float* outp     = (float*)d_out;
    float* coordout = outp + (size_t)NN * HD;

    // zero mi, ssum, histI, cursor
    hipMemsetAsync(ws, 0, (size_t)NN * 133 * 4, stream);

    hist_kernel<<<(EE + 255) / 256, 256, 0, stream>>>(ei, histI);
    prefix_kernel<<<1, 1024, 0, stream>>>(histI, baseI);
    scatter_kernel<<<(EE + 255) / 256, 256, 0, stream>>>(ei, baseI, cursor, perm);
    prep_kernel<<<128, 256, 0, stream>>>(We1, We2, Wc1, Wn1, Wn2, Wip, Wxp, Wdt, Wop,
                                         W12bp, We2bp, Wc1bp,
                                         Wn1hi, Wn1lo, Wn2hi, Wn2lo, Wiphi, Wiplo,
                                         Wxp8hi, Wxp8lo, Wdt2hi, Wdt2lo, Wophi, Woplo);
    p12_kernel<<<(NN + 127) / 128, 256, 0, stream>>>(h, W12bp, P12bp);
    edge_mfma<<<EE / 128, 256, 0, stream>>>(P12bp, coord, ei, perm, We1, be1,
                                            We2bp, be2, watt, batt, Wc1bp, bc1, Wc2,
                                            mi, ssum);
    node_mfma<<<(NN + 127) / 128, 256, 0, stream>>>(mi, h, Wn1hi, Wn1lo, bn1,
                                                    Wn2hi, Wn2lo, bn2, lng, lnb, hnf);
    coord_kernel<<<(NN * 3 + 255) / 256, 256, 0, stream>>>(coord, ssum, histI, coordout);
    xz_mfma<<<(NN + 63) / 64, 256, 0, stream>>>(hnf, Wiphi, Wiplo, ub, zsb);
    convdt_mfma<<<(NN + 127) / 128, 256, 0, stream>>>(ub, convw, convb,
                                                      Wxp8hi, Wxp8lo, Wdt2hi, Wdt2lo,
                                                      bdt, ucb, Bm, Cm, dtb);
    scan1_kernel<<<NC * 8192 / 256, 256, 0, stream>>>(dtb, ucb, Bm, Alog, cP, cSb);
    scan2_kernel<<<8192 / 256, 256, 0, stream>>>(cP, cSb, cIb);
    scan3_kernel<<<NC * 4096 / 256, 256, 0, stream>>>(dtb, ucb, Bm, Cm, Alog, Dskip, cIb, yb);
    out_mfma<<<(NN + 127) / 128, 256, 0, stream>>>(yb, zsb, Wophi, Woplo, outp);
}

// Round 11
// 690.108 us; speedup vs baseline: 4.4150x; 1.1215x over previous
//
#include <hip/hip_runtime.h>
#include <math.h>

#define NN 20000
#define EE 640000
#define HD 128
#define NC 160      // scan chunks
#define CS 125      // chunk size: NC*CS == NN

typedef unsigned short ushort_t;
typedef __attribute__((ext_vector_type(8))) short short8v;
typedef __attribute__((ext_vector_type(4))) float f32x4;

#define MFMA16(a,b,c) __builtin_amdgcn_mfma_f32_16x16x32_bf16(a,b,c,0,0,0)

__device__ __forceinline__ float sigf(float x) { return 1.0f / (1.0f + __expf(-x)); }

__device__ __forceinline__ ushort_t f2b(float x) {
    unsigned u = __builtin_bit_cast(unsigned, x);
    unsigned r = (u + 0x7FFFu + ((u >> 16) & 1u)) >> 16;
    return (ushort_t)r;
}
__device__ __forceinline__ float b2f(ushort_t u) {
    unsigned v = ((unsigned)u) << 16;
    return __builtin_bit_cast(float, v);
}
// split fp32 -> hi/lo bf16 pair (x ~= hi + lo, error ~2^-17 rel)
__device__ __forceinline__ void splitf(float v, ushort_t& h, ushort_t& l) {
    h = f2b(v);
    l = f2b(v - b2f(h));
}
__device__ __forceinline__ void cvt8x2(const float* p, short8v& hi, short8v& lo) {
    #pragma unroll
    for (int j = 0; j < 8; ++j) {
        float v = p[j];
        ushort_t h, l; splitf(v, h, l);
        hi[j] = (short)h; lo[j] = (short)l;
    }
}

// ---------------- counting sort of edges by e0 ----------------
__global__ __launch_bounds__(256) void hist_kernel(const int* __restrict__ ei,
                                                   int* __restrict__ histI)
{
    int i = blockIdx.x * 256 + threadIdx.x;
    if (i < EE) atomicAdd(&histI[ei[i]], 1);
}

__global__ __launch_bounds__(1024) void prefix_kernel(const int* __restrict__ hist,
                                                      int* __restrict__ baseI)
{
    __shared__ int wsum[16];
    const int tid = threadIdx.x, lane = tid & 63, wid = tid >> 6;
    const int PER = 20;                 // 20*1024 >= NN
    int i0 = tid * PER;
    int s = 0;
    for (int k = 0; k < PER; ++k) { int i = i0 + k; if (i < NN) s += hist[i]; }
    int v = s;
    #pragma unroll
    for (int off = 1; off < 64; off <<= 1) {
        int t = __shfl_up(v, off);
        if (lane >= off) v += t;
    }
    if (lane == 63) wsum[wid] = v;
    __syncthreads();
    if (tid == 0) {
        int acc = 0;
        #pragma unroll
        for (int w = 0; w < 16; ++w) { int t = wsum[w]; wsum[w] = acc; acc += t; }
    }
    __syncthreads();
    int excl = v - s + wsum[wid];
    for (int k = 0; k < PER; ++k) {
        int i = i0 + k;
        if (i < NN) { baseI[i] = excl; excl += hist[i]; }
    }
}

__global__ __launch_bounds__(256) void scatter_kernel(const int* __restrict__ ei,
                                                      const int* __restrict__ baseI,
                                                      int* __restrict__ cursor,
                                                      int* __restrict__ perm)
{
    int i = blockIdx.x * 256 + threadIdx.x;
    if (i < EE) {
        int n = ei[i];
        int p = baseI[n] + atomicAdd(&cursor[n], 1);
        perm[p] = i;
    }
}

// ---------------- prep: weight conversions (single bf16 for edge path, hi/lo for mamba) ----
__global__ __launch_bounds__(256) void prep_kernel(
    const float* __restrict__ We1, const float* __restrict__ We2,
    const float* __restrict__ Wc1, const float* __restrict__ Wn1,
    const float* __restrict__ Wn2, const float* __restrict__ Wip,
    const float* __restrict__ Wxp, const float* __restrict__ Wdt,
    const float* __restrict__ Wop,
    ushort_t* __restrict__ W12b, ushort_t* __restrict__ We2b,
    ushort_t* __restrict__ Wc1b,
    ushort_t* __restrict__ Wn1hi, ushort_t* __restrict__ Wn1lo,
    ushort_t* __restrict__ Wn2hi, ushort_t* __restrict__ Wn2lo,
    ushort_t* __restrict__ Wiphi, ushort_t* __restrict__ Wiplo,
    ushort_t* __restrict__ Wxp8hi, ushort_t* __restrict__ Wxp8lo,
    ushort_t* __restrict__ Wdt2hi, ushort_t* __restrict__ Wdt2lo,
    ushort_t* __restrict__ Wophi, ushort_t* __restrict__ Woplo)
{
    int i = blockIdx.x * 256 + threadIdx.x;
    if (i < 256 * 128) {
        int j = i >> 7, k = i & 127;
        W12b[i] = f2b(We1[(j & 127) * 257 + ((j >> 7) << 7) + k]);
        ushort_t h, l;
        splitf(Wn1[i], h, l); Wn1hi[i] = h; Wn1lo[i] = l;
        splitf(Wip[i], h, l); Wiphi[i] = h; Wiplo[i] = l;
    }
    if (i < 128 * 128) {
        We2b[i] = f2b(We2[i]);
        Wc1b[i] = f2b(Wc1[i]);
        ushort_t h, l;
        splitf(Wn2[i], h, l); Wn2hi[i] = h; Wn2lo[i] = l;
        splitf(Wop[i], h, l); Wophi[i] = h; Woplo[i] = l;
        int j = i >> 7, k = i & 127;
        splitf(Wxp[(8 + j) * 128 + k], h, l); Wxp8hi[i] = h; Wxp8lo[i] = l;
        float s = 0.f;
        #pragma unroll
        for (int r = 0; r < 8; ++r) s = fmaf(Wdt[j * 8 + r], Wxp[r * 128 + k], s);
        splitf(s, h, l); Wdt2hi[i] = h; Wdt2lo[i] = l;
    }
}

// ---------------- node projections: P12 = h @ [W1a|W1b]^T ----------------
__global__ __launch_bounds__(256) void p12_kernel(
    const float* __restrict__ h, const ushort_t* __restrict__ W12b,
    ushort_t* __restrict__ P12b)
{
    const int tid = threadIdx.x;
    const int lane = tid & 63;
    const int wid = tid >> 6;
    const int wm = wid >> 1, wn = wid & 1;
    const int g = lane >> 4, r16 = lane & 15;
    const int rbase = blockIdx.x * 128 + wm * 64;

    f32x4 acc[4][8];
    #pragma unroll
    for (int mt = 0; mt < 4; ++mt)
        #pragma unroll
        for (int nt = 0; nt < 8; ++nt) acc[mt][nt] = (f32x4){0.f, 0.f, 0.f, 0.f};

    for (int c = 0; c < 4; ++c) {
        short8v afr[4], bfr[8];
        #pragma unroll
        for (int mt = 0; mt < 4; ++mt) {
            int row = rbase + mt * 16 + r16;
            if (row > NN - 1) row = NN - 1;
            const float* p = h + (size_t)row * HD + c * 32 + g * 8;
            #pragma unroll
            for (int j = 0; j < 8; ++j) afr[mt][j] = (short)f2b(p[j]);
        }
        #pragma unroll
        for (int nt = 0; nt < 8; ++nt)
            bfr[nt] = *(const short8v*)(W12b + (size_t)(wn * 128 + nt * 16 + r16) * 128 + c * 32 + g * 8);
        #pragma unroll
        for (int mt = 0; mt < 4; ++mt)
            #pragma unroll
            for (int nt = 0; nt < 8; ++nt)
                acc[mt][nt] = MFMA16(afr[mt], bfr[nt], acc[mt][nt]);
    }
    #pragma unroll
    for (int mt = 0; mt < 4; ++mt)
        #pragma unroll
        for (int nt = 0; nt < 8; ++nt)
            #pragma unroll
            for (int r = 0; r < 4; ++r) {
                int row = rbase + mt * 16 + g * 4 + r;
                if (row < NN)
                    P12b[(size_t)row * 256 + wn * 128 + nt * 16 + r16] = f2b(acc[mt][nt][r]);
            }
}

// ---------------- edge phase (MFMA bf16, sorted edges, segment-aggregated sums) -------------
__global__ __launch_bounds__(256) void edge_mfma(
    const ushort_t* __restrict__ P12b, const float* __restrict__ coord,
    const int* __restrict__ ei, const int* __restrict__ perm,
    const float* __restrict__ We1, const float* __restrict__ be1,
    const ushort_t* __restrict__ We2b, const float* __restrict__ be2,
    const float* __restrict__ watt, const float* __restrict__ batt,
    const ushort_t* __restrict__ Wc1b, const float* __restrict__ bc1,
    const float* __restrict__ Wc2,
    float* __restrict__ mi, float* __restrict__ ssum)
{
    __shared__ ushort_t ybuf[128 * 128];
    __shared__ float cdp[128][3];
    __shared__ float wcols[128], be1s[128], be2s[128], bc1s[128], watts[128], wc2s[128];
    __shared__ float pq[2][128];
    __shared__ int ej0s[128];

    const int tid = threadIdx.x;
    const int ebase = blockIdx.x * 128;
    const int lane = tid & 63;
    const int wid = tid >> 6;
    const int wm = wid >> 1, wn = wid & 1;
    const int g = lane >> 4, r16 = lane & 15;
    const float batt0 = batt[0];

    // ---- early: per-pair index load + gather issue (before any barrier) ----
    const int e = tid >> 1, hf = tid & 1;
    const int eg = perm[ebase + e];
    const int n0 = ei[eg];
    const int n1 = ei[EE + eg];
    short8v ga[8], gb[8];
    {
        const ushort_t* p1 = P12b + (size_t)n1 * 256 + hf * 64;
        const ushort_t* p2 = P12b + (size_t)n0 * 256 + 128 + hf * 64;
        #pragma unroll
        for (int q = 0; q < 8; ++q) {
            ga[q] = *(const short8v*)(p1 + q * 8);
            gb[q] = *(const short8v*)(p2 + q * 8);
        }
    }
    if (hf == 0) ej0s[e] = n0;
    // stage per-col consts (latency overlaps gathers)
    {
        int t = tid & 127;
        if (tid < 128) {
            wcols[t] = We1[t * 257 + 256];
            be1s[t] = be1[t];
            be2s[t] = be2[t];
        } else {
            bc1s[t] = bc1[t];
            watts[t] = watt[t];
            wc2s[t] = Wc2[t];
        }
    }
    // radial + coord-diff (both pair threads compute rr; even thread writes cdp)
    float rr;
    {
        float d0 = coord[n0 * 3 + 0] - coord[n1 * 3 + 0];
        float d1 = coord[n0 * 3 + 1] - coord[n1 * 3 + 1];
        float d2 = coord[n0 * 3 + 2] - coord[n1 * 3 + 2];
        rr = d0 * d0 + d1 * d1 + d2 * d2;
        if (hf == 0) { cdp[e][0] = d0; cdp[e][1] = d1; cdp[e][2] = d2; }
    }
    __syncthreads();

    // ---- phase A: y1 = relu(P1[e1] + P2[e0] + rad*wcol + be1) -> ybuf ----
    {
        const int colbase = hf * 64;
        #pragma unroll
        for (int q = 0; q < 8; ++q) {
            short8v ov;
            #pragma unroll
            for (int jj = 0; jj < 8; ++jj) {
                int col = colbase + q * 8 + jj;
                float v = b2f((ushort_t)ga[q][jj]) + b2f((ushort_t)gb[q][jj]) + rr * wcols[col] + be1s[col];
                ov[jj] = (short)f2b(fmaxf(v, 0.f));
            }
            int off = (e << 8) + ((colbase * 2 + q * 16) ^ ((e & 15) << 4));
            *(short8v*)((char*)ybuf + off) = ov;
        }
    }
    // preload layer-2 weights (latency hides under the barrier)
    short8v b2_[4][4];
    {
        const ushort_t* W2p = We2b + (size_t)(wn * 64 + r16) * 128 + g * 8;
        #pragma unroll
        for (int nt = 0; nt < 4; ++nt)
            #pragma unroll
            for (int c = 0; c < 4; ++c)
                b2_[nt][c] = *(const short8v*)(W2p + nt * 2048 + c * 32);
    }
    __syncthreads();

    // ---- layer 2: y1 @ We2^T ----
    f32x4 acc[4][4];
    #pragma unroll
    for (int mt = 0; mt < 4; ++mt)
        #pragma unroll
        for (int nt = 0; nt < 4; ++nt) acc[mt][nt] = (f32x4){0.f, 0.f, 0.f, 0.f};
    #pragma unroll
    for (int c = 0; c < 4; ++c) {
        short8v afr[4];
        #pragma unroll
        for (int mt = 0; mt < 4; ++mt) {
            int row = wm * 64 + mt * 16 + r16;
            afr[mt] = *(const short8v*)((const char*)ybuf + (row << 8) + ((c * 64 + g * 16) ^ (r16 << 4)));
        }
        #pragma unroll
        for (int mt = 0; mt < 4; ++mt)
            #pragma unroll
            for (int nt = 0; nt < 4; ++nt)
                acc[mt][nt] = MFMA16(afr[mt], b2_[nt][c], acc[mt][nt]);
    }

    // epilogue 2: mij = relu(+be2); att = sigmoid(mij.watt + batt); ef = mij*att -> ybuf
    {
        float p[4][4];
        #pragma unroll
        for (int mt = 0; mt < 4; ++mt)
            #pragma unroll
            for (int r = 0; r < 4; ++r) p[mt][r] = 0.f;
        #pragma unroll
        for (int mt = 0; mt < 4; ++mt)
            #pragma unroll
            for (int nt = 0; nt < 4; ++nt)
                #pragma unroll
                for (int r = 0; r < 4; ++r) {
                    int col = wn * 64 + nt * 16 + r16;
                    float v = fmaxf(acc[mt][nt][r] + be2s[col], 0.f);
                    acc[mt][nt][r] = v;
                    p[mt][r] += v * watts[col];
                }
        #pragma unroll
        for (int off = 1; off < 16; off <<= 1)
            #pragma unroll
            for (int mt = 0; mt < 4; ++mt)
                #pragma unroll
                for (int r = 0; r < 4; ++r) p[mt][r] += __shfl_xor(p[mt][r], off);
        if (r16 == 0) {
            #pragma unroll
            for (int mt = 0; mt < 4; ++mt)
                #pragma unroll
                for (int r = 0; r < 4; ++r)
                    pq[wn][wm * 64 + mt * 16 + g * 4 + r] = p[mt][r];
        }
        __syncthreads();
        float att[4][4];
        #pragma unroll
        for (int mt = 0; mt < 4; ++mt)
            #pragma unroll
            for (int r = 0; r < 4; ++r) {
                int row = wm * 64 + mt * 16 + g * 4 + r;
                att[mt][r] = sigf(pq[0][row] + pq[1][row] + batt0);
            }
        __syncthreads();   // layer-2 ybuf reads + pq reads done -> safe to overwrite ybuf
        #pragma unroll
        for (int mt = 0; mt < 4; ++mt)
            #pragma unroll
            for (int nt = 0; nt < 4; ++nt)
                #pragma unroll
                for (int r = 0; r < 4; ++r) {
                    int row = wm * 64 + mt * 16 + g * 4 + r;
                    int col = wn * 64 + nt * 16 + r16;
                    int off = (row << 8) + (((col << 1)) ^ ((row & 15) << 4));
                    *(ushort_t*)((char*)ybuf + off) = f2b(acc[mt][nt][r] * att[mt][r]);
                }
    }
    __syncthreads();   // ef visible to all

    // preload layer-3 weights (latency hides under the segment-sum below)
    short8v b3_[4][4];
    {
        const ushort_t* W3p = Wc1b + (size_t)(wn * 64 + r16) * 128 + g * 8;
        #pragma unroll
        for (int nt = 0; nt < 4; ++nt)
            #pragma unroll
            for (int c = 0; c < 4; ++c)
                b3_[nt][c] = *(const short8v*)(W3p + nt * 2048 + c * 32);
    }

    // ---- segment-sum ef over sorted e0 runs -> mi (col-per-thread, coalesced flushes) ----
    {
        const int col = tid & 127, half = tid >> 7;
        const int r0 = half * 64, r1 = r0 + 64;
        float sacc = 0.f; int cur = ej0s[r0];
        for (int r = r0; r < r1; ++r) {
            int node = ej0s[r];
            if (node != cur) {
                atomicAdd(&mi[(size_t)cur * HD + col], sacc);
                sacc = 0.f; cur = node;
            }
            int off = (r << 8) + (((col << 1)) ^ ((r & 15) << 4));
            sacc += b2f(*(const ushort_t*)((const char*)ybuf + off));
        }
        atomicAdd(&mi[(size_t)cur * HD + col], sacc);
    }

    // ---- layer 3: ef @ Wc1^T, dot Wc2 ----
    #pragma unroll
    for (int mt = 0; mt < 4; ++mt)
        #pragma unroll
        for (int nt = 0; nt < 4; ++nt) acc[mt][nt] = (f32x4){0.f, 0.f, 0.f, 0.f};
    #pragma unroll
    for (int c = 0; c < 4; ++c) {
        short8v afr[4];
        #pragma unroll
        for (int mt = 0; mt < 4; ++mt) {
            int row = wm * 64 + mt * 16 + r16;
            afr[mt] = *(const short8v*)((const char*)ybuf + (row << 8) + ((c * 64 + g * 16) ^ (r16 << 4)));
        }
        #pragma unroll
        for (int mt = 0; mt < 4; ++mt)
            #pragma unroll
            for (int nt = 0; nt < 4; ++nt)
                acc[mt][nt] = MFMA16(afr[mt], b3_[nt][c], acc[mt][nt]);
    }
    {
        float q[4][4];
        #pragma unroll
        for (int mt = 0; mt < 4; ++mt)
            #pragma unroll
            for (int r = 0; r < 4; ++r) q[mt][r] = 0.f;
        #pragma unroll
        for (int mt = 0; mt < 4; ++mt)
            #pragma unroll
            for (int nt = 0; nt < 4; ++nt)
                #pragma unroll
                for (int r = 0; r < 4; ++r) {
                    int col = wn * 64 + nt * 16 + r16;
                    float v = fmaxf(acc[mt][nt][r] + bc1s[col], 0.f);
                    q[mt][r] += v * wc2s[col];
                }
        #pragma unroll
        for (int off = 1; off < 16; off <<= 1)
            #pragma unroll
            for (int mt = 0; mt < 4; ++mt)
                #pragma unroll
                for (int r = 0; r < 4; ++r) q[mt][r] += __shfl_xor(q[mt][r], off);
        if (r16 == 0) {
            #pragma unroll
            for (int mt = 0; mt < 4; ++mt)
                #pragma unroll
                for (int r = 0; r < 4; ++r)
                    pq[wn][wm * 64 + mt * 16 + g * 4 + r] = q[mt][r];
        }
        __syncthreads();
        // coord segment sums: 48 lanes, 8 rows each
        if (tid < 48) {
            int c = tid % 3, seg = tid / 3;
            int r0 = seg * 8, r1 = r0 + 8;
            float sacc = 0.f; int cur = ej0s[r0];
            for (int r = r0; r < r1; ++r) {
                int node = ej0s[r];
                if (node != cur) {
                    atomicAdd(&ssum[cur * 3 + c], sacc);
                    sacc = 0.f; cur = node;
                }
                float tv = pq[0][r] + pq[1][r];
                float tr = cdp[r][c] * tv;
                tr = fminf(fmaxf(tr, -100.f), 100.f);
                sacc += tr;
            }
            atomicAdd(&ssum[cur * 3 + c], sacc);
        }
    }
}

// ---------------- node MLP + layernorm + clip (split-bf16 MFMA, ~fp32) -> hn fp32 -----------
__global__ __launch_bounds__(256) void node_mfma(
    const float* __restrict__ mi, const float* __restrict__ h,
    const ushort_t* __restrict__ Wn1hi, const ushort_t* __restrict__ Wn1lo,
    const float* __restrict__ bn1,
    const ushort_t* __restrict__ Wn2hi, const ushort_t* __restrict__ Wn2lo,
    const float* __restrict__ bn2,
    const float* __restrict__ lng, const float* __restrict__ lnb,
    float* __restrict__ hnf)
{
    __shared__ ushort_t yhi[128 * 128];
    __shared__ ushort_t ylo[128 * 128];
    __shared__ float bn1s[128], bn2s[128], lngs[128], lnbs[128];

    const int tid = threadIdx.x;
    const int nbase = blockIdx.x * 128;
    const int lane = tid & 63;
    const int wid = tid >> 6;
    const int wm = wid >> 1, wn = wid & 1;
    const int g = lane >> 4, r16 = lane & 15;

    if (tid < 128) { bn1s[tid] = bn1[tid]; bn2s[tid] = bn2[tid]; lngs[tid] = lng[tid]; lnbs[tid] = lnb[tid]; }
    __syncthreads();

    // layer 1: [mi | h] @ Wn1^T, K=256, split A and B
    f32x4 acc[4][4];
    #pragma unroll
    for (int mt = 0; mt < 4; ++mt)
        #pragma unroll
        for (int nt = 0; nt < 4; ++nt) acc[mt][nt] = (f32x4){0.f, 0.f, 0.f, 0.f};
    for (int c = 0; c < 8; ++c) {
        short8v ahi[4], alo[4], bhi[4], blo[4];
        #pragma unroll
        for (int mt = 0; mt < 4; ++mt) {
            int row = nbase + wm * 64 + mt * 16 + r16;
            if (row > NN - 1) row = NN - 1;
            const float* src = (c < 4) ? (mi + (size_t)row * HD + c * 32 + g * 8)
                                       : (h + (size_t)row * HD + (c - 4) * 32 + g * 8);
            cvt8x2(src, ahi[mt], alo[mt]);
        }
        #pragma unroll
        for (int nt = 0; nt < 4; ++nt) {
            size_t wo = (size_t)(wn * 64 + nt * 16 + r16) * 256 + c * 32 + g * 8;
            bhi[nt] = *(const short8v*)(Wn1hi + wo);
            blo[nt] = *(const short8v*)(Wn1lo + wo);
        }
        #pragma unroll
        for (int mt = 0; mt < 4; ++mt)
            #pragma unroll
            for (int nt = 0; nt < 4; ++nt) {
                acc[mt][nt] = MFMA16(ahi[mt], bhi[nt], acc[mt][nt]);
                acc[mt][nt] = MFMA16(ahi[mt], blo[nt], acc[mt][nt]);
                acc[mt][nt] = MFMA16(alo[mt], bhi[nt], acc[mt][nt]);
            }
    }
    // relu(+bn1) -> hi/lo LDS pair
    #pragma unroll
    for (int mt = 0; mt < 4; ++mt)
        #pragma unroll
        for (int nt = 0; nt < 4; ++nt)
            #pragma unroll
            for (int r = 0; r < 4; ++r) {
                int row = wm * 64 + mt * 16 + g * 4 + r;
                int col = wn * 64 + nt * 16 + r16;
                int off = (row << 8) + (((col << 1)) ^ ((row & 15) << 4));
                float v = fmaxf(acc[mt][nt][r] + bn1s[col], 0.f);
                ushort_t hh, ll; splitf(v, hh, ll);
                *(ushort_t*)((char*)yhi + off) = hh;
                *(ushort_t*)((char*)ylo + off) = ll;
            }
    __syncthreads();

    // layer 2: y1 @ Wn2^T, split A and B
    #pragma unroll
    for (int mt = 0; mt < 4; ++mt)
        #pragma unroll
        for (int nt = 0; nt < 4; ++nt) acc[mt][nt] = (f32x4){0.f, 0.f, 0.f, 0.f};
    #pragma unroll
    for (int c = 0; c < 4; ++c) {
        short8v ahi[4], alo[4], bhi[4], blo[4];
        #pragma unroll
        for (int mt = 0; mt < 4; ++mt) {
            int row = wm * 64 + mt * 16 + r16;
            int off = (row << 8) + ((c * 64 + g * 16) ^ (r16 << 4));
            ahi[mt] = *(const short8v*)((const char*)yhi + off);
            alo[mt] = *(const short8v*)((const char*)ylo + off);
        }
        #pragma unroll
        for (int nt = 0; nt < 4; ++nt) {
            size_t wo = (size_t)(wn * 64 + nt * 16 + r16) * 128 + c * 32 + g * 8;
            bhi[nt] = *(const short8v*)(Wn2hi + wo);
            blo[nt] = *(const short8v*)(Wn2lo + wo);
        }
        #pragma unroll
        for (int mt = 0; mt < 4; ++mt)
            #pragma unroll
            for (int nt = 0; nt < 4; ++nt) {
                acc[mt][nt] = MFMA16(ahi[mt], bhi[nt], acc[mt][nt]);
                acc[mt][nt] = MFMA16(ahi[mt], blo[nt], acc[mt][nt]);
                acc[mt][nt] = MFMA16(alo[mt], bhi[nt], acc[mt][nt]);
            }
    }
    __syncthreads();   // all layer-2 reads done -> safe to overwrite
    #pragma unroll
    for (int mt = 0; mt < 4; ++mt)
        #pragma unroll
        for (int nt = 0; nt < 4; ++nt)
            #pragma unroll
            for (int r = 0; r < 4; ++r) {
                int row = wm * 64 + mt * 16 + g * 4 + r;
                int col = wn * 64 + nt * 16 + r16;
                int off = (row << 8) + (((col << 1)) ^ ((row & 15) << 4));
                float v = acc[mt][nt][r] + bn2s[col];
                ushort_t hh, ll; splitf(v, hh, ll);
                *(ushort_t*)((char*)yhi + off) = hh;
                *(ushort_t*)((char*)ylo + off) = ll;
            }
    __syncthreads();

    // layernorm + clip + store hn fp32 (2 threads per row, 8 chunks each = FULL 128 cols)
    {
        const int row = tid >> 1, hf = tid & 1;
        const int rowg = nbase + row;
        float s1 = 0.f, s2 = 0.f;
        float vals[64];
        #pragma unroll
        for (int q = 0; q < 8; ++q) {
            int c8 = hf * 8 + q;
            int off = (row << 8) + ((c8 * 16) ^ ((row & 15) << 4));
            short8v vh = *(const short8v*)((const char*)yhi + off);
            short8v vl = *(const short8v*)((const char*)ylo + off);
            #pragma unroll
            for (int j = 0; j < 8; ++j) {
                float v = b2f((ushort_t)vh[j]) + b2f((ushort_t)vl[j]);
                vals[q * 8 + j] = v;
                s1 += v; s2 += v * v;
            }
        }
        s1 += __shfl_xor(s1, 1);
        s2 += __shfl_xor(s2, 1);
        float mu = s1 * (1.f / HD);
        float var = s2 * (1.f / HD) - mu * mu;
        float rs = rsqrtf(fmaxf(var, 0.f) + 1e-5f);
        if (rowg < NN) {
            #pragma unroll
            for (int q = 0; q < 8; ++q) {
                int c8 = hf * 8 + q;
                f32x4 o0, o1;
                #pragma unroll
                for (int j = 0; j < 8; ++j) {
                    int col = c8 * 8 + j;
                    float v = (vals[q * 8 + j] - mu) * rs * lngs[col] + lnbs[col];
                    v = fminf(fmaxf(v, -10.f), 10.f);
                    if (j < 4) o0[j] = v; else o1[j - 4] = v;
                }
                *(f32x4*)(hnf + (size_t)rowg * HD + c8 * 8) = o0;
                *(f32x4*)(hnf + (size_t)rowg * HD + c8 * 8 + 4) = o1;
            }
        }
    }
}

// ---------------- coord update (cnt from histogram) ----------------
__global__ __launch_bounds__(256) void coord_kernel(
    const float* __restrict__ coord, const float* __restrict__ ssum,
    const int* __restrict__ histI, float* __restrict__ outp)
{
    int idx = blockIdx.x * 256 + threadIdx.x;
    if (idx < NN * 3) {
        int n = idx / 3;
        float c = (float)histI[n];
        outp[idx] = coord[idx] + ssum[idx] / fmaxf(c, 1.f);
    }
}

// ---------------- mamba in_proj (split MFMA, ~fp32): u bf16, silu(z) fp32 ----------------
__global__ __launch_bounds__(256) void xz_mfma(
    const float* __restrict__ hnf,
    const ushort_t* __restrict__ Wiphi, const ushort_t* __restrict__ Wiplo,
    ushort_t* __restrict__ ub, float* __restrict__ zs)
{
    const int tid = threadIdx.x;
    const int lane = tid & 63;
    const int wn = tid >> 6;               // 4 waves over 256 output cols
    const int g = lane >> 4, r16 = lane & 15;
    const int rbase = blockIdx.x * 64;

    f32x4 acc[4][4];
    #pragma unroll
    for (int mt = 0; mt < 4; ++mt)
        #pragma unroll
        for (int nt = 0; nt < 4; ++nt) acc[mt][nt] = (f32x4){0.f, 0.f, 0.f, 0.f};

    for (int c = 0; c < 4; ++c) {
        short8v ahi[4], alo[4], bhi[4], blo[4];
        #pragma unroll
        for (int mt = 0; mt < 4; ++mt) {
            int row = rbase + mt * 16 + r16;
            if (row > NN - 1) row = NN - 1;
            cvt8x2(hnf + (size_t)row * HD + c * 32 + g * 8, ahi[mt], alo[mt]);
        }
        #pragma unroll
        for (int nt = 0; nt < 4; ++nt) {
            size_t wo = (size_t)(wn * 64 + nt * 16 + r16) * 128 + c * 32 + g * 8;
            bhi[nt] = *(const short8v*)(Wiphi + wo);
            blo[nt] = *(const short8v*)(Wiplo + wo);
        }
        #pragma unroll
        for (int mt = 0; mt < 4; ++mt)
            #pragma unroll
            for (int nt = 0; nt < 4; ++nt) {
                acc[mt][nt] = MFMA16(ahi[mt], bhi[nt], acc[mt][nt]);
                acc[mt][nt] = MFMA16(ahi[mt], blo[nt], acc[mt][nt]);
                acc[mt][nt] = MFMA16(alo[mt], bhi[nt], acc[mt][nt]);
            }
    }
    #pragma unroll
    for (int mt = 0; mt < 4; ++mt)
        #pragma unroll
        for (int nt = 0; nt < 4; ++nt)
            #pragma unroll
            for (int r = 0; r < 4; ++r) {
                int row = rbase + mt * 16 + g * 4 + r;
                if (row >= NN) continue;
                int j = wn * 64 + nt * 16 + r16;
                float v = acc[mt][nt][r];
                if (j < HD) ub[(size_t)row * HD + j] = f2b(v);
                else        zs[(size_t)row * HD + (j - HD)] = v * sigf(v);
            }
}

// ---- fused conv+silu -> uc; B|C = uc@Wxp8^T; dt = softplus(uc@Wdt2^T+bdt)  (split MFMA) ----
__global__ __launch_bounds__(256) void convdt_mfma(
    const ushort_t* __restrict__ ub, const float* __restrict__ cw,
    const float* __restrict__ cb,
    const ushort_t* __restrict__ Wxp8hi, const ushort_t* __restrict__ Wxp8lo,
    const ushort_t* __restrict__ Wdt2hi, const ushort_t* __restrict__ Wdt2lo,
    const float* __restrict__ bdt,
    float* __restrict__ uc, float* __restrict__ Bm, float* __restrict__ Cm,
    float* __restrict__ dt)
{
    __shared__ ushort_t yhi[128 * 128];
    __shared__ ushort_t ylo[128 * 128];
    __shared__ float cws[128][4], cbs[128], bdts[128];

    const int tid = threadIdx.x;
    const int nbase = blockIdx.x * 128;
    const int lane = tid & 63;
    const int wid = tid >> 6;
    const int wm = wid >> 1, wn = wid & 1;
    const int g = lane >> 4, r16 = lane & 15;

    if (tid < 128) {
        cbs[tid] = cb[tid]; bdts[tid] = bdt[tid];
        #pragma unroll
        for (int k = 0; k < 4; ++k) cws[tid][k] = cw[tid * 4 + k];
    }
    __syncthreads();

    // phase 1: causal depthwise conv + silu -> uc (fp32 global) + hi/lo LDS pair
    for (int it = tid; it < 128 * 16; it += 256) {
        int r = it >> 4, cg = it & 15;
        int t = nbase + r;
        int colb = cg * 8;
        float a[8];
        #pragma unroll
        for (int j = 0; j < 8; ++j) a[j] = cbs[colb + j];
        #pragma unroll
        for (int k = 0; k < 4; ++k) {
            int tt = t - 3 + k;
            if (tt >= 0 && tt < NN) {
                short8v uv = *(const short8v*)(ub + (size_t)tt * HD + colb);
                #pragma unroll
                for (int j = 0; j < 8; ++j) a[j] = fmaf(b2f((ushort_t)uv[j]), cws[colb + j][k], a[j]);
            }
        }
        short8v oh, ol;
        f32x4 u0, u1;
        #pragma unroll
        for (int j = 0; j < 8; ++j) {
            float s = (t < NN) ? a[j] * sigf(a[j]) : 0.f;
            ushort_t hh, ll; splitf(s, hh, ll);
            oh[j] = (short)hh; ol[j] = (short)ll;
            if (j < 4) u0[j] = s; else u1[j - 4] = s;
        }
        int off = (r << 8) + ((cg * 16) ^ ((r & 15) << 4));
        *(short8v*)((char*)yhi + off) = oh;
        *(short8v*)((char*)ylo + off) = ol;
        if (t < NN) {
            *(f32x4*)(uc + (size_t)t * HD + colb) = u0;
            *(f32x4*)(uc + (size_t)t * HD + colb + 4) = u1;
        }
    }
    __syncthreads();

    // phase 2: B|C = uc @ Wxp[8:136]^T  (128 cols), split
    f32x4 acc[4][4];
    #pragma unroll
    for (int mt = 0; mt < 4; ++mt)
        #pragma unroll
        for (int nt = 0; nt < 4; ++nt) acc[mt][nt] = (f32x4){0.f, 0.f, 0.f, 0.f};
    #pragma unroll
    for (int c = 0; c < 4; ++c) {
        short8v ahi[4], alo[4], bhi[4], blo[4];
        #pragma unroll
        for (int mt = 0; mt < 4; ++mt) {
            int row = wm * 64 + mt * 16 + r16;
            int off = (row << 8) + ((c * 64 + g * 16) ^ (r16 << 4));
            ahi[mt] = *(const short8v*)((const char*)yhi + off);
            alo[mt] = *(const short8v*)((const char*)ylo + off);
        }
        #pragma unroll
        for (int nt = 0; nt < 4; ++nt) {
            size_t wo = (size_t)(wn * 64 + nt * 16 + r16) * 128 + c * 32 + g * 8;
            bhi[nt] = *(const short8v*)(Wxp8hi + wo);
            blo[nt] = *(const short8v*)(Wxp8lo + wo);
        }
        #pragma unroll
        for (int mt = 0; mt < 4; ++mt)
            #pragma unroll
            for (int nt = 0; nt < 4; ++nt) {
                acc[mt][nt] = MFMA16(ahi[mt], bhi[nt], acc[mt][nt]);
                acc[mt][nt] = MFMA16(ahi[mt], blo[nt], acc[mt][nt]);
                acc[mt][nt] = MFMA16(alo[mt], bhi[nt], acc[mt][nt]);
            }
    }
    #pragma unroll
    for (int mt = 0; mt < 4; ++mt)
        #pragma unroll
        for (int nt = 0; nt < 4; ++nt)
            #pragma unroll
            for (int r = 0; r < 4; ++r) {
                int row = nbase + wm * 64 + mt * 16 + g * 4 + r;
                if (row >= NN) continue;
                int j = wn * 64 + nt * 16 + r16;
                float v = acc[mt][nt][r];
                if (j < 64) Bm[(size_t)row * 64 + j] = v;
                else        Cm[(size_t)row * 64 + (j - 64)] = v;
            }

    // phase 3: dt = softplus(uc @ Wdt2^T + bdt), split
    #pragma unroll
    for (int mt = 0; mt < 4; ++mt)
        #pragma unroll
        for (int nt = 0; nt < 4; ++nt) acc[mt][nt] = (f32x4){0.f, 0.f, 0.f, 0.f};
    #pragma unroll
    for (int c = 0; c < 4; ++c) {
        short8v ahi[4], alo[4], bhi[4], blo[4];
        #pragma unroll
        for (int mt = 0; mt < 4; ++mt) {
            int row = wm * 64 + mt * 16 + r16;
            int off = (row << 8) + ((c * 64 + g * 16) ^ (r16 << 4));
            ahi[mt] = *(const short8v*)((const char*)yhi + off);
            alo[mt] = *(const short8v*)((const char*)ylo + off);
        }
        #pragma unroll
        for (int nt = 0; nt < 4; ++nt) {
            size_t wo = (size_t)(wn * 64 + nt * 16 + r16) * 128 + c * 32 + g * 8;
            bhi[nt] = *(const short8v*)(Wdt2hi + wo);
            blo[nt] = *(const short8v*)(Wdt2lo + wo);
        }
        #pragma unroll
        for (int mt = 0; mt < 4; ++mt)
            #pragma unroll
            for (int nt = 0; nt < 4; ++nt) {
                acc[mt][nt] = MFMA16(ahi[mt], bhi[nt], acc[mt][nt]);
                acc[mt][nt] = MFMA16(ahi[mt], blo[nt], acc[mt][nt]);
                acc[mt][nt] = MFMA16(alo[mt], bhi[nt], acc[mt][nt]);
            }
    }
    #pragma unroll
    for (int mt = 0; mt < 4; ++mt)
        #pragma unroll
        for (int nt = 0; nt < 4; ++nt)
            #pragma unroll
            for (int r = 0; r < 4; ++r) {
                int row = nbase + wm * 64 + mt * 16 + g * 4 + r;
                if (row >= NN) continue;
                int j = wn * 64 + nt * 16 + r16;
                float a = acc[mt][nt][r] + bdts[j];
                float sp = (a > 20.f) ? a : log1pf(__expf(a));
                dt[(size_t)row * HD + j] = sp;
            }
}

// ---------------- chunked SSM scan ----------------
__global__ __launch_bounds__(256) void scan1_kernel(
    const float* __restrict__ dt, const float* __restrict__ uc,
    const float* __restrict__ Bm, const float* __restrict__ Alog,
    float* __restrict__ cP, float* __restrict__ cS)
{
    int g = blockIdx.x * 256 + threadIdx.x;
    int c = g >> 13;
    int r = g & 8191;
    int hh = r >> 6;
    int d = r & 63;
    float A = -__expf(Alog[hh * 64 + d]);
    float P = 1.f, S = 0.f;
    int t0 = c * CS;
    for (int t = t0; t < t0 + CS; ++t) {
        float dtv = dt[t * HD + hh];
        float a = __expf(dtv * A);
        float bv = Bm[t * 64 + d];
        float uv = uc[t * HD + hh];
        P *= a;
        S = fmaf(a, S, dtv * uv * bv);
    }
    cP[g] = P; cS[g] = S;
}

__global__ __launch_bounds__(256) void scan2_kernel(
    const float* __restrict__ cP, const float* __restrict__ cS, float* __restrict__ cI)
{
    int g = blockIdx.x * 256 + threadIdx.x;
    float S = 0.f;
    for (int c = 0; c < NC; ++c) {
        cI[c * 8192 + g] = S;
        S = fmaf(cP[c * 8192 + g], S, cS[c * 8192 + g]);
    }
}

// 2 d-states per thread: 32 lanes per (c,hh); 5-level shfl reduce
__global__ __launch_bounds__(256) void scan3_kernel(
    const float* __restrict__ dt, const float* __restrict__ uc,
    const float* __restrict__ Bm, const float* __restrict__ Cm,
    const float* __restrict__ Alog, const float* __restrict__ Dskip,
    const float* __restrict__ cI, float* __restrict__ y)
{
    int g = blockIdx.x * 256 + threadIdx.x;   // NC*4096 threads
    int c = g >> 12;
    int r = g & 4095;
    int hh = r >> 5;
    int dp = (r & 31) * 2;
    float A0 = -__expf(Alog[hh * 64 + dp]);
    float A1 = -__expf(Alog[hh * 64 + dp + 1]);
    float s0 = cI[c * 8192 + hh * 64 + dp];
    float s1 = cI[c * 8192 + hh * 64 + dp + 1];
    float Dh = Dskip[hh];
    int t0 = c * CS;
    const int lane31 = threadIdx.x & 31;
    for (int t = t0; t < t0 + CS; ++t) {
        float dtv = dt[t * HD + hh];
        float uv = uc[t * HD + hh];
        float du = dtv * uv;
        float2 bv = *(const float2*)(Bm + (size_t)t * 64 + dp);
        float2 cv = *(const float2*)(Cm + (size_t)t * 64 + dp);
        s0 = fmaf(__expf(dtv * A0), s0, du * bv.x);
        s1 = fmaf(__expf(dtv * A1), s1, du * bv.y);
        float yp = fmaf(s0, cv.x, s1 * cv.y);
        #pragma unroll
        for (int off = 1; off < 32; off <<= 1) yp += __shfl_xor(yp, off);
        if (lane31 == 0) y[t * HD + hh] = yp + Dh * uv;
    }
}

// ---------------- out_proj (split MFMA, ~fp32): (y*silu(z)) @ Wop^T ----------------
__global__ __launch_bounds__(256) void out_mfma(
    const float* __restrict__ y, const float* __restrict__ zs,
    const ushort_t* __restrict__ Wophi, const ushort_t* __restrict__ Woplo,
    float* __restrict__ outp)
{
    const int tid = threadIdx.x;
    const int lane = tid & 63;
    const int wid = tid >> 6;
    const int wm = wid >> 1, wn = wid & 1;
    const int g = lane >> 4, r16 = lane & 15;
    const int nbase = blockIdx.x * 128;

    f32x4 acc[4][4];
    #pragma unroll
    for (int mt = 0; mt < 4; ++mt)
        #pragma unroll
        for (int nt = 0; nt < 4; ++nt) acc[mt][nt] = (f32x4){0.f, 0.f, 0.f, 0.f};

    for (int c = 0; c < 4; ++c) {
        short8v ahi[4], alo[4], bhi[4], blo[4];
        #pragma unroll
        for (int mt = 0; mt < 4; ++mt) {
            int row = nbase + wm * 64 + mt * 16 + r16;
            if (row > NN - 1) row = NN - 1;
            const float* yp = y + (size_t)row * HD + c * 32 + g * 8;
            const float* zp = zs + (size_t)row * HD + c * 32 + g * 8;
            #pragma unroll
            for (int j = 0; j < 8; ++j) {
                float v = yp[j] * zp[j];
                ushort_t hh, ll; splitf(v, hh, ll);
                ahi[mt][j] = (short)hh; alo[mt][j] = (short)ll;
            }
        }
        #pragma unroll
        for (int nt = 0; nt < 4; ++nt) {
            size_t wo = (size_t)(wn * 64 + nt * 16 + r16) * 128 + c * 32 + g * 8;
            bhi[nt] = *(const short8v*)(Wophi + wo);
            blo[nt] = *(const short8v*)(Woplo + wo);
        }
        #pragma unroll
        for (int mt = 0; mt < 4; ++mt)
            #pragma unroll
            for (int nt = 0; nt < 4; ++nt) {
                acc[mt][nt] = MFMA16(ahi[mt], bhi[nt], acc[mt][nt]);
                acc[mt][nt] = MFMA16(ahi[mt], blo[nt], acc[mt][nt]);
                acc[mt][nt] = MFMA16(alo[mt], bhi[nt], acc[mt][nt]);
            }
    }
    #pragma unroll
    for (int mt = 0; mt < 4; ++mt)
        #pragma unroll
        for (int nt = 0; nt < 4; ++nt)
            #pragma unroll
            for (int r = 0; r < 4; ++r) {
                int row = nbase + wm * 64 + mt * 16 + g * 4 + r;
                if (row < NN)
                    outp[(size_t)row * HD + wn * 64 + nt * 16 + r16] = acc[mt][nt][r];
            }
}

extern "C" void kernel_launch(void* const* d_in, const int* in_sizes, int n_in,
                              void* d_out, int out_size, void* d_ws, size_t ws_size,
                              hipStream_t stream)
{
    const float* h     = (const float*)d_in[0];
    const float* coord = (const float*)d_in[1];
    const int*   ei    = (const int*)d_in[2];
    const float* We1   = (const float*)d_in[3];
    const float* be1   = (const float*)d_in[4];
    const float* We2   = (const float*)d_in[5];
    const float* be2   = (const float*)d_in[6];
    const float* watt  = (const float*)d_in[7];
    const float* batt  = (const float*)d_in[8];
    const float* Wn1   = (const float*)d_in[9];
    const float* bn1   = (const float*)d_in[10];
    const float* Wn2   = (const float*)d_in[11];
    const float* bn2   = (const float*)d_in[12];
    const float* Wc1   = (const float*)d_in[13];
    const float* bc1   = (const float*)d_in[14];
    const float* Wc2   = (const float*)d_in[15];
    const float* lng   = (const float*)d_in[16];
    const float* lnb   = (const float*)d_in[17];
    const float* Wip   = (const float*)d_in[18];
    const float* convw = (const float*)d_in[19];
    const float* convb = (const float*)d_in[20];
    const float* Wxp   = (const float*)d_in[21];
    const float* Wdt   = (const float*)d_in[22];
    const float* bdt   = (const float*)d_in[23];
    const float* Alog  = (const float*)d_in[24];
    const float* Dskip = (const float*)d_in[25];
    const float* Wop   = (const float*)d_in[26];

    float* ws   = (float*)d_ws;
    float* mi   = ws;                                  // NN*HD f32 (zeroed; reused as y after node)
    float* ssum = mi   + (size_t)NN * HD;              // NN*3  f32 (zeroed)
    int*   histI  = (int*)(ssum + (size_t)NN * 3);     // NN (zeroed)
    int*   cursor = histI + NN;                        // NN (zeroed)
    int*   baseI  = cursor + NN;                       // NN
    int*   perm   = baseI + NN;                        // EE
    float* zsb  = (float*)(perm + EE);                 // NN*HD
    float* ucb  = zsb  + (size_t)NN * HD;              // NN*HD
    float* dtb  = ucb  + (size_t)NN * HD;              // NN*HD
    float* Bm   = dtb  + (size_t)NN * HD;              // NN*64
    float* Cm   = Bm   + (size_t)NN * 64;              // NN*64
    float* cP   = Cm   + (size_t)NN * 64;              // NC*8192
    float* cSb  = cP   + (size_t)NC * 8192;
    float* cIb  = cSb  + (size_t)NC * 8192;
    ushort_t* ub    = (ushort_t*)(cIb + (size_t)NC * 8192);  // NN*HD bf16
    ushort_t* W12bp = ub + (size_t)NN * HD;            // 256*128
    ushort_t* We2bp = W12bp + 256 * 128;
    ushort_t* Wc1bp = We2bp + 128 * 128;
    ushort_t* Wn1hi = Wc1bp + 128 * 128;               // 128*256 pair
    ushort_t* Wn1lo = Wn1hi + 128 * 256;
    ushort_t* Wn2hi = Wn1lo + 128 * 256;               // 128*128 pair
    ushort_t* Wn2lo = Wn2hi + 128 * 128;
    ushort_t* Wiphi = Wn2lo + 128 * 128;               // 256*128 pair
    ushort_t* Wiplo = Wiphi + 256 * 128;
    ushort_t* Wxp8hi = Wiplo + 256 * 128;              // 128*128 pairs
    ushort_t* Wxp8lo = Wxp8hi + 128 * 128;
    ushort_t* Wdt2hi = Wxp8lo + 128 * 128;
    ushort_t* Wdt2lo = Wdt2hi + 128 * 128;
    ushort_t* Wophi  = Wdt2lo + 128 * 128;
    ushort_t* Woplo  = Wophi + 128 * 128;
    // P12b (NN*256 bf16 = 10.24MB) aliases cP+cS: written by p12, dead after edge.
    ushort_t* P12bp = (ushort_t*)cP;
    // hnf (NN*HD f32 = 10.24MB) also aliases cP+cS: written by node (after edge),
    // dead after xz (before scan1 writes cP/cS).
    float* hnf = cP;
    // y aliases mi: mi consumed by node_mfma, re-zeroed each launch by the memset.
    float* yb = mi;

    float* outp     = (float*)d_out;
    float* coordout = outp + (size_t)NN * HD;

    // zero mi, ssum, histI, cursor
    hipMemsetAsync(ws, 0, (size_t)NN * 133 * 4, stream);

    hist_kernel<<<(EE + 255) / 256, 256, 0, stream>>>(ei, histI);
    prefix_kernel<<<1, 1024, 0, stream>>>(histI, baseI);
    scatter_kernel<<<(EE + 255) / 256, 256, 0, stream>>>(ei, baseI, cursor, perm);
    prep_kernel<<<128, 256, 0, stream>>>(We1, We2, Wc1, Wn1, Wn2, Wip, Wxp, Wdt, Wop,
                                         W12bp, We2bp, Wc1bp,
                                         Wn1hi, Wn1lo, Wn2hi, Wn2lo, Wiphi, Wiplo,
                                         Wxp8hi, Wxp8lo, Wdt2hi, Wdt2lo, Wophi, Woplo);
    p12_kernel<<<(NN + 127) / 128, 256, 0, stream>>>(h, W12bp, P12bp);
    edge_mfma<<<EE / 128, 256, 0, stream>>>(P12bp, coord, ei, perm, We1, be1,
                                            We2bp, be2, watt, batt, Wc1bp, bc1, Wc2,
                                            mi, ssum);
    node_mfma<<<(NN + 127) / 128, 256, 0, stream>>>(mi, h, Wn1hi, Wn1lo, bn1,
                                                    Wn2hi, Wn2lo, bn2, lng, lnb, hnf);
    coord_kernel<<<(NN * 3 + 255) / 256, 256, 0, stream>>>(coord, ssum, histI, coordout);
    xz_mfma<<<(NN + 63) / 64, 256, 0, stream>>>(hnf, Wiphi, Wiplo, ub, zsb);
    convdt_mfma<<<(NN + 127) / 128, 256, 0, stream>>>(ub, convw, convb,
                                                      Wxp8hi, Wxp8lo, Wdt2hi, Wdt2lo,
                                                      bdt, ucb, Bm, Cm, dtb);
    scan1_kernel<<<NC * 8192 / 256, 256, 0, stream>>>(dtb, ucb, Bm, Alog, cP, cSb);
    scan2_kernel<<<8192 / 256, 256, 0, stream>>>(cP, cSb, cIb);
    scan3_kernel<<<NC * 4096 / 256, 256, 0, stream>>>(dtb, ucb, Bm, Cm, Alog, Dskip, cIb, yb);
    out_mfma<<<(NN + 127) / 128, 256, 0, stream>>>(yb, zsb, Wophi, Woplo, outp);
}

// Round 12
// 651.853 us; speedup vs baseline: 4.6741x; 1.0587x over previous
//
#include <hip/hip_runtime.h>
#include <math.h>

#define NN 20000
#define EE 640000
#define HD 128
#define NC 160      // scan chunks
#define CS 125      // chunk size: NC*CS == NN

typedef unsigned short ushort_t;
typedef __attribute__((ext_vector_type(8))) short short8v;
typedef __attribute__((ext_vector_type(4))) float f32x4;

#define MFMA16(a,b,c) __builtin_amdgcn_mfma_f32_16x16x32_bf16(a,b,c,0,0,0)

__device__ __forceinline__ float sigf(float x) { return 1.0f / (1.0f + __expf(-x)); }

__device__ __forceinline__ ushort_t f2b(float x) {
    unsigned u = __builtin_bit_cast(unsigned, x);
    unsigned r = (u + 0x7FFFu + ((u >> 16) & 1u)) >> 16;
    return (ushort_t)r;
}
__device__ __forceinline__ float b2f(ushort_t u) {
    unsigned v = ((unsigned)u) << 16;
    return __builtin_bit_cast(float, v);
}
// split fp32 -> hi/lo bf16 pair (x ~= hi + lo, error ~2^-17 rel)
__device__ __forceinline__ void splitf(float v, ushort_t& h, ushort_t& l) {
    h = f2b(v);
    l = f2b(v - b2f(h));
}
__device__ __forceinline__ void cvt8x2(const float* p, short8v& hi, short8v& lo) {
    #pragma unroll
    for (int j = 0; j < 8; ++j) {
        float v = p[j];
        ushort_t h, l; splitf(v, h, l);
        hi[j] = (short)h; lo[j] = (short)l;
    }
}

// ---------------- counting sort of edges by e0 ----------------
__global__ __launch_bounds__(256) void hist_kernel(const int* __restrict__ ei,
                                                   int* __restrict__ histI)
{
    int i = blockIdx.x * 256 + threadIdx.x;
    if (i < EE) atomicAdd(&histI[ei[i]], 1);
}

__global__ __launch_bounds__(1024) void prefix_kernel(const int* __restrict__ hist,
                                                      int* __restrict__ baseI)
{
    __shared__ int wsum[16];
    const int tid = threadIdx.x, lane = tid & 63, wid = tid >> 6;
    const int PER = 20;                 // 20*1024 >= NN
    int i0 = tid * PER;
    int s = 0;
    for (int k = 0; k < PER; ++k) { int i = i0 + k; if (i < NN) s += hist[i]; }
    int v = s;
    #pragma unroll
    for (int off = 1; off < 64; off <<= 1) {
        int t = __shfl_up(v, off);
        if (lane >= off) v += t;
    }
    if (lane == 63) wsum[wid] = v;
    __syncthreads();
    if (tid == 0) {
        int acc = 0;
        #pragma unroll
        for (int w = 0; w < 16; ++w) { int t = wsum[w]; wsum[w] = acc; acc += t; }
    }
    __syncthreads();
    int excl = v - s + wsum[wid];
    for (int k = 0; k < PER; ++k) {
        int i = i0 + k;
        if (i < NN) { baseI[i] = excl; excl += hist[i]; }
    }
}

__global__ __launch_bounds__(256) void scatter_kernel(const int* __restrict__ ei,
                                                      const int* __restrict__ baseI,
                                                      int* __restrict__ cursor,
                                                      int* __restrict__ perm)
{
    int i = blockIdx.x * 256 + threadIdx.x;
    if (i < EE) {
        int n = ei[i];
        int p = baseI[n] + atomicAdd(&cursor[n], 1);
        perm[p] = i;
    }
}

// ---------------- prep: weight conversions (single bf16 for edge path, hi/lo for mamba) ----
__global__ __launch_bounds__(256) void prep_kernel(
    const float* __restrict__ We1, const float* __restrict__ We2,
    const float* __restrict__ Wc1, const float* __restrict__ Wn1,
    const float* __restrict__ Wn2, const float* __restrict__ Wip,
    const float* __restrict__ Wxp, const float* __restrict__ Wdt,
    const float* __restrict__ Wop,
    ushort_t* __restrict__ W12b, ushort_t* __restrict__ We2b,
    ushort_t* __restrict__ Wc1b,
    ushort_t* __restrict__ Wn1hi, ushort_t* __restrict__ Wn1lo,
    ushort_t* __restrict__ Wn2hi, ushort_t* __restrict__ Wn2lo,
    ushort_t* __restrict__ Wiphi, ushort_t* __restrict__ Wiplo,
    ushort_t* __restrict__ Wxp8hi, ushort_t* __restrict__ Wxp8lo,
    ushort_t* __restrict__ Wdt2hi, ushort_t* __restrict__ Wdt2lo,
    ushort_t* __restrict__ Wophi, ushort_t* __restrict__ Woplo)
{
    int i = blockIdx.x * 256 + threadIdx.x;
    if (i < 256 * 128) {
        int j = i >> 7, k = i & 127;
        W12b[i] = f2b(We1[(j & 127) * 257 + ((j >> 7) << 7) + k]);
        ushort_t h, l;
        splitf(Wn1[i], h, l); Wn1hi[i] = h; Wn1lo[i] = l;
        splitf(Wip[i], h, l); Wiphi[i] = h; Wiplo[i] = l;
    }
    if (i < 128 * 128) {
        We2b[i] = f2b(We2[i]);
        Wc1b[i] = f2b(Wc1[i]);
        ushort_t h, l;
        splitf(Wn2[i], h, l); Wn2hi[i] = h; Wn2lo[i] = l;
        splitf(Wop[i], h, l); Wophi[i] = h; Woplo[i] = l;
        int j = i >> 7, k = i & 127;
        splitf(Wxp[(8 + j) * 128 + k], h, l); Wxp8hi[i] = h; Wxp8lo[i] = l;
        float s = 0.f;
        #pragma unroll
        for (int r = 0; r < 8; ++r) s = fmaf(Wdt[j * 8 + r], Wxp[r * 128 + k], s);
        splitf(s, h, l); Wdt2hi[i] = h; Wdt2lo[i] = l;
    }
}

// ---------------- node projections: P12 = h @ [W1a|W1b]^T ----------------
__global__ __launch_bounds__(256) void p12_kernel(
    const float* __restrict__ h, const ushort_t* __restrict__ W12b,
    ushort_t* __restrict__ P12b)
{
    const int tid = threadIdx.x;
    const int lane = tid & 63;
    const int wid = tid >> 6;
    const int wm = wid >> 1, wn = wid & 1;
    const int g = lane >> 4, r16 = lane & 15;
    const int rbase = blockIdx.x * 128 + wm * 64;

    f32x4 acc[4][8];
    #pragma unroll
    for (int mt = 0; mt < 4; ++mt)
        #pragma unroll
        for (int nt = 0; nt < 8; ++nt) acc[mt][nt] = (f32x4){0.f, 0.f, 0.f, 0.f};

    for (int c = 0; c < 4; ++c) {
        short8v afr[4], bfr[8];
        #pragma unroll
        for (int mt = 0; mt < 4; ++mt) {
            int row = rbase + mt * 16 + r16;
            if (row > NN - 1) row = NN - 1;
            const float* p = h + (size_t)row * HD + c * 32 + g * 8;
            #pragma unroll
            for (int j = 0; j < 8; ++j) afr[mt][j] = (short)f2b(p[j]);
        }
        #pragma unroll
        for (int nt = 0; nt < 8; ++nt)
            bfr[nt] = *(const short8v*)(W12b + (size_t)(wn * 128 + nt * 16 + r16) * 128 + c * 32 + g * 8);
        #pragma unroll
        for (int mt = 0; mt < 4; ++mt)
            #pragma unroll
            for (int nt = 0; nt < 8; ++nt)
                acc[mt][nt] = MFMA16(afr[mt], bfr[nt], acc[mt][nt]);
    }
    #pragma unroll
    for (int mt = 0; mt < 4; ++mt)
        #pragma unroll
        for (int nt = 0; nt < 8; ++nt)
            #pragma unroll
            for (int r = 0; r < 4; ++r) {
                int row = rbase + mt * 16 + g * 4 + r;
                if (row < NN)
                    P12b[(size_t)row * 256 + wn * 128 + nt * 16 + r16] = f2b(acc[mt][nt][r]);
            }
}

// ---------------- edge phase (MFMA bf16, sorted edges, segment-aggregated sums) -------------
__global__ __launch_bounds__(256) void edge_mfma(
    const ushort_t* __restrict__ P12b, const float* __restrict__ coord,
    const int* __restrict__ ei, const int* __restrict__ perm,
    const float* __restrict__ We1, const float* __restrict__ be1,
    const ushort_t* __restrict__ We2b, const float* __restrict__ be2,
    const float* __restrict__ watt, const float* __restrict__ batt,
    const ushort_t* __restrict__ Wc1b, const float* __restrict__ bc1,
    const float* __restrict__ Wc2,
    float* __restrict__ mi, float* __restrict__ ssum)
{
    __shared__ ushort_t ybuf[128 * 128];
    __shared__ float cdp[128][3];
    __shared__ float wcols[128], be1s[128], be2s[128], bc1s[128], watts[128], wc2s[128];
    __shared__ float pq[2][128];
    __shared__ int ej0s[128];

    const int tid = threadIdx.x;
    const int ebase = blockIdx.x * 128;
    const int lane = tid & 63;
    const int wid = tid >> 6;
    const int wm = wid >> 1, wn = wid & 1;
    const int g = lane >> 4, r16 = lane & 15;
    const float batt0 = batt[0];

    // ---- early: per-pair index load + RANDOM gather issue (P1[e1] only; P2 is L2-local) ----
    const int e = tid >> 1, hf = tid & 1;
    const int eg = perm[ebase + e];
    const int n0 = ei[eg];
    const int n1 = ei[EE + eg];
    short8v ga[8];
    {
        const ushort_t* p1 = P12b + (size_t)n1 * 256 + hf * 64;
        #pragma unroll
        for (int q = 0; q < 8; ++q)
            ga[q] = *(const short8v*)(p1 + q * 8);
    }
    if (hf == 0) ej0s[e] = n0;
    // stage per-col consts (latency overlaps gathers)
    {
        int t = tid & 127;
        if (tid < 128) {
            wcols[t] = We1[t * 257 + 256];
            be1s[t] = be1[t];
            be2s[t] = be2[t];
        } else {
            bc1s[t] = bc1[t];
            watts[t] = watt[t];
            wc2s[t] = Wc2[t];
        }
    }
    // radial + coord-diff (both pair threads compute rr; even thread writes cdp)
    float rr;
    {
        float d0 = coord[n0 * 3 + 0] - coord[n1 * 3 + 0];
        float d1 = coord[n0 * 3 + 1] - coord[n1 * 3 + 1];
        float d2 = coord[n0 * 3 + 2] - coord[n1 * 3 + 2];
        rr = d0 * d0 + d1 * d1 + d2 * d2;
        if (hf == 0) { cdp[e][0] = d0; cdp[e][1] = d1; cdp[e][2] = d2; }
    }
    __syncthreads();

    // ---- phase A: y1 = relu(P1[e1] + P2[e0] + rad*wcol + be1) -> ybuf ----
    {
        short8v gb[8];
        const ushort_t* p2 = P12b + (size_t)n0 * 256 + 128 + hf * 64;
        #pragma unroll
        for (int q = 0; q < 8; ++q)
            gb[q] = *(const short8v*)(p2 + q * 8);
        const int colbase = hf * 64;
        #pragma unroll
        for (int q = 0; q < 8; ++q) {
            short8v ov;
            #pragma unroll
            for (int jj = 0; jj < 8; ++jj) {
                int col = colbase + q * 8 + jj;
                float v = b2f((ushort_t)ga[q][jj]) + b2f((ushort_t)gb[q][jj]) + rr * wcols[col] + be1s[col];
                ov[jj] = (short)f2b(fmaxf(v, 0.f));
            }
            int off = (e << 8) + ((colbase * 2 + q * 16) ^ ((e & 15) << 4));
            *(short8v*)((char*)ybuf + off) = ov;
        }
    }
    // preload layer-2 weights (latency hides under the barrier)
    short8v b2_[4][4];
    {
        const ushort_t* W2p = We2b + (size_t)(wn * 64 + r16) * 128 + g * 8;
        #pragma unroll
        for (int nt = 0; nt < 4; ++nt)
            #pragma unroll
            for (int c = 0; c < 4; ++c)
                b2_[nt][c] = *(const short8v*)(W2p + nt * 2048 + c * 32);
    }
    __syncthreads();

    // ---- layer 2: y1 @ We2^T ----
    f32x4 acc[4][4];
    #pragma unroll
    for (int mt = 0; mt < 4; ++mt)
        #pragma unroll
        for (int nt = 0; nt < 4; ++nt) acc[mt][nt] = (f32x4){0.f, 0.f, 0.f, 0.f};
    #pragma unroll
    for (int c = 0; c < 4; ++c) {
        short8v afr[4];
        #pragma unroll
        for (int mt = 0; mt < 4; ++mt) {
            int row = wm * 64 + mt * 16 + r16;
            afr[mt] = *(const short8v*)((const char*)ybuf + (row << 8) + ((c * 64 + g * 16) ^ (r16 << 4)));
        }
        #pragma unroll
        for (int mt = 0; mt < 4; ++mt)
            #pragma unroll
            for (int nt = 0; nt < 4; ++nt)
                acc[mt][nt] = MFMA16(afr[mt], b2_[nt][c], acc[mt][nt]);
    }

    // epilogue 2: mij = relu(+be2); att = sigmoid(mij.watt + batt); ef = mij*att -> ybuf
    {
        float p[4][4];
        #pragma unroll
        for (int mt = 0; mt < 4; ++mt)
            #pragma unroll
            for (int r = 0; r < 4; ++r) p[mt][r] = 0.f;
        #pragma unroll
        for (int mt = 0; mt < 4; ++mt)
            #pragma unroll
            for (int nt = 0; nt < 4; ++nt)
                #pragma unroll
                for (int r = 0; r < 4; ++r) {
                    int col = wn * 64 + nt * 16 + r16;
                    float v = fmaxf(acc[mt][nt][r] + be2s[col], 0.f);
                    acc[mt][nt][r] = v;
                    p[mt][r] += v * watts[col];
                }
        #pragma unroll
        for (int off = 1; off < 16; off <<= 1)
            #pragma unroll
            for (int mt = 0; mt < 4; ++mt)
                #pragma unroll
                for (int r = 0; r < 4; ++r) p[mt][r] += __shfl_xor(p[mt][r], off);
        if (r16 == 0) {
            #pragma unroll
            for (int mt = 0; mt < 4; ++mt)
                #pragma unroll
                for (int r = 0; r < 4; ++r)
                    pq[wn][wm * 64 + mt * 16 + g * 4 + r] = p[mt][r];
        }
        __syncthreads();
        float att[4][4];
        #pragma unroll
        for (int mt = 0; mt < 4; ++mt)
            #pragma unroll
            for (int r = 0; r < 4; ++r) {
                int row = wm * 64 + mt * 16 + g * 4 + r;
                att[mt][r] = sigf(pq[0][row] + pq[1][row] + batt0);
            }
        __syncthreads();   // layer-2 ybuf reads + pq reads done -> safe to overwrite ybuf
        #pragma unroll
        for (int mt = 0; mt < 4; ++mt)
            #pragma unroll
            for (int nt = 0; nt < 4; ++nt)
                #pragma unroll
                for (int r = 0; r < 4; ++r) {
                    int row = wm * 64 + mt * 16 + g * 4 + r;
                    int col = wn * 64 + nt * 16 + r16;
                    int off = (row << 8) + (((col << 1)) ^ ((row & 15) << 4));
                    *(ushort_t*)((char*)ybuf + off) = f2b(acc[mt][nt][r] * att[mt][r]);
                }
    }
    __syncthreads();   // ef visible to all

    // preload layer-3 weights (latency hides under the segment-sum below)
    short8v b3_[4][4];
    {
        const ushort_t* W3p = Wc1b + (size_t)(wn * 64 + r16) * 128 + g * 8;
        #pragma unroll
        for (int nt = 0; nt < 4; ++nt)
            #pragma unroll
            for (int c = 0; c < 4; ++c)
                b3_[nt][c] = *(const short8v*)(W3p + nt * 2048 + c * 32);
    }

    // ---- segment-sum ef over sorted e0 runs -> mi ----
    // 256 threads = 64 col-pairs x 4 row-quarters; b32 LDS reads (2 cols at once);
    // flushes stay wave-coalesced (whole wave shares rows/cur, contiguous cols).
    {
        const int cp = tid & 63;          // cols 2*cp, 2*cp+1
        const int qr = tid >> 6;          // row quarter
        const int r0 = qr * 32, r1 = r0 + 32;
        const int colbyte = cp * 4;
        float s0 = 0.f, s1 = 0.f;
        int cur = ej0s[r0];
        for (int r = r0; r < r1; ++r) {
            int node = ej0s[r];
            if (node != cur) {
                atomicAdd(&mi[(size_t)cur * HD + 2 * cp], s0);
                atomicAdd(&mi[(size_t)cur * HD + 2 * cp + 1], s1);
                s0 = 0.f; s1 = 0.f; cur = node;
            }
            int off = (r << 8) + (colbyte ^ ((r & 15) << 4));
            unsigned v = *(const unsigned*)((const char*)ybuf + off);
            s0 += b2f((ushort_t)(v & 0xFFFFu));
            s1 += b2f((ushort_t)(v >> 16));
        }
        atomicAdd(&mi[(size_t)cur * HD + 2 * cp], s0);
        atomicAdd(&mi[(size_t)cur * HD + 2 * cp + 1], s1);
    }

    // ---- layer 3: ef @ Wc1^T, dot Wc2 ----
    #pragma unroll
    for (int mt = 0; mt < 4; ++mt)
        #pragma unroll
        for (int nt = 0; nt < 4; ++nt) acc[mt][nt] = (f32x4){0.f, 0.f, 0.f, 0.f};
    #pragma unroll
    for (int c = 0; c < 4; ++c) {
        short8v afr[4];
        #pragma unroll
        for (int mt = 0; mt < 4; ++mt) {
            int row = wm * 64 + mt * 16 + r16;
            afr[mt] = *(const short8v*)((const char*)ybuf + (row << 8) + ((c * 64 + g * 16) ^ (r16 << 4)));
        }
        #pragma unroll
        for (int mt = 0; mt < 4; ++mt)
            #pragma unroll
            for (int nt = 0; nt < 4; ++nt)
                acc[mt][nt] = MFMA16(afr[mt], b3_[nt][c], acc[mt][nt]);
    }
    {
        float q[4][4];
        #pragma unroll
        for (int mt = 0; mt < 4; ++mt)
            #pragma unroll
            for (int r = 0; r < 4; ++r) q[mt][r] = 0.f;
        #pragma unroll
        for (int mt = 0; mt < 4; ++mt)
            #pragma unroll
            for (int nt = 0; nt < 4; ++nt)
                #pragma unroll
                for (int r = 0; r < 4; ++r) {
                    int col = wn * 64 + nt * 16 + r16;
                    float v = fmaxf(acc[mt][nt][r] + bc1s[col], 0.f);
                    q[mt][r] += v * wc2s[col];
                }
        #pragma unroll
        for (int off = 1; off < 16; off <<= 1)
            #pragma unroll
            for (int mt = 0; mt < 4; ++mt)
                #pragma unroll
                for (int r = 0; r < 4; ++r) q[mt][r] += __shfl_xor(q[mt][r], off);
        if (r16 == 0) {
            #pragma unroll
            for (int mt = 0; mt < 4; ++mt)
                #pragma unroll
                for (int r = 0; r < 4; ++r)
                    pq[wn][wm * 64 + mt * 16 + g * 4 + r] = q[mt][r];
        }
        __syncthreads();
        // coord segment sums: 48 lanes, 8 rows each
        if (tid < 48) {
            int c = tid % 3, seg = tid / 3;
            int r0 = seg * 8, r1 = r0 + 8;
            float sacc = 0.f; int cur = ej0s[r0];
            for (int r = r0; r < r1; ++r) {
                int node = ej0s[r];
                if (node != cur) {
                    atomicAdd(&ssum[cur * 3 + c], sacc);
                    sacc = 0.f; cur = node;
                }
                float tv = pq[0][r] + pq[1][r];
                float tr = cdp[r][c] * tv;
                tr = fminf(fmaxf(tr, -100.f), 100.f);
                sacc += tr;
            }
            atomicAdd(&ssum[cur * 3 + c], sacc);
        }
    }
}

// ---------------- node MLP + layernorm + clip (split-bf16 MFMA, ~fp32) -> hn fp32 -----------
__global__ __launch_bounds__(256) void node_mfma(
    const float* __restrict__ mi, const float* __restrict__ h,
    const ushort_t* __restrict__ Wn1hi, const ushort_t* __restrict__ Wn1lo,
    const float* __restrict__ bn1,
    const ushort_t* __restrict__ Wn2hi, const ushort_t* __restrict__ Wn2lo,
    const float* __restrict__ bn2,
    const float* __restrict__ lng, const float* __restrict__ lnb,
    float* __restrict__ hnf)
{
    __shared__ ushort_t yhi[128 * 128];
    __shared__ ushort_t ylo[128 * 128];
    __shared__ float bn1s[128], bn2s[128], lngs[128], lnbs[128];

    const int tid = threadIdx.x;
    const int nbase = blockIdx.x * 128;
    const int lane = tid & 63;
    const int wid = tid >> 6;
    const int wm = wid >> 1, wn = wid & 1;
    const int g = lane >> 4, r16 = lane & 15;

    if (tid < 128) { bn1s[tid] = bn1[tid]; bn2s[tid] = bn2[tid]; lngs[tid] = lng[tid]; lnbs[tid] = lnb[tid]; }
    __syncthreads();

    // layer 1: [mi | h] @ Wn1^T, K=256, split A and B
    f32x4 acc[4][4];
    #pragma unroll
    for (int mt = 0; mt < 4; ++mt)
        #pragma unroll
        for (int nt = 0; nt < 4; ++nt) acc[mt][nt] = (f32x4){0.f, 0.f, 0.f, 0.f};
    for (int c = 0; c < 8; ++c) {
        short8v ahi[4], alo[4], bhi[4], blo[4];
        #pragma unroll
        for (int mt = 0; mt < 4; ++mt) {
            int row = nbase + wm * 64 + mt * 16 + r16;
            if (row > NN - 1) row = NN - 1;
            const float* src = (c < 4) ? (mi + (size_t)row * HD + c * 32 + g * 8)
                                       : (h + (size_t)row * HD + (c - 4) * 32 + g * 8);
            cvt8x2(src, ahi[mt], alo[mt]);
        }
        #pragma unroll
        for (int nt = 0; nt < 4; ++nt) {
            size_t wo = (size_t)(wn * 64 + nt * 16 + r16) * 256 + c * 32 + g * 8;
            bhi[nt] = *(const short8v*)(Wn1hi + wo);
            blo[nt] = *(const short8v*)(Wn1lo + wo);
        }
        #pragma unroll
        for (int mt = 0; mt < 4; ++mt)
            #pragma unroll
            for (int nt = 0; nt < 4; ++nt) {
                acc[mt][nt] = MFMA16(ahi[mt], bhi[nt], acc[mt][nt]);
                acc[mt][nt] = MFMA16(ahi[mt], blo[nt], acc[mt][nt]);
                acc[mt][nt] = MFMA16(alo[mt], bhi[nt], acc[mt][nt]);
            }
    }
    // relu(+bn1) -> hi/lo LDS pair
    #pragma unroll
    for (int mt = 0; mt < 4; ++mt)
        #pragma unroll
        for (int nt = 0; nt < 4; ++nt)
            #pragma unroll
            for (int r = 0; r < 4; ++r) {
                int row = wm * 64 + mt * 16 + g * 4 + r;
                int col = wn * 64 + nt * 16 + r16;
                int off = (row << 8) + (((col << 1)) ^ ((row & 15) << 4));
                float v = fmaxf(acc[mt][nt][r] + bn1s[col], 0.f);
                ushort_t hh, ll; splitf(v, hh, ll);
                *(ushort_t*)((char*)yhi + off) = hh;
                *(ushort_t*)((char*)ylo + off) = ll;
            }
    __syncthreads();

    // layer 2: y1 @ Wn2^T, split A and B
    #pragma unroll
    for (int mt = 0; mt < 4; ++mt)
        #pragma unroll
        for (int nt = 0; nt < 4; ++nt) acc[mt][nt] = (f32x4){0.f, 0.f, 0.f, 0.f};
    #pragma unroll
    for (int c = 0; c < 4; ++c) {
        short8v ahi[4], alo[4], bhi[4], blo[4];
        #pragma unroll
        for (int mt = 0; mt < 4; ++mt) {
            int row = wm * 64 + mt * 16 + r16;
            int off = (row << 8) + ((c * 64 + g * 16) ^ (r16 << 4));
            ahi[mt] = *(const short8v*)((const char*)yhi + off);
            alo[mt] = *(const short8v*)((const char*)ylo + off);
        }
        #pragma unroll
        for (int nt = 0; nt < 4; ++nt) {
            size_t wo = (size_t)(wn * 64 + nt * 16 + r16) * 128 + c * 32 + g * 8;
            bhi[nt] = *(const short8v*)(Wn2hi + wo);
            blo[nt] = *(const short8v*)(Wn2lo + wo);
        }
        #pragma unroll
        for (int mt = 0; mt < 4; ++mt)
            #pragma unroll
            for (int nt = 0; nt < 4; ++nt) {
                acc[mt][nt] = MFMA16(ahi[mt], bhi[nt], acc[mt][nt]);
                acc[mt][nt] = MFMA16(ahi[mt], blo[nt], acc[mt][nt]);
                acc[mt][nt] = MFMA16(alo[mt], bhi[nt], acc[mt][nt]);
            }
    }
    __syncthreads();   // all layer-2 reads done -> safe to overwrite
    #pragma unroll
    for (int mt = 0; mt < 4; ++mt)
        #pragma unroll
        for (int nt = 0; nt < 4; ++nt)
            #pragma unroll
            for (int r = 0; r < 4; ++r) {
                int row = wm * 64 + mt * 16 + g * 4 + r;
                int col = wn * 64 + nt * 16 + r16;
                int off = (row << 8) + (((col << 1)) ^ ((row & 15) << 4));
                float v = acc[mt][nt][r] + bn2s[col];
                ushort_t hh, ll; splitf(v, hh, ll);
                *(ushort_t*)((char*)yhi + off) = hh;
                *(ushort_t*)((char*)ylo + off) = ll;
            }
    __syncthreads();

    // layernorm + clip + store hn fp32 (2 threads per row, 8 chunks each = FULL 128 cols)
    {
        const int row = tid >> 1, hf = tid & 1;
        const int rowg = nbase + row;
        float s1 = 0.f, s2 = 0.f;
        float vals[64];
        #pragma unroll
        for (int q = 0; q < 8; ++q) {
            int c8 = hf * 8 + q;
            int off = (row << 8) + ((c8 * 16) ^ ((row & 15) << 4));
            short8v vh = *(const short8v*)((const char*)yhi + off);
            short8v vl = *(const short8v*)((const char*)ylo + off);
            #pragma unroll
            for (int j = 0; j < 8; ++j) {
                float v = b2f((ushort_t)vh[j]) + b2f((ushort_t)vl[j]);
                vals[q * 8 + j] = v;
                s1 += v; s2 += v * v;
            }
        }
        s1 += __shfl_xor(s1, 1);
        s2 += __shfl_xor(s2, 1);
        float mu = s1 * (1.f / HD);
        float var = s2 * (1.f / HD) - mu * mu;
        float rs = rsqrtf(fmaxf(var, 0.f) + 1e-5f);
        if (rowg < NN) {
            #pragma unroll
            for (int q = 0; q < 8; ++q) {
                int c8 = hf * 8 + q;
                f32x4 o0, o1;
                #pragma unroll
                for (int j = 0; j < 8; ++j) {
                    int col = c8 * 8 + j;
                    float v = (vals[q * 8 + j] - mu) * rs * lngs[col] + lnbs[col];
                    v = fminf(fmaxf(v, -10.f), 10.f);
                    if (j < 4) o0[j] = v; else o1[j - 4] = v;
                }
                *(f32x4*)(hnf + (size_t)rowg * HD + c8 * 8) = o0;
                *(f32x4*)(hnf + (size_t)rowg * HD + c8 * 8 + 4) = o1;
            }
        }
    }
}

// ---------------- coord update (cnt from histogram) ----------------
__global__ __launch_bounds__(256) void coord_kernel(
    const float* __restrict__ coord, const float* __restrict__ ssum,
    const int* __restrict__ histI, float* __restrict__ outp)
{
    int idx = blockIdx.x * 256 + threadIdx.x;
    if (idx < NN * 3) {
        int n = idx / 3;
        float c = (float)histI[n];
        outp[idx] = coord[idx] + ssum[idx] / fmaxf(c, 1.f);
    }
}

// ---------------- mamba in_proj (split MFMA, ~fp32): u bf16, silu(z) fp32 ----------------
__global__ __launch_bounds__(256) void xz_mfma(
    const float* __restrict__ hnf,
    const ushort_t* __restrict__ Wiphi, const ushort_t* __restrict__ Wiplo,
    ushort_t* __restrict__ ub, float* __restrict__ zs)
{
    const int tid = threadIdx.x;
    const int lane = tid & 63;
    const int wn = tid >> 6;               // 4 waves over 256 output cols
    const int g = lane >> 4, r16 = lane & 15;
    const int rbase = blockIdx.x * 64;

    f32x4 acc[4][4];
    #pragma unroll
    for (int mt = 0; mt < 4; ++mt)
        #pragma unroll
        for (int nt = 0; nt < 4; ++nt) acc[mt][nt] = (f32x4){0.f, 0.f, 0.f, 0.f};

    for (int c = 0; c < 4; ++c) {
        short8v ahi[4], alo[4], bhi[4], blo[4];
        #pragma unroll
        for (int mt = 0; mt < 4; ++mt) {
            int row = rbase + mt * 16 + r16;
            if (row > NN - 1) row = NN - 1;
            cvt8x2(hnf + (size_t)row * HD + c * 32 + g * 8, ahi[mt], alo[mt]);
        }
        #pragma unroll
        for (int nt = 0; nt < 4; ++nt) {
            size_t wo = (size_t)(wn * 64 + nt * 16 + r16) * 128 + c * 32 + g * 8;
            bhi[nt] = *(const short8v*)(Wiphi + wo);
            blo[nt] = *(const short8v*)(Wiplo + wo);
        }
        #pragma unroll
        for (int mt = 0; mt < 4; ++mt)
            #pragma unroll
            for (int nt = 0; nt < 4; ++nt) {
                acc[mt][nt] = MFMA16(ahi[mt], bhi[nt], acc[mt][nt]);
                acc[mt][nt] = MFMA16(ahi[mt], blo[nt], acc[mt][nt]);
                acc[mt][nt] = MFMA16(alo[mt], bhi[nt], acc[mt][nt]);
            }
    }
    #pragma unroll
    for (int mt = 0; mt < 4; ++mt)
        #pragma unroll
        for (int nt = 0; nt < 4; ++nt)
            #pragma unroll
            for (int r = 0; r < 4; ++r) {
                int row = rbase + mt * 16 + g * 4 + r;
                if (row >= NN) continue;
                int j = wn * 64 + nt * 16 + r16;
                float v = acc[mt][nt][r];
                if (j < HD) ub[(size_t)row * HD + j] = f2b(v);
                else        zs[(size_t)row * HD + (j - HD)] = v * sigf(v);
            }
}

// ---- fused conv+silu -> uc; B|C = uc@Wxp8^T; dt = softplus(uc@Wdt2^T+bdt)  (split MFMA) ----
__global__ __launch_bounds__(256) void convdt_mfma(
    const ushort_t* __restrict__ ub, const float* __restrict__ cw,
    const float* __restrict__ cb,
    const ushort_t* __restrict__ Wxp8hi, const ushort_t* __restrict__ Wxp8lo,
    const ushort_t* __restrict__ Wdt2hi, const ushort_t* __restrict__ Wdt2lo,
    const float* __restrict__ bdt,
    float* __restrict__ uc, float* __restrict__ Bm, float* __restrict__ Cm,
    float* __restrict__ dt)
{
    __shared__ ushort_t yhi[128 * 128];
    __shared__ ushort_t ylo[128 * 128];
    __shared__ float cws[128][4], cbs[128], bdts[128];

    const int tid = threadIdx.x;
    const int nbase = blockIdx.x * 128;
    const int lane = tid & 63;
    const int wid = tid >> 6;
    const int wm = wid >> 1, wn = wid & 1;
    const int g = lane >> 4, r16 = lane & 15;

    if (tid < 128) {
        cbs[tid] = cb[tid]; bdts[tid] = bdt[tid];
        #pragma unroll
        for (int k = 0; k < 4; ++k) cws[tid][k] = cw[tid * 4 + k];
    }
    __syncthreads();

    // phase 1: causal depthwise conv + silu -> uc (fp32 global) + hi/lo LDS pair
    for (int it = tid; it < 128 * 16; it += 256) {
        int r = it >> 4, cg = it & 15;
        int t = nbase + r;
        int colb = cg * 8;
        float a[8];
        #pragma unroll
        for (int j = 0; j < 8; ++j) a[j] = cbs[colb + j];
        #pragma unroll
        for (int k = 0; k < 4; ++k) {
            int tt = t - 3 + k;
            if (tt >= 0 && tt < NN) {
                short8v uv = *(const short8v*)(ub + (size_t)tt * HD + colb);
                #pragma unroll
                for (int j = 0; j < 8; ++j) a[j] = fmaf(b2f((ushort_t)uv[j]), cws[colb + j][k], a[j]);
            }
        }
        short8v oh, ol;
        f32x4 u0, u1;
        #pragma unroll
        for (int j = 0; j < 8; ++j) {
            float s = (t < NN) ? a[j] * sigf(a[j]) : 0.f;
            ushort_t hh, ll; splitf(s, hh, ll);
            oh[j] = (short)hh; ol[j] = (short)ll;
            if (j < 4) u0[j] = s; else u1[j - 4] = s;
        }
        int off = (r << 8) + ((cg * 16) ^ ((r & 15) << 4));
        *(short8v*)((char*)yhi + off) = oh;
        *(short8v*)((char*)ylo + off) = ol;
        if (t < NN) {
            *(f32x4*)(uc + (size_t)t * HD + colb) = u0;
            *(f32x4*)(uc + (size_t)t * HD + colb + 4) = u1;
        }
    }
    __syncthreads();

    // phase 2: B|C = uc @ Wxp[8:136]^T  (128 cols), split
    f32x4 acc[4][4];
    #pragma unroll
    for (int mt = 0; mt < 4; ++mt)
        #pragma unroll
        for (int nt = 0; nt < 4; ++nt) acc[mt][nt] = (f32x4){0.f, 0.f, 0.f, 0.f};
    #pragma unroll
    for (int c = 0; c < 4; ++c) {
        short8v ahi[4], alo[4], bhi[4], blo[4];
        #pragma unroll
        for (int mt = 0; mt < 4; ++mt) {
            int row = wm * 64 + mt * 16 + r16;
            int off = (row << 8) + ((c * 64 + g * 16) ^ (r16 << 4));
            ahi[mt] = *(const short8v*)((const char*)yhi + off);
            alo[mt] = *(const short8v*)((const char*)ylo + off);
        }
        #pragma unroll
        for (int nt = 0; nt < 4; ++nt) {
            size_t wo = (size_t)(wn * 64 + nt * 16 + r16) * 128 + c * 32 + g * 8;
            bhi[nt] = *(const short8v*)(Wxp8hi + wo);
            blo[nt] = *(const short8v*)(Wxp8lo + wo);
        }
        #pragma unroll
        for (int mt = 0; mt < 4; ++mt)
            #pragma unroll
            for (int nt = 0; nt < 4; ++nt) {
                acc[mt][nt] = MFMA16(ahi[mt], bhi[nt], acc[mt][nt]);
                acc[mt][nt] = MFMA16(ahi[mt], blo[nt], acc[mt][nt]);
                acc[mt][nt] = MFMA16(alo[mt], bhi[nt], acc[mt][nt]);
            }
    }
    #pragma unroll
    for (int mt = 0; mt < 4; ++mt)
        #pragma unroll
        for (int nt = 0; nt < 4; ++nt)
            #pragma unroll
            for (int r = 0; r < 4; ++r) {
                int row = nbase + wm * 64 + mt * 16 + g * 4 + r;
                if (row >= NN) continue;
                int j = wn * 64 + nt * 16 + r16;
                float v = acc[mt][nt][r];
                if (j < 64) Bm[(size_t)row * 64 + j] = v;
                else        Cm[(size_t)row * 64 + (j - 64)] = v;
            }

    // phase 3: dt = softplus(uc @ Wdt2^T + bdt), split
    #pragma unroll
    for (int mt = 0; mt < 4; ++mt)
        #pragma unroll
        for (int nt = 0; nt < 4; ++nt) acc[mt][nt] = (f32x4){0.f, 0.f, 0.f, 0.f};
    #pragma unroll
    for (int c = 0; c < 4; ++c) {
        short8v ahi[4], alo[4], bhi[4], blo[4];
        #pragma unroll
        for (int mt = 0; mt < 4; ++mt) {
            int row = wm * 64 + mt * 16 + r16;
            int off = (row << 8) + ((c * 64 + g * 16) ^ (r16 << 4));
            ahi[mt] = *(const short8v*)((const char*)yhi + off);
            alo[mt] = *(const short8v*)((const char*)ylo + off);
        }
        #pragma unroll
        for (int nt = 0; nt < 4; ++nt) {
            size_t wo = (size_t)(wn * 64 + nt * 16 + r16) * 128 + c * 32 + g * 8;
            bhi[nt] = *(const short8v*)(Wdt2hi + wo);
            blo[nt] = *(const short8v*)(Wdt2lo + wo);
        }
        #pragma unroll
        for (int mt = 0; mt < 4; ++mt)
            #pragma unroll
            for (int nt = 0; nt < 4; ++nt) {
                acc[mt][nt] = MFMA16(ahi[mt], bhi[nt], acc[mt][nt]);
                acc[mt][nt] = MFMA16(ahi[mt], blo[nt], acc[mt][nt]);
                acc[mt][nt] = MFMA16(alo[mt], bhi[nt], acc[mt][nt]);
            }
    }
    #pragma unroll
    for (int mt = 0; mt < 4; ++mt)
        #pragma unroll
        for (int nt = 0; nt < 4; ++nt)
            #pragma unroll
            for (int r = 0; r < 4; ++r) {
                int row = nbase + wm * 64 + mt * 16 + g * 4 + r;
                if (row >= NN) continue;
                int j = wn * 64 + nt * 16 + r16;
                float a = acc[mt][nt][r] + bdts[j];
                float sp = (a > 20.f) ? a : log1pf(__expf(a));
                dt[(size_t)row * HD + j] = sp;
            }
}

// ---------------- chunked SSM scan ----------------
__global__ __launch_bounds__(256) void scan1_kernel(
    const float* __restrict__ dt, const float* __restrict__ uc,
    const float* __restrict__ Bm, const float* __restrict__ Alog,
    float* __restrict__ cP, float* __restrict__ cS)
{
    int g = blockIdx.x * 256 + threadIdx.x;
    int c = g >> 13;
    int r = g & 8191;
    int hh = r >> 6;
    int d = r & 63;
    float A = -__expf(Alog[hh * 64 + d]);
    float P = 1.f, S = 0.f;
    int t0 = c * CS;
    for (int t = t0; t < t0 + CS; ++t) {
        float dtv = dt[t * HD + hh];
        float a = __expf(dtv * A);
        float bv = Bm[t * 64 + d];
        float uv = uc[t * HD + hh];
        P *= a;
        S = fmaf(a, S, dtv * uv * bv);
    }
    cP[g] = P; cS[g] = S;
}

__global__ __launch_bounds__(256) void scan2_kernel(
    const float* __restrict__ cP, const float* __restrict__ cS, float* __restrict__ cI)
{
    int g = blockIdx.x * 256 + threadIdx.x;
    float S = 0.f;
    for (int c = 0; c < NC; ++c) {
        cI[c * 8192 + g] = S;
        S = fmaf(cP[c * 8192 + g], S, cS[c * 8192 + g]);
    }
}

// 2 d-states per thread: 32 lanes per (c,hh); 5-level shfl reduce
__global__ __launch_bounds__(256) void scan3_kernel(
    const float* __restrict__ dt, const float* __restrict__ uc,
    const float* __restrict__ Bm, const float* __restrict__ Cm,
    const float* __restrict__ Alog, const float* __restrict__ Dskip,
    const float* __restrict__ cI, float* __restrict__ y)
{
    int g = blockIdx.x * 256 + threadIdx.x;   // NC*4096 threads
    int c = g >> 12;
    int r = g & 4095;
    int hh = r >> 5;
    int dp = (r & 31) * 2;
    float A0 = -__expf(Alog[hh * 64 + dp]);
    float A1 = -__expf(Alog[hh * 64 + dp + 1]);
    float s0 = cI[c * 8192 + hh * 64 + dp];
    float s1 = cI[c * 8192 + hh * 64 + dp + 1];
    float Dh = Dskip[hh];
    int t0 = c * CS;
    const int lane31 = threadIdx.x & 31;
    for (int t = t0; t < t0 + CS; ++t) {
        float dtv = dt[t * HD + hh];
        float uv = uc[t * HD + hh];
        float du = dtv * uv;
        float2 bv = *(const float2*)(Bm + (size_t)t * 64 + dp);
        float2 cv = *(const float2*)(Cm + (size_t)t * 64 + dp);
        s0 = fmaf(__expf(dtv * A0), s0, du * bv.x);
        s1 = fmaf(__expf(dtv * A1), s1, du * bv.y);
        float yp = fmaf(s0, cv.x, s1 * cv.y);
        #pragma unroll
        for (int off = 1; off < 32; off <<= 1) yp += __shfl_xor(yp, off);
        if (lane31 == 0) y[t * HD + hh] = yp + Dh * uv;
    }
}

// ---------------- out_proj (split MFMA, ~fp32): (y*silu(z)) @ Wop^T ----------------
__global__ __launch_bounds__(256) void out_mfma(
    const float* __restrict__ y, const float* __restrict__ zs,
    const ushort_t* __restrict__ Wophi, const ushort_t* __restrict__ Woplo,
    float* __restrict__ outp)
{
    const int tid = threadIdx.x;
    const int lane = tid & 63;
    const int wid = tid >> 6;
    const int wm = wid >> 1, wn = wid & 1;
    const int g = lane >> 4, r16 = lane & 15;
    const int nbase = blockIdx.x * 128;

    f32x4 acc[4][4];
    #pragma unroll
    for (int mt = 0; mt < 4; ++mt)
        #pragma unroll
        for (int nt = 0; nt < 4; ++nt) acc[mt][nt] = (f32x4){0.f, 0.f, 0.f, 0.f};

    for (int c = 0; c < 4; ++c) {
        short8v ahi[4], alo[4], bhi[4], blo[4];
        #pragma unroll
        for (int mt = 0; mt < 4; ++mt) {
            int row = nbase + wm * 64 + mt * 16 + r16;
            if (row > NN - 1) row = NN - 1;
            const float* yp = y + (size_t)row * HD + c * 32 + g * 8;
            const float* zp = zs + (size_t)row * HD + c * 32 + g * 8;
            #pragma unroll
            for (int j = 0; j < 8; ++j) {
                float v = yp[j] * zp[j];
                ushort_t hh, ll; splitf(v, hh, ll);
                ahi[mt][j] = (short)hh; alo[mt][j] = (short)ll;
            }
        }
        #pragma unroll
        for (int nt = 0; nt < 4; ++nt) {
            size_t wo = (size_t)(wn * 64 + nt * 16 + r16) * 128 + c * 32 + g * 8;
            bhi[nt] = *(const short8v*)(Wophi + wo);
            blo[nt] = *(const short8v*)(Woplo + wo);
        }
        #pragma unroll
        for (int mt = 0; mt < 4; ++mt)
            #pragma unroll
            for (int nt = 0; nt < 4; ++nt) {
                acc[mt][nt] = MFMA16(ahi[mt], bhi[nt], acc[mt][nt]);
                acc[mt][nt] = MFMA16(ahi[mt], blo[nt], acc[mt][nt]);
                acc[mt][nt] = MFMA16(alo[mt], bhi[nt], acc[mt][nt]);
            }
    }
    #pragma unroll
    for (int mt = 0; mt < 4; ++mt)
        #pragma unroll
        for (int nt = 0; nt < 4; ++nt)
            #pragma unroll
            for (int r = 0; r < 4; ++r) {
                int row = nbase + wm * 64 + mt * 16 + g * 4 + r;
                if (row < NN)
                    outp[(size_t)row * HD + wn * 64 + nt * 16 + r16] = acc[mt][nt][r];
            }
}

extern "C" void kernel_launch(void* const* d_in, const int* in_sizes, int n_in,
                              void* d_out, int out_size, void* d_ws, size_t ws_size,
                              hipStream_t stream)
{
    const float* h     = (const float*)d_in[0];
    const float* coord = (const float*)d_in[1];
    const int*   ei    = (const int*)d_in[2];
    const float* We1   = (const float*)d_in[3];
    const float* be1   = (const float*)d_in[4];
    const float* We2   = (const float*)d_in[5];
    const float* be2   = (const float*)d_in[6];
    const float* watt  = (const float*)d_in[7];
    const float* batt  = (const float*)d_in[8];
    const float* Wn1   = (const float*)d_in[9];
    const float* bn1   = (const float*)d_in[10];
    const float* Wn2   = (const float*)d_in[11];
    const float* bn2   = (const float*)d_in[12];
    const float* Wc1   = (const float*)d_in[13];
    const float* bc1   = (const float*)d_in[14];
    const float* Wc2   = (const float*)d_in[15];
    const float* lng   = (const float*)d_in[16];
    const float* lnb   = (const float*)d_in[17];
    const float* Wip   = (const float*)d_in[18];
    const float* convw = (const float*)d_in[19];
    const float* convb = (const float*)d_in[20];
    const float* Wxp   = (const float*)d_in[21];
    const float* Wdt   = (const float*)d_in[22];
    const float* bdt   = (const float*)d_in[23];
    const float* Alog  = (const float*)d_in[24];
    const float* Dskip = (const float*)d_in[25];
    const float* Wop   = (const float*)d_in[26];

    float* ws   = (float*)d_ws;
    float* mi   = ws;                                  // NN*HD f32 (zeroed; reused as y after node)
    float* ssum = mi   + (size_t)NN * HD;              // NN*3  f32 (zeroed)
    int*   histI  = (int*)(ssum + (size_t)NN * 3);     // NN (zeroed)
    int*   cursor = histI + NN;                        // NN (zeroed)
    int*   baseI  = cursor + NN;                       // NN
    int*   perm   = baseI + NN;                        // EE
    float* zsb  = (float*)(perm + EE);                 // NN*HD
    float* ucb  = zsb  + (size_t)NN * HD;              // NN*HD
    float* dtb  = ucb  + (size_t)NN * HD;              // NN*HD
    float* Bm   = dtb  + (size_t)NN * HD;              // NN*64
    float* Cm   = Bm   + (size_t)NN * 64;              // NN*64
    float* cP   = Cm   + (size_t)NN * 64;              // NC*8192
    float* cSb  = cP   + (size_t)NC * 8192;
    float* cIb  = cSb  + (size_t)NC * 8192;
    ushort_t* ub    = (ushort_t*)(cIb + (size_t)NC * 8192);  // NN*HD bf16
    ushort_t* W12bp = ub + (size_t)NN * HD;            // 256*128
    ushort_t* We2bp = W12bp + 256 * 128;
    ushort_t* Wc1bp = We2bp + 128 * 128;
    ushort_t* Wn1hi = Wc1bp + 128 * 128;               // 128*256 pair
    ushort_t* Wn1lo = Wn1hi + 128 * 256;
    ushort_t* Wn2hi = Wn1lo + 128 * 256;               // 128*128 pair
    ushort_t* Wn2lo = Wn2hi + 128 * 128;
    ushort_t* Wiphi = Wn2lo + 128 * 128;               // 256*128 pair
    ushort_t* Wiplo = Wiphi + 256 * 128;
    ushort_t* Wxp8hi = Wiplo + 256 * 128;              // 128*128 pairs
    ushort_t* Wxp8lo = Wxp8hi + 128 * 128;
    ushort_t* Wdt2hi = Wxp8lo + 128 * 128;
    ushort_t* Wdt2lo = Wdt2hi + 128 * 128;
    ushort_t* Wophi  = Wdt2lo + 128 * 128;
    ushort_t* Woplo  = Wophi + 128 * 128;
    // P12b (NN*256 bf16 = 10.24MB) aliases cP+cS: written by p12, dead after edge.
    ushort_t* P12bp = (ushort_t*)cP;
    // hnf (NN*HD f32 = 10.24MB) also aliases cP+cS: written by node (after edge),
    // dead after xz (before scan1 writes cP/cS).
    float* hnf = cP;
    // y aliases mi: mi consumed by node_mfma, re-zeroed each launch by the memset.
    float* yb = mi;

    float* outp     = (float*)d_out;
    float* coordout = outp + (size_t)NN * HD;

    // zero mi, ssum, histI, cursor
    hipMemsetAsync(ws, 0, (size_t)NN * 133 * 4, stream);

    hist_kernel<<<(EE + 255) / 256, 256, 0, stream>>>(ei, histI);
    prefix_kernel<<<1, 1024, 0, stream>>>(histI, baseI);
    scatter_kernel<<<(EE + 255) / 256, 256, 0, stream>>>(ei, baseI, cursor, perm);
    prep_kernel<<<128, 256, 0, stream>>>(We1, We2, Wc1, Wn1, Wn2, Wip, Wxp, Wdt, Wop,
                                         W12bp, We2bp, Wc1bp,
                                         Wn1hi, Wn1lo, Wn2hi, Wn2lo, Wiphi, Wiplo,
                                         Wxp8hi, Wxp8lo, Wdt2hi, Wdt2lo, Wophi, Woplo);
    p12_kernel<<<(NN + 127) / 128, 256, 0, stream>>>(h, W12bp, P12bp);
    edge_mfma<<<EE / 128, 256, 0, stream>>>(P12bp, coord, ei, perm, We1, be1,
                                            We2bp, be2, watt, batt, Wc1bp, bc1, Wc2,
                                            mi, ssum);
    node_mfma<<<(NN + 127) / 128, 256, 0, stream>>>(mi, h, Wn1hi, Wn1lo, bn1,
                                                    Wn2hi, Wn2lo, bn2, lng, lnb, hnf);
    coord_kernel<<<(NN * 3 + 255) / 256, 256, 0, stream>>>(coord, ssum, histI, coordout);
    xz_mfma<<<(NN + 63) / 64, 256, 0, stream>>>(hnf, Wiphi, Wiplo, ub, zsb);
    convdt_mfma<<<(NN + 127) / 128, 256, 0, stream>>>(ub, convw, convb,
                                                      Wxp8hi, Wxp8lo, Wdt2hi, Wdt2lo,
                                                      bdt, ucb, Bm, Cm, dtb);
    scan1_kernel<<<NC * 8192 / 256, 256, 0, stream>>>(dtb, ucb, Bm, Alog, cP, cSb);
    scan2_kernel<<<8192 / 256, 256, 0, stream>>>(cP, cSb, cIb);
    scan3_kernel<<<NC * 4096 / 256, 256, 0, stream>>>(dtb, ucb, Bm, Cm, Alog, Dskip, cIb, yb);
    out_mfma<<<(NN + 127) / 128, 256, 0, stream>>>(yb, zsb, Wophi, Woplo, outp);
}

// Round 13
// 647.842 us; speedup vs baseline: 4.7031x; 1.0062x over previous
//
#include <hip/hip_runtime.h>
#include <math.h>

#define NN 20000
#define EE 640000
#define HD 128
#define NC 160      // scan chunks
#define CS 125      // chunk size: NC*CS == NN

typedef unsigned short ushort_t;
typedef __attribute__((ext_vector_type(8))) short short8v;
typedef __attribute__((ext_vector_type(4))) float f32x4;

#define MFMA16(a,b,c) __builtin_amdgcn_mfma_f32_16x16x32_bf16(a,b,c,0,0,0)

__device__ __forceinline__ float sigf(float x) { return 1.0f / (1.0f + __expf(-x)); }

__device__ __forceinline__ ushort_t f2b(float x) {
    unsigned u = __builtin_bit_cast(unsigned, x);
    unsigned r = (u + 0x7FFFu + ((u >> 16) & 1u)) >> 16;
    return (ushort_t)r;
}
__device__ __forceinline__ float b2f(ushort_t u) {
    unsigned v = ((unsigned)u) << 16;
    return __builtin_bit_cast(float, v);
}
// split fp32 -> hi/lo bf16 pair (x ~= hi + lo, error ~2^-17 rel)
__device__ __forceinline__ void splitf(float v, ushort_t& h, ushort_t& l) {
    h = f2b(v);
    l = f2b(v - b2f(h));
}
__device__ __forceinline__ void cvt8x2(const float* p, short8v& hi, short8v& lo) {
    #pragma unroll
    for (int j = 0; j < 8; ++j) {
        float v = p[j];
        ushort_t h, l; splitf(v, h, l);
        hi[j] = (short)h; lo[j] = (short)l;
    }
}

// ---------------- prefix / scatter for counting sort ----------------
__global__ __launch_bounds__(1024) void prefix_kernel(const int* __restrict__ hist,
                                                      int* __restrict__ baseI)
{
    __shared__ int wsum[16];
    const int tid = threadIdx.x, lane = tid & 63, wid = tid >> 6;
    const int PER = 20;                 // 20*1024 >= NN
    int i0 = tid * PER;
    int s = 0;
    for (int k = 0; k < PER; ++k) { int i = i0 + k; if (i < NN) s += hist[i]; }
    int v = s;
    #pragma unroll
    for (int off = 1; off < 64; off <<= 1) {
        int t = __shfl_up(v, off);
        if (lane >= off) v += t;
    }
    if (lane == 63) wsum[wid] = v;
    __syncthreads();
    if (tid == 0) {
        int acc = 0;
        #pragma unroll
        for (int w = 0; w < 16; ++w) { int t = wsum[w]; wsum[w] = acc; acc += t; }
    }
    __syncthreads();
    int excl = v - s + wsum[wid];
    for (int k = 0; k < PER; ++k) {
        int i = i0 + k;
        if (i < NN) { baseI[i] = excl; excl += hist[i]; }
    }
}

__global__ __launch_bounds__(256) void scatter_kernel(const int* __restrict__ ei,
                                                      const int* __restrict__ baseI,
                                                      int* __restrict__ cursor,
                                                      int* __restrict__ perm)
{
    int i = blockIdx.x * 256 + threadIdx.x;
    if (i < EE) {
        int n = ei[i];
        int p = baseI[n] + atomicAdd(&cursor[n], 1);
        perm[p] = i;
    }
}

// ------- prep (weight conversions) + histogram, fused (independent work, one grid) -------
__global__ __launch_bounds__(256) void prep_hist_kernel(
    const int* __restrict__ ei, int* __restrict__ histI,
    const float* __restrict__ We1, const float* __restrict__ We2,
    const float* __restrict__ Wc1, const float* __restrict__ Wn1,
    const float* __restrict__ Wn2, const float* __restrict__ Wip,
    const float* __restrict__ Wxp, const float* __restrict__ Wdt,
    const float* __restrict__ Wop,
    ushort_t* __restrict__ W12b, ushort_t* __restrict__ We2b,
    ushort_t* __restrict__ Wc1b,
    ushort_t* __restrict__ Wn1hi, ushort_t* __restrict__ Wn1lo,
    ushort_t* __restrict__ Wn2hi, ushort_t* __restrict__ Wn2lo,
    ushort_t* __restrict__ Wiphi, ushort_t* __restrict__ Wiplo,
    ushort_t* __restrict__ Wxp8hi, ushort_t* __restrict__ Wxp8lo,
    ushort_t* __restrict__ Wdt2hi, ushort_t* __restrict__ Wdt2lo,
    ushort_t* __restrict__ Wophi, ushort_t* __restrict__ Woplo)
{
    int i = blockIdx.x * 256 + threadIdx.x;
    if (i < EE) atomicAdd(&histI[ei[i]], 1);
    if (i < 256 * 128) {
        int j = i >> 7, k = i & 127;
        W12b[i] = f2b(We1[(j & 127) * 257 + ((j >> 7) << 7) + k]);
        ushort_t h, l;
        splitf(Wn1[i], h, l); Wn1hi[i] = h; Wn1lo[i] = l;
        splitf(Wip[i], h, l); Wiphi[i] = h; Wiplo[i] = l;
    }
    if (i < 128 * 128) {
        We2b[i] = f2b(We2[i]);
        Wc1b[i] = f2b(Wc1[i]);
        ushort_t h, l;
        splitf(Wn2[i], h, l); Wn2hi[i] = h; Wn2lo[i] = l;
        splitf(Wop[i], h, l); Wophi[i] = h; Woplo[i] = l;
        int j = i >> 7, k = i & 127;
        splitf(Wxp[(8 + j) * 128 + k], h, l); Wxp8hi[i] = h; Wxp8lo[i] = l;
        float s = 0.f;
        #pragma unroll
        for (int r = 0; r < 8; ++r) s = fmaf(Wdt[j * 8 + r], Wxp[r * 128 + k], s);
        splitf(s, h, l); Wdt2hi[i] = h; Wdt2lo[i] = l;
    }
}

// ---------------- node projections: P12 = h @ [W1a|W1b]^T ----------------
__global__ __launch_bounds__(256) void p12_kernel(
    const float* __restrict__ h, const ushort_t* __restrict__ W12b,
    ushort_t* __restrict__ P12b)
{
    const int tid = threadIdx.x;
    const int lane = tid & 63;
    const int wid = tid >> 6;
    const int wm = wid >> 1, wn = wid & 1;
    const int g = lane >> 4, r16 = lane & 15;
    const int rbase = blockIdx.x * 128 + wm * 64;

    f32x4 acc[4][8];
    #pragma unroll
    for (int mt = 0; mt < 4; ++mt)
        #pragma unroll
        for (int nt = 0; nt < 8; ++nt) acc[mt][nt] = (f32x4){0.f, 0.f, 0.f, 0.f};

    for (int c = 0; c < 4; ++c) {
        short8v afr[4], bfr[8];
        #pragma unroll
        for (int mt = 0; mt < 4; ++mt) {
            int row = rbase + mt * 16 + r16;
            if (row > NN - 1) row = NN - 1;
            const float* p = h + (size_t)row * HD + c * 32 + g * 8;
            #pragma unroll
            for (int j = 0; j < 8; ++j) afr[mt][j] = (short)f2b(p[j]);
        }
        #pragma unroll
        for (int nt = 0; nt < 8; ++nt)
            bfr[nt] = *(const short8v*)(W12b + (size_t)(wn * 128 + nt * 16 + r16) * 128 + c * 32 + g * 8);
        #pragma unroll
        for (int mt = 0; mt < 4; ++mt)
            #pragma unroll
            for (int nt = 0; nt < 8; ++nt)
                acc[mt][nt] = MFMA16(afr[mt], bfr[nt], acc[mt][nt]);
    }
    #pragma unroll
    for (int mt = 0; mt < 4; ++mt)
        #pragma unroll
        for (int nt = 0; nt < 8; ++nt)
            #pragma unroll
            for (int r = 0; r < 4; ++r) {
                int row = rbase + mt * 16 + g * 4 + r;
                if (row < NN)
                    P12b[(size_t)row * 256 + wn * 128 + nt * 16 + r16] = f2b(acc[mt][nt][r]);
            }
}

// ---------------- edge phase (MFMA bf16, sorted edges, segment-aggregated sums) -------------
__global__ __launch_bounds__(256) void edge_mfma(
    const ushort_t* __restrict__ P12b, const float* __restrict__ coord,
    const int* __restrict__ ei, const int* __restrict__ perm,
    const float* __restrict__ We1, const float* __restrict__ be1,
    const ushort_t* __restrict__ We2b, const float* __restrict__ be2,
    const float* __restrict__ watt, const float* __restrict__ batt,
    const ushort_t* __restrict__ Wc1b, const float* __restrict__ bc1,
    const float* __restrict__ Wc2,
    float* __restrict__ mi, float* __restrict__ ssum)
{
    __shared__ ushort_t ybuf[128 * 128];
    __shared__ float cdp[128][3];
    __shared__ float wcols[128], be1s[128], be2s[128], bc1s[128], watts[128], wc2s[128];
    __shared__ float pq[2][128];
    __shared__ int ej0s[128];

    const int tid = threadIdx.x;
    const int ebase = blockIdx.x * 128;
    const int lane = tid & 63;
    const int wid = tid >> 6;
    const int wm = wid >> 1, wn = wid & 1;
    const int g = lane >> 4, r16 = lane & 15;
    const float batt0 = batt[0];

    // ---- early: per-pair index load + RANDOM P1 gather, parked in own ybuf slots ----
    const int e = tid >> 1, hf = tid & 1;
    const int eg = perm[ebase + e];
    const int n0 = ei[eg];
    const int n1 = ei[EE + eg];
    {
        const ushort_t* p1 = P12b + (size_t)n1 * 256 + hf * 64;
        #pragma unroll
        for (int q = 0; q < 8; ++q) {
            short8v t = *(const short8v*)(p1 + q * 8);
            int off = (e << 8) + ((hf * 128 + q * 16) ^ ((e & 15) << 4));
            *(short8v*)((char*)ybuf + off) = t;     // thread-private slot
        }
    }
    if (hf == 0) ej0s[e] = n0;
    // stage per-col consts (latency overlaps gathers)
    {
        int t = tid & 127;
        if (tid < 128) {
            wcols[t] = We1[t * 257 + 256];
            be1s[t] = be1[t];
            be2s[t] = be2[t];
        } else {
            bc1s[t] = bc1[t];
            watts[t] = watt[t];
            wc2s[t] = Wc2[t];
        }
    }
    // radial + coord-diff (both pair threads compute rr; even thread writes cdp)
    float rr;
    {
        float d0 = coord[n0 * 3 + 0] - coord[n1 * 3 + 0];
        float d1 = coord[n0 * 3 + 1] - coord[n1 * 3 + 1];
        float d2 = coord[n0 * 3 + 2] - coord[n1 * 3 + 2];
        rr = d0 * d0 + d1 * d1 + d2 * d2;
        if (hf == 0) { cdp[e][0] = d0; cdp[e][1] = d1; cdp[e][2] = d2; }
    }
    __syncthreads();

    // ---- phase A: y1 = relu(P1[e1] + P2[e0] + rad*wcol + be1) -> ybuf (in place) ----
    {
        short8v gb[8];
        const ushort_t* p2 = P12b + (size_t)n0 * 256 + 128 + hf * 64;
        #pragma unroll
        for (int q = 0; q < 8; ++q)
            gb[q] = *(const short8v*)(p2 + q * 8);
        const int colbase = hf * 64;
        #pragma unroll
        for (int q = 0; q < 8; ++q) {
            int off = (e << 8) + ((colbase * 2 + q * 16) ^ ((e & 15) << 4));
            short8v a = *(const short8v*)((const char*)ybuf + off);
            short8v ov;
            #pragma unroll
            for (int jj = 0; jj < 8; ++jj) {
                int col = colbase + q * 8 + jj;
                float v = b2f((ushort_t)a[jj]) + b2f((ushort_t)gb[q][jj]) + rr * wcols[col] + be1s[col];
                ov[jj] = (short)f2b(fmaxf(v, 0.f));
            }
            *(short8v*)((char*)ybuf + off) = ov;
        }
    }
    // preload layer-2 weights (latency hides under the barrier)
    short8v b2_[4][4];
    {
        const ushort_t* W2p = We2b + (size_t)(wn * 64 + r16) * 128 + g * 8;
        #pragma unroll
        for (int nt = 0; nt < 4; ++nt)
            #pragma unroll
            for (int c = 0; c < 4; ++c)
                b2_[nt][c] = *(const short8v*)(W2p + nt * 2048 + c * 32);
    }
    __syncthreads();

    // ---- layer 2: y1 @ We2^T ----
    f32x4 acc[4][4];
    #pragma unroll
    for (int mt = 0; mt < 4; ++mt)
        #pragma unroll
        for (int nt = 0; nt < 4; ++nt) acc[mt][nt] = (f32x4){0.f, 0.f, 0.f, 0.f};
    #pragma unroll
    for (int c = 0; c < 4; ++c) {
        short8v afr[4];
        #pragma unroll
        for (int mt = 0; mt < 4; ++mt) {
            int row = wm * 64 + mt * 16 + r16;
            afr[mt] = *(const short8v*)((const char*)ybuf + (row << 8) + ((c * 64 + g * 16) ^ (r16 << 4)));
        }
        #pragma unroll
        for (int mt = 0; mt < 4; ++mt)
            #pragma unroll
            for (int nt = 0; nt < 4; ++nt)
                acc[mt][nt] = MFMA16(afr[mt], b2_[nt][c], acc[mt][nt]);
    }

    // epilogue 2: mij = relu(+be2); att = sigmoid(mij.watt + batt); ef = mij*att -> ybuf
    {
        float p[4][4];
        #pragma unroll
        for (int mt = 0; mt < 4; ++mt)
            #pragma unroll
            for (int r = 0; r < 4; ++r) p[mt][r] = 0.f;
        #pragma unroll
        for (int mt = 0; mt < 4; ++mt)
            #pragma unroll
            for (int nt = 0; nt < 4; ++nt)
                #pragma unroll
                for (int r = 0; r < 4; ++r) {
                    int col = wn * 64 + nt * 16 + r16;
                    float v = fmaxf(acc[mt][nt][r] + be2s[col], 0.f);
                    acc[mt][nt][r] = v;
                    p[mt][r] += v * watts[col];
                }
        #pragma unroll
        for (int off = 1; off < 16; off <<= 1)
            #pragma unroll
            for (int mt = 0; mt < 4; ++mt)
                #pragma unroll
                for (int r = 0; r < 4; ++r) p[mt][r] += __shfl_xor(p[mt][r], off);
        if (r16 == 0) {
            #pragma unroll
            for (int mt = 0; mt < 4; ++mt)
                #pragma unroll
                for (int r = 0; r < 4; ++r)
                    pq[wn][wm * 64 + mt * 16 + g * 4 + r] = p[mt][r];
        }
        __syncthreads();
        float att[4][4];
        #pragma unroll
        for (int mt = 0; mt < 4; ++mt)
            #pragma unroll
            for (int r = 0; r < 4; ++r) {
                int row = wm * 64 + mt * 16 + g * 4 + r;
                att[mt][r] = sigf(pq[0][row] + pq[1][row] + batt0);
            }
        __syncthreads();   // layer-2 ybuf reads + pq reads done -> safe to overwrite ybuf
        #pragma unroll
        for (int mt = 0; mt < 4; ++mt)
            #pragma unroll
            for (int nt = 0; nt < 4; ++nt)
                #pragma unroll
                for (int r = 0; r < 4; ++r) {
                    int row = wm * 64 + mt * 16 + g * 4 + r;
                    int col = wn * 64 + nt * 16 + r16;
                    int off = (row << 8) + (((col << 1)) ^ ((row & 15) << 4));
                    *(ushort_t*)((char*)ybuf + off) = f2b(acc[mt][nt][r] * att[mt][r]);
                }
    }
    __syncthreads();   // ef visible to all

    // preload layer-3 weights (latency hides under the segment-sum below)
    short8v b3_[4][4];
    {
        const ushort_t* W3p = Wc1b + (size_t)(wn * 64 + r16) * 128 + g * 8;
        #pragma unroll
        for (int nt = 0; nt < 4; ++nt)
            #pragma unroll
            for (int c = 0; c < 4; ++c)
                b3_[nt][c] = *(const short8v*)(W3p + nt * 2048 + c * 32);
    }

    // ---- segment-sum ef over sorted e0 runs -> mi ----
    // 256 threads = 64 col-pairs x 4 row-quarters; b32 LDS reads (2 cols at once);
    // flushes stay wave-coalesced (whole wave shares rows/cur, contiguous cols).
    {
        const int cp = tid & 63;          // cols 2*cp, 2*cp+1
        const int qr = tid >> 6;          // row quarter
        const int r0 = qr * 32, r1 = r0 + 32;
        const int colbyte = cp * 4;
        float s0 = 0.f, s1 = 0.f;
        int cur = ej0s[r0];
        for (int r = r0; r < r1; ++r) {
            int node = ej0s[r];
            if (node != cur) {
                atomicAdd(&mi[(size_t)cur * HD + 2 * cp], s0);
                atomicAdd(&mi[(size_t)cur * HD + 2 * cp + 1], s1);
                s0 = 0.f; s1 = 0.f; cur = node;
            }
            int off = (r << 8) + (colbyte ^ ((r & 15) << 4));
            unsigned v = *(const unsigned*)((const char*)ybuf + off);
            s0 += b2f((ushort_t)(v & 0xFFFFu));
            s1 += b2f((ushort_t)(v >> 16));
        }
        atomicAdd(&mi[(size_t)cur * HD + 2 * cp], s0);
        atomicAdd(&mi[(size_t)cur * HD + 2 * cp + 1], s1);
    }

    // ---- layer 3: ef @ Wc1^T, dot Wc2 ----
    #pragma unroll
    for (int mt = 0; mt < 4; ++mt)
        #pragma unroll
        for (int nt = 0; nt < 4; ++nt) acc[mt][nt] = (f32x4){0.f, 0.f, 0.f, 0.f};
    #pragma unroll
    for (int c = 0; c < 4; ++c) {
        short8v afr[4];
        #pragma unroll
        for (int mt = 0; mt < 4; ++mt) {
            int row = wm * 64 + mt * 16 + r16;
            afr[mt] = *(const short8v*)((const char*)ybuf + (row << 8) + ((c * 64 + g * 16) ^ (r16 << 4)));
        }
        #pragma unroll
        for (int mt = 0; mt < 4; ++mt)
            #pragma unroll
            for (int nt = 0; nt < 4; ++nt)
                acc[mt][nt] = MFMA16(afr[mt], b3_[nt][c], acc[mt][nt]);
    }
    {
        float q[4][4];
        #pragma unroll
        for (int mt = 0; mt < 4; ++mt)
            #pragma unroll
            for (int r = 0; r < 4; ++r) q[mt][r] = 0.f;
        #pragma unroll
        for (int mt = 0; mt < 4; ++mt)
            #pragma unroll
            for (int nt = 0; nt < 4; ++nt)
                #pragma unroll
                for (int r = 0; r < 4; ++r) {
                    int col = wn * 64 + nt * 16 + r16;
                    float v = fmaxf(acc[mt][nt][r] + bc1s[col], 0.f);
                    q[mt][r] += v * wc2s[col];
                }
        #pragma unroll
        for (int off = 1; off < 16; off <<= 1)
            #pragma unroll
            for (int mt = 0; mt < 4; ++mt)
                #pragma unroll
                for (int r = 0; r < 4; ++r) q[mt][r] += __shfl_xor(q[mt][r], off);
        if (r16 == 0) {
            #pragma unroll
            for (int mt = 0; mt < 4; ++mt)
                #pragma unroll
                for (int r = 0; r < 4; ++r)
                    pq[wn][wm * 64 + mt * 16 + g * 4 + r] = q[mt][r];
        }
        __syncthreads();
        // coord segment sums: 48 lanes, 8 rows each
        if (tid < 48) {
            int c = tid % 3, seg = tid / 3;
            int r0 = seg * 8, r1 = r0 + 8;
            float sacc = 0.f; int cur = ej0s[r0];
            for (int r = r0; r < r1; ++r) {
                int node = ej0s[r];
                if (node != cur) {
                    atomicAdd(&ssum[cur * 3 + c], sacc);
                    sacc = 0.f; cur = node;
                }
                float tv = pq[0][r] + pq[1][r];
                float tr = cdp[r][c] * tv;
                tr = fminf(fmaxf(tr, -100.f), 100.f);
                sacc += tr;
            }
            atomicAdd(&ssum[cur * 3 + c], sacc);
        }
    }
}

// ------- node MLP + layernorm + clip (split-bf16 MFMA) -> hn fp32; fused coord update -------
__global__ __launch_bounds__(256) void node_mfma(
    const float* __restrict__ mi, const float* __restrict__ h,
    const ushort_t* __restrict__ Wn1hi, const ushort_t* __restrict__ Wn1lo,
    const float* __restrict__ bn1,
    const ushort_t* __restrict__ Wn2hi, const ushort_t* __restrict__ Wn2lo,
    const float* __restrict__ bn2,
    const float* __restrict__ lng, const float* __restrict__ lnb,
    float* __restrict__ hnf,
    const float* __restrict__ coord, const float* __restrict__ ssum,
    const int* __restrict__ histI, float* __restrict__ coordout)
{
    __shared__ ushort_t yhi[128 * 128];
    __shared__ ushort_t ylo[128 * 128];
    __shared__ float bn1s[128], bn2s[128], lngs[128], lnbs[128];

    const int tid = threadIdx.x;
    const int nbase = blockIdx.x * 128;
    const int lane = tid & 63;
    const int wid = tid >> 6;
    const int wm = wid >> 1, wn = wid & 1;
    const int g = lane >> 4, r16 = lane & 15;

    if (tid < 128) { bn1s[tid] = bn1[tid]; bn2s[tid] = bn2[tid]; lngs[tid] = lng[tid]; lnbs[tid] = lnb[tid]; }
    __syncthreads();

    // layer 1: [mi | h] @ Wn1^T, K=256, split A and B
    f32x4 acc[4][4];
    #pragma unroll
    for (int mt = 0; mt < 4; ++mt)
        #pragma unroll
        for (int nt = 0; nt < 4; ++nt) acc[mt][nt] = (f32x4){0.f, 0.f, 0.f, 0.f};
    for (int c = 0; c < 8; ++c) {
        short8v ahi[4], alo[4], bhi[4], blo[4];
        #pragma unroll
        for (int mt = 0; mt < 4; ++mt) {
            int row = nbase + wm * 64 + mt * 16 + r16;
            if (row > NN - 1) row = NN - 1;
            const float* src = (c < 4) ? (mi + (size_t)row * HD + c * 32 + g * 8)
                                       : (h + (size_t)row * HD + (c - 4) * 32 + g * 8);
            cvt8x2(src, ahi[mt], alo[mt]);
        }
        #pragma unroll
        for (int nt = 0; nt < 4; ++nt) {
            size_t wo = (size_t)(wn * 64 + nt * 16 + r16) * 256 + c * 32 + g * 8;
            bhi[nt] = *(const short8v*)(Wn1hi + wo);
            blo[nt] = *(const short8v*)(Wn1lo + wo);
        }
        #pragma unroll
        for (int mt = 0; mt < 4; ++mt)
            #pragma unroll
            for (int nt = 0; nt < 4; ++nt) {
                acc[mt][nt] = MFMA16(ahi[mt], bhi[nt], acc[mt][nt]);
                acc[mt][nt] = MFMA16(ahi[mt], blo[nt], acc[mt][nt]);
                acc[mt][nt] = MFMA16(alo[mt], bhi[nt], acc[mt][nt]);
            }
    }
    // relu(+bn1) -> hi/lo LDS pair
    #pragma unroll
    for (int mt = 0; mt < 4; ++mt)
        #pragma unroll
        for (int nt = 0; nt < 4; ++nt)
            #pragma unroll
            for (int r = 0; r < 4; ++r) {
                int row = wm * 64 + mt * 16 + g * 4 + r;
                int col = wn * 64 + nt * 16 + r16;
                int off = (row << 8) + (((col << 1)) ^ ((row & 15) << 4));
                float v = fmaxf(acc[mt][nt][r] + bn1s[col], 0.f);
                ushort_t hh, ll; splitf(v, hh, ll);
                *(ushort_t*)((char*)yhi + off) = hh;
                *(ushort_t*)((char*)ylo + off) = ll;
            }
    __syncthreads();

    // layer 2: y1 @ Wn2^T, split A and B
    #pragma unroll
    for (int mt = 0; mt < 4; ++mt)
        #pragma unroll
        for (int nt = 0; nt < 4; ++nt) acc[mt][nt] = (f32x4){0.f, 0.f, 0.f, 0.f};
    #pragma unroll
    for (int c = 0; c < 4; ++c) {
        short8v ahi[4], alo[4], bhi[4], blo[4];
        #pragma unroll
        for (int mt = 0; mt < 4; ++mt) {
            int row = wm * 64 + mt * 16 + r16;
            int off = (row << 8) + ((c * 64 + g * 16) ^ (r16 << 4));
            ahi[mt] = *(const short8v*)((const char*)yhi + off);
            alo[mt] = *(const short8v*)((const char*)ylo + off);
        }
        #pragma unroll
        for (int nt = 0; nt < 4; ++nt) {
            size_t wo = (size_t)(wn * 64 + nt * 16 + r16) * 128 + c * 32 + g * 8;
            bhi[nt] = *(const short8v*)(Wn2hi + wo);
            blo[nt] = *(const short8v*)(Wn2lo + wo);
        }
        #pragma unroll
        for (int mt = 0; mt < 4; ++mt)
            #pragma unroll
            for (int nt = 0; nt < 4; ++nt) {
                acc[mt][nt] = MFMA16(ahi[mt], bhi[nt], acc[mt][nt]);
                acc[mt][nt] = MFMA16(ahi[mt], blo[nt], acc[mt][nt]);
                acc[mt][nt] = MFMA16(alo[mt], bhi[nt], acc[mt][nt]);
            }
    }
    __syncthreads();   // all layer-2 reads done -> safe to overwrite
    #pragma unroll
    for (int mt = 0; mt < 4; ++mt)
        #pragma unroll
        for (int nt = 0; nt < 4; ++nt)
            #pragma unroll
            for (int r = 0; r < 4; ++r) {
                int row = wm * 64 + mt * 16 + g * 4 + r;
                int col = wn * 64 + nt * 16 + r16;
                int off = (row << 8) + (((col << 1)) ^ ((row & 15) << 4));
                float v = acc[mt][nt][r] + bn2s[col];
                ushort_t hh, ll; splitf(v, hh, ll);
                *(ushort_t*)((char*)yhi + off) = hh;
                *(ushort_t*)((char*)ylo + off) = ll;
            }
    __syncthreads();

    // layernorm + clip + store hn fp32 (2 threads per row, 8 chunks each = FULL 128 cols)
    {
        const int row = tid >> 1, hf = tid & 1;
        const int rowg = nbase + row;
        float s1 = 0.f, s2 = 0.f;
        float vals[64];
        #pragma unroll
        for (int q = 0; q < 8; ++q) {
            int c8 = hf * 8 + q;
            int off = (row << 8) + ((c8 * 16) ^ ((row & 15) << 4));
            short8v vh = *(const short8v*)((const char*)yhi + off);
            short8v vl = *(const short8v*)((const char*)ylo + off);
            #pragma unroll
            for (int j = 0; j < 8; ++j) {
                float v = b2f((ushort_t)vh[j]) + b2f((ushort_t)vl[j]);
                vals[q * 8 + j] = v;
                s1 += v; s2 += v * v;
            }
        }
        s1 += __shfl_xor(s1, 1);
        s2 += __shfl_xor(s2, 1);
        float mu = s1 * (1.f / HD);
        float var = s2 * (1.f / HD) - mu * mu;
        float rs = rsqrtf(fmaxf(var, 0.f) + 1e-5f);
        if (rowg < NN) {
            #pragma unroll
            for (int q = 0; q < 8; ++q) {
                int c8 = hf * 8 + q;
                f32x4 o0, o1;
                #pragma unroll
                for (int j = 0; j < 8; ++j) {
                    int col = c8 * 8 + j;
                    float v = (vals[q * 8 + j] - mu) * rs * lngs[col] + lnbs[col];
                    v = fminf(fmaxf(v, -10.f), 10.f);
                    if (j < 4) o0[j] = v; else o1[j - 4] = v;
                }
                *(f32x4*)(hnf + (size_t)rowg * HD + c8 * 8) = o0;
                *(f32x4*)(hnf + (size_t)rowg * HD + c8 * 8 + 4) = o1;
            }
        }
    }

    // fused coord update for this block's node rows (independent of LN path)
    {
        int base3 = nbase * 3;
        for (int k = tid; k < 384; k += 256) {
            int idx = base3 + k;
            if (idx < NN * 3) {
                int n = idx / 3;
                coordout[idx] = coord[idx] + ssum[idx] / fmaxf((float)histI[n], 1.f);
            }
        }
    }
}

// ---------------- mamba in_proj (split MFMA, ~fp32): u bf16, silu(z) fp32 ----------------
__global__ __launch_bounds__(256) void xz_mfma(
    const float* __restrict__ hnf,
    const ushort_t* __restrict__ Wiphi, const ushort_t* __restrict__ Wiplo,
    ushort_t* __restrict__ ub, float* __restrict__ zs)
{
    const int tid = threadIdx.x;
    const int lane = tid & 63;
    const int wn = tid >> 6;               // 4 waves over 256 output cols
    const int g = lane >> 4, r16 = lane & 15;
    const int rbase = blockIdx.x * 64;

    f32x4 acc[4][4];
    #pragma unroll
    for (int mt = 0; mt < 4; ++mt)
        #pragma unroll
        for (int nt = 0; nt < 4; ++nt) acc[mt][nt] = (f32x4){0.f, 0.f, 0.f, 0.f};

    for (int c = 0; c < 4; ++c) {
        short8v ahi[4], alo[4], bhi[4], blo[4];
        #pragma unroll
        for (int mt = 0; mt < 4; ++mt) {
            int row = rbase + mt * 16 + r16;
            if (row > NN - 1) row = NN - 1;
            cvt8x2(hnf + (size_t)row * HD + c * 32 + g * 8, ahi[mt], alo[mt]);
        }
        #pragma unroll
        for (int nt = 0; nt < 4; ++nt) {
            size_t wo = (size_t)(wn * 64 + nt * 16 + r16) * 128 + c * 32 + g * 8;
            bhi[nt] = *(const short8v*)(Wiphi + wo);
            blo[nt] = *(const short8v*)(Wiplo + wo);
        }
        #pragma unroll
        for (int mt = 0; mt < 4; ++mt)
            #pragma unroll
            for (int nt = 0; nt < 4; ++nt) {
                acc[mt][nt] = MFMA16(ahi[mt], bhi[nt], acc[mt][nt]);
                acc[mt][nt] = MFMA16(ahi[mt], blo[nt], acc[mt][nt]);
                acc[mt][nt] = MFMA16(alo[mt], bhi[nt], acc[mt][nt]);
            }
    }
    #pragma unroll
    for (int mt = 0; mt < 4; ++mt)
        #pragma unroll
        for (int nt = 0; nt < 4; ++nt)
            #pragma unroll
            for (int r = 0; r < 4; ++r) {
                int row = rbase + mt * 16 + g * 4 + r;
                if (row >= NN) continue;
                int j = wn * 64 + nt * 16 + r16;
                float v = acc[mt][nt][r];
                if (j < HD) ub[(size_t)row * HD + j] = f2b(v);
                else        zs[(size_t)row * HD + (j - HD)] = v * sigf(v);
            }
}

// ---- fused conv+silu -> uc; B|C = uc@Wxp8^T; dt = softplus(uc@Wdt2^T+bdt)  (split MFMA) ----
__global__ __launch_bounds__(256) void convdt_mfma(
    const ushort_t* __restrict__ ub, const float* __restrict__ cw,
    const float* __restrict__ cb,
    const ushort_t* __restrict__ Wxp8hi, const ushort_t* __restrict__ Wxp8lo,
    const ushort_t* __restrict__ Wdt2hi, const ushort_t* __restrict__ Wdt2lo,
    const float* __restrict__ bdt,
    float* __restrict__ uc, float* __restrict__ Bm, float* __restrict__ Cm,
    float* __restrict__ dt)
{
    __shared__ ushort_t yhi[128 * 128];
    __shared__ ushort_t ylo[128 * 128];
    __shared__ float cws[128][4], cbs[128], bdts[128];

    const int tid = threadIdx.x;
    const int nbase = blockIdx.x * 128;
    const int lane = tid & 63;
    const int wid = tid >> 6;
    const int wm = wid >> 1, wn = wid & 1;
    const int g = lane >> 4, r16 = lane & 15;

    if (tid < 128) {
        cbs[tid] = cb[tid]; bdts[tid] = bdt[tid];
        #pragma unroll
        for (int k = 0; k < 4; ++k) cws[tid][k] = cw[tid * 4 + k];
    }
    __syncthreads();

    // phase 1: causal depthwise conv + silu -> uc (fp32 global) + hi/lo LDS pair
    for (int it = tid; it < 128 * 16; it += 256) {
        int r = it >> 4, cg = it & 15;
        int t = nbase + r;
        int colb = cg * 8;
        float a[8];
        #pragma unroll
        for (int j = 0; j < 8; ++j) a[j] = cbs[colb + j];
        #pragma unroll
        for (int k = 0; k < 4; ++k) {
            int tt = t - 3 + k;
            if (tt >= 0 && tt < NN) {
                short8v uv = *(const short8v*)(ub + (size_t)tt * HD + colb);
                #pragma unroll
                for (int j = 0; j < 8; ++j) a[j] = fmaf(b2f((ushort_t)uv[j]), cws[colb + j][k], a[j]);
            }
        }
        short8v oh, ol;
        f32x4 u0, u1;
        #pragma unroll
        for (int j = 0; j < 8; ++j) {
            float s = (t < NN) ? a[j] * sigf(a[j]) : 0.f;
            ushort_t hh, ll; splitf(s, hh, ll);
            oh[j] = (short)hh; ol[j] = (short)ll;
            if (j < 4) u0[j] = s; else u1[j - 4] = s;
        }
        int off = (r << 8) + ((cg * 16) ^ ((r & 15) << 4));
        *(short8v*)((char*)yhi + off) = oh;
        *(short8v*)((char*)ylo + off) = ol;
        if (t < NN) {
            *(f32x4*)(uc + (size_t)t * HD + colb) = u0;
            *(f32x4*)(uc + (size_t)t * HD + colb + 4) = u1;
        }
    }
    __syncthreads();

    // phase 2: B|C = uc @ Wxp[8:136]^T  (128 cols), split
    f32x4 acc[4][4];
    #pragma unroll
    for (int mt = 0; mt < 4; ++mt)
        #pragma unroll
        for (int nt = 0; nt < 4; ++nt) acc[mt][nt] = (f32x4){0.f, 0.f, 0.f, 0.f};
    #pragma unroll
    for (int c = 0; c < 4; ++c) {
        short8v ahi[4], alo[4], bhi[4], blo[4];
        #pragma unroll
        for (int mt = 0; mt < 4; ++mt) {
            int row = wm * 64 + mt * 16 + r16;
            int off = (row << 8) + ((c * 64 + g * 16) ^ (r16 << 4));
            ahi[mt] = *(const short8v*)((const char*)yhi + off);
            alo[mt] = *(const short8v*)((const char*)ylo + off);
        }
        #pragma unroll
        for (int nt = 0; nt < 4; ++nt) {
            size_t wo = (size_t)(wn * 64 + nt * 16 + r16) * 128 + c * 32 + g * 8;
            bhi[nt] = *(const short8v*)(Wxp8hi + wo);
            blo[nt] = *(const short8v*)(Wxp8lo + wo);
        }
        #pragma unroll
        for (int mt = 0; mt < 4; ++mt)
            #pragma unroll
            for (int nt = 0; nt < 4; ++nt) {
                acc[mt][nt] = MFMA16(ahi[mt], bhi[nt], acc[mt][nt]);
                acc[mt][nt] = MFMA16(ahi[mt], blo[nt], acc[mt][nt]);
                acc[mt][nt] = MFMA16(alo[mt], bhi[nt], acc[mt][nt]);
            }
    }
    #pragma unroll
    for (int mt = 0; mt < 4; ++mt)
        #pragma unroll
        for (int nt = 0; nt < 4; ++nt)
            #pragma unroll
            for (int r = 0; r < 4; ++r) {
                int row = nbase + wm * 64 + mt * 16 + g * 4 + r;
                if (row >= NN) continue;
                int j = wn * 64 + nt * 16 + r16;
                float v = acc[mt][nt][r];
                if (j < 64) Bm[(size_t)row * 64 + j] = v;
                else        Cm[(size_t)row * 64 + (j - 64)] = v;
            }

    // phase 3: dt = softplus(uc @ Wdt2^T + bdt), split
    #pragma unroll
    for (int mt = 0; mt < 4; ++mt)
        #pragma unroll
        for (int nt = 0; nt < 4; ++nt) acc[mt][nt] = (f32x4){0.f, 0.f, 0.f, 0.f};
    #pragma unroll
    for (int c = 0; c < 4; ++c) {
        short8v ahi[4], alo[4], bhi[4], blo[4];
        #pragma unroll
        for (int mt = 0; mt < 4; ++mt) {
            int row = wm * 64 + mt * 16 + r16;
            int off = (row << 8) + ((c * 64 + g * 16) ^ (r16 << 4));
            ahi[mt] = *(const short8v*)((const char*)yhi + off);
            alo[mt] = *(const short8v*)((const char*)ylo + off);
        }
        #pragma unroll
        for (int nt = 0; nt < 4; ++nt) {
            size_t wo = (size_t)(wn * 64 + nt * 16 + r16) * 128 + c * 32 + g * 8;
            bhi[nt] = *(const short8v*)(Wdt2hi + wo);
            blo[nt] = *(const short8v*)(Wdt2lo + wo);
        }
        #pragma unroll
        for (int mt = 0; mt < 4; ++mt)
            #pragma unroll
            for (int nt = 0; nt < 4; ++nt) {
                acc[mt][nt] = MFMA16(ahi[mt], bhi[nt], acc[mt][nt]);
                acc[mt][nt] = MFMA16(ahi[mt], blo[nt], acc[mt][nt]);
                acc[mt][nt] = MFMA16(alo[mt], bhi[nt], acc[mt][nt]);
            }
    }
    #pragma unroll
    for (int mt = 0; mt < 4; ++mt)
        #pragma unroll
        for (int nt = 0; nt < 4; ++nt)
            #pragma unroll
            for (int r = 0; r < 4; ++r) {
                int row = nbase + wm * 64 + mt * 16 + g * 4 + r;
                if (row >= NN) continue;
                int j = wn * 64 + nt * 16 + r16;
                float a = acc[mt][nt][r] + bdts[j];
                float sp = (a > 20.f) ? a : log1pf(__expf(a));
                dt[(size_t)row * HD + j] = sp;
            }
}

// ---------------- chunked SSM scan ----------------
__global__ __launch_bounds__(256) void scan1_kernel(
    const float* __restrict__ dt, const float* __restrict__ uc,
    const float* __restrict__ Bm, const float* __restrict__ Alog,
    float* __restrict__ cP, float* __restrict__ cS)
{
    int g = blockIdx.x * 256 + threadIdx.x;
    int c = g >> 13;
    int r = g & 8191;
    int hh = r >> 6;
    int d = r & 63;
    float A = -__expf(Alog[hh * 64 + d]);
    float P = 1.f, S = 0.f;
    int t0 = c * CS;
    for (int t = t0; t < t0 + CS; ++t) {
        float dtv = dt[t * HD + hh];
        float a = __expf(dtv * A);
        float bv = Bm[t * 64 + d];
        float uv = uc[t * HD + hh];
        P *= a;
        S = fmaf(a, S, dtv * uv * bv);
    }
    cP[g] = P; cS[g] = S;
}

__global__ __launch_bounds__(256) void scan2_kernel(
    const float* __restrict__ cP, const float* __restrict__ cS, float* __restrict__ cI)
{
    int g = blockIdx.x * 256 + threadIdx.x;
    float S = 0.f;
    for (int c = 0; c < NC; ++c) {
        cI[c * 8192 + g] = S;
        S = fmaf(cP[c * 8192 + g], S, cS[c * 8192 + g]);
    }
}

// 2 d-states per thread: 32 lanes per (c,hh); 5-level shfl reduce
__global__ __launch_bounds__(256) void scan3_kernel(
    const float* __restrict__ dt, const float* __restrict__ uc,
    const float* __restrict__ Bm, const float* __restrict__ Cm,
    const float* __restrict__ Alog, const float* __restrict__ Dskip,
    const float* __restrict__ cI, float* __restrict__ y)
{
    int g = blockIdx.x * 256 + threadIdx.x;   // NC*4096 threads
    int c = g >> 12;
    int r = g & 4095;
    int hh = r >> 5;
    int dp = (r & 31) * 2;
    float A0 = -__expf(Alog[hh * 64 + dp]);
    float A1 = -__expf(Alog[hh * 64 + dp + 1]);
    float s0 = cI[c * 8192 + hh * 64 + dp];
    float s1 = cI[c * 8192 + hh * 64 + dp + 1];
    float Dh = Dskip[hh];
    int t0 = c * CS;
    const int lane31 = threadIdx.x & 31;
    for (int t = t0; t < t0 + CS; ++t) {
        float dtv = dt[t * HD + hh];
        float uv = uc[t * HD + hh];
        float du = dtv * uv;
        float2 bv = *(const float2*)(Bm + (size_t)t * 64 + dp);
        float2 cv = *(const float2*)(Cm + (size_t)t * 64 + dp);
        s0 = fmaf(__expf(dtv * A0), s0, du * bv.x);
        s1 = fmaf(__expf(dtv * A1), s1, du * bv.y);
        float yp = fmaf(s0, cv.x, s1 * cv.y);
        #pragma unroll
        for (int off = 1; off < 32; off <<= 1) yp += __shfl_xor(yp, off);
        if (lane31 == 0) y[t * HD + hh] = yp + Dh * uv;
    }
}

// ---------------- out_proj (split MFMA, ~fp32): (y*silu(z)) @ Wop^T ----------------
__global__ __launch_bounds__(256) void out_mfma(
    const float* __restrict__ y, const float* __restrict__ zs,
    const ushort_t* __restrict__ Wophi, const ushort_t* __restrict__ Woplo,
    float* __restrict__ outp)
{
    const int tid = threadIdx.x;
    const int lane = tid & 63;
    const int wid = tid >> 6;
    const int wm = wid >> 1, wn = wid & 1;
    const int g = lane >> 4, r16 = lane & 15;
    const int nbase = blockIdx.x * 128;

    f32x4 acc[4][4];
    #pragma unroll
    for (int mt = 0; mt < 4; ++mt)
        #pragma unroll
        for (int nt = 0; nt < 4; ++nt) acc[mt][nt] = (f32x4){0.f, 0.f, 0.f, 0.f};

    for (int c = 0; c < 4; ++c) {
        short8v ahi[4], alo[4], bhi[4], blo[4];
        #pragma unroll
        for (int mt = 0; mt < 4; ++mt) {
            int row = nbase + wm * 64 + mt * 16 + r16;
            if (row > NN - 1) row = NN - 1;
            const float* yp = y + (size_t)row * HD + c * 32 + g * 8;
            const float* zp = zs + (size_t)row * HD + c * 32 + g * 8;
            #pragma unroll
            for (int j = 0; j < 8; ++j) {
                float v = yp[j] * zp[j];
                ushort_t hh, ll; splitf(v, hh, ll);
                ahi[mt][j] = (short)hh; alo[mt][j] = (short)ll;
            }
        }
        #pragma unroll
        for (int nt = 0; nt < 4; ++nt) {
            size_t wo = (size_t)(wn * 64 + nt * 16 + r16) * 128 + c * 32 + g * 8;
            bhi[nt] = *(const short8v*)(Wophi + wo);
            blo[nt] = *(const short8v*)(Woplo + wo);
        }
        #pragma unroll
        for (int mt = 0; mt < 4; ++mt)
            #pragma unroll
            for (int nt = 0; nt < 4; ++nt) {
                acc[mt][nt] = MFMA16(ahi[mt], bhi[nt], acc[mt][nt]);
                acc[mt][nt] = MFMA16(ahi[mt], blo[nt], acc[mt][nt]);
                acc[mt][nt] = MFMA16(alo[mt], bhi[nt], acc[mt][nt]);
            }
    }
    #pragma unroll
    for (int mt = 0; mt < 4; ++mt)
        #pragma unroll
        for (int nt = 0; nt < 4; ++nt)
            #pragma unroll
            for (int r = 0; r < 4; ++r) {
                int row = nbase + wm * 64 + mt * 16 + g * 4 + r;
                if (row < NN)
                    outp[(size_t)row * HD + wn * 64 + nt * 16 + r16] = acc[mt][nt][r];
            }
}

extern "C" void kernel_launch(void* const* d_in, const int* in_sizes, int n_in,
                              void* d_out, int out_size, void* d_ws, size_t ws_size,
                              hipStream_t stream)
{
    const float* h     = (const float*)d_in[0];
    const float* coord = (const float*)d_in[1];
    const int*   ei    = (const int*)d_in[2];
    const float* We1   = (const float*)d_in[3];
    const float* be1   = (const float*)d_in[4];
    const float* We2   = (const float*)d_in[5];
    const float* be2   = (const float*)d_in[6];
    const float* watt  = (const float*)d_in[7];
    const float* batt  = (const float*)d_in[8];
    const float* Wn1   = (const float*)d_in[9];
    const float* bn1   = (const float*)d_in[10];
    const float* Wn2   = (const float*)d_in[11];
    const float* bn2   = (const float*)d_in[12];
    const float* Wc1   = (const float*)d_in[13];
    const float* bc1   = (const float*)d_in[14];
    const float* Wc2   = (const float*)d_in[15];
    const float* lng   = (const float*)d_in[16];
    const float* lnb   = (const float*)d_in[17];
    const float* Wip   = (const float*)d_in[18];
    const float* convw = (const float*)d_in[19];
    const float* convb = (const float*)d_in[20];
    const float* Wxp   = (const float*)d_in[21];
    const float* Wdt   = (const float*)d_in[22];
    const float* bdt   = (const float*)d_in[23];
    const float* Alog  = (const float*)d_in[24];
    const float* Dskip = (const float*)d_in[25];
    const float* Wop   = (const float*)d_in[26];

    float* ws   = (float*)d_ws;
    float* mi   = ws;                                  // NN*HD f32 (zeroed; reused as y after node)
    float* ssum = mi   + (size_t)NN * HD;              // NN*3  f32 (zeroed)
    int*   histI  = (int*)(ssum + (size_t)NN * 3);     // NN (zeroed)
    int*   cursor = histI + NN;                        // NN (zeroed)
    int*   baseI  = cursor + NN;                       // NN
    int*   perm   = baseI + NN;                        // EE
    float* zsb  = (float*)(perm + EE);                 // NN*HD
    float* ucb  = zsb  + (size_t)NN * HD;              // NN*HD
    float* dtb  = ucb  + (size_t)NN * HD;              // NN*HD
    float* Bm   = dtb  + (size_t)NN * HD;              // NN*64
    float* Cm   = Bm   + (size_t)NN * 64;              // NN*64
    float* cP   = Cm   + (size_t)NN * 64;              // NC*8192
    float* cSb  = cP   + (size_t)NC * 8192;
    float* cIb  = cSb  + (size_t)NC * 8192;
    ushort_t* ub    = (ushort_t*)(cIb + (size_t)NC * 8192);  // NN*HD bf16
    ushort_t* W12bp = ub + (size_t)NN * HD;            // 256*128
    ushort_t* We2bp = W12bp + 256 * 128;
    ushort_t* Wc1bp = We2bp + 128 * 128;
    ushort_t* Wn1hi = Wc1bp + 128 * 128;               // 128*256 pair
    ushort_t* Wn1lo = Wn1hi + 128 * 256;
    ushort_t* Wn2hi = Wn1lo + 128 * 256;               // 128*128 pair
    ushort_t* Wn2lo = Wn2hi + 128 * 128;
    ushort_t* Wiphi = Wn2lo + 128 * 128;               // 256*128 pair
    ushort_t* Wiplo = Wiphi + 256 * 128;
    ushort_t* Wxp8hi = Wiplo + 256 * 128;              // 128*128 pairs
    ushort_t* Wxp8lo = Wxp8hi + 128 * 128;
    ushort_t* Wdt2hi = Wxp8lo + 128 * 128;
    ushort_t* Wdt2lo = Wdt2hi + 128 * 128;
    ushort_t* Wophi  = Wdt2lo + 128 * 128;
    ushort_t* Woplo  = Wophi + 128 * 128;
    // P12b (NN*256 bf16 = 10.24MB) aliases cP+cS: written by p12, dead after edge.
    ushort_t* P12bp = (ushort_t*)cP;
    // hnf (NN*HD f32 = 10.24MB) also aliases cP+cS: written by node (after edge),
    // dead after xz (before scan1 writes cP/cS).
    float* hnf = cP;
    // y aliases mi: mi consumed by node_mfma, re-zeroed each launch by the memset.
    float* yb = mi;

    float* outp     = (float*)d_out;
    float* coordout = outp + (size_t)NN * HD;

    // zero mi, ssum, histI, cursor
    hipMemsetAsync(ws, 0, (size_t)NN * 133 * 4, stream);

    prep_hist_kernel<<<(EE + 255) / 256, 256, 0, stream>>>(ei, histI,
                                         We1, We2, Wc1, Wn1, Wn2, Wip, Wxp, Wdt, Wop,
                                         W12bp, We2bp, Wc1bp,
                                         Wn1hi, Wn1lo, Wn2hi, Wn2lo, Wiphi, Wiplo,
                                         Wxp8hi, Wxp8lo, Wdt2hi, Wdt2lo, Wophi, Woplo);
    prefix_kernel<<<1, 1024, 0, stream>>>(histI, baseI);
    scatter_kernel<<<(EE + 255) / 256, 256, 0, stream>>>(ei, baseI, cursor, perm);
    p12_kernel<<<(NN + 127) / 128, 256, 0, stream>>>(h, W12bp, P12bp);
    edge_mfma<<<EE / 128, 256, 0, stream>>>(P12bp, coord, ei, perm, We1, be1,
                                            We2bp, be2, watt, batt, Wc1bp, bc1, Wc2,
                                            mi, ssum);
    node_mfma<<<(NN + 127) / 128, 256, 0, stream>>>(mi, h, Wn1hi, Wn1lo, bn1,
                                                    Wn2hi, Wn2lo, bn2, lng, lnb, hnf,
                                                    coord, ssum, histI, coordout);
    xz_mfma<<<(NN + 63) / 64, 256, 0, stream>>>(hnf, Wiphi, Wiplo, ub, zsb);
    convdt_mfma<<<(NN + 127) / 128, 256, 0, stream>>>(ub, convw, convb,
                                                      Wxp8hi, Wxp8lo, Wdt2hi, Wdt2lo,
                                                      bdt, ucb, Bm, Cm, dtb);
    scan1_kernel<<<NC * 8192 / 256, 256, 0, stream>>>(dtb, ucb, Bm, Alog, cP, cSb);
    scan2_kernel<<<8192 / 256, 256, 0, stream>>>(cP, cSb, cIb);
    scan3_kernel<<<NC * 4096 / 256, 256, 0, stream>>>(dtb, ucb, Bm, Cm, Alog, Dskip, cIb, yb);
    out_mfma<<<(NN + 127) / 128, 256, 0, stream>>>(yb, zsb, Wophi, Woplo, outp);
}

// Round 14
// 639.536 us; speedup vs baseline: 4.7641x; 1.0130x over previous
//
#include <hip/hip_runtime.h>
#include <math.h>

#define NN 20000
#define EE 640000
#define HD 128
#define NC 160      // scan chunks
#define CS 125      // chunk size: NC*CS == NN

typedef unsigned short ushort_t;
typedef __attribute__((ext_vector_type(8))) short short8v;
typedef __attribute__((ext_vector_type(4))) float f32x4;

#define MFMA16(a,b,c) __builtin_amdgcn_mfma_f32_16x16x32_bf16(a,b,c,0,0,0)

__device__ __forceinline__ float sigf(float x) { return 1.0f / (1.0f + __expf(-x)); }

__device__ __forceinline__ ushort_t f2b(float x) {
    unsigned u = __builtin_bit_cast(unsigned, x);
    unsigned r = (u + 0x7FFFu + ((u >> 16) & 1u)) >> 16;
    return (ushort_t)r;
}
__device__ __forceinline__ float b2f(ushort_t u) {
    unsigned v = ((unsigned)u) << 16;
    return __builtin_bit_cast(float, v);
}
// split fp32 -> hi/lo bf16 pair (x ~= hi + lo, error ~2^-17 rel)
__device__ __forceinline__ void splitf(float v, ushort_t& h, ushort_t& l) {
    h = f2b(v);
    l = f2b(v - b2f(h));
}
__device__ __forceinline__ void cvt8x2(const float* p, short8v& hi, short8v& lo) {
    #pragma unroll
    for (int j = 0; j < 8; ++j) {
        float v = p[j];
        ushort_t h, l; splitf(v, h, l);
        hi[j] = (short)h; lo[j] = (short)l;
    }
}

// ---------------- prefix / scatter for counting sort ----------------
__global__ __launch_bounds__(1024) void prefix_kernel(const int* __restrict__ hist,
                                                      int* __restrict__ baseI)
{
    __shared__ int wsum[16];
    const int tid = threadIdx.x, lane = tid & 63, wid = tid >> 6;
    const int PER = 20;                 // 20*1024 >= NN
    int i0 = tid * PER;
    int s = 0;
    for (int k = 0; k < PER; ++k) { int i = i0 + k; if (i < NN) s += hist[i]; }
    int v = s;
    #pragma unroll
    for (int off = 1; off < 64; off <<= 1) {
        int t = __shfl_up(v, off);
        if (lane >= off) v += t;
    }
    if (lane == 63) wsum[wid] = v;
    __syncthreads();
    if (tid == 0) {
        int acc = 0;
        #pragma unroll
        for (int w = 0; w < 16; ++w) { int t = wsum[w]; wsum[w] = acc; acc += t; }
    }
    __syncthreads();
    int excl = v - s + wsum[wid];
    for (int k = 0; k < PER; ++k) {
        int i = i0 + k;
        if (i < NN) { baseI[i] = excl; excl += hist[i]; }
    }
}

__global__ __launch_bounds__(256) void scatter_kernel(const int* __restrict__ ei,
                                                      const int* __restrict__ baseI,
                                                      int* __restrict__ cursor,
                                                      int* __restrict__ perm)
{
    int i = blockIdx.x * 256 + threadIdx.x;
    if (i < EE) {
        int n = ei[i];
        int p = baseI[n] + atomicAdd(&cursor[n], 1);
        perm[p] = i;
    }
}

// ------- prep (weight conversions) + histogram, fused (independent work, one grid) -------
__global__ __launch_bounds__(256) void prep_hist_kernel(
    const int* __restrict__ ei, int* __restrict__ histI,
    const float* __restrict__ We1, const float* __restrict__ We2,
    const float* __restrict__ Wc1, const float* __restrict__ Wn1,
    const float* __restrict__ Wn2, const float* __restrict__ Wip,
    const float* __restrict__ Wxp, const float* __restrict__ Wdt,
    const float* __restrict__ Wop,
    ushort_t* __restrict__ W12b, ushort_t* __restrict__ We2b,
    ushort_t* __restrict__ Wc1b,
    ushort_t* __restrict__ Wn1hi, ushort_t* __restrict__ Wn1lo,
    ushort_t* __restrict__ Wn2hi, ushort_t* __restrict__ Wn2lo,
    ushort_t* __restrict__ Wiphi, ushort_t* __restrict__ Wiplo,
    ushort_t* __restrict__ Wxp8hi, ushort_t* __restrict__ Wxp8lo,
    ushort_t* __restrict__ Wdt2hi, ushort_t* __restrict__ Wdt2lo,
    ushort_t* __restrict__ Wophi, ushort_t* __restrict__ Woplo)
{
    int i = blockIdx.x * 256 + threadIdx.x;
    if (i < EE) atomicAdd(&histI[ei[i]], 1);
    if (i < 256 * 128) {
        int j = i >> 7, k = i & 127;
        W12b[i] = f2b(We1[(j & 127) * 257 + ((j >> 7) << 7) + k]);
        ushort_t h, l;
        splitf(Wn1[i], h, l); Wn1hi[i] = h; Wn1lo[i] = l;
        splitf(Wip[i], h, l); Wiphi[i] = h; Wiplo[i] = l;
    }
    if (i < 128 * 128) {
        We2b[i] = f2b(We2[i]);
        Wc1b[i] = f2b(Wc1[i]);
        ushort_t h, l;
        splitf(Wn2[i], h, l); Wn2hi[i] = h; Wn2lo[i] = l;
        splitf(Wop[i], h, l); Wophi[i] = h; Woplo[i] = l;
        int j = i >> 7, k = i & 127;
        splitf(Wxp[(8 + j) * 128 + k], h, l); Wxp8hi[i] = h; Wxp8lo[i] = l;
        float s = 0.f;
        #pragma unroll
        for (int r = 0; r < 8; ++r) s = fmaf(Wdt[j * 8 + r], Wxp[r * 128 + k], s);
        splitf(s, h, l); Wdt2hi[i] = h; Wdt2lo[i] = l;
    }
}

// ---------------- node projections: P12 = h @ [W1a|W1b]^T ----------------
__global__ __launch_bounds__(256) void p12_kernel(
    const float* __restrict__ h, const ushort_t* __restrict__ W12b,
    ushort_t* __restrict__ P12b)
{
    const int tid = threadIdx.x;
    const int lane = tid & 63;
    const int wid = tid >> 6;
    const int wm = wid >> 1, wn = wid & 1;
    const int g = lane >> 4, r16 = lane & 15;
    const int rbase = blockIdx.x * 128 + wm * 64;

    f32x4 acc[4][8];
    #pragma unroll
    for (int mt = 0; mt < 4; ++mt)
        #pragma unroll
        for (int nt = 0; nt < 8; ++nt) acc[mt][nt] = (f32x4){0.f, 0.f, 0.f, 0.f};

    for (int c = 0; c < 4; ++c) {
        short8v afr[4], bfr[8];
        #pragma unroll
        for (int mt = 0; mt < 4; ++mt) {
            int row = rbase + mt * 16 + r16;
            if (row > NN - 1) row = NN - 1;
            const float* p = h + (size_t)row * HD + c * 32 + g * 8;
            #pragma unroll
            for (int j = 0; j < 8; ++j) afr[mt][j] = (short)f2b(p[j]);
        }
        #pragma unroll
        for (int nt = 0; nt < 8; ++nt)
            bfr[nt] = *(const short8v*)(W12b + (size_t)(wn * 128 + nt * 16 + r16) * 128 + c * 32 + g * 8);
        #pragma unroll
        for (int mt = 0; mt < 4; ++mt)
            #pragma unroll
            for (int nt = 0; nt < 8; ++nt)
                acc[mt][nt] = MFMA16(afr[mt], bfr[nt], acc[mt][nt]);
    }
    #pragma unroll
    for (int mt = 0; mt < 4; ++mt)
        #pragma unroll
        for (int nt = 0; nt < 8; ++nt)
            #pragma unroll
            for (int r = 0; r < 4; ++r) {
                int row = rbase + mt * 16 + g * 4 + r;
                if (row < NN)
                    P12b[(size_t)row * 256 + wn * 128 + nt * 16 + r16] = f2b(acc[mt][nt][r]);
            }
}

// ---------------- edge phase (MFMA bf16, sorted edges, segment-aggregated sums) -------------
__global__ __launch_bounds__(256) void edge_mfma(
    const ushort_t* __restrict__ P12b, const float* __restrict__ coord,
    const int* __restrict__ ei, const int* __restrict__ perm,
    const float* __restrict__ We1, const float* __restrict__ be1,
    const ushort_t* __restrict__ We2b, const float* __restrict__ be2,
    const float* __restrict__ watt, const float* __restrict__ batt,
    const ushort_t* __restrict__ Wc1b, const float* __restrict__ bc1,
    const float* __restrict__ Wc2,
    float* __restrict__ mi, float* __restrict__ ssum)
{
    __shared__ ushort_t ybuf[128 * 128];
    __shared__ float cdp[128][3];
    __shared__ float wcols[128], be1s[128], be2s[128], bc1s[128], watts[128], wc2s[128];
    __shared__ float pq[2][128];
    __shared__ int ej0s[128];

    const int tid = threadIdx.x;
    const int ebase = blockIdx.x * 128;
    const int lane = tid & 63;
    const int wid = tid >> 6;
    const int wm = wid >> 1, wn = wid & 1;
    const int g = lane >> 4, r16 = lane & 15;
    const float batt0 = batt[0];

    // ---- early: per-pair index load + RANDOM P1 gather, parked in own ybuf slots ----
    const int e = tid >> 1, hf = tid & 1;
    const int eg = perm[ebase + e];
    const int n0 = ei[eg];
    const int n1 = ei[EE + eg];
    {
        const ushort_t* p1 = P12b + (size_t)n1 * 256 + hf * 64;
        #pragma unroll
        for (int q = 0; q < 8; ++q) {
            short8v t = *(const short8v*)(p1 + q * 8);
            int off = (e << 8) + ((hf * 128 + q * 16) ^ ((e & 15) << 4));
            *(short8v*)((char*)ybuf + off) = t;     // thread-private slot
        }
    }
    if (hf == 0) ej0s[e] = n0;
    // stage per-col consts (latency overlaps gathers)
    {
        int t = tid & 127;
        if (tid < 128) {
            wcols[t] = We1[t * 257 + 256];
            be1s[t] = be1[t];
            be2s[t] = be2[t];
        } else {
            bc1s[t] = bc1[t];
            watts[t] = watt[t];
            wc2s[t] = Wc2[t];
        }
    }
    // radial + coord-diff (both pair threads compute rr; even thread writes cdp)
    float rr;
    {
        float d0 = coord[n0 * 3 + 0] - coord[n1 * 3 + 0];
        float d1 = coord[n0 * 3 + 1] - coord[n1 * 3 + 1];
        float d2 = coord[n0 * 3 + 2] - coord[n1 * 3 + 2];
        rr = d0 * d0 + d1 * d1 + d2 * d2;
        if (hf == 0) { cdp[e][0] = d0; cdp[e][1] = d1; cdp[e][2] = d2; }
    }
    __syncthreads();

    // ---- phase A: y1 = relu(P1[e1] + P2[e0] + rad*wcol + be1) -> ybuf (in place) ----
    {
        short8v gb[8];
        const ushort_t* p2 = P12b + (size_t)n0 * 256 + 128 + hf * 64;
        #pragma unroll
        for (int q = 0; q < 8; ++q)
            gb[q] = *(const short8v*)(p2 + q * 8);
        const int colbase = hf * 64;
        #pragma unroll
        for (int q = 0; q < 8; ++q) {
            int off = (e << 8) + ((colbase * 2 + q * 16) ^ ((e & 15) << 4));
            short8v a = *(const short8v*)((const char*)ybuf + off);
            short8v ov;
            #pragma unroll
            for (int jj = 0; jj < 8; ++jj) {
                int col = colbase + q * 8 + jj;
                float v = b2f((ushort_t)a[jj]) + b2f((ushort_t)gb[q][jj]) + rr * wcols[col] + be1s[col];
                ov[jj] = (short)f2b(fmaxf(v, 0.f));
            }
            *(short8v*)((char*)ybuf + off) = ov;
        }
    }
    // preload layer-2 weights (latency hides under the barrier)
    short8v b2_[4][4];
    {
        const ushort_t* W2p = We2b + (size_t)(wn * 64 + r16) * 128 + g * 8;
        #pragma unroll
        for (int nt = 0; nt < 4; ++nt)
            #pragma unroll
            for (int c = 0; c < 4; ++c)
                b2_[nt][c] = *(const short8v*)(W2p + nt * 2048 + c * 32);
    }
    __syncthreads();

    // ---- layer 2: y1 @ We2^T ----
    f32x4 acc[4][4];
    #pragma unroll
    for (int mt = 0; mt < 4; ++mt)
        #pragma unroll
        for (int nt = 0; nt < 4; ++nt) acc[mt][nt] = (f32x4){0.f, 0.f, 0.f, 0.f};
    #pragma unroll
    for (int c = 0; c < 4; ++c) {
        short8v afr[4];
        #pragma unroll
        for (int mt = 0; mt < 4; ++mt) {
            int row = wm * 64 + mt * 16 + r16;
            afr[mt] = *(const short8v*)((const char*)ybuf + (row << 8) + ((c * 64 + g * 16) ^ (r16 << 4)));
        }
        #pragma unroll
        for (int mt = 0; mt < 4; ++mt)
            #pragma unroll
            for (int nt = 0; nt < 4; ++nt)
                acc[mt][nt] = MFMA16(afr[mt], b2_[nt][c], acc[mt][nt]);
    }

    // epilogue 2: mij = relu(+be2); att = sigmoid(mij.watt + batt); ef = mij*att -> ybuf
    {
        float p[4][4];
        #pragma unroll
        for (int mt = 0; mt < 4; ++mt)
            #pragma unroll
            for (int r = 0; r < 4; ++r) p[mt][r] = 0.f;
        #pragma unroll
        for (int mt = 0; mt < 4; ++mt)
            #pragma unroll
            for (int nt = 0; nt < 4; ++nt)
                #pragma unroll
                for (int r = 0; r < 4; ++r) {
                    int col = wn * 64 + nt * 16 + r16;
                    float v = fmaxf(acc[mt][nt][r] + be2s[col], 0.f);
                    acc[mt][nt][r] = v;
                    p[mt][r] += v * watts[col];
                }
        #pragma unroll
        for (int off = 1; off < 16; off <<= 1)
            #pragma unroll
            for (int mt = 0; mt < 4; ++mt)
                #pragma unroll
                for (int r = 0; r < 4; ++r) p[mt][r] += __shfl_xor(p[mt][r], off);
        if (r16 == 0) {
            #pragma unroll
            for (int mt = 0; mt < 4; ++mt)
                #pragma unroll
                for (int r = 0; r < 4; ++r)
                    pq[wn][wm * 64 + mt * 16 + g * 4 + r] = p[mt][r];
        }
        __syncthreads();
        float att[4][4];
        #pragma unroll
        for (int mt = 0; mt < 4; ++mt)
            #pragma unroll
            for (int r = 0; r < 4; ++r) {
                int row = wm * 64 + mt * 16 + g * 4 + r;
                att[mt][r] = sigf(pq[0][row] + pq[1][row] + batt0);
            }
        __syncthreads();   // layer-2 ybuf reads + pq reads done -> safe to overwrite ybuf
        #pragma unroll
        for (int mt = 0; mt < 4; ++mt)
            #pragma unroll
            for (int nt = 0; nt < 4; ++nt)
                #pragma unroll
                for (int r = 0; r < 4; ++r) {
                    int row = wm * 64 + mt * 16 + g * 4 + r;
                    int col = wn * 64 + nt * 16 + r16;
                    int off = (row << 8) + (((col << 1)) ^ ((row & 15) << 4));
                    *(ushort_t*)((char*)ybuf + off) = f2b(acc[mt][nt][r] * att[mt][r]);
                }
    }
    __syncthreads();   // ef visible to all

    // preload layer-3 weights (latency hides under the segment-sum below)
    short8v b3_[4][4];
    {
        const ushort_t* W3p = Wc1b + (size_t)(wn * 64 + r16) * 128 + g * 8;
        #pragma unroll
        for (int nt = 0; nt < 4; ++nt)
            #pragma unroll
            for (int c = 0; c < 4; ++c)
                b3_[nt][c] = *(const short8v*)(W3p + nt * 2048 + c * 32);
    }

    // ---- segment-sum ef over sorted e0 runs -> mi ----
    {
        const int cp = tid & 63;          // cols 2*cp, 2*cp+1
        const int qr = tid >> 6;          // row quarter
        const int r0 = qr * 32, r1 = r0 + 32;
        const int colbyte = cp * 4;
        float s0 = 0.f, s1 = 0.f;
        int cur = ej0s[r0];
        for (int r = r0; r < r1; ++r) {
            int node = ej0s[r];
            if (node != cur) {
                atomicAdd(&mi[(size_t)cur * HD + 2 * cp], s0);
                atomicAdd(&mi[(size_t)cur * HD + 2 * cp + 1], s1);
                s0 = 0.f; s1 = 0.f; cur = node;
            }
            int off = (r << 8) + (colbyte ^ ((r & 15) << 4));
            unsigned v = *(const unsigned*)((const char*)ybuf + off);
            s0 += b2f((ushort_t)(v & 0xFFFFu));
            s1 += b2f((ushort_t)(v >> 16));
        }
        atomicAdd(&mi[(size_t)cur * HD + 2 * cp], s0);
        atomicAdd(&mi[(size_t)cur * HD + 2 * cp + 1], s1);
    }

    // ---- layer 3: ef @ Wc1^T, dot Wc2 ----
    #pragma unroll
    for (int mt = 0; mt < 4; ++mt)
        #pragma unroll
        for (int nt = 0; nt < 4; ++nt) acc[mt][nt] = (f32x4){0.f, 0.f, 0.f, 0.f};
    #pragma unroll
    for (int c = 0; c < 4; ++c) {
        short8v afr[4];
        #pragma unroll
        for (int mt = 0; mt < 4; ++mt) {
            int row = wm * 64 + mt * 16 + r16;
            afr[mt] = *(const short8v*)((const char*)ybuf + (row << 8) + ((c * 64 + g * 16) ^ (r16 << 4)));
        }
        #pragma unroll
        for (int mt = 0; mt < 4; ++mt)
            #pragma unroll
            for (int nt = 0; nt < 4; ++nt)
                acc[mt][nt] = MFMA16(afr[mt], b3_[nt][c], acc[mt][nt]);
    }
    {
        float q[4][4];
        #pragma unroll
        for (int mt = 0; mt < 4; ++mt)
            #pragma unroll
            for (int r = 0; r < 4; ++r) q[mt][r] = 0.f;
        #pragma unroll
        for (int mt = 0; mt < 4; ++mt)
            #pragma unroll
            for (int nt = 0; nt < 4; ++nt)
                #pragma unroll
                for (int r = 0; r < 4; ++r) {
                    int col = wn * 64 + nt * 16 + r16;
                    float v = fmaxf(acc[mt][nt][r] + bc1s[col], 0.f);
                    q[mt][r] += v * wc2s[col];
                }
        #pragma unroll
        for (int off = 1; off < 16; off <<= 1)
            #pragma unroll
            for (int mt = 0; mt < 4; ++mt)
                #pragma unroll
                for (int r = 0; r < 4; ++r) q[mt][r] += __shfl_xor(q[mt][r], off);
        if (r16 == 0) {
            #pragma unroll
            for (int mt = 0; mt < 4; ++mt)
                #pragma unroll
                for (int r = 0; r < 4; ++r)
                    pq[wn][wm * 64 + mt * 16 + g * 4 + r] = q[mt][r];
        }
        __syncthreads();
        // coord segment sums: 48 lanes, 8 rows each
        if (tid < 48) {
            int c = tid % 3, seg = tid / 3;
            int r0 = seg * 8, r1 = r0 + 8;
            float sacc = 0.f; int cur = ej0s[r0];
            for (int r = r0; r < r1; ++r) {
                int node = ej0s[r];
                if (node != cur) {
                    atomicAdd(&ssum[cur * 3 + c], sacc);
                    sacc = 0.f; cur = node;
                }
                float tv = pq[0][r] + pq[1][r];
                float tr = cdp[r][c] * tv;
                tr = fminf(fmaxf(tr, -100.f), 100.f);
                sacc += tr;
            }
            atomicAdd(&ssum[cur * 3 + c], sacc);
        }
    }
}

// -- node MLP + LN + clip (split MFMA); fused in_proj (u,z) + coord update; no hn roundtrip --
__global__ __launch_bounds__(256) void node_mfma(
    const float* __restrict__ mi, const float* __restrict__ h,
    const ushort_t* __restrict__ Wn1hi, const ushort_t* __restrict__ Wn1lo,
    const float* __restrict__ bn1,
    const ushort_t* __restrict__ Wn2hi, const ushort_t* __restrict__ Wn2lo,
    const float* __restrict__ bn2,
    const float* __restrict__ lng, const float* __restrict__ lnb,
    const ushort_t* __restrict__ Wiphi, const ushort_t* __restrict__ Wiplo,
    ushort_t* __restrict__ ub, float* __restrict__ zs,
    const float* __restrict__ coord, const float* __restrict__ ssum,
    const int* __restrict__ histI, float* __restrict__ coordout)
{
    __shared__ ushort_t yhi[128 * 128];
    __shared__ ushort_t ylo[128 * 128];
    __shared__ float bn1s[128], bn2s[128], lngs[128], lnbs[128];

    const int tid = threadIdx.x;
    const int nbase = blockIdx.x * 128;
    const int lane = tid & 63;
    const int wid = tid >> 6;
    const int wm = wid >> 1, wn = wid & 1;
    const int g = lane >> 4, r16 = lane & 15;

    if (tid < 128) { bn1s[tid] = bn1[tid]; bn2s[tid] = bn2[tid]; lngs[tid] = lng[tid]; lnbs[tid] = lnb[tid]; }
    __syncthreads();

    // layer 1: [mi | h] @ Wn1^T, K=256, split A and B
    f32x4 acc[4][4];
    #pragma unroll
    for (int mt = 0; mt < 4; ++mt)
        #pragma unroll
        for (int nt = 0; nt < 4; ++nt) acc[mt][nt] = (f32x4){0.f, 0.f, 0.f, 0.f};
    for (int c = 0; c < 8; ++c) {
        short8v ahi[4], alo[4], bhi[4], blo[4];
        #pragma unroll
        for (int mt = 0; mt < 4; ++mt) {
            int row = nbase + wm * 64 + mt * 16 + r16;
            if (row > NN - 1) row = NN - 1;
            const float* src = (c < 4) ? (mi + (size_t)row * HD + c * 32 + g * 8)
                                       : (h + (size_t)row * HD + (c - 4) * 32 + g * 8);
            cvt8x2(src, ahi[mt], alo[mt]);
        }
        #pragma unroll
        for (int nt = 0; nt < 4; ++nt) {
            size_t wo = (size_t)(wn * 64 + nt * 16 + r16) * 256 + c * 32 + g * 8;
            bhi[nt] = *(const short8v*)(Wn1hi + wo);
            blo[nt] = *(const short8v*)(Wn1lo + wo);
        }
        #pragma unroll
        for (int mt = 0; mt < 4; ++mt)
            #pragma unroll
            for (int nt = 0; nt < 4; ++nt) {
                acc[mt][nt] = MFMA16(ahi[mt], bhi[nt], acc[mt][nt]);
                acc[mt][nt] = MFMA16(ahi[mt], blo[nt], acc[mt][nt]);
                acc[mt][nt] = MFMA16(alo[mt], bhi[nt], acc[mt][nt]);
            }
    }
    // relu(+bn1) -> hi/lo LDS pair
    #pragma unroll
    for (int mt = 0; mt < 4; ++mt)
        #pragma unroll
        for (int nt = 0; nt < 4; ++nt)
            #pragma unroll
            for (int r = 0; r < 4; ++r) {
                int row = wm * 64 + mt * 16 + g * 4 + r;
                int col = wn * 64 + nt * 16 + r16;
                int off = (row << 8) + (((col << 1)) ^ ((row & 15) << 4));
                float v = fmaxf(acc[mt][nt][r] + bn1s[col], 0.f);
                ushort_t hh, ll; splitf(v, hh, ll);
                *(ushort_t*)((char*)yhi + off) = hh;
                *(ushort_t*)((char*)ylo + off) = ll;
            }
    __syncthreads();

    // layer 2: y1 @ Wn2^T, split A and B
    #pragma unroll
    for (int mt = 0; mt < 4; ++mt)
        #pragma unroll
        for (int nt = 0; nt < 4; ++nt) acc[mt][nt] = (f32x4){0.f, 0.f, 0.f, 0.f};
    #pragma unroll
    for (int c = 0; c < 4; ++c) {
        short8v ahi[4], alo[4], bhi[4], blo[4];
        #pragma unroll
        for (int mt = 0; mt < 4; ++mt) {
            int row = wm * 64 + mt * 16 + r16;
            int off = (row << 8) + ((c * 64 + g * 16) ^ (r16 << 4));
            ahi[mt] = *(const short8v*)((const char*)yhi + off);
            alo[mt] = *(const short8v*)((const char*)ylo + off);
        }
        #pragma unroll
        for (int nt = 0; nt < 4; ++nt) {
            size_t wo = (size_t)(wn * 64 + nt * 16 + r16) * 128 + c * 32 + g * 8;
            bhi[nt] = *(const short8v*)(Wn2hi + wo);
            blo[nt] = *(const short8v*)(Wn2lo + wo);
        }
        #pragma unroll
        for (int mt = 0; mt < 4; ++mt)
            #pragma unroll
            for (int nt = 0; nt < 4; ++nt) {
                acc[mt][nt] = MFMA16(ahi[mt], bhi[nt], acc[mt][nt]);
                acc[mt][nt] = MFMA16(ahi[mt], blo[nt], acc[mt][nt]);
                acc[mt][nt] = MFMA16(alo[mt], bhi[nt], acc[mt][nt]);
            }
    }
    __syncthreads();   // all layer-2 reads done -> safe to overwrite
    #pragma unroll
    for (int mt = 0; mt < 4; ++mt)
        #pragma unroll
        for (int nt = 0; nt < 4; ++nt)
            #pragma unroll
            for (int r = 0; r < 4; ++r) {
                int row = wm * 64 + mt * 16 + g * 4 + r;
                int col = wn * 64 + nt * 16 + r16;
                int off = (row << 8) + (((col << 1)) ^ ((row & 15) << 4));
                float v = acc[mt][nt][r] + bn2s[col];
                ushort_t hh, ll; splitf(v, hh, ll);
                *(ushort_t*)((char*)yhi + off) = hh;
                *(ushort_t*)((char*)ylo + off) = ll;
            }
    __syncthreads();

    // layernorm + clip; write hn (hi/lo split) back IN PLACE (thread-private slots)
    {
        const int row = tid >> 1, hf = tid & 1;
        float s1 = 0.f, s2 = 0.f;
        float vals[64];
        #pragma unroll
        for (int q = 0; q < 8; ++q) {
            int c8 = hf * 8 + q;
            int off = (row << 8) + ((c8 * 16) ^ ((row & 15) << 4));
            short8v vh = *(const short8v*)((const char*)yhi + off);
            short8v vl = *(const short8v*)((const char*)ylo + off);
            #pragma unroll
            for (int j = 0; j < 8; ++j) {
                float v = b2f((ushort_t)vh[j]) + b2f((ushort_t)vl[j]);
                vals[q * 8 + j] = v;
                s1 += v; s2 += v * v;
            }
        }
        s1 += __shfl_xor(s1, 1);
        s2 += __shfl_xor(s2, 1);
        float mu = s1 * (1.f / HD);
        float var = s2 * (1.f / HD) - mu * mu;
        float rs = rsqrtf(fmaxf(var, 0.f) + 1e-5f);
        #pragma unroll
        for (int q = 0; q < 8; ++q) {
            int c8 = hf * 8 + q;
            short8v oh, ol;
            #pragma unroll
            for (int j = 0; j < 8; ++j) {
                int col = c8 * 8 + j;
                float v = (vals[q * 8 + j] - mu) * rs * lngs[col] + lnbs[col];
                v = fminf(fmaxf(v, -10.f), 10.f);
                ushort_t hh, ll; splitf(v, hh, ll);
                oh[j] = (short)hh; ol[j] = (short)ll;
            }
            int off = (row << 8) + ((c8 * 16) ^ ((row & 15) << 4));
            *(short8v*)((char*)yhi + off) = oh;
            *(short8v*)((char*)ylo + off) = ol;
        }
    }

    // fused coord update (independent; overlaps with barrier)
    {
        int base3 = nbase * 3;
        for (int k = tid; k < 384; k += 256) {
            int idx = base3 + k;
            if (idx < NN * 3) {
                int n = idx / 3;
                coordout[idx] = coord[idx] + ssum[idx] / fmaxf((float)histI[n], 1.f);
            }
        }
    }
    __syncthreads();   // hn (hi/lo) visible to all

    // ---- fused in_proj: xz = hn @ Wip^T (256 cols, 2 passes of 64 cols per wave) ----
    #pragma unroll
    for (int jh = 0; jh < 2; ++jh) {
        #pragma unroll
        for (int mt = 0; mt < 4; ++mt)
            #pragma unroll
            for (int nt = 0; nt < 4; ++nt) acc[mt][nt] = (f32x4){0.f, 0.f, 0.f, 0.f};
        #pragma unroll
        for (int c = 0; c < 4; ++c) {
            short8v ahi[4], alo[4], bhi[4], blo[4];
            #pragma unroll
            for (int mt = 0; mt < 4; ++mt) {
                int row = wm * 64 + mt * 16 + r16;
                int off = (row << 8) + ((c * 64 + g * 16) ^ (r16 << 4));
                ahi[mt] = *(const short8v*)((const char*)yhi + off);
                alo[mt] = *(const short8v*)((const char*)ylo + off);
            }
            #pragma unroll
            for (int nt = 0; nt < 4; ++nt) {
                int j = wn * 128 + jh * 64 + nt * 16 + r16;
                size_t wo = (size_t)j * 128 + c * 32 + g * 8;
                bhi[nt] = *(const short8v*)(Wiphi + wo);
                blo[nt] = *(const short8v*)(Wiplo + wo);
            }
            #pragma unroll
            for (int mt = 0; mt < 4; ++mt)
                #pragma unroll
                for (int nt = 0; nt < 4; ++nt) {
                    acc[mt][nt] = MFMA16(ahi[mt], bhi[nt], acc[mt][nt]);
                    acc[mt][nt] = MFMA16(ahi[mt], blo[nt], acc[mt][nt]);
                    acc[mt][nt] = MFMA16(alo[mt], bhi[nt], acc[mt][nt]);
                }
        }
        #pragma unroll
        for (int mt = 0; mt < 4; ++mt)
            #pragma unroll
            for (int nt = 0; nt < 4; ++nt)
                #pragma unroll
                for (int r = 0; r < 4; ++r) {
                    int row = nbase + wm * 64 + mt * 16 + g * 4 + r;
                    if (row >= NN) continue;
                    int j = wn * 128 + jh * 64 + nt * 16 + r16;
                    float v = acc[mt][nt][r];
                    if (j < HD) ub[(size_t)row * HD + j] = f2b(v);
                    else        zs[(size_t)row * HD + (j - HD)] = v * sigf(v);
                }
    }
}

// ---- fused conv+silu -> uc; B|C = uc@Wxp8^T; dt = softplus(uc@Wdt2^T+bdt)  (split MFMA) ----
__global__ __launch_bounds__(256) void convdt_mfma(
    const ushort_t* __restrict__ ub, const float* __restrict__ cw,
    const float* __restrict__ cb,
    const ushort_t* __restrict__ Wxp8hi, const ushort_t* __restrict__ Wxp8lo,
    const ushort_t* __restrict__ Wdt2hi, const ushort_t* __restrict__ Wdt2lo,
    const float* __restrict__ bdt,
    float* __restrict__ uc, float* __restrict__ Bm, float* __restrict__ Cm,
    float* __restrict__ dt)
{
    __shared__ ushort_t yhi[128 * 128];
    __shared__ ushort_t ylo[128 * 128];
    __shared__ float cws[128][4], cbs[128], bdts[128];

    const int tid = threadIdx.x;
    const int nbase = blockIdx.x * 128;
    const int lane = tid & 63;
    const int wid = tid >> 6;
    const int wm = wid >> 1, wn = wid & 1;
    const int g = lane >> 4, r16 = lane & 15;

    if (tid < 128) {
        cbs[tid] = cb[tid]; bdts[tid] = bdt[tid];
        #pragma unroll
        for (int k = 0; k < 4; ++k) cws[tid][k] = cw[tid * 4 + k];
    }
    __syncthreads();

    // phase 1: causal depthwise conv + silu -> uc (fp32 global) + hi/lo LDS pair
    for (int it = tid; it < 128 * 16; it += 256) {
        int r = it >> 4, cg = it & 15;
        int t = nbase + r;
        int colb = cg * 8;
        float a[8];
        #pragma unroll
        for (int j = 0; j < 8; ++j) a[j] = cbs[colb + j];
        #pragma unroll
        for (int k = 0; k < 4; ++k) {
            int tt = t - 3 + k;
            if (tt >= 0 && tt < NN) {
                short8v uv = *(const short8v*)(ub + (size_t)tt * HD + colb);
                #pragma unroll
                for (int j = 0; j < 8; ++j) a[j] = fmaf(b2f((ushort_t)uv[j]), cws[colb + j][k], a[j]);
            }
        }
        short8v oh, ol;
        f32x4 u0, u1;
        #pragma unroll
        for (int j = 0; j < 8; ++j) {
            float s = (t < NN) ? a[j] * sigf(a[j]) : 0.f;
            ushort_t hh, ll; splitf(s, hh, ll);
            oh[j] = (short)hh; ol[j] = (short)ll;
            if (j < 4) u0[j] = s; else u1[j - 4] = s;
        }
        int off = (r << 8) + ((cg * 16) ^ ((r & 15) << 4));
        *(short8v*)((char*)yhi + off) = oh;
        *(short8v*)((char*)ylo + off) = ol;
        if (t < NN) {
            *(f32x4*)(uc + (size_t)t * HD + colb) = u0;
            *(f32x4*)(uc + (size_t)t * HD + colb + 4) = u1;
        }
    }
    __syncthreads();

    // phase 2: B|C = uc @ Wxp[8:136]^T  (128 cols), split
    f32x4 acc[4][4];
    #pragma unroll
    for (int mt = 0; mt < 4; ++mt)
        #pragma unroll
        for (int nt = 0; nt < 4; ++nt) acc[mt][nt] = (f32x4){0.f, 0.f, 0.f, 0.f};
    #pragma unroll
    for (int c = 0; c < 4; ++c) {
        short8v ahi[4], alo[4], bhi[4], blo[4];
        #pragma unroll
        for (int mt = 0; mt < 4; ++mt) {
            int row = wm * 64 + mt * 16 + r16;
            int off = (row << 8) + ((c * 64 + g * 16) ^ (r16 << 4));
            ahi[mt] = *(const short8v*)((const char*)yhi + off);
            alo[mt] = *(const short8v*)((const char*)ylo + off);
        }
        #pragma unroll
        for (int nt = 0; nt < 4; ++nt) {
            size_t wo = (size_t)(wn * 64 + nt * 16 + r16) * 128 + c * 32 + g * 8;
            bhi[nt] = *(const short8v*)(Wxp8hi + wo);
            blo[nt] = *(const short8v*)(Wxp8lo + wo);
        }
        #pragma unroll
        for (int mt = 0; mt < 4; ++mt)
            #pragma unroll
            for (int nt = 0; nt < 4; ++nt) {
                acc[mt][nt] = MFMA16(ahi[mt], bhi[nt], acc[mt][nt]);
                acc[mt][nt] = MFMA16(ahi[mt], blo[nt], acc[mt][nt]);
                acc[mt][nt] = MFMA16(alo[mt], bhi[nt], acc[mt][nt]);
            }
    }
    #pragma unroll
    for (int mt = 0; mt < 4; ++mt)
        #pragma unroll
        for (int nt = 0; nt < 4; ++nt)
            #pragma unroll
            for (int r = 0; r < 4; ++r) {
                int row = nbase + wm * 64 + mt * 16 + g * 4 + r;
                if (row >= NN) continue;
                int j = wn * 64 + nt * 16 + r16;
                float v = acc[mt][nt][r];
                if (j < 64) Bm[(size_t)row * 64 + j] = v;
                else        Cm[(size_t)row * 64 + (j - 64)] = v;
            }

    // phase 3: dt = softplus(uc @ Wdt2^T + bdt), split
    #pragma unroll
    for (int mt = 0; mt < 4; ++mt)
        #pragma unroll
        for (int nt = 0; nt < 4; ++nt) acc[mt][nt] = (f32x4){0.f, 0.f, 0.f, 0.f};
    #pragma unroll
    for (int c = 0; c < 4; ++c) {
        short8v ahi[4], alo[4], bhi[4], blo[4];
        #pragma unroll
        for (int mt = 0; mt < 4; ++mt) {
            int row = wm * 64 + mt * 16 + r16;
            int off = (row << 8) + ((c * 64 + g * 16) ^ (r16 << 4));
            ahi[mt] = *(const short8v*)((const char*)yhi + off);
            alo[mt] = *(const short8v*)((const char*)ylo + off);
        }
        #pragma unroll
        for (int nt = 0; nt < 4; ++nt) {
            size_t wo = (size_t)(wn * 64 + nt * 16 + r16) * 128 + c * 32 + g * 8;
            bhi[nt] = *(const short8v*)(Wdt2hi + wo);
            blo[nt] = *(const short8v*)(Wdt2lo + wo);
        }
        #pragma unroll
        for (int mt = 0; mt < 4; ++mt)
            #pragma unroll
            for (int nt = 0; nt < 4; ++nt) {
                acc[mt][nt] = MFMA16(ahi[mt], bhi[nt], acc[mt][nt]);
                acc[mt][nt] = MFMA16(ahi[mt], blo[nt], acc[mt][nt]);
                acc[mt][nt] = MFMA16(alo[mt], bhi[nt], acc[mt][nt]);
            }
    }
    #pragma unroll
    for (int mt = 0; mt < 4; ++mt)
        #pragma unroll
        for (int nt = 0; nt < 4; ++nt)
            #pragma unroll
            for (int r = 0; r < 4; ++r) {
                int row = nbase + wm * 64 + mt * 16 + g * 4 + r;
                if (row >= NN) continue;
                int j = wn * 64 + nt * 16 + r16;
                float a = acc[mt][nt][r] + bdts[j];
                float sp = (a > 20.f) ? a : log1pf(__expf(a));
                dt[(size_t)row * HD + j] = sp;
            }
}

// ---------------- chunked SSM scan (2 d-states per thread throughout) ----------------
__global__ __launch_bounds__(256) void scan1_kernel(
    const float* __restrict__ dt, const float* __restrict__ uc,
    const float* __restrict__ Bm, const float* __restrict__ Alog,
    float* __restrict__ cP, float* __restrict__ cS)
{
    int g = blockIdx.x * 256 + threadIdx.x;   // NC*4096 threads
    int c = g >> 12;
    int r = g & 4095;
    int hh = r >> 5;
    int dp = (r & 31) * 2;
    float A0 = -__expf(Alog[hh * 64 + dp]);
    float A1 = -__expf(Alog[hh * 64 + dp + 1]);
    float P0 = 1.f, S0 = 0.f, P1 = 1.f, S1 = 0.f;
    int t0 = c * CS;
    for (int t = t0; t < t0 + CS; ++t) {
        float dtv = dt[t * HD + hh];
        float uv = uc[t * HD + hh];
        float du = dtv * uv;
        float2 bv = *(const float2*)(Bm + (size_t)t * 64 + dp);
        float a0 = __expf(dtv * A0);
        float a1 = __expf(dtv * A1);
        P0 *= a0; P1 *= a1;
        S0 = fmaf(a0, S0, du * bv.x);
        S1 = fmaf(a1, S1, du * bv.y);
    }
    *(float2*)(cP + (size_t)c * 8192 + hh * 64 + dp) = make_float2(P0, P1);
    *(float2*)(cS + (size_t)c * 8192 + hh * 64 + dp) = make_float2(S0, S1);
}

__global__ __launch_bounds__(256) void scan2_kernel(
    const float* __restrict__ cP, const float* __restrict__ cS, float* __restrict__ cI)
{
    int g = blockIdx.x * 256 + threadIdx.x;
    float S = 0.f;
    for (int c = 0; c < NC; ++c) {
        cI[c * 8192 + g] = S;
        S = fmaf(cP[c * 8192 + g], S, cS[c * 8192 + g]);
    }
}

// 2 d-states per thread: 32 lanes per (c,hh); 5-level shfl reduce
__global__ __launch_bounds__(256) void scan3_kernel(
    const float* __restrict__ dt, const float* __restrict__ uc,
    const float* __restrict__ Bm, const float* __restrict__ Cm,
    const float* __restrict__ Alog, const float* __restrict__ Dskip,
    const float* __restrict__ cI, float* __restrict__ y)
{
    int g = blockIdx.x * 256 + threadIdx.x;   // NC*4096 threads
    int c = g >> 12;
    int r = g & 4095;
    int hh = r >> 5;
    int dp = (r & 31) * 2;
    float A0 = -__expf(Alog[hh * 64 + dp]);
    float A1 = -__expf(Alog[hh * 64 + dp + 1]);
    float s0 = cI[c * 8192 + hh * 64 + dp];
    float s1 = cI[c * 8192 + hh * 64 + dp + 1];
    float Dh = Dskip[hh];
    int t0 = c * CS;
    const int lane31 = threadIdx.x & 31;
    for (int t = t0; t < t0 + CS; ++t) {
        float dtv = dt[t * HD + hh];
        float uv = uc[t * HD + hh];
        float du = dtv * uv;
        float2 bv = *(const float2*)(Bm + (size_t)t * 64 + dp);
        float2 cv = *(const float2*)(Cm + (size_t)t * 64 + dp);
        s0 = fmaf(__expf(dtv * A0), s0, du * bv.x);
        s1 = fmaf(__expf(dtv * A1), s1, du * bv.y);
        float yp = fmaf(s0, cv.x, s1 * cv.y);
        #pragma unroll
        for (int off = 1; off < 32; off <<= 1) yp += __shfl_xor(yp, off);
        if (lane31 == 0) y[t * HD + hh] = yp + Dh * uv;
    }
}

// ---------------- out_proj (split MFMA, ~fp32): (y*silu(z)) @ Wop^T ----------------
__global__ __launch_bounds__(256) void out_mfma(
    const float* __restrict__ y, const float* __restrict__ zs,
    const ushort_t* __restrict__ Wophi, const ushort_t* __restrict__ Woplo,
    float* __restrict__ outp)
{
    const int tid = threadIdx.x;
    const int lane = tid & 63;
    const int wid = tid >> 6;
    const int wm = wid >> 1, wn = wid & 1;
    const int g = lane >> 4, r16 = lane & 15;
    const int nbase = blockIdx.x * 128;

    f32x4 acc[4][4];
    #pragma unroll
    for (int mt = 0; mt < 4; ++mt)
        #pragma unroll
        for (int nt = 0; nt < 4; ++nt) acc[mt][nt] = (f32x4){0.f, 0.f, 0.f, 0.f};

    for (int c = 0; c < 4; ++c) {
        short8v ahi[4], alo[4], bhi[4], blo[4];
        #pragma unroll
        for (int mt = 0; mt < 4; ++mt) {
            int row = nbase + wm * 64 + mt * 16 + r16;
            if (row > NN - 1) row = NN - 1;
            const float* yp = y + (size_t)row * HD + c * 32 + g * 8;
            const float* zp = zs + (size_t)row * HD + c * 32 + g * 8;
            #pragma unroll
            for (int j = 0; j < 8; ++j) {
                float v = yp[j] * zp[j];
                ushort_t hh, ll; splitf(v, hh, ll);
                ahi[mt][j] = (short)hh; alo[mt][j] = (short)ll;
            }
        }
        #pragma unroll
        for (int nt = 0; nt < 4; ++nt) {
            size_t wo = (size_t)(wn * 64 + nt * 16 + r16) * 128 + c * 32 + g * 8;
            bhi[nt] = *(const short8v*)(Wophi + wo);
            blo[nt] = *(const short8v*)(Woplo + wo);
        }
        #pragma unroll
        for (int mt = 0; mt < 4; ++mt)
            #pragma unroll
            for (int nt = 0; nt < 4; ++nt) {
                acc[mt][nt] = MFMA16(ahi[mt], bhi[nt], acc[mt][nt]);
                acc[mt][nt] = MFMA16(ahi[mt], blo[nt], acc[mt][nt]);
                acc[mt][nt] = MFMA16(alo[mt], bhi[nt], acc[mt][nt]);
            }
    }
    #pragma unroll
    for (int mt = 0; mt < 4; ++mt)
        #pragma unroll
        for (int nt = 0; nt < 4; ++nt)
            #pragma unroll
            for (int r = 0; r < 4; ++r) {
                int row = nbase + wm * 64 + mt * 16 + g * 4 + r;
                if (row < NN)
                    outp[(size_t)row * HD + wn * 64 + nt * 16 + r16] = acc[mt][nt][r];
            }
}

extern "C" void kernel_launch(void* const* d_in, const int* in_sizes, int n_in,
                              void* d_out, int out_size, void* d_ws, size_t ws_size,
                              hipStream_t stream)
{
    const float* h     = (const float*)d_in[0];
    const float* coord = (const float*)d_in[1];
    const int*   ei    = (const int*)d_in[2];
    const float* We1   = (const float*)d_in[3];
    const float* be1   = (const float*)d_in[4];
    const float* We2   = (const float*)d_in[5];
    const float* be2   = (const float*)d_in[6];
    const float* watt  = (const float*)d_in[7];
    const float* batt  = (const float*)d_in[8];
    const float* Wn1   = (const float*)d_in[9];
    const float* bn1   = (const float*)d_in[10];
    const float* Wn2   = (const float*)d_in[11];
    const float* bn2   = (const float*)d_in[12];
    const float* Wc1   = (const float*)d_in[13];
    const float* bc1   = (const float*)d_in[14];
    const float* Wc2   = (const float*)d_in[15];
    const float* lng   = (const float*)d_in[16];
    const float* lnb   = (const float*)d_in[17];
    const float* Wip   = (const float*)d_in[18];
    const float* convw = (const float*)d_in[19];
    const float* convb = (const float*)d_in[20];
    const float* Wxp   = (const float*)d_in[21];
    const float* Wdt   = (const float*)d_in[22];
    const float* bdt   = (const float*)d_in[23];
    const float* Alog  = (const float*)d_in[24];
    const float* Dskip = (const float*)d_in[25];
    const float* Wop   = (const float*)d_in[26];

    float* ws   = (float*)d_ws;
    float* mi   = ws;                                  // NN*HD f32 (zeroed; reused as y after node)
    float* ssum = mi   + (size_t)NN * HD;              // NN*3  f32 (zeroed)
    int*   histI  = (int*)(ssum + (size_t)NN * 3);     // NN (zeroed)
    int*   cursor = histI + NN;                        // NN (zeroed)
    int*   baseI  = cursor + NN;                       // NN
    int*   perm   = baseI + NN;                        // EE
    float* zsb  = (float*)(perm + EE);                 // NN*HD
    float* ucb  = zsb  + (size_t)NN * HD;              // NN*HD
    float* dtb  = ucb  + (size_t)NN * HD;              // NN*HD
    float* Bm   = dtb  + (size_t)NN * HD;              // NN*64
    float* Cm   = Bm   + (size_t)NN * 64;              // NN*64
    float* cP   = Cm   + (size_t)NN * 64;              // NC*8192
    float* cSb  = cP   + (size_t)NC * 8192;
    float* cIb  = cSb  + (size_t)NC * 8192;
    ushort_t* ub    = (ushort_t*)(cIb + (size_t)NC * 8192);  // NN*HD bf16
    ushort_t* W12bp = ub + (size_t)NN * HD;            // 256*128
    ushort_t* We2bp = W12bp + 256 * 128;
    ushort_t* Wc1bp = We2bp + 128 * 128;
    ushort_t* Wn1hi = Wc1bp + 128 * 128;               // 128*256 pair
    ushort_t* Wn1lo = Wn1hi + 128 * 256;
    ushort_t* Wn2hi = Wn1lo + 128 * 256;               // 128*128 pair
    ushort_t* Wn2lo = Wn2hi + 128 * 128;
    ushort_t* Wiphi = Wn2lo + 128 * 128;               // 256*128 pair
    ushort_t* Wiplo = Wiphi + 256 * 128;
    ushort_t* Wxp8hi = Wiplo + 256 * 128;              // 128*128 pairs
    ushort_t* Wxp8lo = Wxp8hi + 128 * 128;
    ushort_t* Wdt2hi = Wxp8lo + 128 * 128;
    ushort_t* Wdt2lo = Wdt2hi + 128 * 128;
    ushort_t* Wophi  = Wdt2lo + 128 * 128;
    ushort_t* Woplo  = Wophi + 128 * 128;
    // P12b (NN*256 bf16 = 10.24MB) aliases cP+cS: written by p12, dead after edge.
    ushort_t* P12bp = (ushort_t*)cP;
    // y aliases mi: mi consumed by node_mfma, re-zeroed each launch by the memset.
    float* yb = mi;

    float* outp     = (float*)d_out;
    float* coordout = outp + (size_t)NN * HD;

    // zero mi, ssum, histI, cursor
    hipMemsetAsync(ws, 0, (size_t)NN * 133 * 4, stream);

    prep_hist_kernel<<<(EE + 255) / 256, 256, 0, stream>>>(ei, histI,
                                         We1, We2, Wc1, Wn1, Wn2, Wip, Wxp, Wdt, Wop,
                                         W12bp, We2bp, Wc1bp,
                                         Wn1hi, Wn1lo, Wn2hi, Wn2lo, Wiphi, Wiplo,
                                         Wxp8hi, Wxp8lo, Wdt2hi, Wdt2lo, Wophi, Woplo);
    prefix_kernel<<<1, 1024, 0, stream>>>(histI, baseI);
    scatter_kernel<<<(EE + 255) / 256, 256, 0, stream>>>(ei, baseI, cursor, perm);
    p12_kernel<<<(NN + 127) / 128, 256, 0, stream>>>(h, W12bp, P12bp);
    edge_mfma<<<EE / 128, 256, 0, stream>>>(P12bp, coord, ei, perm, We1, be1,
                                            We2bp, be2, watt, batt, Wc1bp, bc1, Wc2,
                                            mi, ssum);
    node_mfma<<<(NN + 127) / 128, 256, 0, stream>>>(mi, h, Wn1hi, Wn1lo, bn1,
                                                    Wn2hi, Wn2lo, bn2, lng, lnb,
                                                    Wiphi, Wiplo, ub, zsb,
                                                    coord, ssum, histI, coordout);
    convdt_mfma<<<(NN + 127) / 128, 256, 0, stream>>>(ub, convw, convb,
                                                      Wxp8hi, Wxp8lo, Wdt2hi, Wdt2lo,
                                                      bdt, ucb, Bm, Cm, dtb);
    scan1_kernel<<<NC * 4096 / 256, 256, 0, stream>>>(dtb, ucb, Bm, Alog, cP, cSb);
    scan2_kernel<<<8192 / 256, 256, 0, stream>>>(cP, cSb, cIb);
    scan3_kernel<<<NC * 4096 / 256, 256, 0, stream>>>(dtb, ucb, Bm, Cm, Alog, Dskip, cIb, yb);
    out_mfma<<<(NN + 127) / 128, 256, 0, stream>>>(yb, zsb, Wophi, Woplo, outp);
}